// Round 1
// baseline (963.752 us; speedup 1.0000x reference)
//
#include <hip/hip_runtime.h>
#include <hip/hip_bf16.h>

#define H 768
#define NTOT 192
#define A4W 3072
#define GW 2304

typedef __attribute__((ext_vector_type(4))) float f32x4;
typedef __attribute__((ext_vector_type(8))) unsigned short u16x8;
typedef __attribute__((ext_vector_type(4))) unsigned short u16x4;
typedef __attribute__((ext_vector_type(8))) __bf16 bf16x8v;

static __device__ __forceinline__ unsigned short f2bf(float f) {
  __hip_bfloat16 b = __float2bfloat16(f);
  return __builtin_bit_cast(unsigned short, b);
}
static __device__ __forceinline__ float bf2f(unsigned short u) {
  return __bfloat162float(__builtin_bit_cast(__hip_bfloat16, u));
}
static __device__ __forceinline__ f32x4 MFMA(u16x8 a, u16x8 b, f32x4 c) {
  return __builtin_amdgcn_mfma_f32_16x16x32_bf16(
      __builtin_bit_cast(bf16x8v, a), __builtin_bit_cast(bf16x8v, b), c, 0, 0, 0);
}
static __device__ __forceinline__ u16x8 ld8(const unsigned short* p) {
  return *(const u16x8*)p;
}

// ---------------- elementwise / setup kernels ----------------

__global__ void k_init_h(const float* __restrict__ asp, const float* __restrict__ qry,
                         float* __restrict__ h, unsigned short* __restrict__ hhi,
                         unsigned short* __restrict__ hlo) {
  int e = blockIdx.x * 256 + threadIdx.x;  // 147456
  float v = (e < 64 * H) ? asp[e] : qry[e - 64 * H];
  h[e] = v;
  unsigned short hi = f2bf(v);
  hhi[e] = hi;
  hlo[e] = f2bf(v - bf2f(hi));
}

__global__ void k_cvt(const float* __restrict__ in, unsigned short* __restrict__ out, int n) {
  int e = blockIdx.x * 256 + threadIdx.x;
  if (e < n) out[e] = f2bf(in[e]);
}

__global__ void k_cvt_hilo(const float* __restrict__ in, unsigned short* __restrict__ hi,
                           unsigned short* __restrict__ lo, int n) {
  int e = blockIdx.x * 256 + threadIdx.x;
  if (e < n) {
    float v = in[e];
    unsigned short h = f2bf(v);
    hi[e] = h;
    lo[e] = f2bf(v - bf2f(h));
  }
}

// W1cat rows: [0,768)=W1s[:, :H] ; [768,1536)=W1s[:, H:] ; [1536,2304)=W1d[:, :H] ; [2304,3072)=W1d[:, H:]
__global__ void k_w1cat(const float* __restrict__ W1s, const float* __restrict__ W1d,
                        const float* __restrict__ b1s, const float* __restrict__ b1d,
                        unsigned short* __restrict__ W1cat, float* __restrict__ b1cat) {
  int e = blockIdx.x * 256 + threadIdx.x;  // 3072*768
  int row = e / H, k = e - row * H;
  int part = row / H;      // 0..3
  int o = row - part * H;
  const float* W = (part < 2) ? W1s : W1d;
  W1cat[e] = f2bf(W[(size_t)o * (2 * H) + (part & 1) * H + k]);
  if (e < A4W) {
    int pp = e / H, oo = e - pp * H;
    b1cat[e] = (pp == 0) ? b1s[oo] : (pp == 2) ? b1d[oo] : 0.0f;
  }
}

// ---------------- RsW precompute: RsWt[(set,r,d)][k] = sum_e Rs_set[r][k][e] * Wm1[d][e] (bf16) ----
__global__ __launch_bounds__(256) void k_rsw(const float* __restrict__ Rs,
                                             const float* __restrict__ Rd,
                                             const unsigned short* __restrict__ Wm1bf,
                                             unsigned short* __restrict__ RsWt) {
  __shared__ unsigned short Ast[64][40];
  const int z = blockIdx.z, set = z >> 4, r = z & 15;
  const float* A = (set ? Rd : Rs) + (size_t)r * H * H;  // [k][e]
  const int m0 = blockIdx.y * 64;  // k tile
  const int n0 = blockIdx.x * 64;  // d tile
  const int tid = threadIdx.x;
  const int w = tid >> 6, l = tid & 63, g = l >> 4, ln = l & 15;
  const int sm = tid >> 2;
  const int sk = (tid & 3) * 8;
  const float* Ap = A + (size_t)(m0 + sm) * H + sk;
  f32x4 acc[4];
#pragma unroll
  for (int nt = 0; nt < 4; ++nt) acc[nt] = (f32x4){0.f, 0.f, 0.f, 0.f};
  for (int kb = 0; kb < H; kb += 32) {
    float4 a0 = *(const float4*)(Ap + kb);
    float4 a1 = *(const float4*)(Ap + kb + 4);
    __syncthreads();
    unsigned short hv[8];
    hv[0] = f2bf(a0.x); hv[1] = f2bf(a0.y); hv[2] = f2bf(a0.z); hv[3] = f2bf(a0.w);
    hv[4] = f2bf(a1.x); hv[5] = f2bf(a1.y); hv[6] = f2bf(a1.z); hv[7] = f2bf(a1.w);
    *(u16x4*)&Ast[sm][sk] = *(u16x4*)&hv[0];
    *(u16x4*)&Ast[sm][sk + 4] = *(u16x4*)&hv[4];
    __syncthreads();
    u16x8 af = ld8(&Ast[w * 16 + ln][g * 8]);
#pragma unroll
    for (int nt = 0; nt < 4; ++nt) {
      u16x8 bf = ld8(Wm1bf + (size_t)(n0 + nt * 16 + ln) * H + kb + g * 8);
      acc[nt] = MFMA(af, bf, acc[nt]);
    }
  }
#pragma unroll
  for (int nt = 0; nt < 4; ++nt) {
    const int d = n0 + nt * 16 + ln;
    const size_t outrow = (size_t)set * 12288 + (size_t)r * H + d;
#pragma unroll
    for (int pp = 0; pp < 4; ++pp) {
      const int k = m0 + w * 16 + g * 4 + pp;
      RsWt[outrow * H + k] = f2bf(acc[nt][pp]);
    }
  }
}

// ---------------- generic B-transposed MFMA GEMM, M=192, K=768 -------------
// C[row][col] = sum_k A[row][k]*B[col][k] + bias[col].  HILO: A=Ahi+Alo, B=Bhi+Blo.
template <int HILO, int WHILO>
__global__ __launch_bounds__(256) void k_bt(
    const unsigned short* __restrict__ Ahi, const unsigned short* __restrict__ Alo,
    const unsigned short* __restrict__ Bhi, const unsigned short* __restrict__ Blo,
    const float* __restrict__ bias, float* __restrict__ C,
    unsigned short* __restrict__ Chi, unsigned short* __restrict__ Clo, int N) {
  const int tid = threadIdx.x;
  const int w = tid >> 6, l = tid & 63, g = l >> 4, ln = l & 15;
  const int m0 = blockIdx.y * 64 + w * 16;
  const int n0 = blockIdx.x * 64;
  const unsigned short* aph = Ahi + (size_t)(m0 + ln) * H + g * 8;
  const unsigned short* apl = HILO ? (Alo + (size_t)(m0 + ln) * H + g * 8) : aph;
  const unsigned short* bph[4];
  const unsigned short* bpl[4];
#pragma unroll
  for (int nt = 0; nt < 4; ++nt) {
    bph[nt] = Bhi + (size_t)(n0 + nt * 16 + ln) * H + g * 8;
    bpl[nt] = HILO ? (Blo + (size_t)(n0 + nt * 16 + ln) * H + g * 8) : bph[nt];
  }
  f32x4 acc[4];
#pragma unroll
  for (int nt = 0; nt < 4; ++nt) acc[nt] = (f32x4){0.f, 0.f, 0.f, 0.f};

  u16x8 ah[2], al[2], bh[2][4], bl[2][4];
  ah[0] = ld8(aph);
  if (HILO) al[0] = ld8(apl);
#pragma unroll
  for (int nt = 0; nt < 4; ++nt) {
    bh[0][nt] = ld8(bph[nt]);
    if (HILO) bl[0][nt] = ld8(bpl[nt]);
  }
#pragma unroll
  for (int t = 0; t < 24; ++t) {
    const int cur = t & 1, nxt = cur ^ 1;
    if (t < 23) {
      const int ko = (t + 1) * 32;
      ah[nxt] = ld8(aph + ko);
      if (HILO) al[nxt] = ld8(apl + ko);
#pragma unroll
      for (int nt = 0; nt < 4; ++nt) {
        bh[nxt][nt] = ld8(bph[nt] + ko);
        if (HILO) bl[nxt][nt] = ld8(bpl[nt] + ko);
      }
    }
#pragma unroll
    for (int nt = 0; nt < 4; ++nt) {
      acc[nt] = MFMA(ah[cur], bh[cur][nt], acc[nt]);
      if (HILO) {
        acc[nt] = MFMA(ah[cur], bl[cur][nt], acc[nt]);
        acc[nt] = MFMA(al[cur], bh[cur][nt], acc[nt]);
      }
    }
  }
#pragma unroll
  for (int nt = 0; nt < 4; ++nt) {
    const int col = n0 + nt * 16 + ln;
    const float bv = bias[col];
#pragma unroll
    for (int pp = 0; pp < 4; ++pp) {
      const int row = m0 + g * 4 + pp;
      const float val = acc[nt][pp] + bv;
      C[(size_t)row * N + col] = val;
      if (WHILO) {
        unsigned short hi = f2bf(val);
        Chi[(size_t)row * N + col] = hi;
        Clo[(size_t)row * N + col] = f2bf(val - bf2f(hi));
      }
    }
  }
}

// ---------------- tw = h @ RsWt^T, scattered into twB[j][d][set*16+r] (bf16) ----
__global__ __launch_bounds__(256) void k_twb(const unsigned short* __restrict__ hbf,
                                             const unsigned short* __restrict__ RsWt,
                                             unsigned short* __restrict__ twB) {
  const int tid = threadIdx.x;
  const int w = tid >> 6, l = tid & 63, g = l >> 4, ln = l & 15;
  const int n0 = blockIdx.x * 64;  // 0..24575
  const unsigned short* ap[3];
#pragma unroll
  for (int jt = 0; jt < 3; ++jt) ap[jt] = hbf + (size_t)(w * 48 + jt * 16 + ln) * H + g * 8;
  const unsigned short* bp[4];
#pragma unroll
  for (int nt = 0; nt < 4; ++nt) bp[nt] = RsWt + (size_t)(n0 + nt * 16 + ln) * H + g * 8;

  f32x4 acc[3][4];
#pragma unroll
  for (int jt = 0; jt < 3; ++jt)
#pragma unroll
    for (int nt = 0; nt < 4; ++nt) acc[jt][nt] = (f32x4){0.f, 0.f, 0.f, 0.f};

  u16x8 a[2][3], b[2][4];
#pragma unroll
  for (int jt = 0; jt < 3; ++jt) a[0][jt] = ld8(ap[jt]);
#pragma unroll
  for (int nt = 0; nt < 4; ++nt) b[0][nt] = ld8(bp[nt]);
#pragma unroll
  for (int t = 0; t < 24; ++t) {
    const int cur = t & 1, nxt = cur ^ 1;
    if (t < 23) {
      const int ko = (t + 1) * 32;
#pragma unroll
      for (int jt = 0; jt < 3; ++jt) a[nxt][jt] = ld8(ap[jt] + ko);
#pragma unroll
      for (int nt = 0; nt < 4; ++nt) b[nxt][nt] = ld8(bp[nt] + ko);
    }
#pragma unroll
    for (int jt = 0; jt < 3; ++jt)
#pragma unroll
      for (int nt = 0; nt < 4; ++nt) acc[jt][nt] = MFMA(a[cur][jt], b[cur][nt], acc[jt][nt]);
  }
#pragma unroll
  for (int nt = 0; nt < 4; ++nt) {
    const int c = n0 + nt * 16 + ln;
    const int set = c / 12288;
    const int rr = (c / H) & 15;
    const int d = c % H;
#pragma unroll
    for (int jt = 0; jt < 3; ++jt)
#pragma unroll
      for (int pp = 0; pp < 4; ++pp) {
        const int j = w * 48 + jt * 16 + g * 4 + pp;
        twB[((size_t)j * H + d) * 32 + set * 16 + rr] = f2bf(acc[jt][nt][pp]);
      }
  }
}

// ---------------- pair logits + softmax -> swA[j][i][32] (bf16) -------------
static __device__ __forceinline__ void stage8(const float4 a0, const float4 a1,
                                              const float4 b0, const float4 b1,
                                              unsigned short* dst) {
  unsigned short hv[8];
  hv[0] = f2bf(fmaxf(a0.x + b0.x, 0.f));
  hv[1] = f2bf(fmaxf(a0.y + b0.y, 0.f));
  hv[2] = f2bf(fmaxf(a0.z + b0.z, 0.f));
  hv[3] = f2bf(fmaxf(a0.w + b0.w, 0.f));
  hv[4] = f2bf(fmaxf(a1.x + b1.x, 0.f));
  hv[5] = f2bf(fmaxf(a1.y + b1.y, 0.f));
  hv[6] = f2bf(fmaxf(a1.z + b1.z, 0.f));
  hv[7] = f2bf(fmaxf(a1.w + b1.w, 0.f));
  *(u16x4*)dst = *(u16x4*)&hv[0];
  *(u16x4*)(dst + 4) = *(u16x4*)&hv[4];
}

__global__ __launch_bounds__(256) void k_pairlog(
    const float* __restrict__ A4, const unsigned short* __restrict__ W2sbf,
    const unsigned short* __restrict__ W2dbf, const float* __restrict__ b2s,
    const float* __restrict__ b2d, unsigned short* __restrict__ swA) {
  __shared__ float Asr[H], Adr[H];
  __shared__ unsigned short hs[64][40], hd[64][40];
  const int i = blockIdx.x, jb = blockIdx.y;
  const int tid = threadIdx.x;
  const int w = tid >> 6, l = tid & 63, g = l >> 4, ln = l & 15;
  for (int e = tid; e < H; e += 256) {
    Asr[e] = A4[(size_t)i * A4W + e];           // A_s (b1s folded)
    Adr[e] = A4[(size_t)i * A4W + 1536 + e];    // A_d (b1d folded)
  }
  __syncthreads();
  const int sj = tid >> 2;
  const int sk = (tid & 3) * 8;
  const float* BsP = A4 + (size_t)(jb * 64 + sj) * A4W + 768 + sk;
  const float* BdP = A4 + (size_t)(jb * 64 + sj) * A4W + 2304 + sk;
  f32x4 accs = (f32x4){0.f, 0.f, 0.f, 0.f}, accd = (f32x4){0.f, 0.f, 0.f, 0.f};
  for (int kb = 0; kb < H; kb += 32) {
    float4 gb0 = *(const float4*)(BsP + kb);
    float4 gb1 = *(const float4*)(BsP + kb + 4);
    float4 gd0 = *(const float4*)(BdP + kb);
    float4 gd1 = *(const float4*)(BdP + kb + 4);
    float4 la0 = *(const float4*)(Asr + kb + sk);
    float4 la1 = *(const float4*)(Asr + kb + sk + 4);
    float4 ld0 = *(const float4*)(Adr + kb + sk);
    float4 ld1 = *(const float4*)(Adr + kb + sk + 4);
    __syncthreads();
    stage8(la0, la1, gb0, gb1, &hs[sj][sk]);
    stage8(ld0, ld1, gd0, gd1, &hd[sj][sk]);
    __syncthreads();
    u16x8 afs = ld8(&hs[w * 16 + ln][g * 8]);
    u16x8 bfs = ld8(W2sbf + (size_t)ln * H + kb + g * 8);
    accs = MFMA(afs, bfs, accs);
    u16x8 afd = ld8(&hd[w * 16 + ln][g * 8]);
    u16x8 bfd = ld8(W2dbf + (size_t)ln * H + kb + g * 8);
    accd = MFMA(afd, bfd, accd);
  }
  const float b2sv = b2s[ln], b2dv = b2d[ln];
#pragma unroll
  for (int pp = 0; pp < 4; ++pp) {
    const int j = jb * 64 + w * 16 + g * 4 + pp;
    {
      float v = accs[pp] + b2sv;
      float m = v;
      m = fmaxf(m, __shfl_xor(m, 1));
      m = fmaxf(m, __shfl_xor(m, 2));
      m = fmaxf(m, __shfl_xor(m, 4));
      m = fmaxf(m, __shfl_xor(m, 8));
      float e = __expf(v - m);
      float s = e;
      s += __shfl_xor(s, 1); s += __shfl_xor(s, 2); s += __shfl_xor(s, 4); s += __shfl_xor(s, 8);
      swA[(size_t)j * 6144 + (size_t)i * 32 + ln] = f2bf(e / s);
    }
    {
      float v = accd[pp] + b2dv;
      float m = v;
      m = fmaxf(m, __shfl_xor(m, 1));
      m = fmaxf(m, __shfl_xor(m, 2));
      m = fmaxf(m, __shfl_xor(m, 4));
      m = fmaxf(m, __shfl_xor(m, 8));
      float e = __expf(v - m);
      float s = e;
      s += __shfl_xor(s, 1); s += __shfl_xor(s, 2); s += __shfl_xor(s, 4); s += __shfl_xor(s, 8);
      swA[(size_t)j * 6144 + (size_t)i * 32 + 16 + ln] = f2bf(e / s);
    }
  }
}

// ---------------- per-pair weighted message + relu + sum_j -> v_part --------
__global__ __launch_bounds__(256) void k_pairmsg(const unsigned short* __restrict__ swA,
                                                 const unsigned short* __restrict__ twB,
                                                 const float* __restrict__ bm1,
                                                 float* __restrict__ vpart) {
  const int dt = blockIdx.x, it = blockIdx.y, js = blockIdx.z;
  const int tid = threadIdx.x;
  const int w = tid >> 6, l = tid & 63, g = l >> 4, ln = l & 15;
  const int i0 = it * 64 + w * 16;
  const int d0 = dt * 64;
  float bm1v[4];
#pragma unroll
  for (int nt = 0; nt < 4; ++nt) bm1v[nt] = bm1[d0 + nt * 16 + ln];
  f32x4 vacc[4];
#pragma unroll
  for (int nt = 0; nt < 4; ++nt) vacc[nt] = (f32x4){0.f, 0.f, 0.f, 0.f};
  const unsigned short* ap = swA + (size_t)(i0 + ln) * 32 + g * 8 + (size_t)js * 24 * 6144;
  const unsigned short* bp[4];
#pragma unroll
  for (int nt = 0; nt < 4; ++nt)
    bp[nt] = twB + (size_t)(d0 + nt * 16 + ln) * 32 + g * 8 + (size_t)js * 24 * 24576;
  const f32x4 z4 = (f32x4){0.f, 0.f, 0.f, 0.f};
#pragma unroll 4
  for (int jj = 0; jj < 24; ++jj) {
    u16x8 a = ld8(ap + (size_t)jj * 6144);
#pragma unroll
    for (int nt = 0; nt < 4; ++nt) {
      u16x8 b = ld8(bp[nt] + (size_t)jj * 24576);
      f32x4 mf = MFMA(a, b, z4);
#pragma unroll
      for (int pp = 0; pp < 4; ++pp) vacc[nt][pp] += fmaxf(mf[pp] + bm1v[nt], 0.f);
    }
  }
#pragma unroll
  for (int nt = 0; nt < 4; ++nt)
#pragma unroll
    for (int pp = 0; pp < 4; ++pp) {
      const int row = i0 + g * 4 + pp;
      vpart[(size_t)js * 147456 + (size_t)row * H + d0 + nt * 16 + ln] = vacc[nt][pp];
    }
}

__global__ void k_vred(const float* __restrict__ vpart, unsigned short* __restrict__ vhi,
                       unsigned short* __restrict__ vlo) {
  int e = blockIdx.x * 256 + threadIdx.x;  // 147456
  float s = 0.f;
#pragma unroll
  for (int q = 0; q < 8; ++q) s += vpart[(size_t)q * 147456 + e];
  s *= (1.0f / 192.0f);
  unsigned short hi = f2bf(s);
  vhi[e] = hi;
  vlo[e] = f2bf(s - bf2f(hi));
}

__global__ void k_gru(const float* __restrict__ gx, const float* __restrict__ gh,
                      float* __restrict__ h, unsigned short* __restrict__ hhi,
                      unsigned short* __restrict__ hlo, float* __restrict__ out, int last) {
  int e = blockIdx.x * 256 + threadIdx.x;  // 147456
  int i = e / H, k = e - i * H;
  size_t base = (size_t)i * GW;
  float rr = gx[base + k] + gh[base + k];
  float zz = gx[base + H + k] + gh[base + H + k];
  float r = 1.f / (1.f + __expf(-rr));
  float z = 1.f / (1.f + __expf(-zz));
  float n = tanhf(gx[base + 2 * H + k] + r * gh[base + 2 * H + k]);
  float hv = (1.f - z) * n + z * h[e];
  h[e] = hv;
  unsigned short hi = f2bf(hv);
  hhi[e] = hi;
  hlo[e] = f2bf(hv - bf2f(hi));
  if (last && i >= 64) out[(size_t)(i - 64) * H + k] = hv;
}

// ---------------- launch ----------------------------------------------------

extern "C" void kernel_launch(void* const* d_in, const int* in_sizes, int n_in,
                              void* d_out, int out_size, void* d_ws, size_t ws_size,
                              hipStream_t stream) {
  const float* asp = (const float*)d_in[0];
  const float* qry = (const float*)d_in[1];
  const float* W1s = (const float*)d_in[3];
  const float* b1s = (const float*)d_in[4];
  const float* W2s = (const float*)d_in[5];
  const float* b2s = (const float*)d_in[6];
  const float* W1d = (const float*)d_in[7];
  const float* b1d = (const float*)d_in[8];
  const float* W2d = (const float*)d_in[9];
  const float* b2d = (const float*)d_in[10];
  const float* Rs  = (const float*)d_in[11];
  const float* Rd  = (const float*)d_in[12];
  const float* Wm1 = (const float*)d_in[13];
  const float* bm1 = (const float*)d_in[14];
  const float* Wm2 = (const float*)d_in[15];
  const float* bm2 = (const float*)d_in[16];
  const float* Wih = (const float*)d_in[17];
  const float* Whh = (const float*)d_in[18];
  const float* bih = (const float*)d_in[19];
  const float* bhh = (const float*)d_in[20];
  float* out = (float*)d_out;

  char* p = (char*)d_ws;
  auto take = [&](size_t bytes) {
    char* q = p;
    p += (bytes + 255) & ~(size_t)255;
    return q;
  };
  float* h            = (float*)take((size_t)NTOT * H * 4);
  unsigned short* hhi = (unsigned short*)take((size_t)NTOT * H * 2);
  unsigned short* hlo = (unsigned short*)take((size_t)NTOT * H * 2);
  float* A4           = (float*)take((size_t)NTOT * A4W * 4);
  float* ghb          = (float*)take((size_t)NTOT * GW * 4);
  float* gxb          = (float*)take((size_t)NTOT * GW * 4);
  float* xb           = (float*)take((size_t)NTOT * H * 4);
  unsigned short* xhi = (unsigned short*)take((size_t)NTOT * H * 2);
  unsigned short* xlo = (unsigned short*)take((size_t)NTOT * H * 2);
  unsigned short* vhi = (unsigned short*)take((size_t)NTOT * H * 2);
  unsigned short* vlo = (unsigned short*)take((size_t)NTOT * H * 2);
  float* vpart        = (float*)take((size_t)8 * NTOT * H * 4);
  unsigned short* swA = (unsigned short*)take((size_t)NTOT * NTOT * 32 * 2);
  unsigned short* twB = (unsigned short*)take((size_t)NTOT * H * 32 * 2);
  unsigned short* RsWt = (unsigned short*)take((size_t)2 * 16 * H * H * 2);
  unsigned short* Wm1bf = (unsigned short*)take((size_t)H * H * 2);
  unsigned short* W2sbf = (unsigned short*)take((size_t)16 * H * 2);
  unsigned short* W2dbf = (unsigned short*)take((size_t)16 * H * 2);
  unsigned short* W1cat = (unsigned short*)take((size_t)A4W * H * 2);
  float* b1cat        = (float*)take((size_t)A4W * 4);
  unsigned short* Whhh = (unsigned short*)take((size_t)GW * H * 2);
  unsigned short* Whhl = (unsigned short*)take((size_t)GW * H * 2);
  unsigned short* Wihh = (unsigned short*)take((size_t)GW * H * 2);
  unsigned short* Wihl = (unsigned short*)take((size_t)GW * H * 2);
  unsigned short* Wm2h = (unsigned short*)take((size_t)H * H * 2);
  unsigned short* Wm2l = (unsigned short*)take((size_t)H * H * 2);

  // ---- once-per-launch prep ----
  k_init_h<<<576, 256, 0, stream>>>(asp, qry, h, hhi, hlo);
  k_cvt<<<2304, 256, 0, stream>>>(Wm1, Wm1bf, H * H);
  k_cvt<<<48, 256, 0, stream>>>(W2s, W2sbf, 16 * H);
  k_cvt<<<48, 256, 0, stream>>>(W2d, W2dbf, 16 * H);
  k_cvt_hilo<<<6912, 256, 0, stream>>>(Whh, Whhh, Whhl, GW * H);
  k_cvt_hilo<<<6912, 256, 0, stream>>>(Wih, Wihh, Wihl, GW * H);
  k_cvt_hilo<<<2304, 256, 0, stream>>>(Wm2, Wm2h, Wm2l, H * H);
  k_w1cat<<<9216, 256, 0, stream>>>(W1s, W1d, b1s, b1d, W1cat, b1cat);
  k_rsw<<<dim3(12, 12, 32), 256, 0, stream>>>(Rs, Rd, Wm1bf, RsWt);

  // ---- propagation steps ----
  for (int step = 0; step < 3; ++step) {
    // A_s,B_s,A_d,B_d = h @ W1cat^T + b1cat  (plain bf16)
    k_bt<0, 0><<<dim3(48, 3), 256, 0, stream>>>(hhi, nullptr, W1cat, nullptr, b1cat, A4,
                                                nullptr, nullptr, A4W);
    // gh = h @ Whh^T + bhh  (hi/lo split ~ fp32)
    k_bt<1, 0><<<dim3(36, 3), 256, 0, stream>>>(hhi, hlo, Whhh, Whhl, bhh, ghb,
                                                nullptr, nullptr, GW);
    // twB[j][d][32] = tsW/tdW
    k_twb<<<384, 256, 0, stream>>>(hhi, RsWt, twB);
    // relation softmax weights
    k_pairlog<<<dim3(192, 3), 256, 0, stream>>>(A4, W2sbf, W2dbf, b2s, b2d, swA);
    // v_part[js] = sum_j relu(msg + bm1)
    k_pairmsg<<<dim3(12, 3, 8), 256, 0, stream>>>(swA, twB, bm1, vpart);
    k_vred<<<576, 256, 0, stream>>>(vpart, vhi, vlo);
    // x = v @ Wm2^T + bm2  (hi/lo, also emit x hi/lo)
    k_bt<1, 1><<<dim3(12, 3), 256, 0, stream>>>(vhi, vlo, Wm2h, Wm2l, bm2, xb, xhi, xlo, H);
    // gx = x @ Wih^T + bih (hi/lo)
    k_bt<1, 0><<<dim3(36, 3), 256, 0, stream>>>(xhi, xlo, Wihh, Wihl, bih, gxb,
                                                nullptr, nullptr, GW);
    k_gru<<<576, 256, 0, stream>>>(gxb, ghb, h, hhi, hlo, out, step == 2);
  }
  (void)in_sizes; (void)n_in; (void)out_size; (void)ws_size;
}

// Round 2
// 872.949 us; speedup vs baseline: 1.1040x; 1.1040x over previous
//
#include <hip/hip_runtime.h>
#include <hip/hip_bf16.h>

#define H 768
#define NTOT 192
#define A4W 3072
#define GW 2304

typedef __attribute__((ext_vector_type(4))) float f32x4;
typedef __attribute__((ext_vector_type(8))) unsigned short u16x8;
typedef __attribute__((ext_vector_type(4))) unsigned short u16x4;
typedef __attribute__((ext_vector_type(8))) __bf16 bf16x8v;

static __device__ __forceinline__ unsigned short f2bf(float f) {
  __hip_bfloat16 b = __float2bfloat16(f);
  return __builtin_bit_cast(unsigned short, b);
}
static __device__ __forceinline__ float bf2f(unsigned short u) {
  return __bfloat162float(__builtin_bit_cast(__hip_bfloat16, u));
}
static __device__ __forceinline__ f32x4 MFMA(u16x8 a, u16x8 b, f32x4 c) {
  return __builtin_amdgcn_mfma_f32_16x16x32_bf16(
      __builtin_bit_cast(bf16x8v, a), __builtin_bit_cast(bf16x8v, b), c, 0, 0, 0);
}
static __device__ __forceinline__ u16x8 ld8(const unsigned short* p) {
  return *(const u16x8*)p;
}
static __device__ __forceinline__ unsigned int cvtpk(float lo, float hi) {
  unsigned int r;
  asm("v_cvt_pk_bf16_f32 %0, %1, %2" : "=v"(r) : "v"(lo), "v"(hi));
  return r;
}
static __device__ __forceinline__ float relu(float x) { return fmaxf(x, 0.f); }

#define GLDS16(gp, lp)                                                   \
  __builtin_amdgcn_global_load_lds(                                      \
      (const __attribute__((address_space(1))) void*)(gp),               \
      (__attribute__((address_space(3))) void*)(lp), 16, 0, 0)

// ---------------- fused prep: all weight conversions, vectorized ----------
// segment blocks: Wm1 576 | W2s 12 | W2d 12 | Whh 1728 | Wih 1728 | Wm2 576 | W1cat 2304
__global__ void k_prep(const float* __restrict__ Wm1, const float* __restrict__ W2s,
                       const float* __restrict__ W2d, const float* __restrict__ Whh,
                       const float* __restrict__ Wih, const float* __restrict__ Wm2,
                       const float* __restrict__ W1s, const float* __restrict__ W1d,
                       const float* __restrict__ b1s, const float* __restrict__ b1d,
                       unsigned short* __restrict__ Wm1bf, unsigned short* __restrict__ W2sbf,
                       unsigned short* __restrict__ W2dbf, unsigned short* __restrict__ Whhh,
                       unsigned short* __restrict__ Whhl, unsigned short* __restrict__ Wihh,
                       unsigned short* __restrict__ Wihl, unsigned short* __restrict__ Wm2h,
                       unsigned short* __restrict__ Wm2l, unsigned short* __restrict__ W1cat,
                       float* __restrict__ b1cat) {
  const int b = blockIdx.x, tid = threadIdx.x;
  if (b < 576) {
    int u = b * 256 + tid;
    float4 v = ((const float4*)Wm1)[u];
    u16x4 o; o[0] = f2bf(v.x); o[1] = f2bf(v.y); o[2] = f2bf(v.z); o[3] = f2bf(v.w);
    ((u16x4*)Wm1bf)[u] = o;
  } else if (b < 588) {
    int u = (b - 576) * 256 + tid;
    float4 v = ((const float4*)W2s)[u];
    u16x4 o; o[0] = f2bf(v.x); o[1] = f2bf(v.y); o[2] = f2bf(v.z); o[3] = f2bf(v.w);
    ((u16x4*)W2sbf)[u] = o;
  } else if (b < 600) {
    int u = (b - 588) * 256 + tid;
    float4 v = ((const float4*)W2d)[u];
    u16x4 o; o[0] = f2bf(v.x); o[1] = f2bf(v.y); o[2] = f2bf(v.z); o[3] = f2bf(v.w);
    ((u16x4*)W2dbf)[u] = o;
  } else if (b < 2328) {
    int u = (b - 600) * 256 + tid;
    float4 v = ((const float4*)Whh)[u];
    u16x4 oh, ol;
#pragma unroll
    for (int j = 0; j < 4; ++j) {
      float f = ((const float*)&v)[j];
      oh[j] = f2bf(f); ol[j] = f2bf(f - bf2f(oh[j]));
    }
    ((u16x4*)Whhh)[u] = oh; ((u16x4*)Whhl)[u] = ol;
  } else if (b < 4056) {
    int u = (b - 2328) * 256 + tid;
    float4 v = ((const float4*)Wih)[u];
    u16x4 oh, ol;
#pragma unroll
    for (int j = 0; j < 4; ++j) {
      float f = ((const float*)&v)[j];
      oh[j] = f2bf(f); ol[j] = f2bf(f - bf2f(oh[j]));
    }
    ((u16x4*)Wihh)[u] = oh; ((u16x4*)Wihl)[u] = ol;
  } else if (b < 4632) {
    int u = (b - 4056) * 256 + tid;
    float4 v = ((const float4*)Wm2)[u];
    u16x4 oh, ol;
#pragma unroll
    for (int j = 0; j < 4; ++j) {
      float f = ((const float*)&v)[j];
      oh[j] = f2bf(f); ol[j] = f2bf(f - bf2f(oh[j]));
    }
    ((u16x4*)Wm2h)[u] = oh; ((u16x4*)Wm2l)[u] = ol;
  } else {
    int u = (b - 4632) * 256 + tid;  // f4 index into W1cat [3072][768]
    int e = u * 4;
    int row = e / H, k = e - row * H;
    int part = row / H, o = row - part * H;
    const float* W = (part < 2) ? W1s : W1d;
    float4 v = *(const float4*)(W + (size_t)o * (2 * H) + (part & 1) * H + k);
    u16x4 ov; ov[0] = f2bf(v.x); ov[1] = f2bf(v.y); ov[2] = f2bf(v.z); ov[3] = f2bf(v.w);
    *(u16x4*)(W1cat + e) = ov;
    if (u < 768) {
      int e2 = u * 4, pp = e2 / H, oo = e2 - pp * H;
      float4 bv;
      if (pp == 0) bv = *(const float4*)(b1s + oo);
      else if (pp == 2) bv = *(const float4*)(b1d + oo);
      else bv = (float4){0.f, 0.f, 0.f, 0.f};
      *(float4*)(b1cat + e2) = bv;
    }
  }
}

__global__ void k_cvtR(const float* __restrict__ in, unsigned short* __restrict__ out) {
  int u = blockIdx.x * 256 + threadIdx.x;  // f4 index, 2359296
  float4 v = ((const float4*)in)[u];
  u16x4 o; o[0] = f2bf(v.x); o[1] = f2bf(v.y); o[2] = f2bf(v.z); o[3] = f2bf(v.w);
  ((u16x4*)out)[u] = o;
}

__global__ void k_inith(const float* __restrict__ asp, const float* __restrict__ qry,
                        float* __restrict__ h, unsigned short* __restrict__ hhi,
                        unsigned short* __restrict__ hlo) {
  int u = blockIdx.x * 256 + threadIdx.x;  // f4 index, 36864
  float4 v = (u < 12288) ? ((const float4*)asp)[u] : ((const float4*)qry)[u - 12288];
  ((float4*)h)[u] = v;
  u16x4 oh, ol;
#pragma unroll
  for (int j = 0; j < 4; ++j) {
    float f = ((const float*)&v)[j];
    oh[j] = f2bf(f); ol[j] = f2bf(f - bf2f(oh[j]));
  }
  ((u16x4*)hhi)[u] = oh; ((u16x4*)hlo)[u] = ol;
}

// ---------------- RsW GEMM half (16 z-matrices): RsWt[(zb+z)*H+d][k] = sum_e Rbf[z][k][e]*Wm1[d][e]
// 128x128 tile, BK=64, global_load_lds w/ XOR-swizzle (T2 both-sides), z-chunked XCD swizzle.
__global__ __launch_bounds__(256) void k_rsw2(const unsigned short* __restrict__ Wm1bf,
                                              const unsigned short* __restrict__ Rbf,
                                              unsigned short* __restrict__ RsWt, int zbase) {
  __shared__ unsigned short Asl[8192];  // [128 d][64 e] swizzled
  __shared__ unsigned short Bsl[8192];  // [128 k][64 e] swizzled
  const int wg = blockIdx.x;                      // 576
  const int nb = (wg & 7) * 72 + (wg >> 3);       // chunked XCD swizzle (576%8==0)
  const int z = nb / 36, t = nb - z * 36;
  const int d0 = (t / 6) * 128, k0 = (t - (t / 6) * 6) * 128;
  const int tid = threadIdx.x, w = tid >> 6, l = tid & 63;
  const int g = l >> 4, ln = l & 15;
  const int wr = w >> 1, wc = w & 1;
  // staging: chunk c covers LDS rows c*8..c*8+7; lane l -> row c*8+(l>>3), phys blk l&7
  // phys blk holds logical kblk = (l&7)^(l>>3)  (inverse-swizzled global source)
  const int srow = l >> 3;
  const int skb = ((l & 7) ^ srow) * 8;
  const unsigned short* Ag = Wm1bf + (size_t)(d0 + srow) * H + skb;
  const unsigned short* Bg = Rbf + (size_t)z * (H * H) + (size_t)(k0 + srow) * H + skb;
  f32x4 acc[4][4];
#pragma unroll
  for (int mi = 0; mi < 4; ++mi)
#pragma unroll
    for (int ni = 0; ni < 4; ++ni) acc[mi][ni] = (f32x4){0.f, 0.f, 0.f, 0.f};
  const int x7 = ln & 7;
  for (int kb = 0; kb < H; kb += 64) {
#pragma unroll
    for (int c4 = 0; c4 < 4; ++c4) {
      const int c = w * 4 + c4;
      GLDS16(Ag + (size_t)(c * 8) * H + kb, &Asl[c * 512]);
      GLDS16(Bg + (size_t)(c * 8) * H + kb, &Bsl[c * 512]);
    }
    __syncthreads();  // drains vmcnt
#pragma unroll
    for (int kk = 0; kk < 2; ++kk) {
      u16x8 af[4], bf[4];
      const int pb = ((kk * 4 + g) ^ x7) * 8;  // swizzled read
#pragma unroll
      for (int mi = 0; mi < 4; ++mi) af[mi] = ld8(&Asl[(wr * 64 + mi * 16 + ln) * 64 + pb]);
#pragma unroll
      for (int ni = 0; ni < 4; ++ni) bf[ni] = ld8(&Bsl[(wc * 64 + ni * 16 + ln) * 64 + pb]);
#pragma unroll
      for (int mi = 0; mi < 4; ++mi)
#pragma unroll
        for (int ni = 0; ni < 4; ++ni) acc[mi][ni] = MFMA(af[mi], bf[ni], acc[mi][ni]);
    }
    __syncthreads();
  }
#pragma unroll
  for (int mi = 0; mi < 4; ++mi) {
    const int d = d0 + wr * 64 + mi * 16 + g * 4;
#pragma unroll
    for (int ni = 0; ni < 4; ++ni) {
      const int k = k0 + wc * 64 + ni * 16 + ln;
      unsigned short* o = RsWt + ((size_t)(zbase + z) * H + d) * H + k;
#pragma unroll
      for (int pp = 0; pp < 4; ++pp) o[(size_t)pp * H] = f2bf(acc[mi][ni][pp]);
    }
  }
}

// ---------------- generic B-transposed MFMA GEMM, M=192, K=768 -------------
template <int HILO, int WHILO>
__global__ __launch_bounds__(256) void k_bt(
    const unsigned short* __restrict__ Ahi, const unsigned short* __restrict__ Alo,
    const unsigned short* __restrict__ Bhi, const unsigned short* __restrict__ Blo,
    const float* __restrict__ bias, float* __restrict__ C,
    unsigned short* __restrict__ Chi, unsigned short* __restrict__ Clo, int N) {
  const int tid = threadIdx.x;
  const int w = tid >> 6, l = tid & 63, g = l >> 4, ln = l & 15;
  const int m0 = blockIdx.y * 64 + w * 16;
  const int n0 = blockIdx.x * 64;
  const unsigned short* aph = Ahi + (size_t)(m0 + ln) * H + g * 8;
  const unsigned short* apl = HILO ? (Alo + (size_t)(m0 + ln) * H + g * 8) : aph;
  const unsigned short* bph[4];
  const unsigned short* bpl[4];
#pragma unroll
  for (int nt = 0; nt < 4; ++nt) {
    bph[nt] = Bhi + (size_t)(n0 + nt * 16 + ln) * H + g * 8;
    bpl[nt] = HILO ? (Blo + (size_t)(n0 + nt * 16 + ln) * H + g * 8) : bph[nt];
  }
  f32x4 acc[4];
#pragma unroll
  for (int nt = 0; nt < 4; ++nt) acc[nt] = (f32x4){0.f, 0.f, 0.f, 0.f};

  u16x8 ah[2], al[2], bh[2][4], bl[2][4];
  ah[0] = ld8(aph);
  if (HILO) al[0] = ld8(apl);
#pragma unroll
  for (int nt = 0; nt < 4; ++nt) {
    bh[0][nt] = ld8(bph[nt]);
    if (HILO) bl[0][nt] = ld8(bpl[nt]);
  }
#pragma unroll
  for (int t = 0; t < 24; ++t) {
    const int cur = t & 1, nxt = cur ^ 1;
    if (t < 23) {
      const int ko = (t + 1) * 32;
      ah[nxt] = ld8(aph + ko);
      if (HILO) al[nxt] = ld8(apl + ko);
#pragma unroll
      for (int nt = 0; nt < 4; ++nt) {
        bh[nxt][nt] = ld8(bph[nt] + ko);
        if (HILO) bl[nxt][nt] = ld8(bpl[nt] + ko);
      }
    }
#pragma unroll
    for (int nt = 0; nt < 4; ++nt) {
      acc[nt] = MFMA(ah[cur], bh[cur][nt], acc[nt]);
      if (HILO) {
        acc[nt] = MFMA(ah[cur], bl[cur][nt], acc[nt]);
        acc[nt] = MFMA(al[cur], bh[cur][nt], acc[nt]);
      }
    }
  }
#pragma unroll
  for (int nt = 0; nt < 4; ++nt) {
    const int col = n0 + nt * 16 + ln;
    const float bv = bias[col];
#pragma unroll
    for (int pp = 0; pp < 4; ++pp) {
      const int row = m0 + g * 4 + pp;
      const float val = acc[nt][pp] + bv;
      C[(size_t)row * N + col] = val;
      if (WHILO) {
        unsigned short hi = f2bf(val);
        Chi[(size_t)row * N + col] = hi;
        Clo[(size_t)row * N + col] = f2bf(val - bf2f(hi));
      }
    }
  }
}

// ---------------- tw = h @ RsWt^T, scattered into twB[j][d][set*16+r] (bf16) ----
__global__ __launch_bounds__(256) void k_twb(const unsigned short* __restrict__ hbf,
                                             const unsigned short* __restrict__ RsWt,
                                             unsigned short* __restrict__ twB) {
  const int tid = threadIdx.x;
  const int w = tid >> 6, l = tid & 63, g = l >> 4, ln = l & 15;
  const int n0 = blockIdx.x * 64;  // 0..24575
  const unsigned short* ap[3];
#pragma unroll
  for (int jt = 0; jt < 3; ++jt) ap[jt] = hbf + (size_t)(w * 48 + jt * 16 + ln) * H + g * 8;
  const unsigned short* bp[4];
#pragma unroll
  for (int nt = 0; nt < 4; ++nt) bp[nt] = RsWt + (size_t)(n0 + nt * 16 + ln) * H + g * 8;

  f32x4 acc[3][4];
#pragma unroll
  for (int jt = 0; jt < 3; ++jt)
#pragma unroll
    for (int nt = 0; nt < 4; ++nt) acc[jt][nt] = (f32x4){0.f, 0.f, 0.f, 0.f};

  u16x8 a[2][3], b[2][4];
#pragma unroll
  for (int jt = 0; jt < 3; ++jt) a[0][jt] = ld8(ap[jt]);
#pragma unroll
  for (int nt = 0; nt < 4; ++nt) b[0][nt] = ld8(bp[nt]);
#pragma unroll
  for (int t = 0; t < 24; ++t) {
    const int cur = t & 1, nxt = cur ^ 1;
    if (t < 23) {
      const int ko = (t + 1) * 32;
#pragma unroll
      for (int jt = 0; jt < 3; ++jt) a[nxt][jt] = ld8(ap[jt] + ko);
#pragma unroll
      for (int nt = 0; nt < 4; ++nt) b[nxt][nt] = ld8(bp[nt] + ko);
    }
#pragma unroll
    for (int jt = 0; jt < 3; ++jt)
#pragma unroll
      for (int nt = 0; nt < 4; ++nt) acc[jt][nt] = MFMA(a[cur][jt], b[cur][nt], acc[jt][nt]);
  }
#pragma unroll
  for (int nt = 0; nt < 4; ++nt) {
    const int c = n0 + nt * 16 + ln;
    const int set = c / 12288;
    const int rr = (c / H) & 15;
    const int d = c % H;
#pragma unroll
    for (int jt = 0; jt < 3; ++jt)
#pragma unroll
      for (int pp = 0; pp < 4; ++pp) {
        const int j = w * 48 + jt * 16 + g * 4 + pp;
        twB[((size_t)j * H + d) * 32 + set * 16 + rr] = f2bf(acc[jt][nt][pp]);
      }
  }
}

// ---------------- pair logits + softmax -> swA[j][i][32] (bf16) -------------
// LDS-free: hid = relu(A[i][k] + B[j][k]) built directly in the MFMA A-fragment.
__global__ __launch_bounds__(256) void k_pairlog(
    const float* __restrict__ A4, const unsigned short* __restrict__ W2sbf,
    const unsigned short* __restrict__ W2dbf, const float* __restrict__ b2s,
    const float* __restrict__ b2d, unsigned short* __restrict__ swA) {
  const int i = blockIdx.x, jb = blockIdx.y;
  const int tid = threadIdx.x, w = tid >> 6, l = tid & 63;
  const int g = l >> 4, ln = l & 15;
  const int j = jb * 64 + w * 16 + ln;
  const float* BsP = A4 + (size_t)j * A4W + 768 + g * 8;
  const float* BdP = A4 + (size_t)j * A4W + 2304 + g * 8;
  const float* AsP = A4 + (size_t)i * A4W + g * 8;
  const float* AdP = A4 + (size_t)i * A4W + 1536 + g * 8;
  const unsigned short* WsP = W2sbf + (size_t)ln * H + g * 8;
  const unsigned short* WdP = W2dbf + (size_t)ln * H + g * 8;
  f32x4 accs = (f32x4){0.f, 0.f, 0.f, 0.f}, accd = (f32x4){0.f, 0.f, 0.f, 0.f};
#pragma unroll 4
  for (int t = 0; t < 24; ++t) {
    const int ko = t * 32;
    float4 b0 = *(const float4*)(BsP + ko), b1 = *(const float4*)(BsP + ko + 4);
    float4 a0 = *(const float4*)(AsP + ko), a1 = *(const float4*)(AsP + ko + 4);
    float4 e0 = *(const float4*)(BdP + ko), e1 = *(const float4*)(BdP + ko + 4);
    float4 c0 = *(const float4*)(AdP + ko), c1 = *(const float4*)(AdP + ko + 4);
    u16x8 afs, afd;
    unsigned int* ps = (unsigned int*)&afs;
    ps[0] = cvtpk(relu(a0.x + b0.x), relu(a0.y + b0.y));
    ps[1] = cvtpk(relu(a0.z + b0.z), relu(a0.w + b0.w));
    ps[2] = cvtpk(relu(a1.x + b1.x), relu(a1.y + b1.y));
    ps[3] = cvtpk(relu(a1.z + b1.z), relu(a1.w + b1.w));
    unsigned int* pd = (unsigned int*)&afd;
    pd[0] = cvtpk(relu(c0.x + e0.x), relu(c0.y + e0.y));
    pd[1] = cvtpk(relu(c0.z + e0.z), relu(c0.w + e0.w));
    pd[2] = cvtpk(relu(c1.x + e1.x), relu(c1.y + e1.y));
    pd[3] = cvtpk(relu(c1.z + e1.z), relu(c1.w + e1.w));
    accs = MFMA(afs, ld8(WsP + ko), accs);
    accd = MFMA(afd, ld8(WdP + ko), accd);
  }
  const float b2sv = b2s[ln], b2dv = b2d[ln];
#pragma unroll
  for (int pp = 0; pp < 4; ++pp) {
    const int jr = jb * 64 + w * 16 + g * 4 + pp;
    {
      float v = accs[pp] + b2sv;
      float m = v;
      m = fmaxf(m, __shfl_xor(m, 1));
      m = fmaxf(m, __shfl_xor(m, 2));
      m = fmaxf(m, __shfl_xor(m, 4));
      m = fmaxf(m, __shfl_xor(m, 8));
      float e = __expf(v - m);
      float s = e;
      s += __shfl_xor(s, 1); s += __shfl_xor(s, 2); s += __shfl_xor(s, 4); s += __shfl_xor(s, 8);
      swA[(size_t)jr * 6144 + (size_t)i * 32 + ln] = f2bf(e / s);
    }
    {
      float v = accd[pp] + b2dv;
      float m = v;
      m = fmaxf(m, __shfl_xor(m, 1));
      m = fmaxf(m, __shfl_xor(m, 2));
      m = fmaxf(m, __shfl_xor(m, 4));
      m = fmaxf(m, __shfl_xor(m, 8));
      float e = __expf(v - m);
      float s = e;
      s += __shfl_xor(s, 1); s += __shfl_xor(s, 2); s += __shfl_xor(s, 4); s += __shfl_xor(s, 8);
      swA[(size_t)jr * 6144 + (size_t)i * 32 + 16 + ln] = f2bf(e / s);
    }
  }
}

// ---------------- per-pair weighted message + relu + sum_j -> v_part --------
__global__ __launch_bounds__(256) void k_pairmsg(const unsigned short* __restrict__ swA,
                                                 const unsigned short* __restrict__ twB,
                                                 const float* __restrict__ bm1,
                                                 float* __restrict__ vpart) {
  const int dt = blockIdx.x, it = blockIdx.y, js = blockIdx.z;
  const int tid = threadIdx.x;
  const int w = tid >> 6, l = tid & 63, g = l >> 4, ln = l & 15;
  const int i0 = it * 64 + w * 16;
  const int d0 = dt * 64;
  float bm1v[4];
#pragma unroll
  for (int nt = 0; nt < 4; ++nt) bm1v[nt] = bm1[d0 + nt * 16 + ln];
  f32x4 vacc[4];
#pragma unroll
  for (int nt = 0; nt < 4; ++nt) vacc[nt] = (f32x4){0.f, 0.f, 0.f, 0.f};
  const unsigned short* ap = swA + (size_t)(i0 + ln) * 32 + g * 8 + (size_t)js * 24 * 6144;
  const unsigned short* bp[4];
#pragma unroll
  for (int nt = 0; nt < 4; ++nt)
    bp[nt] = twB + (size_t)(d0 + nt * 16 + ln) * 32 + g * 8 + (size_t)js * 24 * 24576;
  const f32x4 z4 = (f32x4){0.f, 0.f, 0.f, 0.f};
#pragma unroll 4
  for (int jj = 0; jj < 24; ++jj) {
    u16x8 a = ld8(ap + (size_t)jj * 6144);
#pragma unroll
    for (int nt = 0; nt < 4; ++nt) {
      u16x8 b = ld8(bp[nt] + (size_t)jj * 24576);
      f32x4 mf = MFMA(a, b, z4);
#pragma unroll
      for (int pp = 0; pp < 4; ++pp) vacc[nt][pp] += fmaxf(mf[pp] + bm1v[nt], 0.f);
    }
  }
#pragma unroll
  for (int nt = 0; nt < 4; ++nt)
#pragma unroll
    for (int pp = 0; pp < 4; ++pp) {
      const int row = i0 + g * 4 + pp;
      vpart[(size_t)js * 147456 + (size_t)row * H + d0 + nt * 16 + ln] = vacc[nt][pp];
    }
}

__global__ void k_vred(const float* __restrict__ vpart, unsigned short* __restrict__ vhi,
                       unsigned short* __restrict__ vlo) {
  int e = blockIdx.x * 256 + threadIdx.x;  // 147456
  float s = 0.f;
#pragma unroll
  for (int q = 0; q < 8; ++q) s += vpart[(size_t)q * 147456 + e];
  s *= (1.0f / 192.0f);
  unsigned short hi = f2bf(s);
  vhi[e] = hi;
  vlo[e] = f2bf(s - bf2f(hi));
}

__global__ void k_gru(const float* __restrict__ gx, const float* __restrict__ gh,
                      float* __restrict__ h, unsigned short* __restrict__ hhi,
                      unsigned short* __restrict__ hlo, float* __restrict__ out, int last) {
  int e = blockIdx.x * 256 + threadIdx.x;  // 147456
  int i = e / H, k = e - i * H;
  size_t base = (size_t)i * GW;
  float rr = gx[base + k] + gh[base + k];
  float zz = gx[base + H + k] + gh[base + H + k];
  float r = 1.f / (1.f + __expf(-rr));
  float z = 1.f / (1.f + __expf(-zz));
  float n = tanhf(gx[base + 2 * H + k] + r * gh[base + 2 * H + k]);
  float hv = (1.f - z) * n + z * h[e];
  h[e] = hv;
  unsigned short hi = f2bf(hv);
  hhi[e] = hi;
  hlo[e] = f2bf(hv - bf2f(hi));
  if (last && i >= 64) out[(size_t)(i - 64) * H + k] = hv;
}

// ---------------- launch ----------------------------------------------------

extern "C" void kernel_launch(void* const* d_in, const int* in_sizes, int n_in,
                              void* d_out, int out_size, void* d_ws, size_t ws_size,
                              hipStream_t stream) {
  const float* asp = (const float*)d_in[0];
  const float* qry = (const float*)d_in[1];
  const float* W1s = (const float*)d_in[3];
  const float* b1s = (const float*)d_in[4];
  const float* W2s = (const float*)d_in[5];
  const float* b2s = (const float*)d_in[6];
  const float* W1d = (const float*)d_in[7];
  const float* b1d = (const float*)d_in[8];
  const float* W2d = (const float*)d_in[9];
  const float* b2d = (const float*)d_in[10];
  const float* Rs  = (const float*)d_in[11];
  const float* Rd  = (const float*)d_in[12];
  const float* Wm1 = (const float*)d_in[13];
  const float* bm1 = (const float*)d_in[14];
  const float* Wm2 = (const float*)d_in[15];
  const float* bm2 = (const float*)d_in[16];
  const float* Wih = (const float*)d_in[17];
  const float* Whh = (const float*)d_in[18];
  const float* bih = (const float*)d_in[19];
  const float* bhh = (const float*)d_in[20];
  float* out = (float*)d_out;

  char* p = (char*)d_ws;
  auto take = [&](size_t bytes) {
    char* q = p;
    p += (bytes + 255) & ~(size_t)255;
    return q;
  };
  // NOTE: Rbf (bf16 copy of one 16-matrix set, 18.87 MB) ALIASES the step-scratch
  // region [h .. twB] (25.4 MB): it is only live between k_cvtR and k_rsw2,
  // strictly before k_inith / the step kernels touch this region.
  unsigned short* Rbf = (unsigned short*)d_ws;
  float* h            = (float*)take((size_t)NTOT * H * 4);
  unsigned short* hhi = (unsigned short*)take((size_t)NTOT * H * 2);
  unsigned short* hlo = (unsigned short*)take((size_t)NTOT * H * 2);
  float* A4           = (float*)take((size_t)NTOT * A4W * 4);
  float* ghb          = (float*)take((size_t)NTOT * GW * 4);
  float* gxb          = (float*)take((size_t)NTOT * GW * 4);
  float* xb           = (float*)take((size_t)NTOT * H * 4);
  unsigned short* xhi = (unsigned short*)take((size_t)NTOT * H * 2);
  unsigned short* xlo = (unsigned short*)take((size_t)NTOT * H * 2);
  unsigned short* vhi = (unsigned short*)take((size_t)NTOT * H * 2);
  unsigned short* vlo = (unsigned short*)take((size_t)NTOT * H * 2);
  float* vpart        = (float*)take((size_t)8 * NTOT * H * 4);
  unsigned short* swA = (unsigned short*)take((size_t)NTOT * NTOT * 32 * 2);
  unsigned short* twB = (unsigned short*)take((size_t)NTOT * H * 32 * 2);
  unsigned short* RsWt = (unsigned short*)take((size_t)2 * 16 * H * H * 2);
  unsigned short* Wm1bf = (unsigned short*)take((size_t)H * H * 2);
  unsigned short* W2sbf = (unsigned short*)take((size_t)16 * H * 2);
  unsigned short* W2dbf = (unsigned short*)take((size_t)16 * H * 2);
  unsigned short* W1cat = (unsigned short*)take((size_t)A4W * H * 2);
  float* b1cat        = (float*)take((size_t)A4W * 4);
  unsigned short* Whhh = (unsigned short*)take((size_t)GW * H * 2);
  unsigned short* Whhl = (unsigned short*)take((size_t)GW * H * 2);
  unsigned short* Wihh = (unsigned short*)take((size_t)GW * H * 2);
  unsigned short* Wihl = (unsigned short*)take((size_t)GW * H * 2);
  unsigned short* Wm2h = (unsigned short*)take((size_t)H * H * 2);
  unsigned short* Wm2l = (unsigned short*)take((size_t)H * H * 2);

  // ---- once-per-launch prep ----
  k_prep<<<6936, 256, 0, stream>>>(Wm1, W2s, W2d, Whh, Wih, Wm2, W1s, W1d, b1s, b1d,
                                   Wm1bf, W2sbf, W2dbf, Whhh, Whhl, Wihh, Wihl,
                                   Wm2h, Wm2l, W1cat, b1cat);
  k_cvtR<<<9216, 256, 0, stream>>>(Rs, Rbf);
  k_rsw2<<<576, 256, 0, stream>>>(Wm1bf, Rbf, RsWt, 0);
  k_cvtR<<<9216, 256, 0, stream>>>(Rd, Rbf);
  k_rsw2<<<576, 256, 0, stream>>>(Wm1bf, Rbf, RsWt, 16);
  k_inith<<<144, 256, 0, stream>>>(asp, qry, h, hhi, hlo);

  // ---- propagation steps ----
  for (int step = 0; step < 3; ++step) {
    k_bt<0, 0><<<dim3(48, 3), 256, 0, stream>>>(hhi, nullptr, W1cat, nullptr, b1cat, A4,
                                                nullptr, nullptr, A4W);
    k_bt<1, 0><<<dim3(36, 3), 256, 0, stream>>>(hhi, hlo, Whhh, Whhl, bhh, ghb,
                                                nullptr, nullptr, GW);
    k_twb<<<384, 256, 0, stream>>>(hhi, RsWt, twB);
    k_pairlog<<<dim3(192, 3), 256, 0, stream>>>(A4, W2sbf, W2dbf, b2s, b2d, swA);
    k_pairmsg<<<dim3(12, 3, 8), 256, 0, stream>>>(swA, twB, bm1, vpart);
    k_vred<<<576, 256, 0, stream>>>(vpart, vhi, vlo);
    k_bt<1, 1><<<dim3(12, 3), 256, 0, stream>>>(vhi, vlo, Wm2h, Wm2l, bm2, xb, xhi, xlo, H);
    k_bt<1, 0><<<dim3(36, 3), 256, 0, stream>>>(xhi, xlo, Wihh, Wihl, bih, gxb,
                                                nullptr, nullptr, GW);
    k_gru<<<576, 256, 0, stream>>>(gxb, ghb, h, hhi, hlo, out, step == 2);
  }
  (void)in_sizes; (void)n_in; (void)out_size; (void)ws_size;
}

// Round 3
// 731.861 us; speedup vs baseline: 1.3169x; 1.1928x over previous
//
#include <hip/hip_runtime.h>
#include <hip/hip_bf16.h>

#define H 768
#define NTOT 192
#define A4W 3072
#define GW 2304

typedef __attribute__((ext_vector_type(4))) float f32x4;
typedef __attribute__((ext_vector_type(8))) unsigned short u16x8;
typedef __attribute__((ext_vector_type(4))) unsigned short u16x4;
typedef __attribute__((ext_vector_type(8))) __bf16 bf16x8v;

static __device__ __forceinline__ unsigned short f2bf(float f) {
  __hip_bfloat16 b = __float2bfloat16(f);
  return __builtin_bit_cast(unsigned short, b);
}
static __device__ __forceinline__ float bf2f(unsigned short u) {
  return __bfloat162float(__builtin_bit_cast(__hip_bfloat16, u));
}
static __device__ __forceinline__ f32x4 MFMA(u16x8 a, u16x8 b, f32x4 c) {
  return __builtin_amdgcn_mfma_f32_16x16x32_bf16(
      __builtin_bit_cast(bf16x8v, a), __builtin_bit_cast(bf16x8v, b), c, 0, 0, 0);
}
static __device__ __forceinline__ u16x8 ld8(const unsigned short* p) {
  return *(const u16x8*)p;
}
static __device__ __forceinline__ unsigned int cvtpk(float lo, float hi) {
  unsigned int r;
  asm("v_cvt_pk_bf16_f32 %0, %1, %2" : "=v"(r) : "v"(lo), "v"(hi));
  return r;
}
static __device__ __forceinline__ float relu(float x) { return fmaxf(x, 0.f); }

#define GLDS16(gp, lp)                                                   \
  __builtin_amdgcn_global_load_lds(                                      \
      (const __attribute__((address_space(1))) void*)(gp),               \
      (__attribute__((address_space(3))) void*)(lp), 16, 0, 0)

// ---------------- fused prep: all weight conversions, vectorized ----------
// segment blocks: Wm1 576 | W2s 12 | W2d 12 | Whh 1728 | Wih 1728 | Wm2t 576 | W1cat 2304
__global__ void k_prep(const float* __restrict__ Wm1, const float* __restrict__ W2s,
                       const float* __restrict__ W2d, const float* __restrict__ Whh,
                       const float* __restrict__ Wih, const float* __restrict__ Wm2,
                       const float* __restrict__ W1s, const float* __restrict__ W1d,
                       const float* __restrict__ b1s, const float* __restrict__ b1d,
                       unsigned short* __restrict__ Wm1bf, unsigned short* __restrict__ W2sbf,
                       unsigned short* __restrict__ W2dbf, unsigned short* __restrict__ Whhh,
                       unsigned short* __restrict__ Whhl, unsigned short* __restrict__ Wihh,
                       unsigned short* __restrict__ Wihl, unsigned short* __restrict__ Wm2th,
                       unsigned short* __restrict__ Wm2tl, unsigned short* __restrict__ W1cat,
                       float* __restrict__ b1cat) {
  const int b = blockIdx.x, tid = threadIdx.x;
  if (b < 576) {
    int u = b * 256 + tid;
    float4 v = ((const float4*)Wm1)[u];
    u16x4 o; o[0] = f2bf(v.x); o[1] = f2bf(v.y); o[2] = f2bf(v.z); o[3] = f2bf(v.w);
    ((u16x4*)Wm1bf)[u] = o;
  } else if (b < 588) {
    int u = (b - 576) * 256 + tid;
    float4 v = ((const float4*)W2s)[u];
    u16x4 o; o[0] = f2bf(v.x); o[1] = f2bf(v.y); o[2] = f2bf(v.z); o[3] = f2bf(v.w);
    ((u16x4*)W2sbf)[u] = o;
  } else if (b < 600) {
    int u = (b - 588) * 256 + tid;
    float4 v = ((const float4*)W2d)[u];
    u16x4 o; o[0] = f2bf(v.x); o[1] = f2bf(v.y); o[2] = f2bf(v.z); o[3] = f2bf(v.w);
    ((u16x4*)W2dbf)[u] = o;
  } else if (b < 2328) {
    int u = (b - 600) * 256 + tid;
    float4 v = ((const float4*)Whh)[u];
    u16x4 oh, ol;
#pragma unroll
    for (int j = 0; j < 4; ++j) {
      float f = ((const float*)&v)[j];
      oh[j] = f2bf(f); ol[j] = f2bf(f - bf2f(oh[j]));
    }
    ((u16x4*)Whhh)[u] = oh; ((u16x4*)Whhl)[u] = ol;
  } else if (b < 4056) {
    int u = (b - 2328) * 256 + tid;
    float4 v = ((const float4*)Wih)[u];
    u16x4 oh, ol;
#pragma unroll
    for (int j = 0; j < 4; ++j) {
      float f = ((const float*)&v)[j];
      oh[j] = f2bf(f); ol[j] = f2bf(f - bf2f(oh[j]));
    }
    ((u16x4*)Wihh)[u] = oh; ((u16x4*)Wihl)[u] = ol;
  } else if (b < 4632) {
    int u = (b - 4056) * 256 + tid;  // Wm2 f4 index; emit TRANSPOSED hi/lo
    float4 v = ((const float4*)Wm2)[u];
    int e_lin = u * 4;
    int er = e_lin / H, kc = e_lin - er * H;
#pragma unroll
    for (int j = 0; j < 4; ++j) {
      float f = ((const float*)&v)[j];
      unsigned short hi = f2bf(f);
      Wm2th[(size_t)(kc + j) * H + er] = hi;
      Wm2tl[(size_t)(kc + j) * H + er] = f2bf(f - bf2f(hi));
    }
  } else {
    int u = (b - 4632) * 256 + tid;  // f4 index into W1cat [3072][768]
    int e = u * 4;
    int row = e / H, k = e - row * H;
    int part = row / H, o = row - part * H;
    const float* W = (part < 2) ? W1s : W1d;
    float4 v = *(const float4*)(W + (size_t)o * (2 * H) + (part & 1) * H + k);
    u16x4 ov; ov[0] = f2bf(v.x); ov[1] = f2bf(v.y); ov[2] = f2bf(v.z); ov[3] = f2bf(v.w);
    *(u16x4*)(W1cat + e) = ov;
    if (u < 768) {
      int e2 = u * 4, pp = e2 / H, oo = e2 - pp * H;
      float4 bv;
      if (pp == 0) bv = *(const float4*)(b1s + oo);
      else if (pp == 2) bv = *(const float4*)(b1d + oo);
      else bv = (float4){0.f, 0.f, 0.f, 0.f};
      *(float4*)(b1cat + e2) = bv;
    }
  }
}

// bc[g] = bih[g] + sum_e Wih[g][e]*bm2[e]
__global__ void k_bc(const float* __restrict__ Wih, const float* __restrict__ bm2,
                     const float* __restrict__ bih, float* __restrict__ bc) {
  const int w = threadIdx.x >> 6, l = threadIdx.x & 63;
  const int gg = blockIdx.x * 4 + w;
  const float* row = Wih + (size_t)gg * H;
  float s = 0.f;
#pragma unroll
  for (int q = 0; q < 12; ++q) s += row[l + q * 64] * bm2[l + q * 64];
#pragma unroll
  for (int m = 32; m; m >>= 1) s += __shfl_xor(s, m);
  if (l == 0) bc[gg] = bih[gg] + s;
}

__global__ void k_cvtR(const float* __restrict__ in, unsigned short* __restrict__ out) {
  int u = blockIdx.x * 256 + threadIdx.x;  // f4 index, 2359296
  float4 v = ((const float4*)in)[u];
  u16x4 o; o[0] = f2bf(v.x); o[1] = f2bf(v.y); o[2] = f2bf(v.z); o[3] = f2bf(v.w);
  ((u16x4*)out)[u] = o;
}

__global__ void k_inith(const float* __restrict__ asp, const float* __restrict__ qry,
                        float* __restrict__ h, unsigned short* __restrict__ hhi,
                        unsigned short* __restrict__ hlo) {
  int u = blockIdx.x * 256 + threadIdx.x;  // f4 index, 36864
  float4 v = (u < 12288) ? ((const float4*)asp)[u] : ((const float4*)qry)[u - 12288];
  ((float4*)h)[u] = v;
  u16x4 oh, ol;
#pragma unroll
  for (int j = 0; j < 4; ++j) {
    float f = ((const float*)&v)[j];
    oh[j] = f2bf(f); ol[j] = f2bf(f - bf2f(oh[j]));
  }
  ((u16x4*)hhi)[u] = oh; ((u16x4*)hlo)[u] = ol;
}

// ---------------- RsW GEMM half (16 z-matrices) -----------------------------
__global__ __launch_bounds__(256) void k_rsw2(const unsigned short* __restrict__ Wm1bf,
                                              const unsigned short* __restrict__ Rbf,
                                              unsigned short* __restrict__ RsWt, int zbase) {
  __shared__ unsigned short Asl[8192];
  __shared__ unsigned short Bsl[8192];
  const int wg = blockIdx.x;                      // 576
  const int nb = (wg & 7) * 72 + (wg >> 3);
  const int z = nb / 36, t = nb - z * 36;
  const int d0 = (t / 6) * 128, k0 = (t - (t / 6) * 6) * 128;
  const int tid = threadIdx.x, w = tid >> 6, l = tid & 63;
  const int g = l >> 4, ln = l & 15;
  const int wr = w >> 1, wc = w & 1;
  const int srow = l >> 3;
  const int skb = ((l & 7) ^ srow) * 8;
  const unsigned short* Ag = Wm1bf + (size_t)(d0 + srow) * H + skb;
  const unsigned short* Bg = Rbf + (size_t)z * (H * H) + (size_t)(k0 + srow) * H + skb;
  f32x4 acc[4][4];
#pragma unroll
  for (int mi = 0; mi < 4; ++mi)
#pragma unroll
    for (int ni = 0; ni < 4; ++ni) acc[mi][ni] = (f32x4){0.f, 0.f, 0.f, 0.f};
  const int x7 = ln & 7;
  for (int kb = 0; kb < H; kb += 64) {
#pragma unroll
    for (int c4 = 0; c4 < 4; ++c4) {
      const int c = w * 4 + c4;
      GLDS16(Ag + (size_t)(c * 8) * H + kb, &Asl[c * 512]);
      GLDS16(Bg + (size_t)(c * 8) * H + kb, &Bsl[c * 512]);
    }
    __syncthreads();
#pragma unroll
    for (int kk = 0; kk < 2; ++kk) {
      u16x8 af[4], bf[4];
      const int pb = ((kk * 4 + g) ^ x7) * 8;
#pragma unroll
      for (int mi = 0; mi < 4; ++mi) af[mi] = ld8(&Asl[(wr * 64 + mi * 16 + ln) * 64 + pb]);
#pragma unroll
      for (int ni = 0; ni < 4; ++ni) bf[ni] = ld8(&Bsl[(wc * 64 + ni * 16 + ln) * 64 + pb]);
#pragma unroll
      for (int mi = 0; mi < 4; ++mi)
#pragma unroll
        for (int ni = 0; ni < 4; ++ni) acc[mi][ni] = MFMA(af[mi], bf[ni], acc[mi][ni]);
    }
    __syncthreads();
  }
#pragma unroll
  for (int mi = 0; mi < 4; ++mi) {
    const int d = d0 + wr * 64 + mi * 16 + g * 4;
#pragma unroll
    for (int ni = 0; ni < 4; ++ni) {
      const int k = k0 + wc * 64 + ni * 16 + ln;
      unsigned short* o = RsWt + ((size_t)(zbase + z) * H + d) * H + k;
#pragma unroll
      for (int pp = 0; pp < 4; ++pp) o[(size_t)pp * H] = f2bf(acc[mi][ni][pp]);
    }
  }
}

// ---------------- generic B-transposed MFMA GEMM, K=768, M via grid.y ------
template <int HILO, int WHILO, int WF32>
__global__ __launch_bounds__(256) void k_bt(
    const unsigned short* __restrict__ Ahi, const unsigned short* __restrict__ Alo,
    const unsigned short* __restrict__ Bhi, const unsigned short* __restrict__ Blo,
    const float* __restrict__ bias, float* __restrict__ C,
    unsigned short* __restrict__ Chi, unsigned short* __restrict__ Clo, int N) {
  const int tid = threadIdx.x;
  const int w = tid >> 6, l = tid & 63, g = l >> 4, ln = l & 15;
  const int m0 = blockIdx.y * 64 + w * 16;
  const int n0 = blockIdx.x * 64;
  const unsigned short* aph = Ahi + (size_t)(m0 + ln) * H + g * 8;
  const unsigned short* apl = HILO ? (Alo + (size_t)(m0 + ln) * H + g * 8) : aph;
  const unsigned short* bph[4];
  const unsigned short* bpl[4];
#pragma unroll
  for (int nt = 0; nt < 4; ++nt) {
    bph[nt] = Bhi + (size_t)(n0 + nt * 16 + ln) * H + g * 8;
    bpl[nt] = HILO ? (Blo + (size_t)(n0 + nt * 16 + ln) * H + g * 8) : bph[nt];
  }
  f32x4 acc[4];
#pragma unroll
  for (int nt = 0; nt < 4; ++nt) acc[nt] = (f32x4){0.f, 0.f, 0.f, 0.f};

  u16x8 ah[2], al[2], bh[2][4], bl[2][4];
  ah[0] = ld8(aph);
  if (HILO) al[0] = ld8(apl);
#pragma unroll
  for (int nt = 0; nt < 4; ++nt) {
    bh[0][nt] = ld8(bph[nt]);
    if (HILO) bl[0][nt] = ld8(bpl[nt]);
  }
#pragma unroll
  for (int t = 0; t < 24; ++t) {
    const int cur = t & 1, nxt = cur ^ 1;
    if (t < 23) {
      const int ko = (t + 1) * 32;
      ah[nxt] = ld8(aph + ko);
      if (HILO) al[nxt] = ld8(apl + ko);
#pragma unroll
      for (int nt = 0; nt < 4; ++nt) {
        bh[nxt][nt] = ld8(bph[nt] + ko);
        if (HILO) bl[nxt][nt] = ld8(bpl[nt] + ko);
      }
    }
#pragma unroll
    for (int nt = 0; nt < 4; ++nt) {
      acc[nt] = MFMA(ah[cur], bh[cur][nt], acc[nt]);
      if (HILO) {
        acc[nt] = MFMA(ah[cur], bl[cur][nt], acc[nt]);
        acc[nt] = MFMA(al[cur], bh[cur][nt], acc[nt]);
      }
    }
  }
#pragma unroll
  for (int nt = 0; nt < 4; ++nt) {
    const int col = n0 + nt * 16 + ln;
    const float bv = bias[col];
#pragma unroll
    for (int pp = 0; pp < 4; ++pp) {
      const int row = m0 + g * 4 + pp;
      const float val = acc[nt][pp] + bv;
      if (WF32) C[(size_t)row * N + col] = val;
      if (WHILO) {
        unsigned short hi = f2bf(val);
        Chi[(size_t)row * N + col] = hi;
        Clo[(size_t)row * N + col] = f2bf(val - bf2f(hi));
      }
    }
  }
}

// ---------------- merged per-step GEMM: A4 | gh | twB -----------------------
// bid <144: A4 (plain);  144..251: gh (hilo);  252..635: twB (plain, scatter)
__global__ __launch_bounds__(256) void k_step1(
    const unsigned short* __restrict__ hhi, const unsigned short* __restrict__ hlo,
    const unsigned short* __restrict__ W1cat, const float* __restrict__ b1cat,
    const unsigned short* __restrict__ Whhh, const unsigned short* __restrict__ Whhl,
    const float* __restrict__ bhh, const unsigned short* __restrict__ RsWt,
    float* __restrict__ A4, float* __restrict__ ghb, unsigned short* __restrict__ twB) {
  const int bid = blockIdx.x;
  const int tid = threadIdx.x, w = tid >> 6, l = tid & 63, g = l >> 4, ln = l & 15;
  if (bid >= 252) {
    // ----- twB path: tw = h @ RsWt^T scattered to twB[j][d][32]
    const int n0 = (bid - 252) * 64;
    const unsigned short* ap[3];
#pragma unroll
    for (int jt = 0; jt < 3; ++jt) ap[jt] = hhi + (size_t)(w * 48 + jt * 16 + ln) * H + g * 8;
    const unsigned short* bp[4];
#pragma unroll
    for (int nt = 0; nt < 4; ++nt) bp[nt] = RsWt + (size_t)(n0 + nt * 16 + ln) * H + g * 8;
    f32x4 acc[3][4];
#pragma unroll
    for (int jt = 0; jt < 3; ++jt)
#pragma unroll
      for (int nt = 0; nt < 4; ++nt) acc[jt][nt] = (f32x4){0.f, 0.f, 0.f, 0.f};
    u16x8 a[2][3], b[2][4];
#pragma unroll
    for (int jt = 0; jt < 3; ++jt) a[0][jt] = ld8(ap[jt]);
#pragma unroll
    for (int nt = 0; nt < 4; ++nt) b[0][nt] = ld8(bp[nt]);
#pragma unroll
    for (int t = 0; t < 24; ++t) {
      const int cur = t & 1, nxt = cur ^ 1;
      if (t < 23) {
        const int ko = (t + 1) * 32;
#pragma unroll
        for (int jt = 0; jt < 3; ++jt) a[nxt][jt] = ld8(ap[jt] + ko);
#pragma unroll
        for (int nt = 0; nt < 4; ++nt) b[nxt][nt] = ld8(bp[nt] + ko);
      }
#pragma unroll
      for (int jt = 0; jt < 3; ++jt)
#pragma unroll
        for (int nt = 0; nt < 4; ++nt) acc[jt][nt] = MFMA(a[cur][jt], b[cur][nt], acc[jt][nt]);
    }
#pragma unroll
    for (int nt = 0; nt < 4; ++nt) {
      const int c = n0 + nt * 16 + ln;
      const int set = c / 12288;
      const int rr = (c / H) & 15;
      const int d = c % H;
#pragma unroll
      for (int jt = 0; jt < 3; ++jt)
#pragma unroll
        for (int pp = 0; pp < 4; ++pp) {
          const int j = w * 48 + jt * 16 + g * 4 + pp;
          twB[((size_t)j * H + d) * 32 + set * 16 + rr] = f2bf(acc[jt][nt][pp]);
        }
    }
    return;
  }
  // ----- bt path (A4 plain / gh hilo)
  const bool isgh = bid >= 144;
  const int b2 = isgh ? bid - 144 : bid;
  const int nx = isgh ? (b2 % 36) : (b2 % 48);
  const int my = isgh ? (b2 / 36) : (b2 / 48);
  const int N = isgh ? GW : A4W;
  const unsigned short* Bh = isgh ? Whhh : W1cat;
  const unsigned short* Bl = Whhl;
  const float* bias = isgh ? bhh : b1cat;
  float* C = isgh ? ghb : A4;
  const int m0 = my * 64 + w * 16, n0 = nx * 64;
  const unsigned short* aph = hhi + (size_t)(m0 + ln) * H + g * 8;
  const unsigned short* apl = hlo + (size_t)(m0 + ln) * H + g * 8;
  const unsigned short* bph[4];
  const unsigned short* bpl[4];
#pragma unroll
  for (int nt = 0; nt < 4; ++nt) {
    bph[nt] = Bh + (size_t)(n0 + nt * 16 + ln) * H + g * 8;
    bpl[nt] = Bl + (size_t)(n0 + nt * 16 + ln) * H + g * 8;
  }
  f32x4 acc[4];
#pragma unroll
  for (int nt = 0; nt < 4; ++nt) acc[nt] = (f32x4){0.f, 0.f, 0.f, 0.f};
  u16x8 ah[2], al[2], bh[2][4], bl[2][4];
  ah[0] = ld8(aph);
  if (isgh) al[0] = ld8(apl);
#pragma unroll
  for (int nt = 0; nt < 4; ++nt) {
    bh[0][nt] = ld8(bph[nt]);
    if (isgh) bl[0][nt] = ld8(bpl[nt]);
  }
#pragma unroll
  for (int t = 0; t < 24; ++t) {
    const int cur = t & 1, nxt = cur ^ 1;
    if (t < 23) {
      const int ko = (t + 1) * 32;
      ah[nxt] = ld8(aph + ko);
      if (isgh) al[nxt] = ld8(apl + ko);
#pragma unroll
      for (int nt = 0; nt < 4; ++nt) {
        bh[nxt][nt] = ld8(bph[nt] + ko);
        if (isgh) bl[nxt][nt] = ld8(bpl[nt] + ko);
      }
    }
#pragma unroll
    for (int nt = 0; nt < 4; ++nt) {
      acc[nt] = MFMA(ah[cur], bh[cur][nt], acc[nt]);
      if (isgh) {
        acc[nt] = MFMA(ah[cur], bl[cur][nt], acc[nt]);
        acc[nt] = MFMA(al[cur], bh[cur][nt], acc[nt]);
      }
    }
  }
#pragma unroll
  for (int nt = 0; nt < 4; ++nt) {
    const int col = n0 + nt * 16 + ln;
    const float bv = bias[col];
#pragma unroll
    for (int pp = 0; pp < 4; ++pp) {
      const int row = m0 + g * 4 + pp;
      C[(size_t)row * N + col] = acc[nt][pp] + bv;
    }
  }
}

// ---------------- pair logits + softmax -> swA[j][i][32] (bf16) -------------
// K-split across 4 warps (192 each), LDS reduce, wave softmax. Grid (192,12).
__global__ __launch_bounds__(256) void k_pairlog(
    const float* __restrict__ A4, const unsigned short* __restrict__ W2sbf,
    const unsigned short* __restrict__ W2dbf, const float* __restrict__ b2s,
    const float* __restrict__ b2d, unsigned short* __restrict__ swA) {
  __shared__ float red[8][16][17];
  const int i = blockIdx.x, jb = blockIdx.y;
  const int tid = threadIdx.x, w = tid >> 6, l = tid & 63;
  const int g = l >> 4, ln = l & 15;
  const int j = jb * 16 + ln;
  const float* BsP = A4 + (size_t)j * A4W + 768 + g * 8;
  const float* BdP = A4 + (size_t)j * A4W + 2304 + g * 8;
  const float* AsP = A4 + (size_t)i * A4W + g * 8;
  const float* AdP = A4 + (size_t)i * A4W + 1536 + g * 8;
  const unsigned short* WsP = W2sbf + (size_t)ln * H + g * 8;
  const unsigned short* WdP = W2dbf + (size_t)ln * H + g * 8;
  f32x4 accs = (f32x4){0.f, 0.f, 0.f, 0.f}, accd = (f32x4){0.f, 0.f, 0.f, 0.f};
#pragma unroll
  for (int tt = 0; tt < 6; ++tt) {
    const int ko = (w * 6 + tt) * 32;
    float4 b0 = *(const float4*)(BsP + ko), b1 = *(const float4*)(BsP + ko + 4);
    float4 a0 = *(const float4*)(AsP + ko), a1 = *(const float4*)(AsP + ko + 4);
    float4 e0 = *(const float4*)(BdP + ko), e1 = *(const float4*)(BdP + ko + 4);
    float4 c0 = *(const float4*)(AdP + ko), c1 = *(const float4*)(AdP + ko + 4);
    u16x8 afs, afd;
    unsigned int* ps = (unsigned int*)&afs;
    ps[0] = cvtpk(relu(a0.x + b0.x), relu(a0.y + b0.y));
    ps[1] = cvtpk(relu(a0.z + b0.z), relu(a0.w + b0.w));
    ps[2] = cvtpk(relu(a1.x + b1.x), relu(a1.y + b1.y));
    ps[3] = cvtpk(relu(a1.z + b1.z), relu(a1.w + b1.w));
    unsigned int* pd = (unsigned int*)&afd;
    pd[0] = cvtpk(relu(c0.x + e0.x), relu(c0.y + e0.y));
    pd[1] = cvtpk(relu(c0.z + e0.z), relu(c0.w + e0.w));
    pd[2] = cvtpk(relu(c1.x + e1.x), relu(c1.y + e1.y));
    pd[3] = cvtpk(relu(c1.z + e1.z), relu(c1.w + e1.w));
    accs = MFMA(afs, ld8(WsP + ko), accs);
    accd = MFMA(afd, ld8(WdP + ko), accd);
  }
#pragma unroll
  for (int pp = 0; pp < 4; ++pp) {
    red[w * 2][g * 4 + pp][ln] = accs[pp];
    red[w * 2 + 1][g * 4 + pp][ln] = accd[pp];
  }
  __syncthreads();
  const int j2 = tid >> 4, r = tid & 15;
  float vs = red[0][j2][r] + red[2][j2][r] + red[4][j2][r] + red[6][j2][r] + b2s[r];
  float vd = red[1][j2][r] + red[3][j2][r] + red[5][j2][r] + red[7][j2][r] + b2d[r];
  float ms = vs;
  ms = fmaxf(ms, __shfl_xor(ms, 1)); ms = fmaxf(ms, __shfl_xor(ms, 2));
  ms = fmaxf(ms, __shfl_xor(ms, 4)); ms = fmaxf(ms, __shfl_xor(ms, 8));
  float md = vd;
  md = fmaxf(md, __shfl_xor(md, 1)); md = fmaxf(md, __shfl_xor(md, 2));
  md = fmaxf(md, __shfl_xor(md, 4)); md = fmaxf(md, __shfl_xor(md, 8));
  float es = __expf(vs - ms), ed = __expf(vd - md);
  float ss = es;
  ss += __shfl_xor(ss, 1); ss += __shfl_xor(ss, 2); ss += __shfl_xor(ss, 4); ss += __shfl_xor(ss, 8);
  float sd = ed;
  sd += __shfl_xor(sd, 1); sd += __shfl_xor(sd, 2); sd += __shfl_xor(sd, 4); sd += __shfl_xor(sd, 8);
  const size_t o = (size_t)(jb * 16 + j2) * 6144 + (size_t)i * 32;
  swA[o + r] = f2bf(es / ss);
  swA[o + 16 + r] = f2bf(ed / sd);
}

// ---------------- per-pair weighted message + relu + sum_j -> v_part --------
__global__ __launch_bounds__(256) void k_pairmsg(const unsigned short* __restrict__ swA,
                                                 const unsigned short* __restrict__ twB,
                                                 const float* __restrict__ bm1,
                                                 float* __restrict__ vpart) {
  const int dt = blockIdx.x, it = blockIdx.y, js = blockIdx.z;
  const int tid = threadIdx.x;
  const int w = tid >> 6, l = tid & 63, g = l >> 4, ln = l & 15;
  const int i0 = it * 64 + w * 16;
  const int d0 = dt * 64;
  float bm1v[4];
#pragma unroll
  for (int nt = 0; nt < 4; ++nt) bm1v[nt] = bm1[d0 + nt * 16 + ln];
  f32x4 vacc[4];
#pragma unroll
  for (int nt = 0; nt < 4; ++nt) vacc[nt] = (f32x4){0.f, 0.f, 0.f, 0.f};
  const unsigned short* ap = swA + (size_t)(i0 + ln) * 32 + g * 8 + (size_t)js * 24 * 6144;
  const unsigned short* bp[4];
#pragma unroll
  for (int nt = 0; nt < 4; ++nt)
    bp[nt] = twB + (size_t)(d0 + nt * 16 + ln) * 32 + g * 8 + (size_t)js * 24 * 24576;
  const f32x4 z4 = (f32x4){0.f, 0.f, 0.f, 0.f};
#pragma unroll 4
  for (int jj = 0; jj < 24; ++jj) {
    u16x8 a = ld8(ap + (size_t)jj * 6144);
#pragma unroll
    for (int nt = 0; nt < 4; ++nt) {
      u16x8 b = ld8(bp[nt] + (size_t)jj * 24576);
      f32x4 mf = MFMA(a, b, z4);
#pragma unroll
      for (int pp = 0; pp < 4; ++pp) vacc[nt][pp] += fmaxf(mf[pp] + bm1v[nt], 0.f);
    }
  }
#pragma unroll
  for (int nt = 0; nt < 4; ++nt)
#pragma unroll
    for (int pp = 0; pp < 4; ++pp) {
      const int row = i0 + g * 4 + pp;
      vpart[(size_t)js * 147456 + (size_t)row * H + d0 + nt * 16 + ln] = vacc[nt][pp];
    }
}

__global__ void k_vred(const float* __restrict__ vpart, unsigned short* __restrict__ vhi,
                       unsigned short* __restrict__ vlo) {
  int e = blockIdx.x * 256 + threadIdx.x;  // 147456
  float s = 0.f;
#pragma unroll
  for (int q = 0; q < 8; ++q) s += vpart[(size_t)q * 147456 + e];
  s *= (1.0f / 192.0f);
  unsigned short hi = f2bf(s);
  vhi[e] = hi;
  vlo[e] = f2bf(s - bf2f(hi));
}

__global__ void k_gru(const float* __restrict__ gx, const float* __restrict__ gh,
                      float* __restrict__ h, unsigned short* __restrict__ hhi,
                      unsigned short* __restrict__ hlo, float* __restrict__ out, int last) {
  int e = blockIdx.x * 256 + threadIdx.x;  // 147456
  int i = e / H, k = e - i * H;
  size_t base = (size_t)i * GW;
  float rr = gx[base + k] + gh[base + k];
  float zz = gx[base + H + k] + gh[base + H + k];
  float r = 1.f / (1.f + __expf(-rr));
  float z = 1.f / (1.f + __expf(-zz));
  float n = tanhf(gx[base + 2 * H + k] + r * gh[base + 2 * H + k]);
  float hv = (1.f - z) * n + z * h[e];
  h[e] = hv;
  unsigned short hi = f2bf(hv);
  hhi[e] = hi;
  hlo[e] = f2bf(hv - bf2f(hi));
  if (last && i >= 64) out[(size_t)(i - 64) * H + k] = hv;
}

// ---------------- launch ----------------------------------------------------

extern "C" void kernel_launch(void* const* d_in, const int* in_sizes, int n_in,
                              void* d_out, int out_size, void* d_ws, size_t ws_size,
                              hipStream_t stream) {
  const float* asp = (const float*)d_in[0];
  const float* qry = (const float*)d_in[1];
  const float* W1s = (const float*)d_in[3];
  const float* b1s = (const float*)d_in[4];
  const float* W2s = (const float*)d_in[5];
  const float* b2s = (const float*)d_in[6];
  const float* W1d = (const float*)d_in[7];
  const float* b1d = (const float*)d_in[8];
  const float* W2d = (const float*)d_in[9];
  const float* b2d = (const float*)d_in[10];
  const float* Rs  = (const float*)d_in[11];
  const float* Rd  = (const float*)d_in[12];
  const float* Wm1 = (const float*)d_in[13];
  const float* bm1 = (const float*)d_in[14];
  const float* Wm2 = (const float*)d_in[15];
  const float* bih = (const float*)d_in[19];
  const float* bhh = (const float*)d_in[20];
  const float* Wih = (const float*)d_in[17];
  const float* Whh = (const float*)d_in[18];
  const float* bm2 = (const float*)d_in[16];
  float* out = (float*)d_out;

  char* p = (char*)d_ws;
  auto take = [&](size_t bytes) {
    char* q = p;
    p += (bytes + 255) & ~(size_t)255;
    return q;
  };
  // step-scratch region (first ~24.2 MB) — aliased during prep by Rbf / Wm2t
  float* h            = (float*)take((size_t)NTOT * H * 4);
  unsigned short* hhi = (unsigned short*)take((size_t)NTOT * H * 2);
  unsigned short* hlo = (unsigned short*)take((size_t)NTOT * H * 2);
  float* A4           = (float*)take((size_t)NTOT * A4W * 4);
  float* ghb          = (float*)take((size_t)NTOT * GW * 4);
  float* gxb          = (float*)take((size_t)NTOT * GW * 4);
  unsigned short* vhi = (unsigned short*)take((size_t)NTOT * H * 2);
  unsigned short* vlo = (unsigned short*)take((size_t)NTOT * H * 2);
  float* vpart        = (float*)take((size_t)8 * NTOT * H * 4);
  unsigned short* swA = (unsigned short*)take((size_t)NTOT * NTOT * 32 * 2);
  unsigned short* twB = (unsigned short*)take((size_t)NTOT * H * 32 * 2);
  // permanent weights
  unsigned short* RsWt = (unsigned short*)take((size_t)2 * 16 * H * H * 2);
  unsigned short* Wm1bf = (unsigned short*)take((size_t)H * H * 2);
  unsigned short* W2sbf = (unsigned short*)take((size_t)16 * H * 2);
  unsigned short* W2dbf = (unsigned short*)take((size_t)16 * H * 2);
  unsigned short* W1cat = (unsigned short*)take((size_t)A4W * H * 2);
  float* b1cat        = (float*)take((size_t)A4W * 4);
  unsigned short* Whhh = (unsigned short*)take((size_t)GW * H * 2);
  unsigned short* Whhl = (unsigned short*)take((size_t)GW * H * 2);
  unsigned short* Wihh = (unsigned short*)take((size_t)GW * H * 2);
  unsigned short* Wihl = (unsigned short*)take((size_t)GW * H * 2);
  unsigned short* Wch  = (unsigned short*)take((size_t)GW * H * 2);
  unsigned short* Wcl  = (unsigned short*)take((size_t)GW * H * 2);
  float* bc           = (float*)take((size_t)GW * 4);
  // prep-phase aliases (dead once k_inith runs):
  unsigned short* Rbf = (unsigned short*)d_ws;                       // 18,874,368 B
  unsigned short* Wm2th = (unsigned short*)((char*)d_ws + 18875136); // 1,179,648 B
  unsigned short* Wm2tl = Wm2th + (size_t)H * H;                     // 1,179,648 B

  // ---- once-per-launch prep ----
  k_prep<<<6936, 256, 0, stream>>>(Wm1, W2s, W2d, Whh, Wih, Wm2, W1s, W1d, b1s, b1d,
                                   Wm1bf, W2sbf, W2dbf, Whhh, Whhl, Wihh, Wihl,
                                   Wm2th, Wm2tl, W1cat, b1cat);
  k_bc<<<576, 256, 0, stream>>>(Wih, bm2, bih, bc);
  // Wc = Wih @ Wm2  (hi/lo x hi/lo -> fp32-grade), zero bias = b1cat+768
  k_bt<1, 1, 0><<<dim3(12, 36), 256, 0, stream>>>(Wihh, Wihl, Wm2th, Wm2tl,
                                                  b1cat + 768, nullptr, Wch, Wcl, H);
  k_cvtR<<<9216, 256, 0, stream>>>(Rs, Rbf);
  k_rsw2<<<576, 256, 0, stream>>>(Wm1bf, Rbf, RsWt, 0);
  k_cvtR<<<9216, 256, 0, stream>>>(Rd, Rbf);
  k_rsw2<<<576, 256, 0, stream>>>(Wm1bf, Rbf, RsWt, 16);
  k_inith<<<144, 256, 0, stream>>>(asp, qry, h, hhi, hlo);

  // ---- propagation steps ----
  for (int step = 0; step < 3; ++step) {
    k_step1<<<636, 256, 0, stream>>>(hhi, hlo, W1cat, b1cat, Whhh, Whhl, bhh, RsWt,
                                     A4, ghb, twB);
    k_pairlog<<<dim3(192, 12), 256, 0, stream>>>(A4, W2sbf, W2dbf, b2s, b2d, swA);
    k_pairmsg<<<dim3(12, 3, 8), 256, 0, stream>>>(swA, twB, bm1, vpart);
    k_vred<<<576, 256, 0, stream>>>(vpart, vhi, vlo);
    k_bt<1, 0, 1><<<dim3(36, 3), 256, 0, stream>>>(vhi, vlo, Wch, Wcl, bc, gxb,
                                                   nullptr, nullptr, GW);
    k_gru<<<576, 256, 0, stream>>>(gxb, ghb, h, hhi, hlo, out, step == 2);
  }
  (void)in_sizes; (void)n_in; (void)out_size; (void)ws_size;
}

// Round 4
// 644.729 us; speedup vs baseline: 1.4948x; 1.1351x over previous
//
#include <hip/hip_runtime.h>
#include <hip/hip_bf16.h>

#define H 768
#define NTOT 192
#define A4W 3072
#define GW 2304

typedef __attribute__((ext_vector_type(4))) float f32x4;
typedef __attribute__((ext_vector_type(8))) unsigned short u16x8;
typedef __attribute__((ext_vector_type(4))) unsigned short u16x4;
typedef __attribute__((ext_vector_type(8))) __bf16 bf16x8v;

static __device__ __forceinline__ unsigned short f2bf(float f) {
  __hip_bfloat16 b = __float2bfloat16(f);
  return __builtin_bit_cast(unsigned short, b);
}
static __device__ __forceinline__ float bf2f(unsigned short u) {
  return __bfloat162float(__builtin_bit_cast(__hip_bfloat16, u));
}
static __device__ __forceinline__ f32x4 MFMA(u16x8 a, u16x8 b, f32x4 c) {
  return __builtin_amdgcn_mfma_f32_16x16x32_bf16(
      __builtin_bit_cast(bf16x8v, a), __builtin_bit_cast(bf16x8v, b), c, 0, 0, 0);
}
static __device__ __forceinline__ u16x8 ld8(const unsigned short* p) {
  return *(const u16x8*)p;
}
static __device__ __forceinline__ unsigned int cvtpk(float lo, float hi) {
  unsigned int r;
  asm("v_cvt_pk_bf16_f32 %0, %1, %2" : "=v"(r) : "v"(lo), "v"(hi));
  return r;
}
static __device__ __forceinline__ float relu(float x) { return fmaxf(x, 0.f); }

#define GLDS16(gp, lp)                                                   \
  __builtin_amdgcn_global_load_lds(                                      \
      (const __attribute__((address_space(1))) void*)(gp),               \
      (__attribute__((address_space(3))) void*)(lp), 16, 0, 0)

// ---------------- fused prep: weight conversions + bc + inith --------------
// segments: Wm1 576 | W2s 12 | W2d 12 | Whh 1728 | Wih 1728 | Wm2t 576 |
//           W1cat 2304 | bc 576 | inith 144   => grid 7656
__global__ void k_prep(const float* __restrict__ Wm1, const float* __restrict__ W2s,
                       const float* __restrict__ W2d, const float* __restrict__ Whh,
                       const float* __restrict__ Wih, const float* __restrict__ Wm2,
                       const float* __restrict__ W1s, const float* __restrict__ W1d,
                       const float* __restrict__ b1s, const float* __restrict__ b1d,
                       const float* __restrict__ bm2, const float* __restrict__ bih,
                       const float* __restrict__ asp, const float* __restrict__ qry,
                       unsigned short* __restrict__ Wm1bf, unsigned short* __restrict__ W2sbf,
                       unsigned short* __restrict__ W2dbf, unsigned short* __restrict__ Whhh,
                       unsigned short* __restrict__ Whhl, unsigned short* __restrict__ Wihh,
                       unsigned short* __restrict__ Wihl, unsigned short* __restrict__ Wm2th,
                       unsigned short* __restrict__ Wm2tl, unsigned short* __restrict__ W1cat,
                       float* __restrict__ b1cat, float* __restrict__ bc,
                       float* __restrict__ h, unsigned short* __restrict__ hhi,
                       unsigned short* __restrict__ hlo) {
  const int b = blockIdx.x, tid = threadIdx.x;
  if (b < 576) {
    int u = b * 256 + tid;
    float4 v = ((const float4*)Wm1)[u];
    u16x4 o; o[0] = f2bf(v.x); o[1] = f2bf(v.y); o[2] = f2bf(v.z); o[3] = f2bf(v.w);
    ((u16x4*)Wm1bf)[u] = o;
  } else if (b < 588) {
    int u = (b - 576) * 256 + tid;
    float4 v = ((const float4*)W2s)[u];
    u16x4 o; o[0] = f2bf(v.x); o[1] = f2bf(v.y); o[2] = f2bf(v.z); o[3] = f2bf(v.w);
    ((u16x4*)W2sbf)[u] = o;
  } else if (b < 600) {
    int u = (b - 588) * 256 + tid;
    float4 v = ((const float4*)W2d)[u];
    u16x4 o; o[0] = f2bf(v.x); o[1] = f2bf(v.y); o[2] = f2bf(v.z); o[3] = f2bf(v.w);
    ((u16x4*)W2dbf)[u] = o;
  } else if (b < 2328) {
    int u = (b - 600) * 256 + tid;
    float4 v = ((const float4*)Whh)[u];
    u16x4 oh, ol;
#pragma unroll
    for (int j = 0; j < 4; ++j) {
      float f = ((const float*)&v)[j];
      oh[j] = f2bf(f); ol[j] = f2bf(f - bf2f(oh[j]));
    }
    ((u16x4*)Whhh)[u] = oh; ((u16x4*)Whhl)[u] = ol;
  } else if (b < 4056) {
    int u = (b - 2328) * 256 + tid;
    float4 v = ((const float4*)Wih)[u];
    u16x4 oh, ol;
#pragma unroll
    for (int j = 0; j < 4; ++j) {
      float f = ((const float*)&v)[j];
      oh[j] = f2bf(f); ol[j] = f2bf(f - bf2f(oh[j]));
    }
    ((u16x4*)Wihh)[u] = oh; ((u16x4*)Wihl)[u] = ol;
  } else if (b < 4632) {
    int u = (b - 4056) * 256 + tid;  // Wm2 f4 index; emit TRANSPOSED hi/lo
    float4 v = ((const float4*)Wm2)[u];
    int e_lin = u * 4;
    int er = e_lin / H, kc = e_lin - er * H;
#pragma unroll
    for (int j = 0; j < 4; ++j) {
      float f = ((const float*)&v)[j];
      unsigned short hi = f2bf(f);
      Wm2th[(size_t)(kc + j) * H + er] = hi;
      Wm2tl[(size_t)(kc + j) * H + er] = f2bf(f - bf2f(hi));
    }
  } else if (b < 6936) {
    int u = (b - 4632) * 256 + tid;  // f4 index into W1cat [3072][768]
    int e = u * 4;
    int row = e / H, k = e - row * H;
    int part = row / H, o = row - part * H;
    const float* W = (part < 2) ? W1s : W1d;
    float4 v = *(const float4*)(W + (size_t)o * (2 * H) + (part & 1) * H + k);
    u16x4 ov; ov[0] = f2bf(v.x); ov[1] = f2bf(v.y); ov[2] = f2bf(v.z); ov[3] = f2bf(v.w);
    *(u16x4*)(W1cat + e) = ov;
    if (u < 768) {
      int e2 = u * 4, pp = e2 / H, oo = e2 - pp * H;
      float4 bv;
      if (pp == 0) bv = *(const float4*)(b1s + oo);
      else if (pp == 2) bv = *(const float4*)(b1d + oo);
      else bv = (float4){0.f, 0.f, 0.f, 0.f};
      *(float4*)(b1cat + e2) = bv;
    }
  } else if (b < 7512) {
    // bc[g] = bih[g] + sum_e Wih[g][e]*bm2[e]
    const int w = tid >> 6, l = tid & 63;
    const int gg = (b - 6936) * 4 + w;
    const float* row = Wih + (size_t)gg * H;
    float s = 0.f;
#pragma unroll
    for (int q = 0; q < 12; ++q) s += row[l + q * 64] * bm2[l + q * 64];
#pragma unroll
    for (int m = 32; m; m >>= 1) s += __shfl_xor(s, m);
    if (l == 0) bc[gg] = bih[gg] + s;
  } else {
    int u = (b - 7512) * 256 + tid;  // f4 index, 36864
    float4 v = (u < 12288) ? ((const float4*)asp)[u] : ((const float4*)qry)[u - 12288];
    ((float4*)h)[u] = v;
    u16x4 oh, ol;
#pragma unroll
    for (int j = 0; j < 4; ++j) {
      float f = ((const float*)&v)[j];
      oh[j] = f2bf(f); ol[j] = f2bf(f - bf2f(oh[j]));
    }
    ((u16x4*)hhi)[u] = oh; ((u16x4*)hlo)[u] = ol;
  }
}

__global__ void k_cvtR(const float* __restrict__ in, unsigned short* __restrict__ out) {
  int u = blockIdx.x * 256 + threadIdx.x;  // f4 index, 2359296
  float4 v = ((const float4*)in)[u];
  u16x4 o; o[0] = f2bf(v.x); o[1] = f2bf(v.y); o[2] = f2bf(v.z); o[3] = f2bf(v.w);
  ((u16x4*)out)[u] = o;
}

// ---------------- RsW GEMM half (16 z-matrices) -----------------------------
// Output rows PERMUTED: row = d*32 + (zbase+z)  (so twB writes are coalesced).
__global__ __launch_bounds__(256) void k_rsw2(const unsigned short* __restrict__ Wm1bf,
                                              const unsigned short* __restrict__ Rbf,
                                              unsigned short* __restrict__ RsWt, int zbase) {
  __shared__ unsigned short Asl[8192];
  __shared__ unsigned short Bsl[8192];
  const int wg = blockIdx.x;                      // 576
  const int nb = (wg & 7) * 72 + (wg >> 3);
  const int z = nb / 36, t = nb - z * 36;
  const int d0 = (t / 6) * 128, k0 = (t - (t / 6) * 6) * 128;
  const int tid = threadIdx.x, w = tid >> 6, l = tid & 63;
  const int g = l >> 4, ln = l & 15;
  const int wr = w >> 1, wc = w & 1;
  const int srow = l >> 3;
  const int skb = ((l & 7) ^ srow) * 8;
  const unsigned short* Ag = Wm1bf + (size_t)(d0 + srow) * H + skb;
  const unsigned short* Bg = Rbf + (size_t)z * (H * H) + (size_t)(k0 + srow) * H + skb;
  f32x4 acc[4][4];
#pragma unroll
  for (int mi = 0; mi < 4; ++mi)
#pragma unroll
    for (int ni = 0; ni < 4; ++ni) acc[mi][ni] = (f32x4){0.f, 0.f, 0.f, 0.f};
  const int x7 = ln & 7;
  for (int kb = 0; kb < H; kb += 64) {
#pragma unroll
    for (int c4 = 0; c4 < 4; ++c4) {
      const int c = w * 4 + c4;
      GLDS16(Ag + (size_t)(c * 8) * H + kb, &Asl[c * 512]);
      GLDS16(Bg + (size_t)(c * 8) * H + kb, &Bsl[c * 512]);
    }
    __syncthreads();
#pragma unroll
    for (int kk = 0; kk < 2; ++kk) {
      u16x8 af[4], bf[4];
      const int pb = ((kk * 4 + g) ^ x7) * 8;
#pragma unroll
      for (int mi = 0; mi < 4; ++mi) af[mi] = ld8(&Asl[(wr * 64 + mi * 16 + ln) * 64 + pb]);
#pragma unroll
      for (int ni = 0; ni < 4; ++ni) bf[ni] = ld8(&Bsl[(wc * 64 + ni * 16 + ln) * 64 + pb]);
#pragma unroll
      for (int mi = 0; mi < 4; ++mi)
#pragma unroll
        for (int ni = 0; ni < 4; ++ni) acc[mi][ni] = MFMA(af[mi], bf[ni], acc[mi][ni]);
    }
    __syncthreads();
  }
#pragma unroll
  for (int mi = 0; mi < 4; ++mi) {
    const int d = d0 + wr * 64 + mi * 16 + g * 4;
#pragma unroll
    for (int ni = 0; ni < 4; ++ni) {
      const int k = k0 + wc * 64 + ni * 16 + ln;
      unsigned short* o = RsWt + ((size_t)d * 32 + zbase + z) * H + k;
#pragma unroll
      for (int pp = 0; pp < 4; ++pp) o[(size_t)pp * 32 * H] = f2bf(acc[mi][ni][pp]);
    }
  }
}

// ---------------- generic B-transposed MFMA GEMM, K=768 --------------------
template <int HILO, int WHILO, int WF32>
__global__ __launch_bounds__(256) void k_bt(
    const unsigned short* __restrict__ Ahi, const unsigned short* __restrict__ Alo,
    const unsigned short* __restrict__ Bhi, const unsigned short* __restrict__ Blo,
    const float* __restrict__ bias, float* __restrict__ C,
    unsigned short* __restrict__ Chi, unsigned short* __restrict__ Clo, int N) {
  const int tid = threadIdx.x;
  const int w = tid >> 6, l = tid & 63, g = l >> 4, ln = l & 15;
  const int m0 = blockIdx.y * 64 + w * 16;
  const int n0 = blockIdx.x * 64;
  const unsigned short* aph = Ahi + (size_t)(m0 + ln) * H + g * 8;
  const unsigned short* apl = HILO ? (Alo + (size_t)(m0 + ln) * H + g * 8) : aph;
  const unsigned short* bph[4];
  const unsigned short* bpl[4];
#pragma unroll
  for (int nt = 0; nt < 4; ++nt) {
    bph[nt] = Bhi + (size_t)(n0 + nt * 16 + ln) * H + g * 8;
    bpl[nt] = HILO ? (Blo + (size_t)(n0 + nt * 16 + ln) * H + g * 8) : bph[nt];
  }
  f32x4 acc[4];
#pragma unroll
  for (int nt = 0; nt < 4; ++nt) acc[nt] = (f32x4){0.f, 0.f, 0.f, 0.f};

  u16x8 ah[2], al[2], bh[2][4], bl[2][4];
  ah[0] = ld8(aph);
  if (HILO) al[0] = ld8(apl);
#pragma unroll
  for (int nt = 0; nt < 4; ++nt) {
    bh[0][nt] = ld8(bph[nt]);
    if (HILO) bl[0][nt] = ld8(bpl[nt]);
  }
#pragma unroll
  for (int t = 0; t < 24; ++t) {
    const int cur = t & 1, nxt = cur ^ 1;
    if (t < 23) {
      const int ko = (t + 1) * 32;
      ah[nxt] = ld8(aph + ko);
      if (HILO) al[nxt] = ld8(apl + ko);
#pragma unroll
      for (int nt = 0; nt < 4; ++nt) {
        bh[nxt][nt] = ld8(bph[nt] + ko);
        if (HILO) bl[nxt][nt] = ld8(bpl[nt] + ko);
      }
    }
#pragma unroll
    for (int nt = 0; nt < 4; ++nt) {
      acc[nt] = MFMA(ah[cur], bh[cur][nt], acc[nt]);
      if (HILO) {
        acc[nt] = MFMA(ah[cur], bl[cur][nt], acc[nt]);
        acc[nt] = MFMA(al[cur], bh[cur][nt], acc[nt]);
      }
    }
  }
#pragma unroll
  for (int nt = 0; nt < 4; ++nt) {
    const int col = n0 + nt * 16 + ln;
    const float bv = bias[col];
#pragma unroll
    for (int pp = 0; pp < 4; ++pp) {
      const int row = m0 + g * 4 + pp;
      const float val = acc[nt][pp] + bv;
      if (WF32) C[(size_t)row * N + col] = val;
      if (WHILO) {
        unsigned short hi = f2bf(val);
        Chi[(size_t)row * N + col] = hi;
        Clo[(size_t)row * N + col] = f2bf(val - bf2f(hi));
      }
    }
  }
}

// ---------------- K-split hilo GEMM for gx (no bias, raw partials) ----------
__global__ __launch_bounds__(256) void k_btks(
    const unsigned short* __restrict__ Ahi, const unsigned short* __restrict__ Alo,
    const unsigned short* __restrict__ Bhi, const unsigned short* __restrict__ Blo,
    float* __restrict__ Cp) {
  const int tid = threadIdx.x;
  const int w = tid >> 6, l = tid & 63, g = l >> 4, ln = l & 15;
  const int m0 = blockIdx.y * 64 + w * 16;
  const int n0 = blockIdx.x * 64;
  const int kh = blockIdx.z, kb0 = kh * 384;
  const unsigned short* aph = Ahi + (size_t)(m0 + ln) * H + kb0 + g * 8;
  const unsigned short* apl = Alo + (size_t)(m0 + ln) * H + kb0 + g * 8;
  const unsigned short* bph[4];
  const unsigned short* bpl[4];
#pragma unroll
  for (int nt = 0; nt < 4; ++nt) {
    bph[nt] = Bhi + (size_t)(n0 + nt * 16 + ln) * H + kb0 + g * 8;
    bpl[nt] = Blo + (size_t)(n0 + nt * 16 + ln) * H + kb0 + g * 8;
  }
  f32x4 acc[4];
#pragma unroll
  for (int nt = 0; nt < 4; ++nt) acc[nt] = (f32x4){0.f, 0.f, 0.f, 0.f};
  u16x8 ah[2], al[2], bh[2][4], bl[2][4];
  ah[0] = ld8(aph);
  al[0] = ld8(apl);
#pragma unroll
  for (int nt = 0; nt < 4; ++nt) { bh[0][nt] = ld8(bph[nt]); bl[0][nt] = ld8(bpl[nt]); }
#pragma unroll
  for (int t = 0; t < 12; ++t) {
    const int cur = t & 1, nxt = cur ^ 1;
    if (t < 11) {
      const int ko = (t + 1) * 32;
      ah[nxt] = ld8(aph + ko);
      al[nxt] = ld8(apl + ko);
#pragma unroll
      for (int nt = 0; nt < 4; ++nt) {
        bh[nxt][nt] = ld8(bph[nt] + ko);
        bl[nxt][nt] = ld8(bpl[nt] + ko);
      }
    }
#pragma unroll
    for (int nt = 0; nt < 4; ++nt) {
      acc[nt] = MFMA(ah[cur], bh[cur][nt], acc[nt]);
      acc[nt] = MFMA(ah[cur], bl[cur][nt], acc[nt]);
      acc[nt] = MFMA(al[cur], bh[cur][nt], acc[nt]);
    }
  }
#pragma unroll
  for (int nt = 0; nt < 4; ++nt) {
    const int col = n0 + nt * 16 + ln;
#pragma unroll
    for (int pp = 0; pp < 4; ++pp) {
      const int row = m0 + g * 4 + pp;
      Cp[(size_t)kh * (NTOT * GW) + (size_t)row * GW + col] = acc[nt][pp];
    }
  }
}

// ---------------- merged per-step GEMM: A4 | gh | twB -----------------------
// bid <144: A4 (plain);  144..251: gh (hilo);  252..635: twB (plain)
__global__ __launch_bounds__(256) void k_step1(
    const unsigned short* __restrict__ hhi, const unsigned short* __restrict__ hlo,
    const unsigned short* __restrict__ W1cat, const float* __restrict__ b1cat,
    const unsigned short* __restrict__ Whhh, const unsigned short* __restrict__ Whhl,
    const float* __restrict__ bhh, const unsigned short* __restrict__ RsWt,
    float* __restrict__ A4, float* __restrict__ ghb, unsigned short* __restrict__ twB) {
  const int bid = blockIdx.x;
  const int tid = threadIdx.x, w = tid >> 6, l = tid & 63, g = l >> 4, ln = l & 15;
  if (bid >= 252) {
    // ----- twB path: tw = h @ RsWt^T ; N axis is already (d,set,r)
    const int n0 = (bid - 252) * 64;
    const unsigned short* ap[3];
#pragma unroll
    for (int jt = 0; jt < 3; ++jt) ap[jt] = hhi + (size_t)(w * 48 + jt * 16 + ln) * H + g * 8;
    const unsigned short* bp[4];
#pragma unroll
    for (int nt = 0; nt < 4; ++nt) bp[nt] = RsWt + (size_t)(n0 + nt * 16 + ln) * H + g * 8;
    f32x4 acc[3][4];
#pragma unroll
    for (int jt = 0; jt < 3; ++jt)
#pragma unroll
      for (int nt = 0; nt < 4; ++nt) acc[jt][nt] = (f32x4){0.f, 0.f, 0.f, 0.f};
    u16x8 a[2][3], b[2][4];
#pragma unroll
    for (int jt = 0; jt < 3; ++jt) a[0][jt] = ld8(ap[jt]);
#pragma unroll
    for (int nt = 0; nt < 4; ++nt) b[0][nt] = ld8(bp[nt]);
#pragma unroll
    for (int t = 0; t < 24; ++t) {
      const int cur = t & 1, nxt = cur ^ 1;
      if (t < 23) {
        const int ko = (t + 1) * 32;
#pragma unroll
        for (int jt = 0; jt < 3; ++jt) a[nxt][jt] = ld8(ap[jt] + ko);
#pragma unroll
        for (int nt = 0; nt < 4; ++nt) b[nxt][nt] = ld8(bp[nt] + ko);
      }
#pragma unroll
      for (int jt = 0; jt < 3; ++jt)
#pragma unroll
        for (int nt = 0; nt < 4; ++nt) acc[jt][nt] = MFMA(a[cur][jt], b[cur][nt], acc[jt][nt]);
    }
#pragma unroll
    for (int nt = 0; nt < 4; ++nt) {
      const int c = n0 + nt * 16 + ln;
#pragma unroll
      for (int jt = 0; jt < 3; ++jt)
#pragma unroll
        for (int pp = 0; pp < 4; ++pp) {
          const int j = w * 48 + jt * 16 + g * 4 + pp;
          twB[(size_t)j * 24576 + c] = f2bf(acc[jt][nt][pp]);
        }
    }
    return;
  }
  // ----- bt path (A4 plain / gh hilo)
  const bool isgh = bid >= 144;
  const int b2 = isgh ? bid - 144 : bid;
  const int nx = isgh ? (b2 % 36) : (b2 % 48);
  const int my = isgh ? (b2 / 36) : (b2 / 48);
  const int N = isgh ? GW : A4W;
  const unsigned short* Bh = isgh ? Whhh : W1cat;
  const unsigned short* Bl = Whhl;
  const float* bias = isgh ? bhh : b1cat;
  float* C = isgh ? ghb : A4;
  const int m0 = my * 64 + w * 16, n0 = nx * 64;
  const unsigned short* aph = hhi + (size_t)(m0 + ln) * H + g * 8;
  const unsigned short* apl = hlo + (size_t)(m0 + ln) * H + g * 8;
  const unsigned short* bph[4];
  const unsigned short* bpl[4];
#pragma unroll
  for (int nt = 0; nt < 4; ++nt) {
    bph[nt] = Bh + (size_t)(n0 + nt * 16 + ln) * H + g * 8;
    bpl[nt] = Bl + (size_t)(n0 + nt * 16 + ln) * H + g * 8;
  }
  f32x4 acc[4];
#pragma unroll
  for (int nt = 0; nt < 4; ++nt) acc[nt] = (f32x4){0.f, 0.f, 0.f, 0.f};
  u16x8 ah[2], al[2], bh[2][4], bl[2][4];
  ah[0] = ld8(aph);
  if (isgh) al[0] = ld8(apl);
#pragma unroll
  for (int nt = 0; nt < 4; ++nt) {
    bh[0][nt] = ld8(bph[nt]);
    if (isgh) bl[0][nt] = ld8(bpl[nt]);
  }
#pragma unroll
  for (int t = 0; t < 24; ++t) {
    const int cur = t & 1, nxt = cur ^ 1;
    if (t < 23) {
      const int ko = (t + 1) * 32;
      ah[nxt] = ld8(aph + ko);
      if (isgh) al[nxt] = ld8(apl + ko);
#pragma unroll
      for (int nt = 0; nt < 4; ++nt) {
        bh[nxt][nt] = ld8(bph[nt] + ko);
        if (isgh) bl[nxt][nt] = ld8(bpl[nt] + ko);
      }
    }
#pragma unroll
    for (int nt = 0; nt < 4; ++nt) {
      acc[nt] = MFMA(ah[cur], bh[cur][nt], acc[nt]);
      if (isgh) {
        acc[nt] = MFMA(ah[cur], bl[cur][nt], acc[nt]);
        acc[nt] = MFMA(al[cur], bh[cur][nt], acc[nt]);
      }
    }
  }
#pragma unroll
  for (int nt = 0; nt < 4; ++nt) {
    const int col = n0 + nt * 16 + ln;
    const float bv = bias[col];
#pragma unroll
    for (int pp = 0; pp < 4; ++pp) {
      const int row = m0 + g * 4 + pp;
      C[(size_t)row * N + col] = acc[nt][pp] + bv;
    }
  }
}

// ---------------- pair logits + softmax -> swA[j][i][32] (bf16) -------------
__global__ __launch_bounds__(256) void k_pairlog(
    const float* __restrict__ A4, const unsigned short* __restrict__ W2sbf,
    const unsigned short* __restrict__ W2dbf, const float* __restrict__ b2s,
    const float* __restrict__ b2d, unsigned short* __restrict__ swA) {
  __shared__ float red[8][16][17];
  const int i = blockIdx.x, jb = blockIdx.y;
  const int tid = threadIdx.x, w = tid >> 6, l = tid & 63;
  const int g = l >> 4, ln = l & 15;
  const int j = jb * 16 + ln;
  const float* BsP = A4 + (size_t)j * A4W + 768 + g * 8;
  const float* BdP = A4 + (size_t)j * A4W + 2304 + g * 8;
  const float* AsP = A4 + (size_t)i * A4W + g * 8;
  const float* AdP = A4 + (size_t)i * A4W + 1536 + g * 8;
  const unsigned short* WsP = W2sbf + (size_t)ln * H + g * 8;
  const unsigned short* WdP = W2dbf + (size_t)ln * H + g * 8;
  f32x4 accs = (f32x4){0.f, 0.f, 0.f, 0.f}, accd = (f32x4){0.f, 0.f, 0.f, 0.f};
#pragma unroll
  for (int tt = 0; tt < 6; ++tt) {
    const int ko = (w * 6 + tt) * 32;
    float4 b0 = *(const float4*)(BsP + ko), b1 = *(const float4*)(BsP + ko + 4);
    float4 a0 = *(const float4*)(AsP + ko), a1 = *(const float4*)(AsP + ko + 4);
    float4 e0 = *(const float4*)(BdP + ko), e1 = *(const float4*)(BdP + ko + 4);
    float4 c0 = *(const float4*)(AdP + ko), c1 = *(const float4*)(AdP + ko + 4);
    u16x8 afs, afd;
    unsigned int* ps = (unsigned int*)&afs;
    ps[0] = cvtpk(relu(a0.x + b0.x), relu(a0.y + b0.y));
    ps[1] = cvtpk(relu(a0.z + b0.z), relu(a0.w + b0.w));
    ps[2] = cvtpk(relu(a1.x + b1.x), relu(a1.y + b1.y));
    ps[3] = cvtpk(relu(a1.z + b1.z), relu(a1.w + b1.w));
    unsigned int* pd = (unsigned int*)&afd;
    pd[0] = cvtpk(relu(c0.x + e0.x), relu(c0.y + e0.y));
    pd[1] = cvtpk(relu(c0.z + e0.z), relu(c0.w + e0.w));
    pd[2] = cvtpk(relu(c1.x + e1.x), relu(c1.y + e1.y));
    pd[3] = cvtpk(relu(c1.z + e1.z), relu(c1.w + e1.w));
    accs = MFMA(afs, ld8(WsP + ko), accs);
    accd = MFMA(afd, ld8(WdP + ko), accd);
  }
#pragma unroll
  for (int pp = 0; pp < 4; ++pp) {
    red[w * 2][g * 4 + pp][ln] = accs[pp];
    red[w * 2 + 1][g * 4 + pp][ln] = accd[pp];
  }
  __syncthreads();
  const int j2 = tid >> 4, r = tid & 15;
  float vs = red[0][j2][r] + red[2][j2][r] + red[4][j2][r] + red[6][j2][r] + b2s[r];
  float vd = red[1][j2][r] + red[3][j2][r] + red[5][j2][r] + red[7][j2][r] + b2d[r];
  float ms = vs;
  ms = fmaxf(ms, __shfl_xor(ms, 1)); ms = fmaxf(ms, __shfl_xor(ms, 2));
  ms = fmaxf(ms, __shfl_xor(ms, 4)); ms = fmaxf(ms, __shfl_xor(ms, 8));
  float md = vd;
  md = fmaxf(md, __shfl_xor(md, 1)); md = fmaxf(md, __shfl_xor(md, 2));
  md = fmaxf(md, __shfl_xor(md, 4)); md = fmaxf(md, __shfl_xor(md, 8));
  float es = __expf(vs - ms), ed = __expf(vd - md);
  float ss = es;
  ss += __shfl_xor(ss, 1); ss += __shfl_xor(ss, 2); ss += __shfl_xor(ss, 4); ss += __shfl_xor(ss, 8);
  float sd = ed;
  sd += __shfl_xor(sd, 1); sd += __shfl_xor(sd, 2); sd += __shfl_xor(sd, 4); sd += __shfl_xor(sd, 8);
  const size_t o = (size_t)(jb * 16 + j2) * 6144 + (size_t)i * 32;
  swA[o + r] = f2bf(es / ss);
  swA[o + 16 + r] = f2bf(ed / sd);
}

// ---------------- per-pair weighted message + relu + sum_j -> v_part --------
__global__ __launch_bounds__(256) void k_pairmsg(const unsigned short* __restrict__ swA,
                                                 const unsigned short* __restrict__ twB,
                                                 const float* __restrict__ bm1,
                                                 float* __restrict__ vpart) {
  const int dt = blockIdx.x, it = blockIdx.y, js = blockIdx.z;
  const int tid = threadIdx.x;
  const int w = tid >> 6, l = tid & 63, g = l >> 4, ln = l & 15;
  const int i0 = it * 64 + w * 16;
  const int d0 = dt * 64;
  float bm1v[4];
#pragma unroll
  for (int nt = 0; nt < 4; ++nt) bm1v[nt] = bm1[d0 + nt * 16 + ln];
  f32x4 vacc[4];
#pragma unroll
  for (int nt = 0; nt < 4; ++nt) vacc[nt] = (f32x4){0.f, 0.f, 0.f, 0.f};
  const unsigned short* ap = swA + (size_t)(i0 + ln) * 32 + g * 8 + (size_t)js * 24 * 6144;
  const unsigned short* bp[4];
#pragma unroll
  for (int nt = 0; nt < 4; ++nt)
    bp[nt] = twB + (size_t)(d0 + nt * 16 + ln) * 32 + g * 8 + (size_t)js * 24 * 24576;
  const f32x4 z4 = (f32x4){0.f, 0.f, 0.f, 0.f};
#pragma unroll 4
  for (int jj = 0; jj < 24; ++jj) {
    u16x8 a = ld8(ap + (size_t)jj * 6144);
#pragma unroll
    for (int nt = 0; nt < 4; ++nt) {
      u16x8 b = ld8(bp[nt] + (size_t)jj * 24576);
      f32x4 mf = MFMA(a, b, z4);
#pragma unroll
      for (int pp = 0; pp < 4; ++pp) vacc[nt][pp] += fmaxf(mf[pp] + bm1v[nt], 0.f);
    }
  }
#pragma unroll
  for (int nt = 0; nt < 4; ++nt)
#pragma unroll
    for (int pp = 0; pp < 4; ++pp) {
      const int row = i0 + g * 4 + pp;
      vpart[(size_t)js * 147456 + (size_t)row * H + d0 + nt * 16 + ln] = vacc[nt][pp];
    }
}

__global__ void k_vred(const float* __restrict__ vpart, unsigned short* __restrict__ vhi,
                       unsigned short* __restrict__ vlo) {
  int e = blockIdx.x * 256 + threadIdx.x;  // 147456
  float s = 0.f;
#pragma unroll
  for (int q = 0; q < 8; ++q) s += vpart[(size_t)q * 147456 + e];
  s *= (1.0f / 192.0f);
  unsigned short hi = f2bf(s);
  vhi[e] = hi;
  vlo[e] = f2bf(s - bf2f(hi));
}

__global__ void k_gru(const float* __restrict__ gxp, const float* __restrict__ bcv,
                      const float* __restrict__ gh, float* __restrict__ h,
                      unsigned short* __restrict__ hhi, unsigned short* __restrict__ hlo,
                      float* __restrict__ out, int last) {
  int e = blockIdx.x * 256 + threadIdx.x;  // 147456
  int i = e / H, k = e - i * H;
  size_t base = (size_t)i * GW;
  const float* gx0 = gxp;
  const float* gx1 = gxp + (size_t)NTOT * GW;
  float rr = gx0[base + k] + gx1[base + k] + bcv[k] + gh[base + k];
  float zz = gx0[base + H + k] + gx1[base + H + k] + bcv[H + k] + gh[base + H + k];
  float r = 1.f / (1.f + __expf(-rr));
  float z = 1.f / (1.f + __expf(-zz));
  float n = tanhf(gx0[base + 2 * H + k] + gx1[base + 2 * H + k] + bcv[2 * H + k] +
                  r * gh[base + 2 * H + k]);
  float hv = (1.f - z) * n + z * h[e];
  h[e] = hv;
  unsigned short hi = f2bf(hv);
  hhi[e] = hi;
  hlo[e] = f2bf(hv - bf2f(hi));
  if (last && i >= 64) out[(size_t)(i - 64) * H + k] = hv;
}

// ---------------- launch ----------------------------------------------------

extern "C" void kernel_launch(void* const* d_in, const int* in_sizes, int n_in,
                              void* d_out, int out_size, void* d_ws, size_t ws_size,
                              hipStream_t stream) {
  const float* asp = (const float*)d_in[0];
  const float* qry = (const float*)d_in[1];
  const float* W1s = (const float*)d_in[3];
  const float* b1s = (const float*)d_in[4];
  const float* W2s = (const float*)d_in[5];
  const float* b2s = (const float*)d_in[6];
  const float* W1d = (const float*)d_in[7];
  const float* b1d = (const float*)d_in[8];
  const float* W2d = (const float*)d_in[9];
  const float* b2d = (const float*)d_in[10];
  const float* Rs  = (const float*)d_in[11];
  const float* Rd  = (const float*)d_in[12];
  const float* Wm1 = (const float*)d_in[13];
  const float* bm1 = (const float*)d_in[14];
  const float* Wm2 = (const float*)d_in[15];
  const float* bm2 = (const float*)d_in[16];
  const float* Wih = (const float*)d_in[17];
  const float* Whh = (const float*)d_in[18];
  const float* bih = (const float*)d_in[19];
  const float* bhh = (const float*)d_in[20];
  float* out = (float*)d_out;

  char* p = (char*)d_ws;
  auto take = [&](size_t bytes) {
    char* q = p;
    p += (bytes + 255) & ~(size_t)255;
    return q;
  };
  // ---- step-scratch region (~24.2 MB), aliased during prep ----
  float* h            = (float*)take((size_t)NTOT * H * 4);
  unsigned short* hhi = (unsigned short*)take((size_t)NTOT * H * 2);
  unsigned short* hlo = (unsigned short*)take((size_t)NTOT * H * 2);
  float* A4           = (float*)take((size_t)NTOT * A4W * 4);
  float* ghb          = (float*)take((size_t)NTOT * GW * 4);
  unsigned short* vhi = (unsigned short*)take((size_t)NTOT * H * 2);
  unsigned short* vlo = (unsigned short*)take((size_t)NTOT * H * 2);
  float* vpart        = (float*)take((size_t)8 * NTOT * H * 4);  // also gx partials
  unsigned short* swA = (unsigned short*)take((size_t)NTOT * NTOT * 32 * 2);
  unsigned short* twB = (unsigned short*)take((size_t)NTOT * H * 32 * 2);
  // ---- permanent weights ----
  unsigned short* RsWt = (unsigned short*)take((size_t)2 * 16 * H * H * 2);
  unsigned short* Wm1bf = (unsigned short*)take((size_t)H * H * 2);
  unsigned short* W2sbf = (unsigned short*)take((size_t)16 * H * 2);
  unsigned short* W2dbf = (unsigned short*)take((size_t)16 * H * 2);
  unsigned short* W1cat = (unsigned short*)take((size_t)A4W * H * 2);
  float* b1cat        = (float*)take((size_t)A4W * 4);
  unsigned short* Whhh = (unsigned short*)take((size_t)GW * H * 2);
  unsigned short* Whhl = (unsigned short*)take((size_t)GW * H * 2);
  unsigned short* Wihh = (unsigned short*)take((size_t)GW * H * 2);
  unsigned short* Wihl = (unsigned short*)take((size_t)GW * H * 2);
  unsigned short* Wch  = (unsigned short*)take((size_t)GW * H * 2);
  unsigned short* Wcl  = (unsigned short*)take((size_t)GW * H * 2);
  float* bc           = (float*)take((size_t)GW * 4);
  // ---- prep-phase aliases (within step-scratch, after h/hhi/hlo) ----
  // h+hhi+hlo end at offset 1,179,648. Rbf: 18,874,368 B -> ends 20,054,016.
  unsigned short* Rbf   = (unsigned short*)((char*)d_ws + 1179648);
  unsigned short* Wm2th = (unsigned short*)((char*)d_ws + 20054016);
  unsigned short* Wm2tl = Wm2th + (size_t)H * H;  // ends 22,413,312 < 24.1 MB scratch

  // ---- once-per-launch prep ----
  k_prep<<<7656, 256, 0, stream>>>(Wm1, W2s, W2d, Whh, Wih, Wm2, W1s, W1d, b1s, b1d,
                                   bm2, bih, asp, qry,
                                   Wm1bf, W2sbf, W2dbf, Whhh, Whhl, Wihh, Wihl,
                                   Wm2th, Wm2tl, W1cat, b1cat, bc, h, hhi, hlo);
  // Wc = Wih @ Wm2 (hi/lo x hi/lo), zero bias = b1cat+768
  k_bt<1, 1, 0><<<dim3(12, 36), 256, 0, stream>>>(Wihh, Wihl, Wm2th, Wm2tl,
                                                  b1cat + 768, nullptr, Wch, Wcl, H);
  k_cvtR<<<9216, 256, 0, stream>>>(Rs, Rbf);
  k_rsw2<<<576, 256, 0, stream>>>(Wm1bf, Rbf, RsWt, 0);
  k_cvtR<<<9216, 256, 0, stream>>>(Rd, Rbf);
  k_rsw2<<<576, 256, 0, stream>>>(Wm1bf, Rbf, RsWt, 16);

  // ---- propagation steps ----
  for (int step = 0; step < 3; ++step) {
    k_step1<<<636, 256, 0, stream>>>(hhi, hlo, W1cat, b1cat, Whhh, Whhl, bhh, RsWt,
                                     A4, ghb, twB);
    k_pairlog<<<dim3(192, 12), 256, 0, stream>>>(A4, W2sbf, W2dbf, b2s, b2d, swA);
    k_pairmsg<<<dim3(12, 3, 8), 256, 0, stream>>>(swA, twB, bm1, vpart);
    k_vred<<<576, 256, 0, stream>>>(vpart, vhi, vlo);
    k_btks<<<dim3(36, 3, 2), 256, 0, stream>>>(vhi, vlo, Wch, Wcl, vpart);
    k_gru<<<576, 256, 0, stream>>>(vpart, bc, ghb, h, hhi, hlo, out, step == 2);
  }
  (void)in_sizes; (void)n_in; (void)out_size; (void)ws_size;
}

// Round 5
// 612.689 us; speedup vs baseline: 1.5730x; 1.0523x over previous
//
#include <hip/hip_runtime.h>
#include <hip/hip_bf16.h>

#define H 768
#define NTOT 192
#define A4W 3072
#define GW 2304

typedef __attribute__((ext_vector_type(4))) float f32x4;
typedef __attribute__((ext_vector_type(8))) unsigned short u16x8;
typedef __attribute__((ext_vector_type(4))) unsigned short u16x4;
typedef __attribute__((ext_vector_type(8))) __bf16 bf16x8v;

static __device__ __forceinline__ unsigned short f2bf(float f) {
  __hip_bfloat16 b = __float2bfloat16(f);
  return __builtin_bit_cast(unsigned short, b);
}
static __device__ __forceinline__ float bf2f(unsigned short u) {
  return __bfloat162float(__builtin_bit_cast(__hip_bfloat16, u));
}
static __device__ __forceinline__ f32x4 MFMA(u16x8 a, u16x8 b, f32x4 c) {
  return __builtin_amdgcn_mfma_f32_16x16x32_bf16(
      __builtin_bit_cast(bf16x8v, a), __builtin_bit_cast(bf16x8v, b), c, 0, 0, 0);
}
static __device__ __forceinline__ u16x8 ld8(const unsigned short* p) {
  return *(const u16x8*)p;
}
static __device__ __forceinline__ unsigned int cvtpk(float lo, float hi) {
  unsigned int r;
  asm("v_cvt_pk_bf16_f32 %0, %1, %2" : "=v"(r) : "v"(lo), "v"(hi));
  return r;
}
static __device__ __forceinline__ float relu(float x) { return fmaxf(x, 0.f); }

#define GLDS16(gp, lp)                                                   \
  __builtin_amdgcn_global_load_lds(                                      \
      (const __attribute__((address_space(1))) void*)(gp),               \
      (__attribute__((address_space(3))) void*)(lp), 16, 0, 0)

// ---------------- fused prep: weight conversions + bc + inith --------------
// segments: Wm1 576 | W2s 12 | W2d 12 | Whh 1728 | Wm2t 576 | W1cat 2304 |
//           bc 576 | inith 144  => grid 5928
__global__ void k_prep(const float* __restrict__ Wm1, const float* __restrict__ W2s,
                       const float* __restrict__ W2d, const float* __restrict__ Whh,
                       const float* __restrict__ Wih, const float* __restrict__ Wm2,
                       const float* __restrict__ W1s, const float* __restrict__ W1d,
                       const float* __restrict__ b1s, const float* __restrict__ b1d,
                       const float* __restrict__ bm2, const float* __restrict__ bih,
                       const float* __restrict__ asp, const float* __restrict__ qry,
                       unsigned short* __restrict__ Wm1bf, unsigned short* __restrict__ W2sbf,
                       unsigned short* __restrict__ W2dbf, unsigned short* __restrict__ Whhh,
                       unsigned short* __restrict__ Whhl, unsigned short* __restrict__ Wm2th,
                       unsigned short* __restrict__ Wm2tl, unsigned short* __restrict__ W1cat,
                       float* __restrict__ b1cat, float* __restrict__ bc,
                       float* __restrict__ h, unsigned short* __restrict__ hhi,
                       unsigned short* __restrict__ hlo) {
  const int b = blockIdx.x, tid = threadIdx.x;
  if (b < 576) {
    int u = b * 256 + tid;
    float4 v = ((const float4*)Wm1)[u];
    u16x4 o; o[0] = f2bf(v.x); o[1] = f2bf(v.y); o[2] = f2bf(v.z); o[3] = f2bf(v.w);
    ((u16x4*)Wm1bf)[u] = o;
  } else if (b < 588) {
    int u = (b - 576) * 256 + tid;
    float4 v = ((const float4*)W2s)[u];
    u16x4 o; o[0] = f2bf(v.x); o[1] = f2bf(v.y); o[2] = f2bf(v.z); o[3] = f2bf(v.w);
    ((u16x4*)W2sbf)[u] = o;
  } else if (b < 600) {
    int u = (b - 588) * 256 + tid;
    float4 v = ((const float4*)W2d)[u];
    u16x4 o; o[0] = f2bf(v.x); o[1] = f2bf(v.y); o[2] = f2bf(v.z); o[3] = f2bf(v.w);
    ((u16x4*)W2dbf)[u] = o;
  } else if (b < 2328) {
    int u = (b - 600) * 256 + tid;
    float4 v = ((const float4*)Whh)[u];
    u16x4 oh, ol;
#pragma unroll
    for (int j = 0; j < 4; ++j) {
      float f = ((const float*)&v)[j];
      oh[j] = f2bf(f); ol[j] = f2bf(f - bf2f(oh[j]));
    }
    ((u16x4*)Whhh)[u] = oh; ((u16x4*)Whhl)[u] = ol;
  } else if (b < 2904) {
    int u = (b - 2328) * 256 + tid;  // Wm2 f4 index; emit TRANSPOSED hi/lo
    float4 v = ((const float4*)Wm2)[u];
    int e_lin = u * 4;
    int er = e_lin / H, kc = e_lin - er * H;
#pragma unroll
    for (int j = 0; j < 4; ++j) {
      float f = ((const float*)&v)[j];
      unsigned short hi = f2bf(f);
      Wm2th[(size_t)(kc + j) * H + er] = hi;
      Wm2tl[(size_t)(kc + j) * H + er] = f2bf(f - bf2f(hi));
    }
  } else if (b < 5208) {
    int u = (b - 2904) * 256 + tid;  // f4 index into W1cat [3072][768]
    int e = u * 4;
    int row = e / H, k = e - row * H;
    int part = row / H, o = row - part * H;
    const float* W = (part < 2) ? W1s : W1d;
    float4 v = *(const float4*)(W + (size_t)o * (2 * H) + (part & 1) * H + k);
    u16x4 ov; ov[0] = f2bf(v.x); ov[1] = f2bf(v.y); ov[2] = f2bf(v.z); ov[3] = f2bf(v.w);
    *(u16x4*)(W1cat + e) = ov;
    if (u < 768) {
      int e2 = u * 4, pp = e2 / H, oo = e2 - pp * H;
      float4 bv;
      if (pp == 0) bv = *(const float4*)(b1s + oo);
      else if (pp == 2) bv = *(const float4*)(b1d + oo);
      else bv = (float4){0.f, 0.f, 0.f, 0.f};
      *(float4*)(b1cat + e2) = bv;
    }
  } else if (b < 5784) {
    // bc[g] = bih[g] + sum_e Wih[g][e]*bm2[e]
    const int w = tid >> 6, l = tid & 63;
    const int gg = (b - 5208) * 4 + w;
    const float* row = Wih + (size_t)gg * H;
    float s = 0.f;
#pragma unroll
    for (int q = 0; q < 12; ++q) s += row[l + q * 64] * bm2[l + q * 64];
#pragma unroll
    for (int m = 32; m; m >>= 1) s += __shfl_xor(s, m);
    if (l == 0) bc[gg] = bih[gg] + s;
  } else {
    int u = (b - 5784) * 256 + tid;  // f4 index, 36864
    float4 v = (u < 12288) ? ((const float4*)asp)[u] : ((const float4*)qry)[u - 12288];
    ((float4*)h)[u] = v;
    u16x4 oh, ol;
#pragma unroll
    for (int j = 0; j < 4; ++j) {
      float f = ((const float*)&v)[j];
      oh[j] = f2bf(f); ol[j] = f2bf(f - bf2f(oh[j]));
    }
    ((u16x4*)hhi)[u] = oh; ((u16x4*)hlo)[u] = ol;
  }
}

// ---------------- Wc = Wih @ Wm2t^T (hilo x hilo), 128x128 tiles ------------
// A = Wih fp32, reg-staged with in-register hi/lo split; B = Wm2t bf16 hi/lo
// via global_load_lds. Output Wch/Wcl [2304][768]. Grid 108 = 18(M) x 6(N).
__global__ __launch_bounds__(256) void k_wc(
    const float* __restrict__ Wih, const unsigned short* __restrict__ Bth,
    const unsigned short* __restrict__ Btl, unsigned short* __restrict__ Ch,
    unsigned short* __restrict__ Cl) {
  __shared__ unsigned short Ahl[8192], All[8192], Bhl[8192], Bll[8192];
  const int bid = blockIdx.x;
  const int mt = bid / 6, nti = bid % 6;
  const int m0 = mt * 128, n0 = nti * 128;
  const int tid = threadIdx.x, w = tid >> 6, l = tid & 63;
  const int g = l >> 4, ln = l & 15;
  const int wr = w >> 1, wc = w & 1;
  const int srow = l >> 3;
  const int skb = ((l & 7) ^ srow) * 8;
  const unsigned short* Bgh = Bth + (size_t)(n0 + srow) * H + skb;
  const unsigned short* Bgl = Btl + (size_t)(n0 + srow) * H + skb;
  f32x4 acc[4][4];
#pragma unroll
  for (int mi = 0; mi < 4; ++mi)
#pragma unroll
    for (int ni = 0; ni < 4; ++ni) acc[mi][ni] = (f32x4){0.f, 0.f, 0.f, 0.f};
  const int x7 = ln & 15 & 7;
  for (int kb = 0; kb < H; kb += 64) {
#pragma unroll
    for (int c4 = 0; c4 < 4; ++c4) {
      const int c = w * 4 + c4;
      GLDS16(Bgh + (size_t)(c * 8) * H + kb, &Bhl[c * 512]);
      GLDS16(Bgl + (size_t)(c * 8) * H + kb, &Bll[c * 512]);
    }
    // A: reg-staged fp32 -> hi/lo bf16, pre-swizzled ds_write
#pragma unroll
    for (int q = 0; q < 4; ++q) {
      const int idx = q * 256 + tid;
      const int row = idx >> 3, kb8 = idx & 7;
      const float* src = Wih + (size_t)(m0 + row) * H + kb + kb8 * 8;
      float4 v0 = *(const float4*)src;
      float4 v1 = *(const float4*)(src + 4);
      float fv[8] = {v0.x, v0.y, v0.z, v0.w, v1.x, v1.y, v1.z, v1.w};
      u16x8 oh, ol;
#pragma unroll
      for (int jq = 0; jq < 8; ++jq) {
        unsigned short hi = f2bf(fv[jq]);
        oh[jq] = hi;
        ol[jq] = f2bf(fv[jq] - bf2f(hi));
      }
      const int dst = row * 64 + (kb8 ^ (row & 7)) * 8;
      *(u16x8*)&Ahl[dst] = oh;
      *(u16x8*)&All[dst] = ol;
    }
    __syncthreads();
#pragma unroll
    for (int kk = 0; kk < 2; ++kk) {
      const int pb = ((kk * 4 + g) ^ x7) * 8;
      u16x8 ahf[4], alf[4], bhf[4], blf[4];
#pragma unroll
      for (int mi = 0; mi < 4; ++mi) {
        ahf[mi] = ld8(&Ahl[(wr * 64 + mi * 16 + ln) * 64 + pb]);
        alf[mi] = ld8(&All[(wr * 64 + mi * 16 + ln) * 64 + pb]);
      }
#pragma unroll
      for (int ni = 0; ni < 4; ++ni) {
        bhf[ni] = ld8(&Bhl[(wc * 64 + ni * 16 + ln) * 64 + pb]);
        blf[ni] = ld8(&Bll[(wc * 64 + ni * 16 + ln) * 64 + pb]);
      }
#pragma unroll
      for (int mi = 0; mi < 4; ++mi)
#pragma unroll
        for (int ni = 0; ni < 4; ++ni) {
          acc[mi][ni] = MFMA(ahf[mi], bhf[ni], acc[mi][ni]);
          acc[mi][ni] = MFMA(ahf[mi], blf[ni], acc[mi][ni]);
          acc[mi][ni] = MFMA(alf[mi], bhf[ni], acc[mi][ni]);
        }
    }
    __syncthreads();
  }
#pragma unroll
  for (int mi = 0; mi < 4; ++mi) {
#pragma unroll
    for (int ni = 0; ni < 4; ++ni) {
      const int col = n0 + wc * 64 + ni * 16 + ln;
#pragma unroll
      for (int pp = 0; pp < 4; ++pp) {
        const int row = m0 + wr * 64 + mi * 16 + g * 4 + pp;
        const float val = acc[mi][ni][pp];
        unsigned short hi = f2bf(val);
        Ch[(size_t)row * H + col] = hi;
        Cl[(size_t)row * H + col] = f2bf(val - bf2f(hi));
      }
    }
  }
}

// ---------------- RsW GEMM half (16 z-matrices), FUSED fp32-R conversion ----
// B (R) read as fp32 from d_in, cvt_pk to bf16 in regs, pre-swizzled ds_write.
// Output rows PERMUTED: row = d*32 + (zbase+z).
__global__ __launch_bounds__(256) void k_rsw2f(const unsigned short* __restrict__ Wm1bf,
                                               const float* __restrict__ Rf,
                                               unsigned short* __restrict__ RsWt, int zbase) {
  __shared__ unsigned short Asl[8192];
  __shared__ unsigned short Bsl[8192];
  const int wg = blockIdx.x;                      // 576
  const int nb = (wg & 7) * 72 + (wg >> 3);       // chunked XCD swizzle
  const int z = nb / 36, t = nb - z * 36;
  const int d0 = (t / 6) * 128, k0 = (t - (t / 6) * 6) * 128;
  const int tid = threadIdx.x, w = tid >> 6, l = tid & 63;
  const int g = l >> 4, ln = l & 15;
  const int wr = w >> 1, wc = w & 1;
  const int srow = l >> 3;
  const int skb = ((l & 7) ^ srow) * 8;
  const unsigned short* Ag = Wm1bf + (size_t)(d0 + srow) * H + skb;
  const float* Bg = Rf + (size_t)z * (H * H);
  f32x4 acc[4][4];
#pragma unroll
  for (int mi = 0; mi < 4; ++mi)
#pragma unroll
    for (int ni = 0; ni < 4; ++ni) acc[mi][ni] = (f32x4){0.f, 0.f, 0.f, 0.f};
  const int x7 = ln & 7;
  for (int kb = 0; kb < H; kb += 64) {
#pragma unroll
    for (int c4 = 0; c4 < 4; ++c4) {
      const int c = w * 4 + c4;
      GLDS16(Ag + (size_t)(c * 8) * H + kb, &Asl[c * 512]);
    }
#pragma unroll
    for (int q = 0; q < 4; ++q) {
      const int idx = q * 256 + tid;
      const int row = idx >> 3, kb8 = idx & 7;
      const float* src = Bg + (size_t)(k0 + row) * H + kb + kb8 * 8;
      float4 v0 = *(const float4*)src;
      float4 v1 = *(const float4*)(src + 4);
      u16x8 o;
      unsigned int* po = (unsigned int*)&o;
      po[0] = cvtpk(v0.x, v0.y);
      po[1] = cvtpk(v0.z, v0.w);
      po[2] = cvtpk(v1.x, v1.y);
      po[3] = cvtpk(v1.z, v1.w);
      *(u16x8*)&Bsl[row * 64 + (kb8 ^ (row & 7)) * 8] = o;
    }
    __syncthreads();
#pragma unroll
    for (int kk = 0; kk < 2; ++kk) {
      u16x8 af[4], bf[4];
      const int pb = ((kk * 4 + g) ^ x7) * 8;
#pragma unroll
      for (int mi = 0; mi < 4; ++mi) af[mi] = ld8(&Asl[(wr * 64 + mi * 16 + ln) * 64 + pb]);
#pragma unroll
      for (int ni = 0; ni < 4; ++ni) bf[ni] = ld8(&Bsl[(wc * 64 + ni * 16 + ln) * 64 + pb]);
#pragma unroll
      for (int mi = 0; mi < 4; ++mi)
#pragma unroll
        for (int ni = 0; ni < 4; ++ni) acc[mi][ni] = MFMA(af[mi], bf[ni], acc[mi][ni]);
    }
    __syncthreads();
  }
#pragma unroll
  for (int mi = 0; mi < 4; ++mi) {
    const int d = d0 + wr * 64 + mi * 16 + g * 4;
#pragma unroll
    for (int ni = 0; ni < 4; ++ni) {
      const int k = k0 + wc * 64 + ni * 16 + ln;
      unsigned short* o = RsWt + ((size_t)d * 32 + zbase + z) * H + k;
#pragma unroll
      for (int pp = 0; pp < 4; ++pp) o[(size_t)pp * 32 * H] = f2bf(acc[mi][ni][pp]);
    }
  }
}

// ---------------- K-split(4) hilo GEMM for gx (no bias, raw partials) -------
__global__ __launch_bounds__(256) void k_btks(
    const unsigned short* __restrict__ Ahi, const unsigned short* __restrict__ Alo,
    const unsigned short* __restrict__ Bhi, const unsigned short* __restrict__ Blo,
    float* __restrict__ Cp) {
  const int tid = threadIdx.x;
  const int w = tid >> 6, l = tid & 63, g = l >> 4, ln = l & 15;
  const int m0 = blockIdx.y * 64 + w * 16;
  const int n0 = blockIdx.x * 64;
  const int kh = blockIdx.z, kb0 = kh * 192;
  const unsigned short* aph = Ahi + (size_t)(m0 + ln) * H + kb0 + g * 8;
  const unsigned short* apl = Alo + (size_t)(m0 + ln) * H + kb0 + g * 8;
  const unsigned short* bph[4];
  const unsigned short* bpl[4];
#pragma unroll
  for (int nt = 0; nt < 4; ++nt) {
    bph[nt] = Bhi + (size_t)(n0 + nt * 16 + ln) * H + kb0 + g * 8;
    bpl[nt] = Blo + (size_t)(n0 + nt * 16 + ln) * H + kb0 + g * 8;
  }
  f32x4 acc[4];
#pragma unroll
  for (int nt = 0; nt < 4; ++nt) acc[nt] = (f32x4){0.f, 0.f, 0.f, 0.f};
  u16x8 ah[2], al[2], bh[2][4], bl[2][4];
  ah[0] = ld8(aph);
  al[0] = ld8(apl);
#pragma unroll
  for (int nt = 0; nt < 4; ++nt) { bh[0][nt] = ld8(bph[nt]); bl[0][nt] = ld8(bpl[nt]); }
#pragma unroll
  for (int t = 0; t < 6; ++t) {
    const int cur = t & 1, nxt = cur ^ 1;
    if (t < 5) {
      const int ko = (t + 1) * 32;
      ah[nxt] = ld8(aph + ko);
      al[nxt] = ld8(apl + ko);
#pragma unroll
      for (int nt = 0; nt < 4; ++nt) {
        bh[nxt][nt] = ld8(bph[nt] + ko);
        bl[nxt][nt] = ld8(bpl[nt] + ko);
      }
    }
#pragma unroll
    for (int nt = 0; nt < 4; ++nt) {
      acc[nt] = MFMA(ah[cur], bh[cur][nt], acc[nt]);
      acc[nt] = MFMA(ah[cur], bl[cur][nt], acc[nt]);
      acc[nt] = MFMA(al[cur], bh[cur][nt], acc[nt]);
    }
  }
#pragma unroll
  for (int nt = 0; nt < 4; ++nt) {
    const int col = n0 + nt * 16 + ln;
#pragma unroll
    for (int pp = 0; pp < 4; ++pp) {
      const int row = m0 + g * 4 + pp;
      Cp[(size_t)kh * (NTOT * GW) + (size_t)row * GW + col] = acc[nt][pp];
    }
  }
}

// ---------------- merged per-step GEMM: A4 | gh | twB -----------------------
__global__ __launch_bounds__(256) void k_step1(
    const unsigned short* __restrict__ hhi, const unsigned short* __restrict__ hlo,
    const unsigned short* __restrict__ W1cat, const float* __restrict__ b1cat,
    const unsigned short* __restrict__ Whhh, const unsigned short* __restrict__ Whhl,
    const float* __restrict__ bhh, const unsigned short* __restrict__ RsWt,
    float* __restrict__ A4, float* __restrict__ ghb, unsigned short* __restrict__ twB) {
  const int bid = blockIdx.x;
  const int tid = threadIdx.x, w = tid >> 6, l = tid & 63, g = l >> 4, ln = l & 15;
  if (bid >= 252) {
    const int n0 = (bid - 252) * 64;
    const unsigned short* ap[3];
#pragma unroll
    for (int jt = 0; jt < 3; ++jt) ap[jt] = hhi + (size_t)(w * 48 + jt * 16 + ln) * H + g * 8;
    const unsigned short* bp[4];
#pragma unroll
    for (int nt = 0; nt < 4; ++nt) bp[nt] = RsWt + (size_t)(n0 + nt * 16 + ln) * H + g * 8;
    f32x4 acc[3][4];
#pragma unroll
    for (int jt = 0; jt < 3; ++jt)
#pragma unroll
      for (int nt = 0; nt < 4; ++nt) acc[jt][nt] = (f32x4){0.f, 0.f, 0.f, 0.f};
    u16x8 a[2][3], b[2][4];
#pragma unroll
    for (int jt = 0; jt < 3; ++jt) a[0][jt] = ld8(ap[jt]);
#pragma unroll
    for (int nt = 0; nt < 4; ++nt) b[0][nt] = ld8(bp[nt]);
#pragma unroll
    for (int t = 0; t < 24; ++t) {
      const int cur = t & 1, nxt = cur ^ 1;
      if (t < 23) {
        const int ko = (t + 1) * 32;
#pragma unroll
        for (int jt = 0; jt < 3; ++jt) a[nxt][jt] = ld8(ap[jt] + ko);
#pragma unroll
        for (int nt = 0; nt < 4; ++nt) b[nxt][nt] = ld8(bp[nt] + ko);
      }
#pragma unroll
      for (int jt = 0; jt < 3; ++jt)
#pragma unroll
        for (int nt = 0; nt < 4; ++nt) acc[jt][nt] = MFMA(a[cur][jt], b[cur][nt], acc[jt][nt]);
    }
#pragma unroll
    for (int nt = 0; nt < 4; ++nt) {
      const int c = n0 + nt * 16 + ln;
#pragma unroll
      for (int jt = 0; jt < 3; ++jt)
#pragma unroll
        for (int pp = 0; pp < 4; ++pp) {
          const int j = w * 48 + jt * 16 + g * 4 + pp;
          twB[(size_t)j * 24576 + c] = f2bf(acc[jt][nt][pp]);
        }
    }
    return;
  }
  const bool isgh = bid >= 144;
  const int b2 = isgh ? bid - 144 : bid;
  const int nx = isgh ? (b2 % 36) : (b2 % 48);
  const int my = isgh ? (b2 / 36) : (b2 / 48);
  const int N = isgh ? GW : A4W;
  const unsigned short* Bh = isgh ? Whhh : W1cat;
  const unsigned short* Bl = Whhl;
  const float* bias = isgh ? bhh : b1cat;
  float* C = isgh ? ghb : A4;
  const int m0 = my * 64 + w * 16, n0 = nx * 64;
  const unsigned short* aph = hhi + (size_t)(m0 + ln) * H + g * 8;
  const unsigned short* apl = hlo + (size_t)(m0 + ln) * H + g * 8;
  const unsigned short* bph[4];
  const unsigned short* bpl[4];
#pragma unroll
  for (int nt = 0; nt < 4; ++nt) {
    bph[nt] = Bh + (size_t)(n0 + nt * 16 + ln) * H + g * 8;
    bpl[nt] = Bl + (size_t)(n0 + nt * 16 + ln) * H + g * 8;
  }
  f32x4 acc[4];
#pragma unroll
  for (int nt = 0; nt < 4; ++nt) acc[nt] = (f32x4){0.f, 0.f, 0.f, 0.f};
  u16x8 ah[2], al[2], bh[2][4], bl[2][4];
  ah[0] = ld8(aph);
  if (isgh) al[0] = ld8(apl);
#pragma unroll
  for (int nt = 0; nt < 4; ++nt) {
    bh[0][nt] = ld8(bph[nt]);
    if (isgh) bl[0][nt] = ld8(bpl[nt]);
  }
#pragma unroll
  for (int t = 0; t < 24; ++t) {
    const int cur = t & 1, nxt = cur ^ 1;
    if (t < 23) {
      const int ko = (t + 1) * 32;
      ah[nxt] = ld8(aph + ko);
      if (isgh) al[nxt] = ld8(apl + ko);
#pragma unroll
      for (int nt = 0; nt < 4; ++nt) {
        bh[nxt][nt] = ld8(bph[nt] + ko);
        if (isgh) bl[nxt][nt] = ld8(bpl[nt] + ko);
      }
    }
#pragma unroll
    for (int nt = 0; nt < 4; ++nt) {
      acc[nt] = MFMA(ah[cur], bh[cur][nt], acc[nt]);
      if (isgh) {
        acc[nt] = MFMA(ah[cur], bl[cur][nt], acc[nt]);
        acc[nt] = MFMA(al[cur], bh[cur][nt], acc[nt]);
      }
    }
  }
#pragma unroll
  for (int nt = 0; nt < 4; ++nt) {
    const int col = n0 + nt * 16 + ln;
    const float bv = bias[col];
#pragma unroll
    for (int pp = 0; pp < 4; ++pp) {
      const int row = m0 + g * 4 + pp;
      C[(size_t)row * N + col] = acc[nt][pp] + bv;
    }
  }
}

// ---------------- pair logits + softmax -> swA[j][i][32] (bf16) -------------
__global__ __launch_bounds__(256) void k_pairlog(
    const float* __restrict__ A4, const unsigned short* __restrict__ W2sbf,
    const unsigned short* __restrict__ W2dbf, const float* __restrict__ b2s,
    const float* __restrict__ b2d, unsigned short* __restrict__ swA) {
  __shared__ float red[8][16][17];
  const int i = blockIdx.x, jb = blockIdx.y;
  const int tid = threadIdx.x, w = tid >> 6, l = tid & 63;
  const int g = l >> 4, ln = l & 15;
  const int j = jb * 16 + ln;
  const float* BsP = A4 + (size_t)j * A4W + 768 + g * 8;
  const float* BdP = A4 + (size_t)j * A4W + 2304 + g * 8;
  const float* AsP = A4 + (size_t)i * A4W + g * 8;
  const float* AdP = A4 + (size_t)i * A4W + 1536 + g * 8;
  const unsigned short* WsP = W2sbf + (size_t)ln * H + g * 8;
  const unsigned short* WdP = W2dbf + (size_t)ln * H + g * 8;
  f32x4 accs = (f32x4){0.f, 0.f, 0.f, 0.f}, accd = (f32x4){0.f, 0.f, 0.f, 0.f};
#pragma unroll
  for (int tt = 0; tt < 6; ++tt) {
    const int ko = (w * 6 + tt) * 32;
    float4 b0 = *(const float4*)(BsP + ko), b1 = *(const float4*)(BsP + ko + 4);
    float4 a0 = *(const float4*)(AsP + ko), a1 = *(const float4*)(AsP + ko + 4);
    float4 e0 = *(const float4*)(BdP + ko), e1 = *(const float4*)(BdP + ko + 4);
    float4 c0 = *(const float4*)(AdP + ko), c1 = *(const float4*)(AdP + ko + 4);
    u16x8 afs, afd;
    unsigned int* ps = (unsigned int*)&afs;
    ps[0] = cvtpk(relu(a0.x + b0.x), relu(a0.y + b0.y));
    ps[1] = cvtpk(relu(a0.z + b0.z), relu(a0.w + b0.w));
    ps[2] = cvtpk(relu(a1.x + b1.x), relu(a1.y + b1.y));
    ps[3] = cvtpk(relu(a1.z + b1.z), relu(a1.w + b1.w));
    unsigned int* pd = (unsigned int*)&afd;
    pd[0] = cvtpk(relu(c0.x + e0.x), relu(c0.y + e0.y));
    pd[1] = cvtpk(relu(c0.z + e0.z), relu(c0.w + e0.w));
    pd[2] = cvtpk(relu(c1.x + e1.x), relu(c1.y + e1.y));
    pd[3] = cvtpk(relu(c1.z + e1.z), relu(c1.w + e1.w));
    accs = MFMA(afs, ld8(WsP + ko), accs);
    accd = MFMA(afd, ld8(WdP + ko), accd);
  }
#pragma unroll
  for (int pp = 0; pp < 4; ++pp) {
    red[w * 2][g * 4 + pp][ln] = accs[pp];
    red[w * 2 + 1][g * 4 + pp][ln] = accd[pp];
  }
  __syncthreads();
  const int j2 = tid >> 4, r = tid & 15;
  float vs = red[0][j2][r] + red[2][j2][r] + red[4][j2][r] + red[6][j2][r] + b2s[r];
  float vd = red[1][j2][r] + red[3][j2][r] + red[5][j2][r] + red[7][j2][r] + b2d[r];
  float ms = vs;
  ms = fmaxf(ms, __shfl_xor(ms, 1)); ms = fmaxf(ms, __shfl_xor(ms, 2));
  ms = fmaxf(ms, __shfl_xor(ms, 4)); ms = fmaxf(ms, __shfl_xor(ms, 8));
  float md = vd;
  md = fmaxf(md, __shfl_xor(md, 1)); md = fmaxf(md, __shfl_xor(md, 2));
  md = fmaxf(md, __shfl_xor(md, 4)); md = fmaxf(md, __shfl_xor(md, 8));
  float es = __expf(vs - ms), ed = __expf(vd - md);
  float ss = es;
  ss += __shfl_xor(ss, 1); ss += __shfl_xor(ss, 2); ss += __shfl_xor(ss, 4); ss += __shfl_xor(ss, 8);
  float sd = ed;
  sd += __shfl_xor(sd, 1); sd += __shfl_xor(sd, 2); sd += __shfl_xor(sd, 4); sd += __shfl_xor(sd, 8);
  const size_t o = (size_t)(jb * 16 + j2) * 6144 + (size_t)i * 32;
  swA[o + r] = f2bf(es / ss);
  swA[o + 16 + r] = f2bf(ed / sd);
}

// ---------------- per-pair weighted message + relu + sum_j -> v_part --------
__global__ __launch_bounds__(256) void k_pairmsg(const unsigned short* __restrict__ swA,
                                                 const unsigned short* __restrict__ twB,
                                                 const float* __restrict__ bm1,
                                                 float* __restrict__ vpart) {
  const int dt = blockIdx.x, it = blockIdx.y, js = blockIdx.z;
  const int tid = threadIdx.x;
  const int w = tid >> 6, l = tid & 63, g = l >> 4, ln = l & 15;
  const int i0 = it * 64 + w * 16;
  const int d0 = dt * 64;
  float bm1v[4];
#pragma unroll
  for (int nt = 0; nt < 4; ++nt) bm1v[nt] = bm1[d0 + nt * 16 + ln];
  f32x4 vacc[4];
#pragma unroll
  for (int nt = 0; nt < 4; ++nt) vacc[nt] = (f32x4){0.f, 0.f, 0.f, 0.f};
  const unsigned short* ap = swA + (size_t)(i0 + ln) * 32 + g * 8 + (size_t)js * 24 * 6144;
  const unsigned short* bp[4];
#pragma unroll
  for (int nt = 0; nt < 4; ++nt)
    bp[nt] = twB + (size_t)(d0 + nt * 16 + ln) * 32 + g * 8 + (size_t)js * 24 * 24576;
  const f32x4 z4 = (f32x4){0.f, 0.f, 0.f, 0.f};
#pragma unroll 4
  for (int jj = 0; jj < 24; ++jj) {
    u16x8 a = ld8(ap + (size_t)jj * 6144);
#pragma unroll
    for (int nt = 0; nt < 4; ++nt) {
      u16x8 b = ld8(bp[nt] + (size_t)jj * 24576);
      f32x4 mf = MFMA(a, b, z4);
#pragma unroll
      for (int pp = 0; pp < 4; ++pp) vacc[nt][pp] += fmaxf(mf[pp] + bm1v[nt], 0.f);
    }
  }
#pragma unroll
  for (int nt = 0; nt < 4; ++nt)
#pragma unroll
    for (int pp = 0; pp < 4; ++pp) {
      const int row = i0 + g * 4 + pp;
      vpart[(size_t)js * 147456 + (size_t)row * H + d0 + nt * 16 + ln] = vacc[nt][pp];
    }
}

__global__ void k_vred(const float* __restrict__ vpart, unsigned short* __restrict__ vhi,
                       unsigned short* __restrict__ vlo) {
  int e = blockIdx.x * 256 + threadIdx.x;  // 147456
  float s = 0.f;
#pragma unroll
  for (int q = 0; q < 8; ++q) s += vpart[(size_t)q * 147456 + e];
  s *= (1.0f / 192.0f);
  unsigned short hi = f2bf(s);
  vhi[e] = hi;
  vlo[e] = f2bf(s - bf2f(hi));
}

__global__ void k_gru(const float* __restrict__ gxp, const float* __restrict__ bcv,
                      const float* __restrict__ gh, float* __restrict__ h,
                      unsigned short* __restrict__ hhi, unsigned short* __restrict__ hlo,
                      float* __restrict__ out, int last) {
  int e = blockIdx.x * 256 + threadIdx.x;  // 147456
  int i = e / H, k = e - i * H;
  size_t base = (size_t)i * GW;
  const size_t S = (size_t)NTOT * GW;
  float rr = gxp[base + k] + gxp[S + base + k] + gxp[2 * S + base + k] +
             gxp[3 * S + base + k] + bcv[k] + gh[base + k];
  float zz = gxp[base + H + k] + gxp[S + base + H + k] + gxp[2 * S + base + H + k] +
             gxp[3 * S + base + H + k] + bcv[H + k] + gh[base + H + k];
  float r = 1.f / (1.f + __expf(-rr));
  float z = 1.f / (1.f + __expf(-zz));
  float nn = gxp[base + 2 * H + k] + gxp[S + base + 2 * H + k] +
             gxp[2 * S + base + 2 * H + k] + gxp[3 * S + base + 2 * H + k] +
             bcv[2 * H + k];
  float n = tanhf(nn + r * gh[base + 2 * H + k]);
  float hv = (1.f - z) * n + z * h[e];
  h[e] = hv;
  unsigned short hi = f2bf(hv);
  hhi[e] = hi;
  hlo[e] = f2bf(hv - bf2f(hi));
  if (last && i >= 64) out[(size_t)(i - 64) * H + k] = hv;
}

// ---------------- launch ----------------------------------------------------

extern "C" void kernel_launch(void* const* d_in, const int* in_sizes, int n_in,
                              void* d_out, int out_size, void* d_ws, size_t ws_size,
                              hipStream_t stream) {
  const float* asp = (const float*)d_in[0];
  const float* qry = (const float*)d_in[1];
  const float* W1s = (const float*)d_in[3];
  const float* b1s = (const float*)d_in[4];
  const float* W2s = (const float*)d_in[5];
  const float* b2s = (const float*)d_in[6];
  const float* W1d = (const float*)d_in[7];
  const float* b1d = (const float*)d_in[8];
  const float* W2d = (const float*)d_in[9];
  const float* b2d = (const float*)d_in[10];
  const float* Rs  = (const float*)d_in[11];
  const float* Rd  = (const float*)d_in[12];
  const float* Wm1 = (const float*)d_in[13];
  const float* bm1 = (const float*)d_in[14];
  const float* Wm2 = (const float*)d_in[15];
  const float* bm2 = (const float*)d_in[16];
  const float* Wih = (const float*)d_in[17];
  const float* Whh = (const float*)d_in[18];
  const float* bih = (const float*)d_in[19];
  const float* bhh = (const float*)d_in[20];
  float* out = (float*)d_out;

  char* p = (char*)d_ws;
  auto take = [&](size_t bytes) {
    char* q = p;
    p += (bytes + 255) & ~(size_t)255;
    return q;
  };
  // ---- step-scratch region, aliased during prep ----
  float* h            = (float*)take((size_t)NTOT * H * 4);
  unsigned short* hhi = (unsigned short*)take((size_t)NTOT * H * 2);
  unsigned short* hlo = (unsigned short*)take((size_t)NTOT * H * 2);
  float* A4           = (float*)take((size_t)NTOT * A4W * 4);
  float* ghb          = (float*)take((size_t)NTOT * GW * 4);
  unsigned short* vhi = (unsigned short*)take((size_t)NTOT * H * 2);
  unsigned short* vlo = (unsigned short*)take((size_t)NTOT * H * 2);
  float* vpart        = (float*)take((size_t)8 * NTOT * H * 4);
  unsigned short* swA = (unsigned short*)take((size_t)NTOT * NTOT * 32 * 2);
  unsigned short* twB = (unsigned short*)take((size_t)NTOT * H * 32 * 2);  // also gx partials
  // ---- permanent weights ----
  unsigned short* RsWt = (unsigned short*)take((size_t)2 * 16 * H * H * 2);
  unsigned short* Wm1bf = (unsigned short*)take((size_t)H * H * 2);
  unsigned short* W2sbf = (unsigned short*)take((size_t)16 * H * 2);
  unsigned short* W2dbf = (unsigned short*)take((size_t)16 * H * 2);
  unsigned short* W1cat = (unsigned short*)take((size_t)A4W * H * 2);
  float* b1cat        = (float*)take((size_t)A4W * 4);
  unsigned short* Whhh = (unsigned short*)take((size_t)GW * H * 2);
  unsigned short* Whhl = (unsigned short*)take((size_t)GW * H * 2);
  unsigned short* Wch  = (unsigned short*)take((size_t)GW * H * 2);
  unsigned short* Wcl  = (unsigned short*)take((size_t)GW * H * 2);
  float* bc           = (float*)take((size_t)GW * 4);
  // ---- prep-phase aliases (within step-scratch, after h/hhi/hlo @1,179,648) ----
  unsigned short* Wm2th = (unsigned short*)((char*)d_ws + 1179648);
  unsigned short* Wm2tl = Wm2th + (size_t)H * H;  // ends ~3.54 MB

  // ---- once-per-launch prep ----
  k_prep<<<5928, 256, 0, stream>>>(Wm1, W2s, W2d, Whh, Wih, Wm2, W1s, W1d, b1s, b1d,
                                   bm2, bih, asp, qry,
                                   Wm1bf, W2sbf, W2dbf, Whhh, Whhl,
                                   Wm2th, Wm2tl, W1cat, b1cat, bc, h, hhi, hlo);
  k_wc<<<108, 256, 0, stream>>>(Wih, Wm2th, Wm2tl, Wch, Wcl);
  k_rsw2f<<<576, 256, 0, stream>>>(Wm1bf, Rs, RsWt, 0);
  k_rsw2f<<<576, 256, 0, stream>>>(Wm1bf, Rd, RsWt, 16);

  // ---- propagation steps ----
  for (int step = 0; step < 3; ++step) {
    k_step1<<<636, 256, 0, stream>>>(hhi, hlo, W1cat, b1cat, Whhh, Whhl, bhh, RsWt,
                                     A4, ghb, twB);
    k_pairlog<<<dim3(192, 12), 256, 0, stream>>>(A4, W2sbf, W2dbf, b2s, b2d, swA);
    k_pairmsg<<<dim3(12, 3, 8), 256, 0, stream>>>(swA, twB, bm1, vpart);
    k_vred<<<576, 256, 0, stream>>>(vpart, vhi, vlo);
    k_btks<<<dim3(36, 3, 4), 256, 0, stream>>>(vhi, vlo, Wch, Wcl, (float*)twB);
    k_gru<<<576, 256, 0, stream>>>((float*)twB, bc, ghb, h, hhi, hlo, out, step == 2);
  }
  (void)in_sizes; (void)n_in; (void)out_size; (void)ws_size;
}

// Round 6
// 595.029 us; speedup vs baseline: 1.6197x; 1.0297x over previous
//
#include <hip/hip_runtime.h>
#include <hip/hip_bf16.h>

#define H 768
#define NTOT 192
#define A4W 3072
#define GW 2304

typedef __attribute__((ext_vector_type(4))) float f32x4;
typedef __attribute__((ext_vector_type(8))) unsigned short u16x8;
typedef __attribute__((ext_vector_type(4))) unsigned short u16x4;
typedef __attribute__((ext_vector_type(8))) __bf16 bf16x8v;

static __device__ __forceinline__ unsigned short f2bf(float f) {
  __hip_bfloat16 b = __float2bfloat16(f);
  return __builtin_bit_cast(unsigned short, b);
}
static __device__ __forceinline__ float bf2f(unsigned short u) {
  return __bfloat162float(__builtin_bit_cast(__hip_bfloat16, u));
}
static __device__ __forceinline__ f32x4 MFMA(u16x8 a, u16x8 b, f32x4 c) {
  return __builtin_amdgcn_mfma_f32_16x16x32_bf16(
      __builtin_bit_cast(bf16x8v, a), __builtin_bit_cast(bf16x8v, b), c, 0, 0, 0);
}
static __device__ __forceinline__ u16x8 ld8(const unsigned short* p) {
  return *(const u16x8*)p;
}
static __device__ __forceinline__ unsigned int cvtpk(float lo, float hi) {
  unsigned int r;
  asm("v_cvt_pk_bf16_f32 %0, %1, %2" : "=v"(r) : "v"(lo), "v"(hi));
  return r;
}
static __device__ __forceinline__ float relu(float x) { return fmaxf(x, 0.f); }

#define GLDS16(gp, lp)                                                   \
  __builtin_amdgcn_global_load_lds(                                      \
      (const __attribute__((address_space(1))) void*)(gp),               \
      (__attribute__((address_space(3))) void*)(lp), 16, 0, 0)

// ---------------- fused prep: weight conversions + bc + inith --------------
// segments: Wm1 576 | W2s 12 | W2d 12 | Whh 1728 | Wm2t 576 | W1cat 2304 |
//           bc 576 | inith 144  => grid 5928
__global__ void k_prep(const float* __restrict__ Wm1, const float* __restrict__ W2s,
                       const float* __restrict__ W2d, const float* __restrict__ Whh,
                       const float* __restrict__ Wih, const float* __restrict__ Wm2,
                       const float* __restrict__ W1s, const float* __restrict__ W1d,
                       const float* __restrict__ b1s, const float* __restrict__ b1d,
                       const float* __restrict__ bm2, const float* __restrict__ bih,
                       const float* __restrict__ asp, const float* __restrict__ qry,
                       unsigned short* __restrict__ Wm1bf, unsigned short* __restrict__ W2sbf,
                       unsigned short* __restrict__ W2dbf, unsigned short* __restrict__ Whhh,
                       unsigned short* __restrict__ Whhl, unsigned short* __restrict__ Wm2th,
                       unsigned short* __restrict__ Wm2tl, unsigned short* __restrict__ W1cat,
                       float* __restrict__ b1cat, float* __restrict__ bc,
                       float* __restrict__ h, unsigned short* __restrict__ hhi,
                       unsigned short* __restrict__ hlo) {
  const int b = blockIdx.x, tid = threadIdx.x;
  if (b < 576) {
    int u = b * 256 + tid;
    float4 v = ((const float4*)Wm1)[u];
    u16x4 o; o[0] = f2bf(v.x); o[1] = f2bf(v.y); o[2] = f2bf(v.z); o[3] = f2bf(v.w);
    ((u16x4*)Wm1bf)[u] = o;
  } else if (b < 588) {
    int u = (b - 576) * 256 + tid;
    float4 v = ((const float4*)W2s)[u];
    u16x4 o; o[0] = f2bf(v.x); o[1] = f2bf(v.y); o[2] = f2bf(v.z); o[3] = f2bf(v.w);
    ((u16x4*)W2sbf)[u] = o;
  } else if (b < 600) {
    int u = (b - 588) * 256 + tid;
    float4 v = ((const float4*)W2d)[u];
    u16x4 o; o[0] = f2bf(v.x); o[1] = f2bf(v.y); o[2] = f2bf(v.z); o[3] = f2bf(v.w);
    ((u16x4*)W2dbf)[u] = o;
  } else if (b < 2328) {
    int u = (b - 600) * 256 + tid;
    float4 v = ((const float4*)Whh)[u];
    u16x4 oh, ol;
#pragma unroll
    for (int j = 0; j < 4; ++j) {
      float f = ((const float*)&v)[j];
      oh[j] = f2bf(f); ol[j] = f2bf(f - bf2f(oh[j]));
    }
    ((u16x4*)Whhh)[u] = oh; ((u16x4*)Whhl)[u] = ol;
  } else if (b < 2904) {
    int u = (b - 2328) * 256 + tid;  // Wm2 f4 index; emit TRANSPOSED hi/lo
    float4 v = ((const float4*)Wm2)[u];
    int e_lin = u * 4;
    int er = e_lin / H, kc = e_lin - er * H;
#pragma unroll
    for (int j = 0; j < 4; ++j) {
      float f = ((const float*)&v)[j];
      unsigned short hi = f2bf(f);
      Wm2th[(size_t)(kc + j) * H + er] = hi;
      Wm2tl[(size_t)(kc + j) * H + er] = f2bf(f - bf2f(hi));
    }
  } else if (b < 5208) {
    int u = (b - 2904) * 256 + tid;  // f4 index into W1cat [3072][768]
    int e = u * 4;
    int row = e / H, k = e - row * H;
    int part = row / H, o = row - part * H;
    const float* W = (part < 2) ? W1s : W1d;
    float4 v = *(const float4*)(W + (size_t)o * (2 * H) + (part & 1) * H + k);
    u16x4 ov; ov[0] = f2bf(v.x); ov[1] = f2bf(v.y); ov[2] = f2bf(v.z); ov[3] = f2bf(v.w);
    *(u16x4*)(W1cat + e) = ov;
    if (u < 768) {
      int e2 = u * 4, pp = e2 / H, oo = e2 - pp * H;
      float4 bv;
      if (pp == 0) bv = *(const float4*)(b1s + oo);
      else if (pp == 2) bv = *(const float4*)(b1d + oo);
      else bv = (float4){0.f, 0.f, 0.f, 0.f};
      *(float4*)(b1cat + e2) = bv;
    }
  } else if (b < 5784) {
    // bc[g] = bih[g] + sum_e Wih[g][e]*bm2[e]
    const int w = tid >> 6, l = tid & 63;
    const int gg = (b - 5208) * 4 + w;
    const float* row = Wih + (size_t)gg * H;
    float s = 0.f;
#pragma unroll
    for (int q = 0; q < 12; ++q) s += row[l + q * 64] * bm2[l + q * 64];
#pragma unroll
    for (int m = 32; m; m >>= 1) s += __shfl_xor(s, m);
    if (l == 0) bc[gg] = bih[gg] + s;
  } else {
    int u = (b - 5784) * 256 + tid;  // f4 index, 36864
    float4 v = (u < 12288) ? ((const float4*)asp)[u] : ((const float4*)qry)[u - 12288];
    ((float4*)h)[u] = v;
    u16x4 oh, ol;
#pragma unroll
    for (int j = 0; j < 4; ++j) {
      float f = ((const float*)&v)[j];
      oh[j] = f2bf(f); ol[j] = f2bf(f - bf2f(oh[j]));
    }
    ((u16x4*)hhi)[u] = oh; ((u16x4*)hlo)[u] = ol;
  }
}

// ---------------- Wc = Wih @ Wm2t^T (hilo x hilo), 128x128 tiles ------------
__global__ __launch_bounds__(256) void k_wc(
    const float* __restrict__ Wih, const unsigned short* __restrict__ Bth,
    const unsigned short* __restrict__ Btl, unsigned short* __restrict__ Ch,
    unsigned short* __restrict__ Cl) {
  __shared__ unsigned short Ahl[8192], All[8192], Bhl[8192], Bll[8192];
  const int bid = blockIdx.x;
  const int mt = bid / 6, nti = bid % 6;
  const int m0 = mt * 128, n0 = nti * 128;
  const int tid = threadIdx.x, w = tid >> 6, l = tid & 63;
  const int g = l >> 4, ln = l & 15;
  const int wr = w >> 1, wc = w & 1;
  const int srow = l >> 3;
  const int skb = ((l & 7) ^ srow) * 8;
  const unsigned short* Bgh = Bth + (size_t)(n0 + srow) * H + skb;
  const unsigned short* Bgl = Btl + (size_t)(n0 + srow) * H + skb;
  f32x4 acc[4][4];
#pragma unroll
  for (int mi = 0; mi < 4; ++mi)
#pragma unroll
    for (int ni = 0; ni < 4; ++ni) acc[mi][ni] = (f32x4){0.f, 0.f, 0.f, 0.f};
  const int x7 = ln & 7;
  for (int kb = 0; kb < H; kb += 64) {
#pragma unroll
    for (int c4 = 0; c4 < 4; ++c4) {
      const int c = w * 4 + c4;
      GLDS16(Bgh + (size_t)(c * 8) * H + kb, &Bhl[c * 512]);
      GLDS16(Bgl + (size_t)(c * 8) * H + kb, &Bll[c * 512]);
    }
#pragma unroll
    for (int q = 0; q < 4; ++q) {
      const int idx = q * 256 + tid;
      const int row = idx >> 3, kb8 = idx & 7;
      const float* src = Wih + (size_t)(m0 + row) * H + kb + kb8 * 8;
      float4 v0 = *(const float4*)src;
      float4 v1 = *(const float4*)(src + 4);
      float fv[8] = {v0.x, v0.y, v0.z, v0.w, v1.x, v1.y, v1.z, v1.w};
      u16x8 oh, ol;
#pragma unroll
      for (int jq = 0; jq < 8; ++jq) {
        unsigned short hi = f2bf(fv[jq]);
        oh[jq] = hi;
        ol[jq] = f2bf(fv[jq] - bf2f(hi));
      }
      const int dst = row * 64 + (kb8 ^ (row & 7)) * 8;
      *(u16x8*)&Ahl[dst] = oh;
      *(u16x8*)&All[dst] = ol;
    }
    __syncthreads();
#pragma unroll
    for (int kk = 0; kk < 2; ++kk) {
      const int pb = ((kk * 4 + g) ^ x7) * 8;
      u16x8 ahf[4], alf[4], bhf[4], blf[4];
#pragma unroll
      for (int mi = 0; mi < 4; ++mi) {
        ahf[mi] = ld8(&Ahl[(wr * 64 + mi * 16 + ln) * 64 + pb]);
        alf[mi] = ld8(&All[(wr * 64 + mi * 16 + ln) * 64 + pb]);
      }
#pragma unroll
      for (int ni = 0; ni < 4; ++ni) {
        bhf[ni] = ld8(&Bhl[(wc * 64 + ni * 16 + ln) * 64 + pb]);
        blf[ni] = ld8(&Bll[(wc * 64 + ni * 16 + ln) * 64 + pb]);
      }
#pragma unroll
      for (int mi = 0; mi < 4; ++mi)
#pragma unroll
        for (int ni = 0; ni < 4; ++ni) {
          acc[mi][ni] = MFMA(ahf[mi], bhf[ni], acc[mi][ni]);
          acc[mi][ni] = MFMA(ahf[mi], blf[ni], acc[mi][ni]);
          acc[mi][ni] = MFMA(alf[mi], bhf[ni], acc[mi][ni]);
        }
    }
    __syncthreads();
  }
#pragma unroll
  for (int mi = 0; mi < 4; ++mi) {
#pragma unroll
    for (int ni = 0; ni < 4; ++ni) {
      const int col = n0 + wc * 64 + ni * 16 + ln;
#pragma unroll
      for (int pp = 0; pp < 4; ++pp) {
        const int row = m0 + wr * 64 + mi * 16 + g * 4 + pp;
        const float val = acc[mi][ni][pp];
        unsigned short hi = f2bf(val);
        Ch[(size_t)row * H + col] = hi;
        Cl[(size_t)row * H + col] = f2bf(val - bf2f(hi));
      }
    }
  }
}

// ---------------- RsW GEMM, BOTH sets in one dispatch (grid 1152) -----------
// z in [0,32): z<16 -> Rs[z], else Rd[z-16]. Output rows: row = d*32 + z.
__global__ __launch_bounds__(256) void k_rsw2f(const unsigned short* __restrict__ Wm1bf,
                                               const float* __restrict__ Rsf,
                                               const float* __restrict__ Rdf,
                                               unsigned short* __restrict__ RsWt) {
  __shared__ unsigned short Asl[8192];
  __shared__ unsigned short Bsl[8192];
  const int wg = blockIdx.x;                       // 1152
  const int nb = (wg & 7) * 144 + (wg >> 3);       // chunked XCD swizzle
  const int z = nb / 36, t = nb - z * 36;
  const int d0 = (t / 6) * 128, k0 = (t - (t / 6) * 6) * 128;
  const int tid = threadIdx.x, w = tid >> 6, l = tid & 63;
  const int g = l >> 4, ln = l & 15;
  const int wr = w >> 1, wc = w & 1;
  const int srow = l >> 3;
  const int skb = ((l & 7) ^ srow) * 8;
  const unsigned short* Ag = Wm1bf + (size_t)(d0 + srow) * H + skb;
  const float* Bg = ((z < 16) ? Rsf : Rdf) + (size_t)(z & 15) * (H * H);
  f32x4 acc[4][4];
#pragma unroll
  for (int mi = 0; mi < 4; ++mi)
#pragma unroll
    for (int ni = 0; ni < 4; ++ni) acc[mi][ni] = (f32x4){0.f, 0.f, 0.f, 0.f};
  const int x7 = ln & 7;
  for (int kb = 0; kb < H; kb += 64) {
#pragma unroll
    for (int c4 = 0; c4 < 4; ++c4) {
      const int c = w * 4 + c4;
      GLDS16(Ag + (size_t)(c * 8) * H + kb, &Asl[c * 512]);
    }
#pragma unroll
    for (int q = 0; q < 4; ++q) {
      const int idx = q * 256 + tid;
      const int row = idx >> 3, kb8 = idx & 7;
      const float* src = Bg + (size_t)(k0 + row) * H + kb + kb8 * 8;
      float4 v0 = *(const float4*)src;
      float4 v1 = *(const float4*)(src + 4);
      u16x8 o;
      unsigned int* po = (unsigned int*)&o;
      po[0] = cvtpk(v0.x, v0.y);
      po[1] = cvtpk(v0.z, v0.w);
      po[2] = cvtpk(v1.x, v1.y);
      po[3] = cvtpk(v1.z, v1.w);
      *(u16x8*)&Bsl[row * 64 + (kb8 ^ (row & 7)) * 8] = o;
    }
    __syncthreads();
#pragma unroll
    for (int kk = 0; kk < 2; ++kk) {
      u16x8 af[4], bf[4];
      const int pb = ((kk * 4 + g) ^ x7) * 8;
#pragma unroll
      for (int mi = 0; mi < 4; ++mi) af[mi] = ld8(&Asl[(wr * 64 + mi * 16 + ln) * 64 + pb]);
#pragma unroll
      for (int ni = 0; ni < 4; ++ni) bf[ni] = ld8(&Bsl[(wc * 64 + ni * 16 + ln) * 64 + pb]);
#pragma unroll
      for (int mi = 0; mi < 4; ++mi)
#pragma unroll
        for (int ni = 0; ni < 4; ++ni) acc[mi][ni] = MFMA(af[mi], bf[ni], acc[mi][ni]);
    }
    __syncthreads();
  }
#pragma unroll
  for (int mi = 0; mi < 4; ++mi) {
    const int d = d0 + wr * 64 + mi * 16 + g * 4;
#pragma unroll
    for (int ni = 0; ni < 4; ++ni) {
      const int k = k0 + wc * 64 + ni * 16 + ln;
      unsigned short* o = RsWt + ((size_t)d * 32 + z) * H + k;
#pragma unroll
      for (int pp = 0; pp < 4; ++pp) o[(size_t)pp * 32 * H] = f2bf(acc[mi][ni][pp]);
    }
  }
}

// ---------------- K-split(4) hilo GEMM for gx (no bias, raw partials) -------
__global__ __launch_bounds__(256) void k_btks(
    const unsigned short* __restrict__ Ahi, const unsigned short* __restrict__ Alo,
    const unsigned short* __restrict__ Bhi, const unsigned short* __restrict__ Blo,
    float* __restrict__ Cp) {
  const int tid = threadIdx.x;
  const int w = tid >> 6, l = tid & 63, g = l >> 4, ln = l & 15;
  const int m0 = blockIdx.y * 64 + w * 16;
  const int n0 = blockIdx.x * 64;
  const int kh = blockIdx.z, kb0 = kh * 192;
  const unsigned short* aph = Ahi + (size_t)(m0 + ln) * H + kb0 + g * 8;
  const unsigned short* apl = Alo + (size_t)(m0 + ln) * H + kb0 + g * 8;
  const unsigned short* bph[4];
  const unsigned short* bpl[4];
#pragma unroll
  for (int nt = 0; nt < 4; ++nt) {
    bph[nt] = Bhi + (size_t)(n0 + nt * 16 + ln) * H + kb0 + g * 8;
    bpl[nt] = Blo + (size_t)(n0 + nt * 16 + ln) * H + kb0 + g * 8;
  }
  f32x4 acc[4];
#pragma unroll
  for (int nt = 0; nt < 4; ++nt) acc[nt] = (f32x4){0.f, 0.f, 0.f, 0.f};
  u16x8 ah[2], al[2], bh[2][4], bl[2][4];
  ah[0] = ld8(aph);
  al[0] = ld8(apl);
#pragma unroll
  for (int nt = 0; nt < 4; ++nt) { bh[0][nt] = ld8(bph[nt]); bl[0][nt] = ld8(bpl[nt]); }
#pragma unroll
  for (int t = 0; t < 6; ++t) {
    const int cur = t & 1, nxt = cur ^ 1;
    if (t < 5) {
      const int ko = (t + 1) * 32;
      ah[nxt] = ld8(aph + ko);
      al[nxt] = ld8(apl + ko);
#pragma unroll
      for (int nt = 0; nt < 4; ++nt) {
        bh[nxt][nt] = ld8(bph[nt] + ko);
        bl[nxt][nt] = ld8(bpl[nt] + ko);
      }
    }
#pragma unroll
    for (int nt = 0; nt < 4; ++nt) {
      acc[nt] = MFMA(ah[cur], bh[cur][nt], acc[nt]);
      acc[nt] = MFMA(ah[cur], bl[cur][nt], acc[nt]);
      acc[nt] = MFMA(al[cur], bh[cur][nt], acc[nt]);
    }
  }
#pragma unroll
  for (int nt = 0; nt < 4; ++nt) {
    const int col = n0 + nt * 16 + ln;
#pragma unroll
    for (int pp = 0; pp < 4; ++pp) {
      const int row = m0 + g * 4 + pp;
      Cp[(size_t)kh * (NTOT * GW) + (size_t)row * GW + col] = acc[nt][pp];
    }
  }
}

// ---------------- merged per-step GEMM: A4 | gh | twB (depth-4 B prefetch) --
__global__ __launch_bounds__(256) void k_step1(
    const unsigned short* __restrict__ hhi, const unsigned short* __restrict__ hlo,
    const unsigned short* __restrict__ W1cat, const float* __restrict__ b1cat,
    const unsigned short* __restrict__ Whhh, const unsigned short* __restrict__ Whhl,
    const float* __restrict__ bhh, const unsigned short* __restrict__ RsWt,
    float* __restrict__ A4, float* __restrict__ ghb, unsigned short* __restrict__ twB) {
  const int bid = blockIdx.x;
  const int tid = threadIdx.x, w = tid >> 6, l = tid & 63, g = l >> 4, ln = l & 15;
  if (bid >= 252) {
    // ----- twB path: tw = h @ RsWt^T ; N axis is (d,set,r)
    const int n0 = (bid - 252) * 64;
    const unsigned short* ap[3];
#pragma unroll
    for (int jt = 0; jt < 3; ++jt) ap[jt] = hhi + (size_t)(w * 48 + jt * 16 + ln) * H + g * 8;
    const unsigned short* bp[4];
#pragma unroll
    for (int nt = 0; nt < 4; ++nt) bp[nt] = RsWt + (size_t)(n0 + nt * 16 + ln) * H + g * 8;
    f32x4 acc[3][4];
#pragma unroll
    for (int jt = 0; jt < 3; ++jt)
#pragma unroll
      for (int nt = 0; nt < 4; ++nt) acc[jt][nt] = (f32x4){0.f, 0.f, 0.f, 0.f};
    u16x8 a[2][3], b[4][4];
#pragma unroll
    for (int jt = 0; jt < 3; ++jt) a[0][jt] = ld8(ap[jt]);
#pragma unroll
    for (int d = 0; d < 3; ++d)
#pragma unroll
      for (int nt = 0; nt < 4; ++nt) b[d][nt] = ld8(bp[nt] + d * 32);
#pragma unroll
    for (int t = 0; t < 24; ++t) {
      const int c2 = t & 1, c4 = t & 3;
      if (t < 23) {
        const int ko = (t + 1) * 32;
#pragma unroll
        for (int jt = 0; jt < 3; ++jt) a[c2 ^ 1][jt] = ld8(ap[jt] + ko);
      }
      if (t < 21) {
        const int ko = (t + 3) * 32;
#pragma unroll
        for (int nt = 0; nt < 4; ++nt) b[(t + 3) & 3][nt] = ld8(bp[nt] + ko);
      }
#pragma unroll
      for (int jt = 0; jt < 3; ++jt)
#pragma unroll
        for (int nt = 0; nt < 4; ++nt) acc[jt][nt] = MFMA(a[c2][jt], b[c4][nt], acc[jt][nt]);
    }
#pragma unroll
    for (int nt = 0; nt < 4; ++nt) {
      const int c = n0 + nt * 16 + ln;
#pragma unroll
      for (int jt = 0; jt < 3; ++jt)
#pragma unroll
        for (int pp = 0; pp < 4; ++pp) {
          const int j = w * 48 + jt * 16 + g * 4 + pp;
          twB[(size_t)j * 24576 + c] = f2bf(acc[jt][nt][pp]);
        }
    }
    return;
  }
  // ----- bt path (A4 plain / gh hilo), depth-4 B prefetch
  const bool isgh = bid >= 144;
  const int b2 = isgh ? bid - 144 : bid;
  const int nx = isgh ? (b2 % 36) : (b2 % 48);
  const int my = isgh ? (b2 / 36) : (b2 / 48);
  const int N = isgh ? GW : A4W;
  const unsigned short* Bh = isgh ? Whhh : W1cat;
  const unsigned short* Bl = Whhl;
  const float* bias = isgh ? bhh : b1cat;
  float* C = isgh ? ghb : A4;
  const int m0 = my * 64 + w * 16, n0 = nx * 64;
  const unsigned short* aph = hhi + (size_t)(m0 + ln) * H + g * 8;
  const unsigned short* apl = hlo + (size_t)(m0 + ln) * H + g * 8;
  const unsigned short* bph[4];
  const unsigned short* bpl[4];
#pragma unroll
  for (int nt = 0; nt < 4; ++nt) {
    bph[nt] = Bh + (size_t)(n0 + nt * 16 + ln) * H + g * 8;
    bpl[nt] = Bl + (size_t)(n0 + nt * 16 + ln) * H + g * 8;
  }
  f32x4 acc[4];
#pragma unroll
  for (int nt = 0; nt < 4; ++nt) acc[nt] = (f32x4){0.f, 0.f, 0.f, 0.f};
  u16x8 ah[2], al[2], bh[4][4], bl[4][4];
  ah[0] = ld8(aph);
  if (isgh) al[0] = ld8(apl);
#pragma unroll
  for (int d = 0; d < 3; ++d)
#pragma unroll
    for (int nt = 0; nt < 4; ++nt) {
      bh[d][nt] = ld8(bph[nt] + d * 32);
      if (isgh) bl[d][nt] = ld8(bpl[nt] + d * 32);
    }
#pragma unroll
  for (int t = 0; t < 24; ++t) {
    const int c2 = t & 1, c4 = t & 3;
    if (t < 23) {
      const int ko = (t + 1) * 32;
      ah[c2 ^ 1] = ld8(aph + ko);
      if (isgh) al[c2 ^ 1] = ld8(apl + ko);
    }
    if (t < 21) {
      const int ko = (t + 3) * 32;
#pragma unroll
      for (int nt = 0; nt < 4; ++nt) {
        bh[(t + 3) & 3][nt] = ld8(bph[nt] + ko);
        if (isgh) bl[(t + 3) & 3][nt] = ld8(bpl[nt] + ko);
      }
    }
#pragma unroll
    for (int nt = 0; nt < 4; ++nt) {
      acc[nt] = MFMA(ah[c2], bh[c4][nt], acc[nt]);
      if (isgh) {
        acc[nt] = MFMA(ah[c2], bl[c4][nt], acc[nt]);
        acc[nt] = MFMA(al[c2], bh[c4][nt], acc[nt]);
      }
    }
  }
#pragma unroll
  for (int nt = 0; nt < 4; ++nt) {
    const int col = n0 + nt * 16 + ln;
    const float bv = bias[col];
#pragma unroll
    for (int pp = 0; pp < 4; ++pp) {
      const int row = m0 + g * 4 + pp;
      C[(size_t)row * N + col] = acc[nt][pp] + bv;
    }
  }
}

// ---------------- pair logits + softmax -> swA[j][i][32] (bf16) -------------
__global__ __launch_bounds__(256) void k_pairlog(
    const float* __restrict__ A4, const unsigned short* __restrict__ W2sbf,
    const unsigned short* __restrict__ W2dbf, const float* __restrict__ b2s,
    const float* __restrict__ b2d, unsigned short* __restrict__ swA) {
  __shared__ float red[8][16][17];
  const int i = blockIdx.x, jb = blockIdx.y;
  const int tid = threadIdx.x, w = tid >> 6, l = tid & 63;
  const int g = l >> 4, ln = l & 15;
  const int j = jb * 16 + ln;
  const float* BsP = A4 + (size_t)j * A4W + 768 + g * 8;
  const float* BdP = A4 + (size_t)j * A4W + 2304 + g * 8;
  const float* AsP = A4 + (size_t)i * A4W + g * 8;
  const float* AdP = A4 + (size_t)i * A4W + 1536 + g * 8;
  const unsigned short* WsP = W2sbf + (size_t)ln * H + g * 8;
  const unsigned short* WdP = W2dbf + (size_t)ln * H + g * 8;
  f32x4 accs = (f32x4){0.f, 0.f, 0.f, 0.f}, accd = (f32x4){0.f, 0.f, 0.f, 0.f};
#pragma unroll
  for (int tt = 0; tt < 6; ++tt) {
    const int ko = (w * 6 + tt) * 32;
    float4 b0 = *(const float4*)(BsP + ko), b1 = *(const float4*)(BsP + ko + 4);
    float4 a0 = *(const float4*)(AsP + ko), a1 = *(const float4*)(AsP + ko + 4);
    float4 e0 = *(const float4*)(BdP + ko), e1 = *(const float4*)(BdP + ko + 4);
    float4 c0 = *(const float4*)(AdP + ko), c1 = *(const float4*)(AdP + ko + 4);
    u16x8 afs, afd;
    unsigned int* ps = (unsigned int*)&afs;
    ps[0] = cvtpk(relu(a0.x + b0.x), relu(a0.y + b0.y));
    ps[1] = cvtpk(relu(a0.z + b0.z), relu(a0.w + b0.w));
    ps[2] = cvtpk(relu(a1.x + b1.x), relu(a1.y + b1.y));
    ps[3] = cvtpk(relu(a1.z + b1.z), relu(a1.w + b1.w));
    unsigned int* pd = (unsigned int*)&afd;
    pd[0] = cvtpk(relu(c0.x + e0.x), relu(c0.y + e0.y));
    pd[1] = cvtpk(relu(c0.z + e0.z), relu(c0.w + e0.w));
    pd[2] = cvtpk(relu(c1.x + e1.x), relu(c1.y + e1.y));
    pd[3] = cvtpk(relu(c1.z + e1.z), relu(c1.w + e1.w));
    accs = MFMA(afs, ld8(WsP + ko), accs);
    accd = MFMA(afd, ld8(WdP + ko), accd);
  }
#pragma unroll
  for (int pp = 0; pp < 4; ++pp) {
    red[w * 2][g * 4 + pp][ln] = accs[pp];
    red[w * 2 + 1][g * 4 + pp][ln] = accd[pp];
  }
  __syncthreads();
  const int j2 = tid >> 4, r = tid & 15;
  float vs = red[0][j2][r] + red[2][j2][r] + red[4][j2][r] + red[6][j2][r] + b2s[r];
  float vd = red[1][j2][r] + red[3][j2][r] + red[5][j2][r] + red[7][j2][r] + b2d[r];
  float ms = vs;
  ms = fmaxf(ms, __shfl_xor(ms, 1)); ms = fmaxf(ms, __shfl_xor(ms, 2));
  ms = fmaxf(ms, __shfl_xor(ms, 4)); ms = fmaxf(ms, __shfl_xor(ms, 8));
  float md = vd;
  md = fmaxf(md, __shfl_xor(md, 1)); md = fmaxf(md, __shfl_xor(md, 2));
  md = fmaxf(md, __shfl_xor(md, 4)); md = fmaxf(md, __shfl_xor(md, 8));
  float es = __expf(vs - ms), ed = __expf(vd - md);
  float ss = es;
  ss += __shfl_xor(ss, 1); ss += __shfl_xor(ss, 2); ss += __shfl_xor(ss, 4); ss += __shfl_xor(ss, 8);
  float sd = ed;
  sd += __shfl_xor(sd, 1); sd += __shfl_xor(sd, 2); sd += __shfl_xor(sd, 4); sd += __shfl_xor(sd, 8);
  const size_t o = (size_t)(jb * 16 + j2) * 6144 + (size_t)i * 32;
  swA[o + r] = f2bf(es / ss);
  swA[o + 16 + r] = f2bf(ed / sd);
}

// ---------------- per-pair weighted message + relu + sum_j -> v_part --------
__global__ __launch_bounds__(256) void k_pairmsg(const unsigned short* __restrict__ swA,
                                                 const unsigned short* __restrict__ twB,
                                                 const float* __restrict__ bm1,
                                                 float* __restrict__ vpart) {
  const int dt = blockIdx.x, it = blockIdx.y, js = blockIdx.z;
  const int tid = threadIdx.x;
  const int w = tid >> 6, l = tid & 63, g = l >> 4, ln = l & 15;
  const int i0 = it * 64 + w * 16;
  const int d0 = dt * 64;
  float bm1v[4];
#pragma unroll
  for (int nt = 0; nt < 4; ++nt) bm1v[nt] = bm1[d0 + nt * 16 + ln];
  f32x4 vacc[4];
#pragma unroll
  for (int nt = 0; nt < 4; ++nt) vacc[nt] = (f32x4){0.f, 0.f, 0.f, 0.f};
  const unsigned short* ap = swA + (size_t)(i0 + ln) * 32 + g * 8 + (size_t)js * 24 * 6144;
  const unsigned short* bp[4];
#pragma unroll
  for (int nt = 0; nt < 4; ++nt)
    bp[nt] = twB + (size_t)(d0 + nt * 16 + ln) * 32 + g * 8 + (size_t)js * 24 * 24576;
  const f32x4 z4 = (f32x4){0.f, 0.f, 0.f, 0.f};
#pragma unroll 4
  for (int jj = 0; jj < 24; ++jj) {
    u16x8 a = ld8(ap + (size_t)jj * 6144);
#pragma unroll
    for (int nt = 0; nt < 4; ++nt) {
      u16x8 b = ld8(bp[nt] + (size_t)jj * 24576);
      f32x4 mf = MFMA(a, b, z4);
#pragma unroll
      for (int pp = 0; pp < 4; ++pp) vacc[nt][pp] += fmaxf(mf[pp] + bm1v[nt], 0.f);
    }
  }
#pragma unroll
  for (int nt = 0; nt < 4; ++nt)
#pragma unroll
    for (int pp = 0; pp < 4; ++pp) {
      const int row = i0 + g * 4 + pp;
      vpart[(size_t)js * 147456 + (size_t)row * H + d0 + nt * 16 + ln] = vacc[nt][pp];
    }
}

__global__ void k_vred(const float* __restrict__ vpart, unsigned short* __restrict__ vhi,
                       unsigned short* __restrict__ vlo) {
  int e = blockIdx.x * 256 + threadIdx.x;  // 147456
  float s = 0.f;
#pragma unroll
  for (int q = 0; q < 8; ++q) s += vpart[(size_t)q * 147456 + e];
  s *= (1.0f / 192.0f);
  unsigned short hi = f2bf(s);
  vhi[e] = hi;
  vlo[e] = f2bf(s - bf2f(hi));
}

__global__ void k_gru(const float* __restrict__ gxp, const float* __restrict__ bcv,
                      const float* __restrict__ gh, float* __restrict__ h,
                      unsigned short* __restrict__ hhi, unsigned short* __restrict__ hlo,
                      float* __restrict__ out, int last) {
  int e = blockIdx.x * 256 + threadIdx.x;  // 147456
  int i = e / H, k = e - i * H;
  size_t base = (size_t)i * GW;
  const size_t S = (size_t)NTOT * GW;
  float rr = gxp[base + k] + gxp[S + base + k] + gxp[2 * S + base + k] +
             gxp[3 * S + base + k] + bcv[k] + gh[base + k];
  float zz = gxp[base + H + k] + gxp[S + base + H + k] + gxp[2 * S + base + H + k] +
             gxp[3 * S + base + H + k] + bcv[H + k] + gh[base + H + k];
  float r = 1.f / (1.f + __expf(-rr));
  float z = 1.f / (1.f + __expf(-zz));
  float nn = gxp[base + 2 * H + k] + gxp[S + base + 2 * H + k] +
             gxp[2 * S + base + 2 * H + k] + gxp[3 * S + base + 2 * H + k] +
             bcv[2 * H + k];
  float n = tanhf(nn + r * gh[base + 2 * H + k]);
  float hv = (1.f - z) * n + z * h[e];
  h[e] = hv;
  unsigned short hi = f2bf(hv);
  hhi[e] = hi;
  hlo[e] = f2bf(hv - bf2f(hi));
  if (last && i >= 64) out[(size_t)(i - 64) * H + k] = hv;
}

// ---------------- launch ----------------------------------------------------

extern "C" void kernel_launch(void* const* d_in, const int* in_sizes, int n_in,
                              void* d_out, int out_size, void* d_ws, size_t ws_size,
                              hipStream_t stream) {
  const float* asp = (const float*)d_in[0];
  const float* qry = (const float*)d_in[1];
  const float* W1s = (const float*)d_in[3];
  const float* b1s = (const float*)d_in[4];
  const float* W2s = (const float*)d_in[5];
  const float* b2s = (const float*)d_in[6];
  const float* W1d = (const float*)d_in[7];
  const float* b1d = (const float*)d_in[8];
  const float* W2d = (const float*)d_in[9];
  const float* b2d = (const float*)d_in[10];
  const float* Rs  = (const float*)d_in[11];
  const float* Rd  = (const float*)d_in[12];
  const float* Wm1 = (const float*)d_in[13];
  const float* bm1 = (const float*)d_in[14];
  const float* Wm2 = (const float*)d_in[15];
  const float* bm2 = (const float*)d_in[16];
  const float* Wih = (const float*)d_in[17];
  const float* Whh = (const float*)d_in[18];
  const float* bih = (const float*)d_in[19];
  const float* bhh = (const float*)d_in[20];
  float* out = (float*)d_out;

  char* p = (char*)d_ws;
  auto take = [&](size_t bytes) {
    char* q = p;
    p += (bytes + 255) & ~(size_t)255;
    return q;
  };
  // ---- step-scratch region, aliased during prep ----
  float* h            = (float*)take((size_t)NTOT * H * 4);
  unsigned short* hhi = (unsigned short*)take((size_t)NTOT * H * 2);
  unsigned short* hlo = (unsigned short*)take((size_t)NTOT * H * 2);
  float* A4           = (float*)take((size_t)NTOT * A4W * 4);
  float* ghb          = (float*)take((size_t)NTOT * GW * 4);
  unsigned short* vhi = (unsigned short*)take((size_t)NTOT * H * 2);
  unsigned short* vlo = (unsigned short*)take((size_t)NTOT * H * 2);
  float* vpart        = (float*)take((size_t)8 * NTOT * H * 4);
  unsigned short* swA = (unsigned short*)take((size_t)NTOT * NTOT * 32 * 2);
  unsigned short* twB = (unsigned short*)take((size_t)NTOT * H * 32 * 2);  // also gx partials
  // ---- permanent weights ----
  unsigned short* RsWt = (unsigned short*)take((size_t)2 * 16 * H * H * 2);
  unsigned short* Wm1bf = (unsigned short*)take((size_t)H * H * 2);
  unsigned short* W2sbf = (unsigned short*)take((size_t)16 * H * 2);
  unsigned short* W2dbf = (unsigned short*)take((size_t)16 * H * 2);
  unsigned short* W1cat = (unsigned short*)take((size_t)A4W * H * 2);
  float* b1cat        = (float*)take((size_t)A4W * 4);
  unsigned short* Whhh = (unsigned short*)take((size_t)GW * H * 2);
  unsigned short* Whhl = (unsigned short*)take((size_t)GW * H * 2);
  unsigned short* Wch  = (unsigned short*)take((size_t)GW * H * 2);
  unsigned short* Wcl  = (unsigned short*)take((size_t)GW * H * 2);
  float* bc           = (float*)take((size_t)GW * 4);
  // ---- prep-phase aliases (within step-scratch, after h/hhi/hlo @1,179,648) ----
  unsigned short* Wm2th = (unsigned short*)((char*)d_ws + 1179648);
  unsigned short* Wm2tl = Wm2th + (size_t)H * H;  // ends ~3.54 MB

  // ---- once-per-launch prep ----
  k_prep<<<5928, 256, 0, stream>>>(Wm1, W2s, W2d, Whh, Wih, Wm2, W1s, W1d, b1s, b1d,
                                   bm2, bih, asp, qry,
                                   Wm1bf, W2sbf, W2dbf, Whhh, Whhl,
                                   Wm2th, Wm2tl, W1cat, b1cat, bc, h, hhi, hlo);
  k_wc<<<108, 256, 0, stream>>>(Wih, Wm2th, Wm2tl, Wch, Wcl);
  k_rsw2f<<<1152, 256, 0, stream>>>(Wm1bf, Rs, Rd, RsWt);

  // ---- propagation steps ----
  for (int step = 0; step < 3; ++step) {
    k_step1<<<636, 256, 0, stream>>>(hhi, hlo, W1cat, b1cat, Whhh, Whhl, bhh, RsWt,
                                     A4, ghb, twB);
    k_pairlog<<<dim3(192, 12), 256, 0, stream>>>(A4, W2sbf, W2dbf, b2s, b2d, swA);
    k_pairmsg<<<dim3(12, 3, 8), 256, 0, stream>>>(swA, twB, bm1, vpart);
    k_vred<<<576, 256, 0, stream>>>(vpart, vhi, vlo);
    k_btks<<<dim3(36, 3, 4), 256, 0, stream>>>(vhi, vlo, Wch, Wcl, (float*)twB);
    k_gru<<<576, 256, 0, stream>>>((float*)twB, bc, ghb, h, hhi, hlo, out, step == 2);
  }
  (void)in_sizes; (void)n_in; (void)out_size; (void)ws_size;
}

// Round 7
// 543.017 us; speedup vs baseline: 1.7748x; 1.0958x over previous
//
#include <hip/hip_runtime.h>
#include <hip/hip_bf16.h>

#define H 768
#define NTOT 192
#define A4W 3072
#define GW 2304

typedef __attribute__((ext_vector_type(4))) float f32x4;
typedef __attribute__((ext_vector_type(8))) unsigned short u16x8;
typedef __attribute__((ext_vector_type(4))) unsigned short u16x4;
typedef __attribute__((ext_vector_type(8))) __bf16 bf16x8v;

static __device__ __forceinline__ unsigned short f2bf(float f) {
  __hip_bfloat16 b = __float2bfloat16(f);
  return __builtin_bit_cast(unsigned short, b);
}
static __device__ __forceinline__ float bf2f(unsigned short u) {
  return __bfloat162float(__builtin_bit_cast(__hip_bfloat16, u));
}
static __device__ __forceinline__ f32x4 MFMA(u16x8 a, u16x8 b, f32x4 c) {
  return __builtin_amdgcn_mfma_f32_16x16x32_bf16(
      __builtin_bit_cast(bf16x8v, a), __builtin_bit_cast(bf16x8v, b), c, 0, 0, 0);
}
static __device__ __forceinline__ u16x8 ld8(const unsigned short* p) {
  return *(const u16x8*)p;
}
static __device__ __forceinline__ unsigned int cvtpk(float lo, float hi) {
  unsigned int r;
  asm("v_cvt_pk_bf16_f32 %0, %1, %2" : "=v"(r) : "v"(lo), "v"(hi));
  return r;
}
static __device__ __forceinline__ float relu(float x) { return fmaxf(x, 0.f); }

#define GLDS16(gp, lp)                                                   \
  __builtin_amdgcn_global_load_lds(                                      \
      (const __attribute__((address_space(1))) void*)(gp),               \
      (__attribute__((address_space(3))) void*)(lp), 16, 0, 0)

// ---------------- fused prep: weight conversions + bc + inith --------------
// segments: Wm1 576 | W2s 12 | W2d 12 | Whh 1728 | Wm2t 576 | W1cat 2304 |
//           bc 576 | inith 144  => grid 5928
__global__ void k_prep(const float* __restrict__ Wm1, const float* __restrict__ W2s,
                       const float* __restrict__ W2d, const float* __restrict__ Whh,
                       const float* __restrict__ Wih, const float* __restrict__ Wm2,
                       const float* __restrict__ W1s, const float* __restrict__ W1d,
                       const float* __restrict__ b1s, const float* __restrict__ b1d,
                       const float* __restrict__ bm2, const float* __restrict__ bih,
                       const float* __restrict__ asp, const float* __restrict__ qry,
                       unsigned short* __restrict__ Wm1bf, unsigned short* __restrict__ W2sbf,
                       unsigned short* __restrict__ W2dbf, unsigned short* __restrict__ Whhh,
                       unsigned short* __restrict__ Whhl, unsigned short* __restrict__ Wm2th,
                       unsigned short* __restrict__ Wm2tl, unsigned short* __restrict__ W1cat,
                       float* __restrict__ b1cat, float* __restrict__ bc,
                       float* __restrict__ h, unsigned short* __restrict__ hhi,
                       unsigned short* __restrict__ hlo) {
  const int b = blockIdx.x, tid = threadIdx.x;
  if (b < 576) {
    int u = b * 256 + tid;
    float4 v = ((const float4*)Wm1)[u];
    u16x4 o; o[0] = f2bf(v.x); o[1] = f2bf(v.y); o[2] = f2bf(v.z); o[3] = f2bf(v.w);
    ((u16x4*)Wm1bf)[u] = o;
  } else if (b < 588) {
    int u = (b - 576) * 256 + tid;
    float4 v = ((const float4*)W2s)[u];
    u16x4 o; o[0] = f2bf(v.x); o[1] = f2bf(v.y); o[2] = f2bf(v.z); o[3] = f2bf(v.w);
    ((u16x4*)W2sbf)[u] = o;
  } else if (b < 600) {
    int u = (b - 588) * 256 + tid;
    float4 v = ((const float4*)W2d)[u];
    u16x4 o; o[0] = f2bf(v.x); o[1] = f2bf(v.y); o[2] = f2bf(v.z); o[3] = f2bf(v.w);
    ((u16x4*)W2dbf)[u] = o;
  } else if (b < 2328) {
    int u = (b - 600) * 256 + tid;
    float4 v = ((const float4*)Whh)[u];
    u16x4 oh, ol;
#pragma unroll
    for (int j = 0; j < 4; ++j) {
      float f = ((const float*)&v)[j];
      oh[j] = f2bf(f); ol[j] = f2bf(f - bf2f(oh[j]));
    }
    ((u16x4*)Whhh)[u] = oh; ((u16x4*)Whhl)[u] = ol;
  } else if (b < 2904) {
    int u = (b - 2328) * 256 + tid;  // Wm2 f4 index; emit TRANSPOSED hi/lo
    float4 v = ((const float4*)Wm2)[u];
    int e_lin = u * 4;
    int er = e_lin / H, kc = e_lin - er * H;
#pragma unroll
    for (int j = 0; j < 4; ++j) {
      float f = ((const float*)&v)[j];
      unsigned short hi = f2bf(f);
      Wm2th[(size_t)(kc + j) * H + er] = hi;
      Wm2tl[(size_t)(kc + j) * H + er] = f2bf(f - bf2f(hi));
    }
  } else if (b < 5208) {
    int u = (b - 2904) * 256 + tid;  // f4 index into W1cat [3072][768]
    int e = u * 4;
    int row = e / H, k = e - row * H;
    int part = row / H, o = row - part * H;
    const float* W = (part < 2) ? W1s : W1d;
    float4 v = *(const float4*)(W + (size_t)o * (2 * H) + (part & 1) * H + k);
    u16x4 ov; ov[0] = f2bf(v.x); ov[1] = f2bf(v.y); ov[2] = f2bf(v.z); ov[3] = f2bf(v.w);
    *(u16x4*)(W1cat + e) = ov;
    if (u < 768) {
      int e2 = u * 4, pp = e2 / H, oo = e2 - pp * H;
      float4 bv;
      if (pp == 0) bv = *(const float4*)(b1s + oo);
      else if (pp == 2) bv = *(const float4*)(b1d + oo);
      else bv = (float4){0.f, 0.f, 0.f, 0.f};
      *(float4*)(b1cat + e2) = bv;
    }
  } else if (b < 5784) {
    // bc[g] = bih[g] + sum_e Wih[g][e]*bm2[e]
    const int w = tid >> 6, l = tid & 63;
    const int gg = (b - 5208) * 4 + w;
    const float* row = Wih + (size_t)gg * H;
    float s = 0.f;
#pragma unroll
    for (int q = 0; q < 12; ++q) s += row[l + q * 64] * bm2[l + q * 64];
#pragma unroll
    for (int m = 32; m; m >>= 1) s += __shfl_xor(s, m);
    if (l == 0) bc[gg] = bih[gg] + s;
  } else {
    int u = (b - 5784) * 256 + tid;  // f4 index, 36864
    float4 v = (u < 12288) ? ((const float4*)asp)[u] : ((const float4*)qry)[u - 12288];
    ((float4*)h)[u] = v;
    u16x4 oh, ol;
#pragma unroll
    for (int j = 0; j < 4; ++j) {
      float f = ((const float*)&v)[j];
      oh[j] = f2bf(f); ol[j] = f2bf(f - bf2f(oh[j]));
    }
    ((u16x4*)hhi)[u] = oh; ((u16x4*)hlo)[u] = ol;
  }
}

// ---------------- Wc = Wih @ Wm2t^T (hilo x hilo), 128x128 tiles ------------
__global__ __launch_bounds__(256) void k_wc(
    const float* __restrict__ Wih, const unsigned short* __restrict__ Bth,
    const unsigned short* __restrict__ Btl, unsigned short* __restrict__ Ch,
    unsigned short* __restrict__ Cl) {
  __shared__ unsigned short Ahl[8192], All[8192], Bhl[8192], Bll[8192];
  const int bid = blockIdx.x;
  const int mt = bid / 6, nti = bid % 6;
  const int m0 = mt * 128, n0 = nti * 128;
  const int tid = threadIdx.x, w = tid >> 6, l = tid & 63;
  const int g = l >> 4, ln = l & 15;
  const int wr = w >> 1, wc = w & 1;
  const int srow = l >> 3;
  const int skb = ((l & 7) ^ srow) * 8;
  const unsigned short* Bgh = Bth + (size_t)(n0 + srow) * H + skb;
  const unsigned short* Bgl = Btl + (size_t)(n0 + srow) * H + skb;
  f32x4 acc[4][4];
#pragma unroll
  for (int mi = 0; mi < 4; ++mi)
#pragma unroll
    for (int ni = 0; ni < 4; ++ni) acc[mi][ni] = (f32x4){0.f, 0.f, 0.f, 0.f};
  const int x7 = ln & 7;
  for (int kb = 0; kb < H; kb += 64) {
#pragma unroll
    for (int c4 = 0; c4 < 4; ++c4) {
      const int c = w * 4 + c4;
      GLDS16(Bgh + (size_t)(c * 8) * H + kb, &Bhl[c * 512]);
      GLDS16(Bgl + (size_t)(c * 8) * H + kb, &Bll[c * 512]);
    }
#pragma unroll
    for (int q = 0; q < 4; ++q) {
      const int idx = q * 256 + tid;
      const int row = idx >> 3, kb8 = idx & 7;
      const float* src = Wih + (size_t)(m0 + row) * H + kb + kb8 * 8;
      float4 v0 = *(const float4*)src;
      float4 v1 = *(const float4*)(src + 4);
      float fv[8] = {v0.x, v0.y, v0.z, v0.w, v1.x, v1.y, v1.z, v1.w};
      u16x8 oh, ol;
#pragma unroll
      for (int jq = 0; jq < 8; ++jq) {
        unsigned short hi = f2bf(fv[jq]);
        oh[jq] = hi;
        ol[jq] = f2bf(fv[jq] - bf2f(hi));
      }
      const int dst = row * 64 + (kb8 ^ (row & 7)) * 8;
      *(u16x8*)&Ahl[dst] = oh;
      *(u16x8*)&All[dst] = ol;
    }
    __syncthreads();
#pragma unroll
    for (int kk = 0; kk < 2; ++kk) {
      const int pb = ((kk * 4 + g) ^ x7) * 8;
      u16x8 ahf[4], alf[4], bhf[4], blf[4];
#pragma unroll
      for (int mi = 0; mi < 4; ++mi) {
        ahf[mi] = ld8(&Ahl[(wr * 64 + mi * 16 + ln) * 64 + pb]);
        alf[mi] = ld8(&All[(wr * 64 + mi * 16 + ln) * 64 + pb]);
      }
#pragma unroll
      for (int ni = 0; ni < 4; ++ni) {
        bhf[ni] = ld8(&Bhl[(wc * 64 + ni * 16 + ln) * 64 + pb]);
        blf[ni] = ld8(&Bll[(wc * 64 + ni * 16 + ln) * 64 + pb]);
      }
#pragma unroll
      for (int mi = 0; mi < 4; ++mi)
#pragma unroll
        for (int ni = 0; ni < 4; ++ni) {
          acc[mi][ni] = MFMA(ahf[mi], bhf[ni], acc[mi][ni]);
          acc[mi][ni] = MFMA(ahf[mi], blf[ni], acc[mi][ni]);
          acc[mi][ni] = MFMA(alf[mi], bhf[ni], acc[mi][ni]);
        }
    }
    __syncthreads();
  }
#pragma unroll
  for (int mi = 0; mi < 4; ++mi) {
#pragma unroll
    for (int ni = 0; ni < 4; ++ni) {
      const int col = n0 + wc * 64 + ni * 16 + ln;
#pragma unroll
      for (int pp = 0; pp < 4; ++pp) {
        const int row = m0 + wr * 64 + mi * 16 + g * 4 + pp;
        const float val = acc[mi][ni][pp];
        unsigned short hi = f2bf(val);
        Ch[(size_t)row * H + col] = hi;
        Cl[(size_t)row * H + col] = f2bf(val - bf2f(hi));
      }
    }
  }
}

// ---------------- RsW GEMM, both sets, DOUBLE-BUFFERED + pipelined B --------
// z in [0,32): z<16 -> Rs[z], else Rd[z-16]. Output rows: row = d*32 + z.
__global__ __launch_bounds__(256) void k_rsw2f(const unsigned short* __restrict__ Wm1bf,
                                               const float* __restrict__ Rsf,
                                               const float* __restrict__ Rdf,
                                               unsigned short* __restrict__ RsWt) {
  __shared__ unsigned short Asl[2][8192];
  __shared__ unsigned short Bsl[2][8192];
  const int wg = blockIdx.x;                       // 1152
  const int nb = (wg & 7) * 144 + (wg >> 3);       // chunked XCD swizzle
  const int z = nb / 36, t5 = nb - z * 36;
  const int d0 = (t5 / 6) * 128, k0 = (t5 - (t5 / 6) * 6) * 128;
  const int tid = threadIdx.x, w = tid >> 6, l = tid & 63;
  const int g = l >> 4, ln = l & 15;
  const int wr = w >> 1, wc = w & 1;
  const int srow = l >> 3;
  const int skb = ((l & 7) ^ srow) * 8;
  const unsigned short* Ag = Wm1bf + (size_t)(d0 + srow) * H + skb;
  const float* Bg = ((z < 16) ? Rsf : Rdf) + (size_t)(z & 15) * (H * H);
  // B reg-staging: per-thread fixed kb8 = tid&7, rows rb + q*32
  const int kb8 = tid & 7, rb = tid >> 3;
  const float* Bq = Bg + (size_t)(k0 + rb) * H + kb8 * 8;
  const int bdst = rb * 64 + (kb8 ^ (rb & 7)) * 8;

#define LOADB_(kbv, Ra, Rb)                                  \
  _Pragma("unroll") for (int q = 0; q < 4; ++q) {            \
    const float* s_ = Bq + (size_t)(q * 32) * H + (kbv);     \
    Ra[q] = *(const float4*)s_;                              \
    Rb[q] = *(const float4*)(s_ + 4);                        \
  }
#define WRITEB_(Ra, Rb, buf)                                 \
  _Pragma("unroll") for (int q = 0; q < 4; ++q) {            \
    u16x8 o_; unsigned int* po_ = (unsigned int*)&o_;        \
    po_[0] = cvtpk(Ra[q].x, Ra[q].y);                        \
    po_[1] = cvtpk(Ra[q].z, Ra[q].w);                        \
    po_[2] = cvtpk(Rb[q].x, Rb[q].y);                        \
    po_[3] = cvtpk(Rb[q].z, Rb[q].w);                        \
    *(u16x8*)&buf[q * 2048 + bdst] = o_;                     \
  }
#define GLDSA_(kbv, buf)                                     \
  _Pragma("unroll") for (int c4 = 0; c4 < 4; ++c4) {         \
    const int c_ = w * 4 + c4;                               \
    GLDS16(Ag + (size_t)(c_ * 8) * H + (kbv), &buf[c_ * 512]); \
  }

  f32x4 acc[4][4];
#pragma unroll
  for (int mi = 0; mi < 4; ++mi)
#pragma unroll
    for (int ni = 0; ni < 4; ++ni) acc[mi][ni] = (f32x4){0.f, 0.f, 0.f, 0.f};
  const int x7 = ln & 7;
  float4 r0a[4], r0b[4], r1a[4], r1b[4];
  // prologue: tile 0 staged, tile 1 B issued
  LOADB_(0, r0a, r0b);
  GLDSA_(0, Asl[0]);
  WRITEB_(r0a, r0b, Bsl[0]);
  __syncthreads();
  LOADB_(64, r1a, r1b);
#pragma unroll
  for (int t = 0; t < 12; ++t) {
    const int cur = t & 1;
    if (t < 11) { GLDSA_((t + 1) * 64, Asl[cur ^ 1]); }
#pragma unroll
    for (int kk = 0; kk < 2; ++kk) {
      u16x8 af[4], bf[4];
      const int pb = ((kk * 4 + g) ^ x7) * 8;
#pragma unroll
      for (int mi = 0; mi < 4; ++mi)
        af[mi] = ld8(&Asl[cur][(wr * 64 + mi * 16 + ln) * 64 + pb]);
#pragma unroll
      for (int ni = 0; ni < 4; ++ni)
        bf[ni] = ld8(&Bsl[cur][(wc * 64 + ni * 16 + ln) * 64 + pb]);
#pragma unroll
      for (int mi = 0; mi < 4; ++mi)
#pragma unroll
        for (int ni = 0; ni < 4; ++ni) acc[mi][ni] = MFMA(af[mi], bf[ni], acc[mi][ni]);
    }
    if (t < 11) {
      if (cur) { WRITEB_(r0a, r0b, Bsl[0]); } else { WRITEB_(r1a, r1b, Bsl[1]); }
    }
    __syncthreads();
    if (t < 10) {
      if (cur) { LOADB_((t + 2) * 64, r1a, r1b); } else { LOADB_((t + 2) * 64, r0a, r0b); }
    }
  }
#pragma unroll
  for (int mi = 0; mi < 4; ++mi) {
    const int d = d0 + wr * 64 + mi * 16 + g * 4;
#pragma unroll
    for (int ni = 0; ni < 4; ++ni) {
      const int k = k0 + wc * 64 + ni * 16 + ln;
      unsigned short* o = RsWt + ((size_t)d * 32 + z) * H + k;
#pragma unroll
      for (int pp = 0; pp < 4; ++pp) o[(size_t)pp * 32 * H] = f2bf(acc[mi][ni][pp]);
    }
  }
#undef LOADB_
#undef WRITEB_
#undef GLDSA_
}

// ---------------- K-split(4) hilo GEMM for gx (no bias, raw partials) -------
__global__ __launch_bounds__(256) void k_btks(
    const unsigned short* __restrict__ Ahi, const unsigned short* __restrict__ Alo,
    const unsigned short* __restrict__ Bhi, const unsigned short* __restrict__ Blo,
    float* __restrict__ Cp) {
  const int tid = threadIdx.x;
  const int w = tid >> 6, l = tid & 63, g = l >> 4, ln = l & 15;
  const int m0 = blockIdx.y * 64 + w * 16;
  const int n0 = blockIdx.x * 64;
  const int kh = blockIdx.z, kb0 = kh * 192;
  const unsigned short* aph = Ahi + (size_t)(m0 + ln) * H + kb0 + g * 8;
  const unsigned short* apl = Alo + (size_t)(m0 + ln) * H + kb0 + g * 8;
  const unsigned short* bph[4];
  const unsigned short* bpl[4];
#pragma unroll
  for (int nt = 0; nt < 4; ++nt) {
    bph[nt] = Bhi + (size_t)(n0 + nt * 16 + ln) * H + kb0 + g * 8;
    bpl[nt] = Blo + (size_t)(n0 + nt * 16 + ln) * H + kb0 + g * 8;
  }
  f32x4 acc[4];
#pragma unroll
  for (int nt = 0; nt < 4; ++nt) acc[nt] = (f32x4){0.f, 0.f, 0.f, 0.f};
  u16x8 ah[2], al[2], bh[2][4], bl[2][4];
  ah[0] = ld8(aph);
  al[0] = ld8(apl);
#pragma unroll
  for (int nt = 0; nt < 4; ++nt) { bh[0][nt] = ld8(bph[nt]); bl[0][nt] = ld8(bpl[nt]); }
#pragma unroll
  for (int t = 0; t < 6; ++t) {
    const int cur = t & 1, nxt = cur ^ 1;
    if (t < 5) {
      const int ko = (t + 1) * 32;
      ah[nxt] = ld8(aph + ko);
      al[nxt] = ld8(apl + ko);
#pragma unroll
      for (int nt = 0; nt < 4; ++nt) {
        bh[nxt][nt] = ld8(bph[nt] + ko);
        bl[nxt][nt] = ld8(bpl[nt] + ko);
      }
    }
#pragma unroll
    for (int nt = 0; nt < 4; ++nt) {
      acc[nt] = MFMA(ah[cur], bh[cur][nt], acc[nt]);
      acc[nt] = MFMA(ah[cur], bl[cur][nt], acc[nt]);
      acc[nt] = MFMA(al[cur], bh[cur][nt], acc[nt]);
    }
  }
#pragma unroll
  for (int nt = 0; nt < 4; ++nt) {
    const int col = n0 + nt * 16 + ln;
#pragma unroll
    for (int pp = 0; pp < 4; ++pp) {
      const int row = m0 + g * 4 + pp;
      Cp[(size_t)kh * (NTOT * GW) + (size_t)row * GW + col] = acc[nt][pp];
    }
  }
}

// ---------------- per-step LDS-staged tiled GEMM: gh | A4 | twB -------------
// 64(M) x 256(N) tiles, BK=64, global_load_lds + XOR swizzle.
// bid<27: gh (hilo); 27..62: A4; 63..350: twB. grid 351.
__global__ __launch_bounds__(256) void k_tile(
    const unsigned short* __restrict__ hhi, const unsigned short* __restrict__ hlo,
    const unsigned short* __restrict__ W1cat, const float* __restrict__ b1cat,
    const unsigned short* __restrict__ Whhh, const unsigned short* __restrict__ Whhl,
    const float* __restrict__ bhh, const unsigned short* __restrict__ RsWt,
    float* __restrict__ A4, float* __restrict__ ghb, unsigned short* __restrict__ twB) {
  __shared__ unsigned short Ah[4096], Al[4096], Bh[16384], Bl[16384];
  const int bid = blockIdx.x;
  const int tid = threadIdx.x, w = tid >> 6, l = tid & 63, g = l >> 4, ln = l & 15;
  int path, m, n;
  if (bid < 27)      { path = 0; n = bid / 3;        m = bid % 3; }
  else if (bid < 63) { path = 1; n = (bid - 27) / 3; m = (bid - 27) % 3; }
  else               { path = 2; n = (bid - 63) / 3; m = (bid - 63) % 3; }
  const int m0 = m * 64, n0 = n * 256;
  const bool isgh = (path == 0);
  const unsigned short* Bsrc = (path == 0) ? Whhh : (path == 1) ? W1cat : RsWt;
  const int srow = l >> 3;
  const int skb = ((l & 7) ^ srow) * 8;
  const unsigned short* Agh = hhi + (size_t)(m0 + srow) * H + skb;
  const unsigned short* Agl = hlo + (size_t)(m0 + srow) * H + skb;
  const unsigned short* Bgh = Bsrc + (size_t)(n0 + srow) * H + skb;
  const unsigned short* Bgl = Whhl + (size_t)((isgh ? n0 : 0) + srow) * H + skb;
  f32x4 acc[4][4];
#pragma unroll
  for (int mi = 0; mi < 4; ++mi)
#pragma unroll
    for (int ni = 0; ni < 4; ++ni) acc[mi][ni] = (f32x4){0.f, 0.f, 0.f, 0.f};
  const int x7 = ln & 7;
  for (int kb = 0; kb < H; kb += 64) {
#pragma unroll
    for (int c2 = 0; c2 < 2; ++c2) {
      const int c = w * 2 + c2;
      GLDS16(Agh + (size_t)(c * 8) * H + kb, &Ah[c * 512]);
      if (isgh) GLDS16(Agl + (size_t)(c * 8) * H + kb, &Al[c * 512]);
    }
#pragma unroll
    for (int c8 = 0; c8 < 8; ++c8) {
      const int c = w * 8 + c8;
      GLDS16(Bgh + (size_t)(c * 8) * H + kb, &Bh[c * 512]);
      if (isgh) GLDS16(Bgl + (size_t)(c * 8) * H + kb, &Bl[c * 512]);
    }
    __syncthreads();
#pragma unroll
    for (int kk = 0; kk < 2; ++kk) {
      const int pb = ((kk * 4 + g) ^ x7) * 8;
      u16x8 af[4], bf[4];
#pragma unroll
      for (int mi = 0; mi < 4; ++mi) af[mi] = ld8(&Ah[(mi * 16 + ln) * 64 + pb]);
#pragma unroll
      for (int ni = 0; ni < 4; ++ni) bf[ni] = ld8(&Bh[(w * 64 + ni * 16 + ln) * 64 + pb]);
      if (isgh) {
        u16x8 alf[4], blf[4];
#pragma unroll
        for (int mi = 0; mi < 4; ++mi) alf[mi] = ld8(&Al[(mi * 16 + ln) * 64 + pb]);
#pragma unroll
        for (int ni = 0; ni < 4; ++ni) blf[ni] = ld8(&Bl[(w * 64 + ni * 16 + ln) * 64 + pb]);
#pragma unroll
        for (int mi = 0; mi < 4; ++mi)
#pragma unroll
          for (int ni = 0; ni < 4; ++ni) {
            acc[mi][ni] = MFMA(af[mi], bf[ni], acc[mi][ni]);
            acc[mi][ni] = MFMA(af[mi], blf[ni], acc[mi][ni]);
            acc[mi][ni] = MFMA(alf[mi], bf[ni], acc[mi][ni]);
          }
      } else {
#pragma unroll
        for (int mi = 0; mi < 4; ++mi)
#pragma unroll
          for (int ni = 0; ni < 4; ++ni) acc[mi][ni] = MFMA(af[mi], bf[ni], acc[mi][ni]);
      }
    }
    __syncthreads();
  }
  if (path == 2) {
#pragma unroll
    for (int mi = 0; mi < 4; ++mi)
#pragma unroll
      for (int ni = 0; ni < 4; ++ni) {
        const int c = n0 + w * 64 + ni * 16 + ln;
#pragma unroll
        for (int pp = 0; pp < 4; ++pp) {
          const int j = m0 + mi * 16 + g * 4 + pp;
          twB[(size_t)j * 24576 + c] = f2bf(acc[mi][ni][pp]);
        }
      }
  } else {
    const int N = isgh ? GW : A4W;
    float* C = isgh ? ghb : A4;
    const float* bias = isgh ? bhh : b1cat;
#pragma unroll
    for (int mi = 0; mi < 4; ++mi)
#pragma unroll
      for (int ni = 0; ni < 4; ++ni) {
        const int col = n0 + w * 64 + ni * 16 + ln;
        const float bv = bias[col];
#pragma unroll
        for (int pp = 0; pp < 4; ++pp) {
          const int row = m0 + mi * 16 + g * 4 + pp;
          C[(size_t)row * N + col] = acc[mi][ni][pp] + bv;
        }
      }
  }
}

// ---------------- pair logits + softmax -> swA[j][i][32] (bf16) -------------
__global__ __launch_bounds__(256) void k_pairlog(
    const float* __restrict__ A4, const unsigned short* __restrict__ W2sbf,
    const unsigned short* __restrict__ W2dbf, const float* __restrict__ b2s,
    const float* __restrict__ b2d, unsigned short* __restrict__ swA) {
  __shared__ float red[8][16][17];
  const int i = blockIdx.x, jb = blockIdx.y;
  const int tid = threadIdx.x, w = tid >> 6, l = tid & 63;
  const int g = l >> 4, ln = l & 15;
  const int j = jb * 16 + ln;
  const float* BsP = A4 + (size_t)j * A4W + 768 + g * 8;
  const float* BdP = A4 + (size_t)j * A4W + 2304 + g * 8;
  const float* AsP = A4 + (size_t)i * A4W + g * 8;
  const float* AdP = A4 + (size_t)i * A4W + 1536 + g * 8;
  const unsigned short* WsP = W2sbf + (size_t)ln * H + g * 8;
  const unsigned short* WdP = W2dbf + (size_t)ln * H + g * 8;
  f32x4 accs = (f32x4){0.f, 0.f, 0.f, 0.f}, accd = (f32x4){0.f, 0.f, 0.f, 0.f};
#pragma unroll
  for (int tt = 0; tt < 6; ++tt) {
    const int ko = (w * 6 + tt) * 32;
    float4 b0 = *(const float4*)(BsP + ko), b1 = *(const float4*)(BsP + ko + 4);
    float4 a0 = *(const float4*)(AsP + ko), a1 = *(const float4*)(AsP + ko + 4);
    float4 e0 = *(const float4*)(BdP + ko), e1 = *(const float4*)(BdP + ko + 4);
    float4 c0 = *(const float4*)(AdP + ko), c1 = *(const float4*)(AdP + ko + 4);
    u16x8 afs, afd;
    unsigned int* ps = (unsigned int*)&afs;
    ps[0] = cvtpk(relu(a0.x + b0.x), relu(a0.y + b0.y));
    ps[1] = cvtpk(relu(a0.z + b0.z), relu(a0.w + b0.w));
    ps[2] = cvtpk(relu(a1.x + b1.x), relu(a1.y + b1.y));
    ps[3] = cvtpk(relu(a1.z + b1.z), relu(a1.w + b1.w));
    unsigned int* pd = (unsigned int*)&afd;
    pd[0] = cvtpk(relu(c0.x + e0.x), relu(c0.y + e0.y));
    pd[1] = cvtpk(relu(c0.z + e0.z), relu(c0.w + e0.w));
    pd[2] = cvtpk(relu(c1.x + e1.x), relu(c1.y + e1.y));
    pd[3] = cvtpk(relu(c1.z + e1.z), relu(c1.w + e1.w));
    accs = MFMA(afs, ld8(WsP + ko), accs);
    accd = MFMA(afd, ld8(WdP + ko), accd);
  }
#pragma unroll
  for (int pp = 0; pp < 4; ++pp) {
    red[w * 2][g * 4 + pp][ln] = accs[pp];
    red[w * 2 + 1][g * 4 + pp][ln] = accd[pp];
  }
  __syncthreads();
  const int j2 = tid >> 4, r = tid & 15;
  float vs = red[0][j2][r] + red[2][j2][r] + red[4][j2][r] + red[6][j2][r] + b2s[r];
  float vd = red[1][j2][r] + red[3][j2][r] + red[5][j2][r] + red[7][j2][r] + b2d[r];
  float ms = vs;
  ms = fmaxf(ms, __shfl_xor(ms, 1)); ms = fmaxf(ms, __shfl_xor(ms, 2));
  ms = fmaxf(ms, __shfl_xor(ms, 4)); ms = fmaxf(ms, __shfl_xor(ms, 8));
  float md = vd;
  md = fmaxf(md, __shfl_xor(md, 1)); md = fmaxf(md, __shfl_xor(md, 2));
  md = fmaxf(md, __shfl_xor(md, 4)); md = fmaxf(md, __shfl_xor(md, 8));
  float es = __expf(vs - ms), ed = __expf(vd - md);
  float ss = es;
  ss += __shfl_xor(ss, 1); ss += __shfl_xor(ss, 2); ss += __shfl_xor(ss, 4); ss += __shfl_xor(ss, 8);
  float sd = ed;
  sd += __shfl_xor(sd, 1); sd += __shfl_xor(sd, 2); sd += __shfl_xor(sd, 4); sd += __shfl_xor(sd, 8);
  const size_t o = (size_t)(jb * 16 + j2) * 6144 + (size_t)i * 32;
  swA[o + r] = f2bf(es / ss);
  swA[o + 16 + r] = f2bf(ed / sd);
}

// ---------------- per-pair weighted message + relu + sum_j -> v_part --------
__global__ __launch_bounds__(256) void k_pairmsg(const unsigned short* __restrict__ swA,
                                                 const unsigned short* __restrict__ twB,
                                                 const float* __restrict__ bm1,
                                                 float* __restrict__ vpart) {
  const int dt = blockIdx.x, it = blockIdx.y, js = blockIdx.z;
  const int tid = threadIdx.x;
  const int w = tid >> 6, l = tid & 63, g = l >> 4, ln = l & 15;
  const int i0 = it * 64 + w * 16;
  const int d0 = dt * 64;
  float bm1v[4];
#pragma unroll
  for (int nt = 0; nt < 4; ++nt) bm1v[nt] = bm1[d0 + nt * 16 + ln];
  f32x4 vacc[4];
#pragma unroll
  for (int nt = 0; nt < 4; ++nt) vacc[nt] = (f32x4){0.f, 0.f, 0.f, 0.f};
  const unsigned short* ap = swA + (size_t)(i0 + ln) * 32 + g * 8 + (size_t)js * 24 * 6144;
  const unsigned short* bp[4];
#pragma unroll
  for (int nt = 0; nt < 4; ++nt)
    bp[nt] = twB + (size_t)(d0 + nt * 16 + ln) * 32 + g * 8 + (size_t)js * 24 * 24576;
  const f32x4 z4 = (f32x4){0.f, 0.f, 0.f, 0.f};
#pragma unroll 4
  for (int jj = 0; jj < 24; ++jj) {
    u16x8 a = ld8(ap + (size_t)jj * 6144);
#pragma unroll
    for (int nt = 0; nt < 4; ++nt) {
      u16x8 b = ld8(bp[nt] + (size_t)jj * 24576);
      f32x4 mf = MFMA(a, b, z4);
#pragma unroll
      for (int pp = 0; pp < 4; ++pp) vacc[nt][pp] += fmaxf(mf[pp] + bm1v[nt], 0.f);
    }
  }
#pragma unroll
  for (int nt = 0; nt < 4; ++nt)
#pragma unroll
    for (int pp = 0; pp < 4; ++pp) {
      const int row = i0 + g * 4 + pp;
      vpart[(size_t)js * 147456 + (size_t)row * H + d0 + nt * 16 + ln] = vacc[nt][pp];
    }
}

__global__ void k_vred(const float* __restrict__ vpart, unsigned short* __restrict__ vhi,
                       unsigned short* __restrict__ vlo) {
  int e = blockIdx.x * 256 + threadIdx.x;  // 147456
  float s = 0.f;
#pragma unroll
  for (int q = 0; q < 8; ++q) s += vpart[(size_t)q * 147456 + e];
  s *= (1.0f / 192.0f);
  unsigned short hi = f2bf(s);
  vhi[e] = hi;
  vlo[e] = f2bf(s - bf2f(hi));
}

__global__ void k_gru(const float* __restrict__ gxp, const float* __restrict__ bcv,
                      const float* __restrict__ gh, float* __restrict__ h,
                      unsigned short* __restrict__ hhi, unsigned short* __restrict__ hlo,
                      float* __restrict__ out, int last) {
  int e = blockIdx.x * 256 + threadIdx.x;  // 147456
  int i = e / H, k = e - i * H;
  size_t base = (size_t)i * GW;
  const size_t S = (size_t)NTOT * GW;
  float rr = gxp[base + k] + gxp[S + base + k] + gxp[2 * S + base + k] +
             gxp[3 * S + base + k] + bcv[k] + gh[base + k];
  float zz = gxp[base + H + k] + gxp[S + base + H + k] + gxp[2 * S + base + H + k] +
             gxp[3 * S + base + H + k] + bcv[H + k] + gh[base + H + k];
  float r = 1.f / (1.f + __expf(-rr));
  float z = 1.f / (1.f + __expf(-zz));
  float nn = gxp[base + 2 * H + k] + gxp[S + base + 2 * H + k] +
             gxp[2 * S + base + 2 * H + k] + gxp[3 * S + base + 2 * H + k] +
             bcv[2 * H + k];
  float n = tanhf(nn + r * gh[base + 2 * H + k]);
  float hv = (1.f - z) * n + z * h[e];
  h[e] = hv;
  unsigned short hi = f2bf(hv);
  hhi[e] = hi;
  hlo[e] = f2bf(hv - bf2f(hi));
  if (last && i >= 64) out[(size_t)(i - 64) * H + k] = hv;
}

// ---------------- launch ----------------------------------------------------

extern "C" void kernel_launch(void* const* d_in, const int* in_sizes, int n_in,
                              void* d_out, int out_size, void* d_ws, size_t ws_size,
                              hipStream_t stream) {
  const float* asp = (const float*)d_in[0];
  const float* qry = (const float*)d_in[1];
  const float* W1s = (const float*)d_in[3];
  const float* b1s = (const float*)d_in[4];
  const float* W2s = (const float*)d_in[5];
  const float* b2s = (const float*)d_in[6];
  const float* W1d = (const float*)d_in[7];
  const float* b1d = (const float*)d_in[8];
  const float* W2d = (const float*)d_in[9];
  const float* b2d = (const float*)d_in[10];
  const float* Rs  = (const float*)d_in[11];
  const float* Rd  = (const float*)d_in[12];
  const float* Wm1 = (const float*)d_in[13];
  const float* bm1 = (const float*)d_in[14];
  const float* Wm2 = (const float*)d_in[15];
  const float* bm2 = (const float*)d_in[16];
  const float* Wih = (const float*)d_in[17];
  const float* Whh = (const float*)d_in[18];
  const float* bih = (const float*)d_in[19];
  const float* bhh = (const float*)d_in[20];
  float* out = (float*)d_out;

  char* p = (char*)d_ws;
  auto take = [&](size_t bytes) {
    char* q = p;
    p += (bytes + 255) & ~(size_t)255;
    return q;
  };
  // ---- step-scratch region, aliased during prep ----
  float* h            = (float*)take((size_t)NTOT * H * 4);
  unsigned short* hhi = (unsigned short*)take((size_t)NTOT * H * 2);
  unsigned short* hlo = (unsigned short*)take((size_t)NTOT * H * 2);
  float* A4           = (float*)take((size_t)NTOT * A4W * 4);
  float* ghb          = (float*)take((size_t)NTOT * GW * 4);
  unsigned short* vhi = (unsigned short*)take((size_t)NTOT * H * 2);
  unsigned short* vlo = (unsigned short*)take((size_t)NTOT * H * 2);
  float* vpart        = (float*)take((size_t)8 * NTOT * H * 4);
  unsigned short* swA = (unsigned short*)take((size_t)NTOT * NTOT * 32 * 2);
  unsigned short* twB = (unsigned short*)take((size_t)NTOT * H * 32 * 2);  // also gx partials
  // ---- permanent weights ----
  unsigned short* RsWt = (unsigned short*)take((size_t)2 * 16 * H * H * 2);
  unsigned short* Wm1bf = (unsigned short*)take((size_t)H * H * 2);
  unsigned short* W2sbf = (unsigned short*)take((size_t)16 * H * 2);
  unsigned short* W2dbf = (unsigned short*)take((size_t)16 * H * 2);
  unsigned short* W1cat = (unsigned short*)take((size_t)A4W * H * 2);
  float* b1cat        = (float*)take((size_t)A4W * 4);
  unsigned short* Whhh = (unsigned short*)take((size_t)GW * H * 2);
  unsigned short* Whhl = (unsigned short*)take((size_t)GW * H * 2);
  unsigned short* Wch  = (unsigned short*)take((size_t)GW * H * 2);
  unsigned short* Wcl  = (unsigned short*)take((size_t)GW * H * 2);
  float* bc           = (float*)take((size_t)GW * 4);
  // ---- prep-phase aliases (within step-scratch, after h/hhi/hlo @1,179,648) ----
  unsigned short* Wm2th = (unsigned short*)((char*)d_ws + 1179648);
  unsigned short* Wm2tl = Wm2th + (size_t)H * H;  // ends ~3.54 MB

  // ---- once-per-launch prep ----
  k_prep<<<5928, 256, 0, stream>>>(Wm1, W2s, W2d, Whh, Wih, Wm2, W1s, W1d, b1s, b1d,
                                   bm2, bih, asp, qry,
                                   Wm1bf, W2sbf, W2dbf, Whhh, Whhl,
                                   Wm2th, Wm2tl, W1cat, b1cat, bc, h, hhi, hlo);
  k_wc<<<108, 256, 0, stream>>>(Wih, Wm2th, Wm2tl, Wch, Wcl);
  k_rsw2f<<<1152, 256, 0, stream>>>(Wm1bf, Rs, Rd, RsWt);

  // ---- propagation steps ----
  for (int step = 0; step < 3; ++step) {
    k_tile<<<351, 256, 0, stream>>>(hhi, hlo, W1cat, b1cat, Whhh, Whhl, bhh, RsWt,
                                    A4, ghb, twB);
    k_pairlog<<<dim3(192, 12), 256, 0, stream>>>(A4, W2sbf, W2dbf, b2s, b2d, swA);
    k_pairmsg<<<dim3(12, 3, 8), 256, 0, stream>>>(swA, twB, bm1, vpart);
    k_vred<<<576, 256, 0, stream>>>(vpart, vhi, vlo);
    k_btks<<<dim3(36, 3, 4), 256, 0, stream>>>(vhi, vlo, Wch, Wcl, (float*)twB);
    k_gru<<<576, 256, 0, stream>>>((float*)twB, bc, ghb, h, hhi, hlo, out, step == 2);
  }
  (void)in_sizes; (void)n_in; (void)out_size; (void)ws_size;
}

// Round 8
// 523.265 us; speedup vs baseline: 1.8418x; 1.0377x over previous
//
#include <hip/hip_runtime.h>
#include <hip/hip_bf16.h>

#define H 768
#define NTOT 192
#define A4W 3072
#define GW 2304

typedef __attribute__((ext_vector_type(4))) float f32x4;
typedef __attribute__((ext_vector_type(8))) unsigned short u16x8;
typedef __attribute__((ext_vector_type(4))) unsigned short u16x4;
typedef __attribute__((ext_vector_type(8))) __bf16 bf16x8v;

static __device__ __forceinline__ unsigned short f2bf(float f) {
  __hip_bfloat16 b = __float2bfloat16(f);
  return __builtin_bit_cast(unsigned short, b);
}
static __device__ __forceinline__ float bf2f(unsigned short u) {
  return __bfloat162float(__builtin_bit_cast(__hip_bfloat16, u));
}
static __device__ __forceinline__ f32x4 MFMA(u16x8 a, u16x8 b, f32x4 c) {
  return __builtin_amdgcn_mfma_f32_16x16x32_bf16(
      __builtin_bit_cast(bf16x8v, a), __builtin_bit_cast(bf16x8v, b), c, 0, 0, 0);
}
static __device__ __forceinline__ u16x8 ld8(const unsigned short* p) {
  return *(const u16x8*)p;
}
static __device__ __forceinline__ unsigned int cvtpk(float lo, float hi) {
  unsigned int r;
  asm("v_cvt_pk_bf16_f32 %0, %1, %2" : "=v"(r) : "v"(lo), "v"(hi));
  return r;
}
static __device__ __forceinline__ float relu(float x) { return fmaxf(x, 0.f); }

#define GLDS16(gp, lp)                                                   \
  __builtin_amdgcn_global_load_lds(                                      \
      (const __attribute__((address_space(1))) void*)(gp),               \
      (__attribute__((address_space(3))) void*)(lp), 16, 0, 0)

// ---------------- fused prep: weight conversions + bc + inith --------------
// segments: Wm1 576 | W2s 12 | W2d 12 | Whh 1728 | Wm2t 576 | W1cat 2304 |
//           bc 576 | inith 144  => grid 5928
__global__ void k_prep(const float* __restrict__ Wm1, const float* __restrict__ W2s,
                       const float* __restrict__ W2d, const float* __restrict__ Whh,
                       const float* __restrict__ Wih, const float* __restrict__ Wm2,
                       const float* __restrict__ W1s, const float* __restrict__ W1d,
                       const float* __restrict__ b1s, const float* __restrict__ b1d,
                       const float* __restrict__ bm2, const float* __restrict__ bih,
                       const float* __restrict__ asp, const float* __restrict__ qry,
                       unsigned short* __restrict__ Wm1bf, unsigned short* __restrict__ W2sbf,
                       unsigned short* __restrict__ W2dbf, unsigned short* __restrict__ Whhh,
                       unsigned short* __restrict__ Whhl, unsigned short* __restrict__ Wm2th,
                       unsigned short* __restrict__ Wm2tl, unsigned short* __restrict__ W1cat,
                       float* __restrict__ b1cat, float* __restrict__ bc,
                       float* __restrict__ h, unsigned short* __restrict__ hhi,
                       unsigned short* __restrict__ hlo) {
  const int b = blockIdx.x, tid = threadIdx.x;
  if (b < 576) {
    int u = b * 256 + tid;
    float4 v = ((const float4*)Wm1)[u];
    u16x4 o; o[0] = f2bf(v.x); o[1] = f2bf(v.y); o[2] = f2bf(v.z); o[3] = f2bf(v.w);
    ((u16x4*)Wm1bf)[u] = o;
  } else if (b < 588) {
    int u = (b - 576) * 256 + tid;
    float4 v = ((const float4*)W2s)[u];
    u16x4 o; o[0] = f2bf(v.x); o[1] = f2bf(v.y); o[2] = f2bf(v.z); o[3] = f2bf(v.w);
    ((u16x4*)W2sbf)[u] = o;
  } else if (b < 600) {
    int u = (b - 588) * 256 + tid;
    float4 v = ((const float4*)W2d)[u];
    u16x4 o; o[0] = f2bf(v.x); o[1] = f2bf(v.y); o[2] = f2bf(v.z); o[3] = f2bf(v.w);
    ((u16x4*)W2dbf)[u] = o;
  } else if (b < 2328) {
    int u = (b - 600) * 256 + tid;
    float4 v = ((const float4*)Whh)[u];
    u16x4 oh, ol;
#pragma unroll
    for (int j = 0; j < 4; ++j) {
      float f = ((const float*)&v)[j];
      oh[j] = f2bf(f); ol[j] = f2bf(f - bf2f(oh[j]));
    }
    ((u16x4*)Whhh)[u] = oh; ((u16x4*)Whhl)[u] = ol;
  } else if (b < 2904) {
    int u = (b - 2328) * 256 + tid;  // Wm2 f4 index; emit TRANSPOSED hi/lo
    float4 v = ((const float4*)Wm2)[u];
    int e_lin = u * 4;
    int er = e_lin / H, kc = e_lin - er * H;
#pragma unroll
    for (int j = 0; j < 4; ++j) {
      float f = ((const float*)&v)[j];
      unsigned short hi = f2bf(f);
      Wm2th[(size_t)(kc + j) * H + er] = hi;
      Wm2tl[(size_t)(kc + j) * H + er] = f2bf(f - bf2f(hi));
    }
  } else if (b < 5208) {
    int u = (b - 2904) * 256 + tid;  // f4 index into W1cat [3072][768]
    int e = u * 4;
    int row = e / H, k = e - row * H;
    int part = row / H, o = row - part * H;
    const float* W = (part < 2) ? W1s : W1d;
    float4 v = *(const float4*)(W + (size_t)o * (2 * H) + (part & 1) * H + k);
    u16x4 ov; ov[0] = f2bf(v.x); ov[1] = f2bf(v.y); ov[2] = f2bf(v.z); ov[3] = f2bf(v.w);
    *(u16x4*)(W1cat + e) = ov;
    if (u < 768) {
      int e2 = u * 4, pp = e2 / H, oo = e2 - pp * H;
      float4 bv;
      if (pp == 0) bv = *(const float4*)(b1s + oo);
      else if (pp == 2) bv = *(const float4*)(b1d + oo);
      else bv = (float4){0.f, 0.f, 0.f, 0.f};
      *(float4*)(b1cat + e2) = bv;
    }
  } else if (b < 5784) {
    // bc[g] = bih[g] + sum_e Wih[g][e]*bm2[e]
    const int w = tid >> 6, l = tid & 63;
    const int gg = (b - 5208) * 4 + w;
    const float* row = Wih + (size_t)gg * H;
    float s = 0.f;
#pragma unroll
    for (int q = 0; q < 12; ++q) s += row[l + q * 64] * bm2[l + q * 64];
#pragma unroll
    for (int m = 32; m; m >>= 1) s += __shfl_xor(s, m);
    if (l == 0) bc[gg] = bih[gg] + s;
  } else {
    int u = (b - 5784) * 256 + tid;  // f4 index, 36864
    float4 v = (u < 12288) ? ((const float4*)asp)[u] : ((const float4*)qry)[u - 12288];
    ((float4*)h)[u] = v;
    u16x4 oh, ol;
#pragma unroll
    for (int j = 0; j < 4; ++j) {
      float f = ((const float*)&v)[j];
      oh[j] = f2bf(f); ol[j] = f2bf(f - bf2f(oh[j]));
    }
    ((u16x4*)hhi)[u] = oh; ((u16x4*)hlo)[u] = ol;
  }
}

// ---------------- merged prep GEMM: RsW (blocks 0..1151) + Wc (1152..1259) --
// RsW: counted-vmcnt pipeline — B loads stay in flight across raw s_barrier.
// Wc: 128x128 hilo GEMM (LDS arrays reused).
__global__ __launch_bounds__(256) void k_pre2(const unsigned short* __restrict__ Wm1bf,
                                              const float* __restrict__ Rsf,
                                              const float* __restrict__ Rdf,
                                              unsigned short* __restrict__ RsWt,
                                              const float* __restrict__ Wih,
                                              const unsigned short* __restrict__ Bth,
                                              const unsigned short* __restrict__ Btl,
                                              unsigned short* __restrict__ Ch,
                                              unsigned short* __restrict__ Cl) {
  __shared__ unsigned short Asl[2][8192];
  __shared__ unsigned short Bsl[2][8192];
  const int wg = blockIdx.x;
  const int tid = threadIdx.x, w = tid >> 6, l = tid & 63;
  const int g = l >> 4, ln = l & 15;
  const int wr = w >> 1, wc = w & 1;
  const int srow = l >> 3;
  const int skb = ((l & 7) ^ srow) * 8;
  const int x7 = ln & 7;

  if (wg >= 1152) {
    // ----------------- Wc = Wih @ Wm2t^T (hilo x hilo) ----------------------
    const int bid = wg - 1152;
    const int m0 = (bid / 6) * 128, n0 = (bid % 6) * 128;
    const unsigned short* Bgh = Bth + (size_t)(n0 + srow) * H + skb;
    const unsigned short* Bgl = Btl + (size_t)(n0 + srow) * H + skb;
    f32x4 acc[4][4];
#pragma unroll
    for (int mi = 0; mi < 4; ++mi)
#pragma unroll
      for (int ni = 0; ni < 4; ++ni) acc[mi][ni] = (f32x4){0.f, 0.f, 0.f, 0.f};
    for (int kb = 0; kb < H; kb += 64) {
#pragma unroll
      for (int c4 = 0; c4 < 4; ++c4) {
        const int c = w * 4 + c4;
        GLDS16(Bgh + (size_t)(c * 8) * H + kb, &Bsl[0][c * 512]);
        GLDS16(Bgl + (size_t)(c * 8) * H + kb, &Bsl[1][c * 512]);
      }
#pragma unroll
      for (int q = 0; q < 4; ++q) {
        const int idx = q * 256 + tid;
        const int row = idx >> 3, kb8 = idx & 7;
        const float* src = Wih + (size_t)(m0 + row) * H + kb + kb8 * 8;
        float4 v0 = *(const float4*)src;
        float4 v1 = *(const float4*)(src + 4);
        float fv[8] = {v0.x, v0.y, v0.z, v0.w, v1.x, v1.y, v1.z, v1.w};
        u16x8 oh, ol;
#pragma unroll
        for (int jq = 0; jq < 8; ++jq) {
          unsigned short hi = f2bf(fv[jq]);
          oh[jq] = hi;
          ol[jq] = f2bf(fv[jq] - bf2f(hi));
        }
        const int dst = row * 64 + (kb8 ^ (row & 7)) * 8;
        *(u16x8*)&Asl[0][dst] = oh;
        *(u16x8*)&Asl[1][dst] = ol;
      }
      __syncthreads();
#pragma unroll
      for (int kk = 0; kk < 2; ++kk) {
        const int pb = ((kk * 4 + g) ^ x7) * 8;
        u16x8 ahf[4], alf[4], bhf[4], blf[4];
#pragma unroll
        for (int mi = 0; mi < 4; ++mi) {
          ahf[mi] = ld8(&Asl[0][(wr * 64 + mi * 16 + ln) * 64 + pb]);
          alf[mi] = ld8(&Asl[1][(wr * 64 + mi * 16 + ln) * 64 + pb]);
        }
#pragma unroll
        for (int ni = 0; ni < 4; ++ni) {
          bhf[ni] = ld8(&Bsl[0][(wc * 64 + ni * 16 + ln) * 64 + pb]);
          blf[ni] = ld8(&Bsl[1][(wc * 64 + ni * 16 + ln) * 64 + pb]);
        }
#pragma unroll
        for (int mi = 0; mi < 4; ++mi)
#pragma unroll
          for (int ni = 0; ni < 4; ++ni) {
            acc[mi][ni] = MFMA(ahf[mi], bhf[ni], acc[mi][ni]);
            acc[mi][ni] = MFMA(ahf[mi], blf[ni], acc[mi][ni]);
            acc[mi][ni] = MFMA(alf[mi], bhf[ni], acc[mi][ni]);
          }
      }
      __syncthreads();
    }
#pragma unroll
    for (int mi = 0; mi < 4; ++mi) {
#pragma unroll
      for (int ni = 0; ni < 4; ++ni) {
        const int col = n0 + wc * 64 + ni * 16 + ln;
#pragma unroll
        for (int pp = 0; pp < 4; ++pp) {
          const int row = m0 + wr * 64 + mi * 16 + g * 4 + pp;
          const float val = acc[mi][ni][pp];
          unsigned short hi = f2bf(val);
          Ch[(size_t)row * H + col] = hi;
          Cl[(size_t)row * H + col] = f2bf(val - bf2f(hi));
        }
      }
    }
    return;
  }

  // ----------------- RsW: z<16 -> Rs[z], else Rd[z-16]; out row = d*32+z ----
  const int nb = (wg & 7) * 144 + (wg >> 3);       // chunked XCD swizzle
  const int z = nb / 36, t5 = nb - z * 36;
  const int d0 = (t5 / 6) * 128, k0 = (t5 % 6) * 128;
  const unsigned short* Ag = Wm1bf + (size_t)(d0 + srow) * H + skb;
  const float* Bg = ((z < 16) ? Rsf : Rdf) + (size_t)(z & 15) * (H * H);
  const int kb8 = tid & 7, rb = tid >> 3;
  const float* Bq = Bg + (size_t)(k0 + rb) * H + kb8 * 8;
  const int bdst = rb * 64 + (kb8 ^ (rb & 7)) * 8;

#define LOADB_(kbv, Ra, Rb)                                  \
  _Pragma("unroll") for (int q = 0; q < 4; ++q) {            \
    const float* s_ = Bq + (size_t)(q * 32) * H + (kbv);     \
    Ra[q] = *(const float4*)s_;                              \
    Rb[q] = *(const float4*)(s_ + 4);                        \
  }
#define WRITEB_(Ra, Rb, buf)                                 \
  _Pragma("unroll") for (int q = 0; q < 4; ++q) {            \
    u16x8 o_; unsigned int* po_ = (unsigned int*)&o_;        \
    po_[0] = cvtpk(Ra[q].x, Ra[q].y);                        \
    po_[1] = cvtpk(Ra[q].z, Ra[q].w);                        \
    po_[2] = cvtpk(Rb[q].x, Rb[q].y);                        \
    po_[3] = cvtpk(Rb[q].z, Rb[q].w);                        \
    *(u16x8*)&buf[q * 2048 + bdst] = o_;                     \
  }
#define GLDSA_(kbv, buf)                                     \
  _Pragma("unroll") for (int c4 = 0; c4 < 4; ++c4) {         \
    const int c_ = w * 4 + c4;                               \
    GLDS16(Ag + (size_t)(c_ * 8) * H + (kbv), &buf[c_ * 512]); \
  }

  f32x4 acc[4][4];
#pragma unroll
  for (int mi = 0; mi < 4; ++mi)
#pragma unroll
    for (int ni = 0; ni < 4; ++ni) acc[mi][ni] = (f32x4){0.f, 0.f, 0.f, 0.f};
  float4 e0a[4], e0b[4], e1a[4], e1b[4];
  // prologue: tile0 staged; tile1 B issued and left in flight
  GLDSA_(0, Asl[0]);
  LOADB_(0, e0a, e0b);
  WRITEB_(e0a, e0b, Bsl[0]);
  __builtin_amdgcn_sched_barrier(0);
  LOADB_(64, e1a, e1b);
  asm volatile("s_waitcnt vmcnt(8) lgkmcnt(0)\n\ts_barrier" ::: "memory");
#pragma unroll
  for (int t = 0; t < 12; ++t) {
    const int cur = t & 1;
    if (t < 11) GLDSA_((t + 1) * 64, Asl[cur ^ 1]);   // A first (oldest at fence)
#pragma unroll
    for (int kk = 0; kk < 2; ++kk) {
      const int pb = ((kk * 4 + g) ^ x7) * 8;
      u16x8 af[4], bf[4];
#pragma unroll
      for (int mi = 0; mi < 4; ++mi)
        af[mi] = ld8(&Asl[cur][(wr * 64 + mi * 16 + ln) * 64 + pb]);
#pragma unroll
      for (int ni = 0; ni < 4; ++ni)
        bf[ni] = ld8(&Bsl[cur][(wc * 64 + ni * 16 + ln) * 64 + pb]);
#pragma unroll
      for (int mi = 0; mi < 4; ++mi)
#pragma unroll
        for (int ni = 0; ni < 4; ++ni) acc[mi][ni] = MFMA(af[mi], bf[ni], acc[mi][ni]);
    }
    if (t < 11) {
      if (cur == 0) { WRITEB_(e1a, e1b, Bsl[1]); }    // B(t+1): oldest loads, cheap wait
      else          { WRITEB_(e0a, e0b, Bsl[0]); }
    }
    __builtin_amdgcn_sched_barrier(0);                // pin: GLDSA above, LOADB below
    if (t < 10) {
      if (cur == 0) { LOADB_((t + 2) * 64, e0a, e0b); }
      else          { LOADB_((t + 2) * 64, e1a, e1b); }
    }
    if (t < 10) {
      // outstanding: A(t+1)=4 (older) + B(t+2)=8 (younger) -> retire A only
      asm volatile("s_waitcnt vmcnt(8) lgkmcnt(0)\n\ts_barrier" ::: "memory");
    } else if (t == 10) {
      asm volatile("s_waitcnt vmcnt(0) lgkmcnt(0)\n\ts_barrier" ::: "memory");
    }
  }
#pragma unroll
  for (int mi = 0; mi < 4; ++mi) {
    const int d = d0 + wr * 64 + mi * 16 + g * 4;
#pragma unroll
    for (int ni = 0; ni < 4; ++ni) {
      const int k = k0 + wc * 64 + ni * 16 + ln;
      unsigned short* o = RsWt + ((size_t)d * 32 + z) * H + k;
#pragma unroll
      for (int pp = 0; pp < 4; ++pp) o[(size_t)pp * 32 * H] = f2bf(acc[mi][ni][pp]);
    }
  }
#undef LOADB_
#undef WRITEB_
#undef GLDSA_
}

// ---------------- K-split(4) hilo GEMM for gx (no bias, raw partials) -------
__global__ __launch_bounds__(256) void k_btks(
    const unsigned short* __restrict__ Ahi, const unsigned short* __restrict__ Alo,
    const unsigned short* __restrict__ Bhi, const unsigned short* __restrict__ Blo,
    float* __restrict__ Cp) {
  const int tid = threadIdx.x;
  const int w = tid >> 6, l = tid & 63, g = l >> 4, ln = l & 15;
  const int m0 = blockIdx.y * 64 + w * 16;
  const int n0 = blockIdx.x * 64;
  const int kh = blockIdx.z, kb0 = kh * 192;
  const unsigned short* aph = Ahi + (size_t)(m0 + ln) * H + kb0 + g * 8;
  const unsigned short* apl = Alo + (size_t)(m0 + ln) * H + kb0 + g * 8;
  const unsigned short* bph[4];
  const unsigned short* bpl[4];
#pragma unroll
  for (int nt = 0; nt < 4; ++nt) {
    bph[nt] = Bhi + (size_t)(n0 + nt * 16 + ln) * H + kb0 + g * 8;
    bpl[nt] = Blo + (size_t)(n0 + nt * 16 + ln) * H + kb0 + g * 8;
  }
  f32x4 acc[4];
#pragma unroll
  for (int nt = 0; nt < 4; ++nt) acc[nt] = (f32x4){0.f, 0.f, 0.f, 0.f};
  u16x8 ah[2], al[2], bh[2][4], bl[2][4];
  ah[0] = ld8(aph);
  al[0] = ld8(apl);
#pragma unroll
  for (int nt = 0; nt < 4; ++nt) { bh[0][nt] = ld8(bph[nt]); bl[0][nt] = ld8(bpl[nt]); }
#pragma unroll
  for (int t = 0; t < 6; ++t) {
    const int cur = t & 1, nxt = cur ^ 1;
    if (t < 5) {
      const int ko = (t + 1) * 32;
      ah[nxt] = ld8(aph + ko);
      al[nxt] = ld8(apl + ko);
#pragma unroll
      for (int nt = 0; nt < 4; ++nt) {
        bh[nxt][nt] = ld8(bph[nt] + ko);
        bl[nxt][nt] = ld8(bpl[nt] + ko);
      }
    }
#pragma unroll
    for (int nt = 0; nt < 4; ++nt) {
      acc[nt] = MFMA(ah[cur], bh[cur][nt], acc[nt]);
      acc[nt] = MFMA(ah[cur], bl[cur][nt], acc[nt]);
      acc[nt] = MFMA(al[cur], bh[cur][nt], acc[nt]);
    }
  }
#pragma unroll
  for (int nt = 0; nt < 4; ++nt) {
    const int col = n0 + nt * 16 + ln;
#pragma unroll
    for (int pp = 0; pp < 4; ++pp) {
      const int row = m0 + g * 4 + pp;
      Cp[(size_t)kh * (NTOT * GW) + (size_t)row * GW + col] = acc[nt][pp];
    }
  }
}

// ---------------- per-step LDS-staged tiled GEMM: gh | A4 | twB -------------
// 64(M) x 256(N) tiles, BK=64, global_load_lds + XOR swizzle.
// bid<27: gh (hilo); 27..62: A4; 63..350: twB. grid 351.
__global__ __launch_bounds__(256) void k_tile(
    const unsigned short* __restrict__ hhi, const unsigned short* __restrict__ hlo,
    const unsigned short* __restrict__ W1cat, const float* __restrict__ b1cat,
    const unsigned short* __restrict__ Whhh, const unsigned short* __restrict__ Whhl,
    const float* __restrict__ bhh, const unsigned short* __restrict__ RsWt,
    float* __restrict__ A4, float* __restrict__ ghb, unsigned short* __restrict__ twB) {
  __shared__ unsigned short Ah[4096], Al[4096], Bh[16384], Bl[16384];
  const int bid = blockIdx.x;
  const int tid = threadIdx.x, w = tid >> 6, l = tid & 63, g = l >> 4, ln = l & 15;
  int path, m, n;
  if (bid < 27)      { path = 0; n = bid / 3;        m = bid % 3; }
  else if (bid < 63) { path = 1; n = (bid - 27) / 3; m = (bid - 27) % 3; }
  else               { path = 2; n = (bid - 63) / 3; m = (bid - 63) % 3; }
  const int m0 = m * 64, n0 = n * 256;
  const bool isgh = (path == 0);
  const unsigned short* Bsrc = (path == 0) ? Whhh : (path == 1) ? W1cat : RsWt;
  const int srow = l >> 3;
  const int skb = ((l & 7) ^ srow) * 8;
  const unsigned short* Agh = hhi + (size_t)(m0 + srow) * H + skb;
  const unsigned short* Agl = hlo + (size_t)(m0 + srow) * H + skb;
  const unsigned short* Bgh = Bsrc + (size_t)(n0 + srow) * H + skb;
  const unsigned short* Bgl = Whhl + (size_t)((isgh ? n0 : 0) + srow) * H + skb;
  f32x4 acc[4][4];
#pragma unroll
  for (int mi = 0; mi < 4; ++mi)
#pragma unroll
    for (int ni = 0; ni < 4; ++ni) acc[mi][ni] = (f32x4){0.f, 0.f, 0.f, 0.f};
  const int x7 = ln & 7;
  for (int kb = 0; kb < H; kb += 64) {
#pragma unroll
    for (int c2 = 0; c2 < 2; ++c2) {
      const int c = w * 2 + c2;
      GLDS16(Agh + (size_t)(c * 8) * H + kb, &Ah[c * 512]);
      if (isgh) GLDS16(Agl + (size_t)(c * 8) * H + kb, &Al[c * 512]);
    }
#pragma unroll
    for (int c8 = 0; c8 < 8; ++c8) {
      const int c = w * 8 + c8;
      GLDS16(Bgh + (size_t)(c * 8) * H + kb, &Bh[c * 512]);
      if (isgh) GLDS16(Bgl + (size_t)(c * 8) * H + kb, &Bl[c * 512]);
    }
    __syncthreads();
#pragma unroll
    for (int kk = 0; kk < 2; ++kk) {
      const int pb = ((kk * 4 + g) ^ x7) * 8;
      u16x8 af[4], bf[4];
#pragma unroll
      for (int mi = 0; mi < 4; ++mi) af[mi] = ld8(&Ah[(mi * 16 + ln) * 64 + pb]);
#pragma unroll
      for (int ni = 0; ni < 4; ++ni) bf[ni] = ld8(&Bh[(w * 64 + ni * 16 + ln) * 64 + pb]);
      if (isgh) {
        u16x8 alf[4], blf[4];
#pragma unroll
        for (int mi = 0; mi < 4; ++mi) alf[mi] = ld8(&Al[(mi * 16 + ln) * 64 + pb]);
#pragma unroll
        for (int ni = 0; ni < 4; ++ni) blf[ni] = ld8(&Bl[(w * 64 + ni * 16 + ln) * 64 + pb]);
#pragma unroll
        for (int mi = 0; mi < 4; ++mi)
#pragma unroll
          for (int ni = 0; ni < 4; ++ni) {
            acc[mi][ni] = MFMA(af[mi], bf[ni], acc[mi][ni]);
            acc[mi][ni] = MFMA(af[mi], blf[ni], acc[mi][ni]);
            acc[mi][ni] = MFMA(alf[mi], bf[ni], acc[mi][ni]);
          }
      } else {
#pragma unroll
        for (int mi = 0; mi < 4; ++mi)
#pragma unroll
          for (int ni = 0; ni < 4; ++ni) acc[mi][ni] = MFMA(af[mi], bf[ni], acc[mi][ni]);
      }
    }
    __syncthreads();
  }
  if (path == 2) {
#pragma unroll
    for (int mi = 0; mi < 4; ++mi)
#pragma unroll
      for (int ni = 0; ni < 4; ++ni) {
        const int c = n0 + w * 64 + ni * 16 + ln;
#pragma unroll
        for (int pp = 0; pp < 4; ++pp) {
          const int j = m0 + mi * 16 + g * 4 + pp;
          twB[(size_t)j * 24576 + c] = f2bf(acc[mi][ni][pp]);
        }
      }
  } else {
    const int N = isgh ? GW : A4W;
    float* C = isgh ? ghb : A4;
    const float* bias = isgh ? bhh : b1cat;
#pragma unroll
    for (int mi = 0; mi < 4; ++mi)
#pragma unroll
      for (int ni = 0; ni < 4; ++ni) {
        const int col = n0 + w * 64 + ni * 16 + ln;
        const float bv = bias[col];
#pragma unroll
        for (int pp = 0; pp < 4; ++pp) {
          const int row = m0 + mi * 16 + g * 4 + pp;
          C[(size_t)row * N + col] = acc[mi][ni][pp] + bv;
        }
      }
  }
}

// ---------------- pair logits + softmax -> swA[j][i][32] (bf16) -------------
__global__ __launch_bounds__(256) void k_pairlog(
    const float* __restrict__ A4, const unsigned short* __restrict__ W2sbf,
    const unsigned short* __restrict__ W2dbf, const float* __restrict__ b2s,
    const float* __restrict__ b2d, unsigned short* __restrict__ swA) {
  __shared__ float red[8][16][17];
  const int i = blockIdx.x, jb = blockIdx.y;
  const int tid = threadIdx.x, w = tid >> 6, l = tid & 63;
  const int g = l >> 4, ln = l & 15;
  const int j = jb * 16 + ln;
  const float* BsP = A4 + (size_t)j * A4W + 768 + g * 8;
  const float* BdP = A4 + (size_t)j * A4W + 2304 + g * 8;
  const float* AsP = A4 + (size_t)i * A4W + g * 8;
  const float* AdP = A4 + (size_t)i * A4W + 1536 + g * 8;
  const unsigned short* WsP = W2sbf + (size_t)ln * H + g * 8;
  const unsigned short* WdP = W2dbf + (size_t)ln * H + g * 8;
  f32x4 accs = (f32x4){0.f, 0.f, 0.f, 0.f}, accd = (f32x4){0.f, 0.f, 0.f, 0.f};
#pragma unroll
  for (int tt = 0; tt < 6; ++tt) {
    const int ko = (w * 6 + tt) * 32;
    float4 b0 = *(const float4*)(BsP + ko), b1 = *(const float4*)(BsP + ko + 4);
    float4 a0 = *(const float4*)(AsP + ko), a1 = *(const float4*)(AsP + ko + 4);
    float4 e0 = *(const float4*)(BdP + ko), e1 = *(const float4*)(BdP + ko + 4);
    float4 c0 = *(const float4*)(AdP + ko), c1 = *(const float4*)(AdP + ko + 4);
    u16x8 afs, afd;
    unsigned int* ps = (unsigned int*)&afs;
    ps[0] = cvtpk(relu(a0.x + b0.x), relu(a0.y + b0.y));
    ps[1] = cvtpk(relu(a0.z + b0.z), relu(a0.w + b0.w));
    ps[2] = cvtpk(relu(a1.x + b1.x), relu(a1.y + b1.y));
    ps[3] = cvtpk(relu(a1.z + b1.z), relu(a1.w + b1.w));
    unsigned int* pd = (unsigned int*)&afd;
    pd[0] = cvtpk(relu(c0.x + e0.x), relu(c0.y + e0.y));
    pd[1] = cvtpk(relu(c0.z + e0.z), relu(c0.w + e0.w));
    pd[2] = cvtpk(relu(c1.x + e1.x), relu(c1.y + e1.y));
    pd[3] = cvtpk(relu(c1.z + e1.z), relu(c1.w + e1.w));
    accs = MFMA(afs, ld8(WsP + ko), accs);
    accd = MFMA(afd, ld8(WdP + ko), accd);
  }
#pragma unroll
  for (int pp = 0; pp < 4; ++pp) {
    red[w * 2][g * 4 + pp][ln] = accs[pp];
    red[w * 2 + 1][g * 4 + pp][ln] = accd[pp];
  }
  __syncthreads();
  const int j2 = tid >> 4, r = tid & 15;
  float vs = red[0][j2][r] + red[2][j2][r] + red[4][j2][r] + red[6][j2][r] + b2s[r];
  float vd = red[1][j2][r] + red[3][j2][r] + red[5][j2][r] + red[7][j2][r] + b2d[r];
  float ms = vs;
  ms = fmaxf(ms, __shfl_xor(ms, 1)); ms = fmaxf(ms, __shfl_xor(ms, 2));
  ms = fmaxf(ms, __shfl_xor(ms, 4)); ms = fmaxf(ms, __shfl_xor(ms, 8));
  float md = vd;
  md = fmaxf(md, __shfl_xor(md, 1)); md = fmaxf(md, __shfl_xor(md, 2));
  md = fmaxf(md, __shfl_xor(md, 4)); md = fmaxf(md, __shfl_xor(md, 8));
  float es = __expf(vs - ms), ed = __expf(vd - md);
  float ss = es;
  ss += __shfl_xor(ss, 1); ss += __shfl_xor(ss, 2); ss += __shfl_xor(ss, 4); ss += __shfl_xor(ss, 8);
  float sd = ed;
  sd += __shfl_xor(sd, 1); sd += __shfl_xor(sd, 2); sd += __shfl_xor(sd, 4); sd += __shfl_xor(sd, 8);
  const size_t o = (size_t)(jb * 16 + j2) * 6144 + (size_t)i * 32;
  swA[o + r] = f2bf(es / ss);
  swA[o + 16 + r] = f2bf(ed / sd);
}

// ---------------- per-pair weighted message + relu + sum_j -> v_part --------
__global__ __launch_bounds__(256) void k_pairmsg(const unsigned short* __restrict__ swA,
                                                 const unsigned short* __restrict__ twB,
                                                 const float* __restrict__ bm1,
                                                 float* __restrict__ vpart) {
  const int dt = blockIdx.x, it = blockIdx.y, js = blockIdx.z;
  const int tid = threadIdx.x;
  const int w = tid >> 6, l = tid & 63, g = l >> 4, ln = l & 15;
  const int i0 = it * 64 + w * 16;
  const int d0 = dt * 64;
  float bm1v[4];
#pragma unroll
  for (int nt = 0; nt < 4; ++nt) bm1v[nt] = bm1[d0 + nt * 16 + ln];
  f32x4 vacc[4];
#pragma unroll
  for (int nt = 0; nt < 4; ++nt) vacc[nt] = (f32x4){0.f, 0.f, 0.f, 0.f};
  const unsigned short* ap = swA + (size_t)(i0 + ln) * 32 + g * 8 + (size_t)js * 24 * 6144;
  const unsigned short* bp[4];
#pragma unroll
  for (int nt = 0; nt < 4; ++nt)
    bp[nt] = twB + (size_t)(d0 + nt * 16 + ln) * 32 + g * 8 + (size_t)js * 24 * 24576;
  const f32x4 z4 = (f32x4){0.f, 0.f, 0.f, 0.f};
#pragma unroll 4
  for (int jj = 0; jj < 24; ++jj) {
    u16x8 a = ld8(ap + (size_t)jj * 6144);
#pragma unroll
    for (int nt = 0; nt < 4; ++nt) {
      u16x8 b = ld8(bp[nt] + (size_t)jj * 24576);
      f32x4 mf = MFMA(a, b, z4);
#pragma unroll
      for (int pp = 0; pp < 4; ++pp) vacc[nt][pp] += fmaxf(mf[pp] + bm1v[nt], 0.f);
    }
  }
#pragma unroll
  for (int nt = 0; nt < 4; ++nt)
#pragma unroll
    for (int pp = 0; pp < 4; ++pp) {
      const int row = i0 + g * 4 + pp;
      vpart[(size_t)js * 147456 + (size_t)row * H + d0 + nt * 16 + ln] = vacc[nt][pp];
    }
}

__global__ void k_vred(const float* __restrict__ vpart, unsigned short* __restrict__ vhi,
                       unsigned short* __restrict__ vlo) {
  int e = blockIdx.x * 256 + threadIdx.x;  // 147456
  float s = 0.f;
#pragma unroll
  for (int q = 0; q < 8; ++q) s += vpart[(size_t)q * 147456 + e];
  s *= (1.0f / 192.0f);
  unsigned short hi = f2bf(s);
  vhi[e] = hi;
  vlo[e] = f2bf(s - bf2f(hi));
}

__global__ void k_gru(const float* __restrict__ gxp, const float* __restrict__ bcv,
                      const float* __restrict__ gh, float* __restrict__ h,
                      unsigned short* __restrict__ hhi, unsigned short* __restrict__ hlo,
                      float* __restrict__ out, int last) {
  int e = blockIdx.x * 256 + threadIdx.x;  // 147456
  int i = e / H, k = e - i * H;
  size_t base = (size_t)i * GW;
  const size_t S = (size_t)NTOT * GW;
  float rr = gxp[base + k] + gxp[S + base + k] + gxp[2 * S + base + k] +
             gxp[3 * S + base + k] + bcv[k] + gh[base + k];
  float zz = gxp[base + H + k] + gxp[S + base + H + k] + gxp[2 * S + base + H + k] +
             gxp[3 * S + base + H + k] + bcv[H + k] + gh[base + H + k];
  float r = 1.f / (1.f + __expf(-rr));
  float z = 1.f / (1.f + __expf(-zz));
  float nn = gxp[base + 2 * H + k] + gxp[S + base + 2 * H + k] +
             gxp[2 * S + base + 2 * H + k] + gxp[3 * S + base + 2 * H + k] +
             bcv[2 * H + k];
  float n = tanhf(nn + r * gh[base + 2 * H + k]);
  float hv = (1.f - z) * n + z * h[e];
  h[e] = hv;
  unsigned short hi = f2bf(hv);
  hhi[e] = hi;
  hlo[e] = f2bf(hv - bf2f(hi));
  if (last && i >= 64) out[(size_t)(i - 64) * H + k] = hv;
}

// ---------------- launch ----------------------------------------------------

extern "C" void kernel_launch(void* const* d_in, const int* in_sizes, int n_in,
                              void* d_out, int out_size, void* d_ws, size_t ws_size,
                              hipStream_t stream) {
  const float* asp = (const float*)d_in[0];
  const float* qry = (const float*)d_in[1];
  const float* W1s = (const float*)d_in[3];
  const float* b1s = (const float*)d_in[4];
  const float* W2s = (const float*)d_in[5];
  const float* b2s = (const float*)d_in[6];
  const float* W1d = (const float*)d_in[7];
  const float* b1d = (const float*)d_in[8];
  const float* W2d = (const float*)d_in[9];
  const float* b2d = (const float*)d_in[10];
  const float* Rs  = (const float*)d_in[11];
  const float* Rd  = (const float*)d_in[12];
  const float* Wm1 = (const float*)d_in[13];
  const float* bm1 = (const float*)d_in[14];
  const float* Wm2 = (const float*)d_in[15];
  const float* bm2 = (const float*)d_in[16];
  const float* Wih = (const float*)d_in[17];
  const float* Whh = (const float*)d_in[18];
  const float* bih = (const float*)d_in[19];
  const float* bhh = (const float*)d_in[20];
  float* out = (float*)d_out;

  char* p = (char*)d_ws;
  auto take = [&](size_t bytes) {
    char* q = p;
    p += (bytes + 255) & ~(size_t)255;
    return q;
  };
  // ---- step-scratch region, aliased during prep ----
  float* h            = (float*)take((size_t)NTOT * H * 4);
  unsigned short* hhi = (unsigned short*)take((size_t)NTOT * H * 2);
  unsigned short* hlo = (unsigned short*)take((size_t)NTOT * H * 2);
  float* A4           = (float*)take((size_t)NTOT * A4W * 4);
  float* ghb          = (float*)take((size_t)NTOT * GW * 4);
  unsigned short* vhi = (unsigned short*)take((size_t)NTOT * H * 2);
  unsigned short* vlo = (unsigned short*)take((size_t)NTOT * H * 2);
  float* vpart        = (float*)take((size_t)8 * NTOT * H * 4);
  unsigned short* swA = (unsigned short*)take((size_t)NTOT * NTOT * 32 * 2);
  unsigned short* twB = (unsigned short*)take((size_t)NTOT * H * 32 * 2);  // also gx partials
  // ---- permanent weights ----
  unsigned short* RsWt = (unsigned short*)take((size_t)2 * 16 * H * H * 2);
  unsigned short* Wm1bf = (unsigned short*)take((size_t)H * H * 2);
  unsigned short* W2sbf = (unsigned short*)take((size_t)16 * H * 2);
  unsigned short* W2dbf = (unsigned short*)take((size_t)16 * H * 2);
  unsigned short* W1cat = (unsigned short*)take((size_t)A4W * H * 2);
  float* b1cat        = (float*)take((size_t)A4W * 4);
  unsigned short* Whhh = (unsigned short*)take((size_t)GW * H * 2);
  unsigned short* Whhl = (unsigned short*)take((size_t)GW * H * 2);
  unsigned short* Wch  = (unsigned short*)take((size_t)GW * H * 2);
  unsigned short* Wcl  = (unsigned short*)take((size_t)GW * H * 2);
  float* bc           = (float*)take((size_t)GW * 4);
  // ---- prep-phase aliases (within step-scratch, after h/hhi/hlo @1,179,648) ----
  unsigned short* Wm2th = (unsigned short*)((char*)d_ws + 1179648);
  unsigned short* Wm2tl = Wm2th + (size_t)H * H;  // ends ~3.54 MB

  // ---- once-per-launch prep ----
  k_prep<<<5928, 256, 0, stream>>>(Wm1, W2s, W2d, Whh, Wih, Wm2, W1s, W1d, b1s, b1d,
                                   bm2, bih, asp, qry,
                                   Wm1bf, W2sbf, W2dbf, Whhh, Whhl,
                                   Wm2th, Wm2tl, W1cat, b1cat, bc, h, hhi, hlo);
  k_pre2<<<1260, 256, 0, stream>>>(Wm1bf, Rs, Rd, RsWt, Wih, Wm2th, Wm2tl, Wch, Wcl);

  // ---- propagation steps ----
  for (int step = 0; step < 3; ++step) {
    k_tile<<<351, 256, 0, stream>>>(hhi, hlo, W1cat, b1cat, Whhh, Whhl, bhh, RsWt,
                                    A4, ghb, twB);
    k_pairlog<<<dim3(192, 12), 256, 0, stream>>>(A4, W2sbf, W2dbf, b2s, b2d, swA);
    k_pairmsg<<<dim3(12, 3, 8), 256, 0, stream>>>(swA, twB, bm1, vpart);
    k_vred<<<576, 256, 0, stream>>>(vpart, vhi, vlo);
    k_btks<<<dim3(36, 3, 4), 256, 0, stream>>>(vhi, vlo, Wch, Wcl, (float*)twB);
    k_gru<<<576, 256, 0, stream>>>((float*)twB, bc, ghb, h, hhi, hlo, out, step == 2);
  }
  (void)in_sizes; (void)n_in; (void)out_size; (void)ws_size;
}

// Round 9
// 493.696 us; speedup vs baseline: 1.9521x; 1.0599x over previous
//
#include <hip/hip_runtime.h>
#include <hip/hip_bf16.h>

#define H 768
#define NTOT 192
#define A4W 3072
#define GW 2304

typedef __attribute__((ext_vector_type(4))) float f32x4;
typedef __attribute__((ext_vector_type(8))) unsigned short u16x8;
typedef __attribute__((ext_vector_type(4))) unsigned short u16x4;
typedef __attribute__((ext_vector_type(8))) __bf16 bf16x8v;

static __device__ __forceinline__ unsigned short f2bf(float f) {
  __hip_bfloat16 b = __float2bfloat16(f);
  return __builtin_bit_cast(unsigned short, b);
}
static __device__ __forceinline__ float bf2f(unsigned short u) {
  return __bfloat162float(__builtin_bit_cast(__hip_bfloat16, u));
}
static __device__ __forceinline__ f32x4 MFMA(u16x8 a, u16x8 b, f32x4 c) {
  return __builtin_amdgcn_mfma_f32_16x16x32_bf16(
      __builtin_bit_cast(bf16x8v, a), __builtin_bit_cast(bf16x8v, b), c, 0, 0, 0);
}
static __device__ __forceinline__ u16x8 ld8(const unsigned short* p) {
  return *(const u16x8*)p;
}
static __device__ __forceinline__ unsigned int cvtpk(float lo, float hi) {
  unsigned int r;
  asm("v_cvt_pk_bf16_f32 %0, %1, %2" : "=v"(r) : "v"(lo), "v"(hi));
  return r;
}
static __device__ __forceinline__ float relu(float x) { return fmaxf(x, 0.f); }

#define GLDS16(gp, lp)                                                   \
  __builtin_amdgcn_global_load_lds(                                      \
      (const __attribute__((address_space(1))) void*)(gp),               \
      (__attribute__((address_space(3))) void*)(lp), 16, 0, 0)

// ---------------- fused prep: weight conversions + bc + inith --------------
// segments: Wm1 576 | W2s 12 | W2d 12 | Whh 1728 | Wm2t 576 | W1cat 2304 |
//           bc 576 | inith 144  => grid 5928
__global__ void k_prep(const float* __restrict__ Wm1, const float* __restrict__ W2s,
                       const float* __restrict__ W2d, const float* __restrict__ Whh,
                       const float* __restrict__ Wih, const float* __restrict__ Wm2,
                       const float* __restrict__ W1s, const float* __restrict__ W1d,
                       const float* __restrict__ b1s, const float* __restrict__ b1d,
                       const float* __restrict__ bm2, const float* __restrict__ bih,
                       const float* __restrict__ asp, const float* __restrict__ qry,
                       unsigned short* __restrict__ Wm1bf, unsigned short* __restrict__ W2sbf,
                       unsigned short* __restrict__ W2dbf, unsigned short* __restrict__ Whhh,
                       unsigned short* __restrict__ Whhl, unsigned short* __restrict__ Wm2th,
                       unsigned short* __restrict__ Wm2tl, unsigned short* __restrict__ W1cat,
                       float* __restrict__ b1cat, float* __restrict__ bc,
                       float* __restrict__ h, unsigned short* __restrict__ hhi,
                       unsigned short* __restrict__ hlo) {
  const int b = blockIdx.x, tid = threadIdx.x;
  if (b < 576) {
    int u = b * 256 + tid;
    float4 v = ((const float4*)Wm1)[u];
    u16x4 o; o[0] = f2bf(v.x); o[1] = f2bf(v.y); o[2] = f2bf(v.z); o[3] = f2bf(v.w);
    ((u16x4*)Wm1bf)[u] = o;
  } else if (b < 588) {
    int u = (b - 576) * 256 + tid;
    float4 v = ((const float4*)W2s)[u];
    u16x4 o; o[0] = f2bf(v.x); o[1] = f2bf(v.y); o[2] = f2bf(v.z); o[3] = f2bf(v.w);
    ((u16x4*)W2sbf)[u] = o;
  } else if (b < 600) {
    int u = (b - 588) * 256 + tid;
    float4 v = ((const float4*)W2d)[u];
    u16x4 o; o[0] = f2bf(v.x); o[1] = f2bf(v.y); o[2] = f2bf(v.z); o[3] = f2bf(v.w);
    ((u16x4*)W2dbf)[u] = o;
  } else if (b < 2328) {
    int u = (b - 600) * 256 + tid;
    float4 v = ((const float4*)Whh)[u];
    u16x4 oh, ol;
#pragma unroll
    for (int j = 0; j < 4; ++j) {
      float f = ((const float*)&v)[j];
      oh[j] = f2bf(f); ol[j] = f2bf(f - bf2f(oh[j]));
    }
    ((u16x4*)Whhh)[u] = oh; ((u16x4*)Whhl)[u] = ol;
  } else if (b < 2904) {
    int u = (b - 2328) * 256 + tid;  // Wm2 f4 index; emit TRANSPOSED hi/lo
    float4 v = ((const float4*)Wm2)[u];
    int e_lin = u * 4;
    int er = e_lin / H, kc = e_lin - er * H;
#pragma unroll
    for (int j = 0; j < 4; ++j) {
      float f = ((const float*)&v)[j];
      unsigned short hi = f2bf(f);
      Wm2th[(size_t)(kc + j) * H + er] = hi;
      Wm2tl[(size_t)(kc + j) * H + er] = f2bf(f - bf2f(hi));
    }
  } else if (b < 5208) {
    int u = (b - 2904) * 256 + tid;  // f4 index into W1cat [3072][768]
    int e = u * 4;
    int row = e / H, k = e - row * H;
    int part = row / H, o = row - part * H;
    const float* W = (part < 2) ? W1s : W1d;
    float4 v = *(const float4*)(W + (size_t)o * (2 * H) + (part & 1) * H + k);
    u16x4 ov; ov[0] = f2bf(v.x); ov[1] = f2bf(v.y); ov[2] = f2bf(v.z); ov[3] = f2bf(v.w);
    *(u16x4*)(W1cat + e) = ov;
    if (u < 768) {
      int e2 = u * 4, pp = e2 / H, oo = e2 - pp * H;
      float4 bv;
      if (pp == 0) bv = *(const float4*)(b1s + oo);
      else if (pp == 2) bv = *(const float4*)(b1d + oo);
      else bv = (float4){0.f, 0.f, 0.f, 0.f};
      *(float4*)(b1cat + e2) = bv;
    }
  } else if (b < 5784) {
    // bc[g] = bih[g] + sum_e Wih[g][e]*bm2[e]
    const int w = tid >> 6, l = tid & 63;
    const int gg = (b - 5208) * 4 + w;
    const float* row = Wih + (size_t)gg * H;
    float s = 0.f;
#pragma unroll
    for (int q = 0; q < 12; ++q) s += row[l + q * 64] * bm2[l + q * 64];
#pragma unroll
    for (int m = 32; m; m >>= 1) s += __shfl_xor(s, m);
    if (l == 0) bc[gg] = bih[gg] + s;
  } else {
    int u = (b - 5784) * 256 + tid;  // f4 index, 36864
    float4 v = (u < 12288) ? ((const float4*)asp)[u] : ((const float4*)qry)[u - 12288];
    ((float4*)h)[u] = v;
    u16x4 oh, ol;
#pragma unroll
    for (int j = 0; j < 4; ++j) {
      float f = ((const float*)&v)[j];
      oh[j] = f2bf(f); ol[j] = f2bf(f - bf2f(oh[j]));
    }
    ((u16x4*)hhi)[u] = oh; ((u16x4*)hlo)[u] = ol;
  }
}

// ---------------- merged prep GEMM, 32 KB LDS, 1584 blocks ------------------
// blocks 0..1151: RsW (single-buffer, fused fp32->bf16 cvt of R)
// blocks 1152..1583: Wc = Wih @ Wm2t^T, 64x64 tiles (hilo x hilo)
__global__ __launch_bounds__(256) void k_pre2(const unsigned short* __restrict__ Wm1bf,
                                              const float* __restrict__ Rsf,
                                              const float* __restrict__ Rdf,
                                              unsigned short* __restrict__ RsWt,
                                              const float* __restrict__ Wih,
                                              const unsigned short* __restrict__ Bth,
                                              const unsigned short* __restrict__ Btl,
                                              unsigned short* __restrict__ Ch,
                                              unsigned short* __restrict__ Cl) {
  __shared__ unsigned short LDS[16384];  // 32 KB
  const int wg = blockIdx.x;
  const int tid = threadIdx.x, w = tid >> 6, l = tid & 63;
  const int g = l >> 4, ln = l & 15;
  const int srow = l >> 3;
  const int skb = ((l & 7) ^ srow) * 8;
  const int x7 = ln & 7;

  if (wg >= 1152) {
    // --------- Wc: 64x64 tile, BK=64; warp w owns cols n0+w*16 --------------
    unsigned short* Ahl = LDS;             // 64x64 bf16 = 8 KB
    unsigned short* All = LDS + 4096;
    unsigned short* Bhl = LDS + 8192;
    unsigned short* Bll = LDS + 12288;
    const int bid = wg - 1152;
    const int m0 = (bid / 12) * 64, n0 = (bid % 12) * 64;
    const unsigned short* Bgh = Bth + (size_t)(n0 + srow) * H + skb;
    const unsigned short* Bgl = Btl + (size_t)(n0 + srow) * H + skb;
    f32x4 acc[4];
#pragma unroll
    for (int mi = 0; mi < 4; ++mi) acc[mi] = (f32x4){0.f, 0.f, 0.f, 0.f};
    for (int kb = 0; kb < H; kb += 64) {
#pragma unroll
      for (int c2 = 0; c2 < 2; ++c2) {
        const int c = w * 2 + c2;
        GLDS16(Bgh + (size_t)(c * 8) * H + kb, &Bhl[c * 512]);
        GLDS16(Bgl + (size_t)(c * 8) * H + kb, &Bll[c * 512]);
      }
#pragma unroll
      for (int q = 0; q < 2; ++q) {
        const int idx = q * 256 + tid;
        const int row = idx >> 3, kb8 = idx & 7;
        const float* src = Wih + (size_t)(m0 + row) * H + kb + kb8 * 8;
        float4 v0 = *(const float4*)src;
        float4 v1 = *(const float4*)(src + 4);
        float fv[8] = {v0.x, v0.y, v0.z, v0.w, v1.x, v1.y, v1.z, v1.w};
        u16x8 oh, ol;
#pragma unroll
        for (int jq = 0; jq < 8; ++jq) {
          unsigned short hi = f2bf(fv[jq]);
          oh[jq] = hi;
          ol[jq] = f2bf(fv[jq] - bf2f(hi));
        }
        const int dst = row * 64 + (kb8 ^ (row & 7)) * 8;
        *(u16x8*)&Ahl[dst] = oh;
        *(u16x8*)&All[dst] = ol;
      }
      __syncthreads();
#pragma unroll
      for (int kk = 0; kk < 2; ++kk) {
        const int pb = ((kk * 4 + g) ^ x7) * 8;
        u16x8 bh = ld8(&Bhl[(w * 16 + ln) * 64 + pb]);
        u16x8 bl = ld8(&Bll[(w * 16 + ln) * 64 + pb]);
#pragma unroll
        for (int mi = 0; mi < 4; ++mi) {
          u16x8 ah = ld8(&Ahl[(mi * 16 + ln) * 64 + pb]);
          u16x8 al = ld8(&All[(mi * 16 + ln) * 64 + pb]);
          acc[mi] = MFMA(ah, bh, acc[mi]);
          acc[mi] = MFMA(ah, bl, acc[mi]);
          acc[mi] = MFMA(al, bh, acc[mi]);
        }
      }
      __syncthreads();
    }
#pragma unroll
    for (int mi = 0; mi < 4; ++mi) {
      const int col = n0 + w * 16 + ln;
#pragma unroll
      for (int pp = 0; pp < 4; ++pp) {
        const int row = m0 + mi * 16 + g * 4 + pp;
        const float val = acc[mi][pp];
        unsigned short hi = f2bf(val);
        Ch[(size_t)row * H + col] = hi;
        Cl[(size_t)row * H + col] = f2bf(val - bf2f(hi));
      }
    }
    return;
  }

  // --------- RsW: z<16 -> Rs[z], else Rd[z-16]; out row = d*32+z ------------
  unsigned short* Asl = LDS;          // 128x64 bf16 = 16 KB
  unsigned short* Bsl = LDS + 8192;   // 128x64 bf16 = 16 KB
  const int nb = (wg & 7) * 144 + (wg >> 3);       // chunked XCD swizzle
  const int z = nb / 36, t5 = nb - z * 36;
  const int d0 = (t5 / 6) * 128, k0 = (t5 % 6) * 128;
  const int wr = w >> 1, wc = w & 1;
  const unsigned short* Ag = Wm1bf + (size_t)(d0 + srow) * H + skb;
  const float* Bg = ((z < 16) ? Rsf : Rdf) + (size_t)(z & 15) * (H * H);
  f32x4 acc[4][4];
#pragma unroll
  for (int mi = 0; mi < 4; ++mi)
#pragma unroll
    for (int ni = 0; ni < 4; ++ni) acc[mi][ni] = (f32x4){0.f, 0.f, 0.f, 0.f};
  for (int kb = 0; kb < H; kb += 64) {
#pragma unroll
    for (int c4 = 0; c4 < 4; ++c4) {
      const int c = w * 4 + c4;
      GLDS16(Ag + (size_t)(c * 8) * H + kb, &Asl[c * 512]);
    }
#pragma unroll
    for (int q = 0; q < 4; ++q) {
      const int idx = q * 256 + tid;
      const int row = idx >> 3, kb8 = idx & 7;
      const float* src = Bg + (size_t)(k0 + row) * H + kb + kb8 * 8;
      float4 v0 = *(const float4*)src;
      float4 v1 = *(const float4*)(src + 4);
      u16x8 o;
      unsigned int* po = (unsigned int*)&o;
      po[0] = cvtpk(v0.x, v0.y);
      po[1] = cvtpk(v0.z, v0.w);
      po[2] = cvtpk(v1.x, v1.y);
      po[3] = cvtpk(v1.z, v1.w);
      *(u16x8*)&Bsl[row * 64 + (kb8 ^ (row & 7)) * 8] = o;
    }
    __syncthreads();
#pragma unroll
    for (int kk = 0; kk < 2; ++kk) {
      u16x8 af[4], bf[4];
      const int pb = ((kk * 4 + g) ^ x7) * 8;
#pragma unroll
      for (int mi = 0; mi < 4; ++mi) af[mi] = ld8(&Asl[(wr * 64 + mi * 16 + ln) * 64 + pb]);
#pragma unroll
      for (int ni = 0; ni < 4; ++ni) bf[ni] = ld8(&Bsl[(wc * 64 + ni * 16 + ln) * 64 + pb]);
#pragma unroll
      for (int mi = 0; mi < 4; ++mi)
#pragma unroll
        for (int ni = 0; ni < 4; ++ni) acc[mi][ni] = MFMA(af[mi], bf[ni], acc[mi][ni]);
    }
    __syncthreads();
  }
#pragma unroll
  for (int mi = 0; mi < 4; ++mi) {
    const int d = d0 + wr * 64 + mi * 16 + g * 4;
#pragma unroll
    for (int ni = 0; ni < 4; ++ni) {
      const int k = k0 + wc * 64 + ni * 16 + ln;
      unsigned short* o = RsWt + ((size_t)d * 32 + z) * H + k;
#pragma unroll
      for (int pp = 0; pp < 4; ++pp) o[(size_t)pp * 32 * H] = f2bf(acc[mi][ni][pp]);
    }
  }
}

// ---------------- K-split(4) hilo GEMM for gx (no bias, raw partials) -------
__global__ __launch_bounds__(256) void k_btks(
    const unsigned short* __restrict__ Ahi, const unsigned short* __restrict__ Alo,
    const unsigned short* __restrict__ Bhi, const unsigned short* __restrict__ Blo,
    float* __restrict__ Cp) {
  const int tid = threadIdx.x;
  const int w = tid >> 6, l = tid & 63, g = l >> 4, ln = l & 15;
  const int m0 = blockIdx.y * 64 + w * 16;
  const int n0 = blockIdx.x * 64;
  const int kh = blockIdx.z, kb0 = kh * 192;
  const unsigned short* aph = Ahi + (size_t)(m0 + ln) * H + kb0 + g * 8;
  const unsigned short* apl = Alo + (size_t)(m0 + ln) * H + kb0 + g * 8;
  const unsigned short* bph[4];
  const unsigned short* bpl[4];
#pragma unroll
  for (int nt = 0; nt < 4; ++nt) {
    bph[nt] = Bhi + (size_t)(n0 + nt * 16 + ln) * H + kb0 + g * 8;
    bpl[nt] = Blo + (size_t)(n0 + nt * 16 + ln) * H + kb0 + g * 8;
  }
  f32x4 acc[4];
#pragma unroll
  for (int nt = 0; nt < 4; ++nt) acc[nt] = (f32x4){0.f, 0.f, 0.f, 0.f};
  u16x8 ah[2], al[2], bh[2][4], bl[2][4];
  ah[0] = ld8(aph);
  al[0] = ld8(apl);
#pragma unroll
  for (int nt = 0; nt < 4; ++nt) { bh[0][nt] = ld8(bph[nt]); bl[0][nt] = ld8(bpl[nt]); }
#pragma unroll
  for (int t = 0; t < 6; ++t) {
    const int cur = t & 1, nxt = cur ^ 1;
    if (t < 5) {
      const int ko = (t + 1) * 32;
      ah[nxt] = ld8(aph + ko);
      al[nxt] = ld8(apl + ko);
#pragma unroll
      for (int nt = 0; nt < 4; ++nt) {
        bh[nxt][nt] = ld8(bph[nt] + ko);
        bl[nxt][nt] = ld8(bpl[nt] + ko);
      }
    }
#pragma unroll
    for (int nt = 0; nt < 4; ++nt) {
      acc[nt] = MFMA(ah[cur], bh[cur][nt], acc[nt]);
      acc[nt] = MFMA(ah[cur], bl[cur][nt], acc[nt]);
      acc[nt] = MFMA(al[cur], bh[cur][nt], acc[nt]);
    }
  }
#pragma unroll
  for (int nt = 0; nt < 4; ++nt) {
    const int col = n0 + nt * 16 + ln;
#pragma unroll
    for (int pp = 0; pp < 4; ++pp) {
      const int row = m0 + g * 4 + pp;
      Cp[(size_t)kh * (NTOT * GW) + (size_t)row * GW + col] = acc[nt][pp];
    }
  }
}

// ---------------- per-step LDS-staged tiled GEMM: gh | A4 | twB -------------
// 64(M) x 128(N) tiles, BK=64. bid<54: gh (hilo); 54..125: A4; 126..701: twB.
__global__ __launch_bounds__(256) void k_tile(
    const unsigned short* __restrict__ hhi, const unsigned short* __restrict__ hlo,
    const unsigned short* __restrict__ W1cat, const float* __restrict__ b1cat,
    const unsigned short* __restrict__ Whhh, const unsigned short* __restrict__ Whhl,
    const float* __restrict__ bhh, const unsigned short* __restrict__ RsWt,
    float* __restrict__ A4, float* __restrict__ ghb, unsigned short* __restrict__ twB) {
  __shared__ unsigned short Ah[4096], Al[4096], Bh[8192], Bl[8192];  // 48 KB
  const int bid = blockIdx.x;
  const int tid = threadIdx.x, w = tid >> 6, l = tid & 63, g = l >> 4, ln = l & 15;
  int path, m, n;
  if (bid < 54)       { path = 0; n = bid / 3;         m = bid % 3; }
  else if (bid < 126) { path = 1; n = (bid - 54) / 3;  m = (bid - 54) % 3; }
  else                { path = 2; n = (bid - 126) / 3; m = (bid - 126) % 3; }
  const int m0 = m * 64, n0 = n * 128;
  const bool isgh = (path == 0);
  const unsigned short* Bsrc = (path == 0) ? Whhh : (path == 1) ? W1cat : RsWt;
  const int srow = l >> 3;
  const int skb = ((l & 7) ^ srow) * 8;
  const unsigned short* Agh = hhi + (size_t)(m0 + srow) * H + skb;
  const unsigned short* Agl = hlo + (size_t)(m0 + srow) * H + skb;
  const unsigned short* Bgh = Bsrc + (size_t)(n0 + srow) * H + skb;
  const unsigned short* Bgl = Whhl + (size_t)((isgh ? n0 : 0) + srow) * H + skb;
  f32x4 acc[4][2];
#pragma unroll
  for (int mi = 0; mi < 4; ++mi)
#pragma unroll
    for (int ni = 0; ni < 2; ++ni) acc[mi][ni] = (f32x4){0.f, 0.f, 0.f, 0.f};
  const int x7 = ln & 7;
  for (int kb = 0; kb < H; kb += 64) {
#pragma unroll
    for (int c2 = 0; c2 < 2; ++c2) {
      const int c = w * 2 + c2;
      GLDS16(Agh + (size_t)(c * 8) * H + kb, &Ah[c * 512]);
      if (isgh) GLDS16(Agl + (size_t)(c * 8) * H + kb, &Al[c * 512]);
    }
#pragma unroll
    for (int c4 = 0; c4 < 4; ++c4) {
      const int c = w * 4 + c4;
      GLDS16(Bgh + (size_t)(c * 8) * H + kb, &Bh[c * 512]);
      if (isgh) GLDS16(Bgl + (size_t)(c * 8) * H + kb, &Bl[c * 512]);
    }
    __syncthreads();
#pragma unroll
    for (int kk = 0; kk < 2; ++kk) {
      const int pb = ((kk * 4 + g) ^ x7) * 8;
      u16x8 af[4], bf[2];
#pragma unroll
      for (int mi = 0; mi < 4; ++mi) af[mi] = ld8(&Ah[(mi * 16 + ln) * 64 + pb]);
#pragma unroll
      for (int ni = 0; ni < 2; ++ni) bf[ni] = ld8(&Bh[(w * 32 + ni * 16 + ln) * 64 + pb]);
      if (isgh) {
        u16x8 alf[4], blf[2];
#pragma unroll
        for (int mi = 0; mi < 4; ++mi) alf[mi] = ld8(&Al[(mi * 16 + ln) * 64 + pb]);
#pragma unroll
        for (int ni = 0; ni < 2; ++ni) blf[ni] = ld8(&Bl[(w * 32 + ni * 16 + ln) * 64 + pb]);
#pragma unroll
        for (int mi = 0; mi < 4; ++mi)
#pragma unroll
          for (int ni = 0; ni < 2; ++ni) {
            acc[mi][ni] = MFMA(af[mi], bf[ni], acc[mi][ni]);
            acc[mi][ni] = MFMA(af[mi], blf[ni], acc[mi][ni]);
            acc[mi][ni] = MFMA(alf[mi], bf[ni], acc[mi][ni]);
          }
      } else {
#pragma unroll
        for (int mi = 0; mi < 4; ++mi)
#pragma unroll
          for (int ni = 0; ni < 2; ++ni) acc[mi][ni] = MFMA(af[mi], bf[ni], acc[mi][ni]);
      }
    }
    __syncthreads();
  }
  if (path == 2) {
#pragma unroll
    for (int mi = 0; mi < 4; ++mi)
#pragma unroll
      for (int ni = 0; ni < 2; ++ni) {
        const int c = n0 + w * 32 + ni * 16 + ln;
#pragma unroll
        for (int pp = 0; pp < 4; ++pp) {
          const int j = m0 + mi * 16 + g * 4 + pp;
          twB[(size_t)j * 24576 + c] = f2bf(acc[mi][ni][pp]);
        }
      }
  } else {
    const int N = isgh ? GW : A4W;
    float* C = isgh ? ghb : A4;
    const float* bias = isgh ? bhh : b1cat;
#pragma unroll
    for (int mi = 0; mi < 4; ++mi)
#pragma unroll
      for (int ni = 0; ni < 2; ++ni) {
        const int col = n0 + w * 32 + ni * 16 + ln;
        const float bv = bias[col];
#pragma unroll
        for (int pp = 0; pp < 4; ++pp) {
          const int row = m0 + mi * 16 + g * 4 + pp;
          C[(size_t)row * N + col] = acc[mi][ni][pp] + bv;
        }
      }
  }
}

// ---------------- pair logits + softmax -> swA[j][i][32] (bf16) -------------
__global__ __launch_bounds__(256) void k_pairlog(
    const float* __restrict__ A4, const unsigned short* __restrict__ W2sbf,
    const unsigned short* __restrict__ W2dbf, const float* __restrict__ b2s,
    const float* __restrict__ b2d, unsigned short* __restrict__ swA) {
  __shared__ float red[8][16][17];
  const int i = blockIdx.x, jb = blockIdx.y;
  const int tid = threadIdx.x, w = tid >> 6, l = tid & 63;
  const int g = l >> 4, ln = l & 15;
  const int j = jb * 16 + ln;
  const float* BsP = A4 + (size_t)j * A4W + 768 + g * 8;
  const float* BdP = A4 + (size_t)j * A4W + 2304 + g * 8;
  const float* AsP = A4 + (size_t)i * A4W + g * 8;
  const float* AdP = A4 + (size_t)i * A4W + 1536 + g * 8;
  const unsigned short* WsP = W2sbf + (size_t)ln * H + g * 8;
  const unsigned short* WdP = W2dbf + (size_t)ln * H + g * 8;
  f32x4 accs = (f32x4){0.f, 0.f, 0.f, 0.f}, accd = (f32x4){0.f, 0.f, 0.f, 0.f};
#pragma unroll
  for (int tt = 0; tt < 6; ++tt) {
    const int ko = (w * 6 + tt) * 32;
    float4 b0 = *(const float4*)(BsP + ko), b1 = *(const float4*)(BsP + ko + 4);
    float4 a0 = *(const float4*)(AsP + ko), a1 = *(const float4*)(AsP + ko + 4);
    float4 e0 = *(const float4*)(BdP + ko), e1 = *(const float4*)(BdP + ko + 4);
    float4 c0 = *(const float4*)(AdP + ko), c1 = *(const float4*)(AdP + ko + 4);
    u16x8 afs, afd;
    unsigned int* ps = (unsigned int*)&afs;
    ps[0] = cvtpk(relu(a0.x + b0.x), relu(a0.y + b0.y));
    ps[1] = cvtpk(relu(a0.z + b0.z), relu(a0.w + b0.w));
    ps[2] = cvtpk(relu(a1.x + b1.x), relu(a1.y + b1.y));
    ps[3] = cvtpk(relu(a1.z + b1.z), relu(a1.w + b1.w));
    unsigned int* pd = (unsigned int*)&afd;
    pd[0] = cvtpk(relu(c0.x + e0.x), relu(c0.y + e0.y));
    pd[1] = cvtpk(relu(c0.z + e0.z), relu(c0.w + e0.w));
    pd[2] = cvtpk(relu(c1.x + e1.x), relu(c1.y + e1.y));
    pd[3] = cvtpk(relu(c1.z + e1.z), relu(c1.w + e1.w));
    accs = MFMA(afs, ld8(WsP + ko), accs);
    accd = MFMA(afd, ld8(WdP + ko), accd);
  }
#pragma unroll
  for (int pp = 0; pp < 4; ++pp) {
    red[w * 2][g * 4 + pp][ln] = accs[pp];
    red[w * 2 + 1][g * 4 + pp][ln] = accd[pp];
  }
  __syncthreads();
  const int j2 = tid >> 4, r = tid & 15;
  float vs = red[0][j2][r] + red[2][j2][r] + red[4][j2][r] + red[6][j2][r] + b2s[r];
  float vd = red[1][j2][r] + red[3][j2][r] + red[5][j2][r] + red[7][j2][r] + b2d[r];
  float ms = vs;
  ms = fmaxf(ms, __shfl_xor(ms, 1)); ms = fmaxf(ms, __shfl_xor(ms, 2));
  ms = fmaxf(ms, __shfl_xor(ms, 4)); ms = fmaxf(ms, __shfl_xor(ms, 8));
  float md = vd;
  md = fmaxf(md, __shfl_xor(md, 1)); md = fmaxf(md, __shfl_xor(md, 2));
  md = fmaxf(md, __shfl_xor(md, 4)); md = fmaxf(md, __shfl_xor(md, 8));
  float es = __expf(vs - ms), ed = __expf(vd - md);
  float ss = es;
  ss += __shfl_xor(ss, 1); ss += __shfl_xor(ss, 2); ss += __shfl_xor(ss, 4); ss += __shfl_xor(ss, 8);
  float sd = ed;
  sd += __shfl_xor(sd, 1); sd += __shfl_xor(sd, 2); sd += __shfl_xor(sd, 4); sd += __shfl_xor(sd, 8);
  const size_t o = (size_t)(jb * 16 + j2) * 6144 + (size_t)i * 32;
  swA[o + r] = f2bf(es / ss);
  swA[o + 16 + r] = f2bf(ed / sd);
}

// ---------------- per-pair weighted message + relu + sum_j -> v_part --------
__global__ __launch_bounds__(256) void k_pairmsg(const unsigned short* __restrict__ swA,
                                                 const unsigned short* __restrict__ twB,
                                                 const float* __restrict__ bm1,
                                                 float* __restrict__ vpart) {
  const int dt = blockIdx.x, it = blockIdx.y, js = blockIdx.z;
  const int tid = threadIdx.x;
  const int w = tid >> 6, l = tid & 63, g = l >> 4, ln = l & 15;
  const int i0 = it * 64 + w * 16;
  const int d0 = dt * 64;
  float bm1v[4];
#pragma unroll
  for (int nt = 0; nt < 4; ++nt) bm1v[nt] = bm1[d0 + nt * 16 + ln];
  f32x4 vacc[4];
#pragma unroll
  for (int nt = 0; nt < 4; ++nt) vacc[nt] = (f32x4){0.f, 0.f, 0.f, 0.f};
  const unsigned short* ap = swA + (size_t)(i0 + ln) * 32 + g * 8 + (size_t)js * 24 * 6144;
  const unsigned short* bp[4];
#pragma unroll
  for (int nt = 0; nt < 4; ++nt)
    bp[nt] = twB + (size_t)(d0 + nt * 16 + ln) * 32 + g * 8 + (size_t)js * 24 * 24576;
  const f32x4 z4 = (f32x4){0.f, 0.f, 0.f, 0.f};
#pragma unroll 4
  for (int jj = 0; jj < 24; ++jj) {
    u16x8 a = ld8(ap + (size_t)jj * 6144);
#pragma unroll
    for (int nt = 0; nt < 4; ++nt) {
      u16x8 b = ld8(bp[nt] + (size_t)jj * 24576);
      f32x4 mf = MFMA(a, b, z4);
#pragma unroll
      for (int pp = 0; pp < 4; ++pp) vacc[nt][pp] += fmaxf(mf[pp] + bm1v[nt], 0.f);
    }
  }
#pragma unroll
  for (int nt = 0; nt < 4; ++nt)
#pragma unroll
    for (int pp = 0; pp < 4; ++pp) {
      const int row = i0 + g * 4 + pp;
      vpart[(size_t)js * 147456 + (size_t)row * H + d0 + nt * 16 + ln] = vacc[nt][pp];
    }
}

__global__ void k_vred(const float* __restrict__ vpart, unsigned short* __restrict__ vhi,
                       unsigned short* __restrict__ vlo) {
  int e = blockIdx.x * 256 + threadIdx.x;  // 147456
  float s = 0.f;
#pragma unroll
  for (int q = 0; q < 8; ++q) s += vpart[(size_t)q * 147456 + e];
  s *= (1.0f / 192.0f);
  unsigned short hi = f2bf(s);
  vhi[e] = hi;
  vlo[e] = f2bf(s - bf2f(hi));
}

__global__ void k_gru(const float* __restrict__ gxp, const float* __restrict__ bcv,
                      const float* __restrict__ gh, float* __restrict__ h,
                      unsigned short* __restrict__ hhi, unsigned short* __restrict__ hlo,
                      float* __restrict__ out, int last) {
  int e = blockIdx.x * 256 + threadIdx.x;  // 147456
  int i = e / H, k = e - i * H;
  size_t base = (size_t)i * GW;
  const size_t S = (size_t)NTOT * GW;
  float rr = gxp[base + k] + gxp[S + base + k] + gxp[2 * S + base + k] +
             gxp[3 * S + base + k] + bcv[k] + gh[base + k];
  float zz = gxp[base + H + k] + gxp[S + base + H + k] + gxp[2 * S + base + H + k] +
             gxp[3 * S + base + H + k] + bcv[H + k] + gh[base + H + k];
  float r = 1.f / (1.f + __expf(-rr));
  float z = 1.f / (1.f + __expf(-zz));
  float nn = gxp[base + 2 * H + k] + gxp[S + base + 2 * H + k] +
             gxp[2 * S + base + 2 * H + k] + gxp[3 * S + base + 2 * H + k] +
             bcv[2 * H + k];
  float n = tanhf(nn + r * gh[base + 2 * H + k]);
  float hv = (1.f - z) * n + z * h[e];
  h[e] = hv;
  unsigned short hi = f2bf(hv);
  hhi[e] = hi;
  hlo[e] = f2bf(hv - bf2f(hi));
  if (last && i >= 64) out[(size_t)(i - 64) * H + k] = hv;
}

// ---------------- launch ----------------------------------------------------

extern "C" void kernel_launch(void* const* d_in, const int* in_sizes, int n_in,
                              void* d_out, int out_size, void* d_ws, size_t ws_size,
                              hipStream_t stream) {
  const float* asp = (const float*)d_in[0];
  const float* qry = (const float*)d_in[1];
  const float* W1s = (const float*)d_in[3];
  const float* b1s = (const float*)d_in[4];
  const float* W2s = (const float*)d_in[5];
  const float* b2s = (const float*)d_in[6];
  const float* W1d = (const float*)d_in[7];
  const float* b1d = (const float*)d_in[8];
  const float* W2d = (const float*)d_in[9];
  const float* b2d = (const float*)d_in[10];
  const float* Rs  = (const float*)d_in[11];
  const float* Rd  = (const float*)d_in[12];
  const float* Wm1 = (const float*)d_in[13];
  const float* bm1 = (const float*)d_in[14];
  const float* Wm2 = (const float*)d_in[15];
  const float* bm2 = (const float*)d_in[16];
  const float* Wih = (const float*)d_in[17];
  const float* Whh = (const float*)d_in[18];
  const float* bih = (const float*)d_in[19];
  const float* bhh = (const float*)d_in[20];
  float* out = (float*)d_out;

  char* p = (char*)d_ws;
  auto take = [&](size_t bytes) {
    char* q = p;
    p += (bytes + 255) & ~(size_t)255;
    return q;
  };
  // ---- step-scratch region, aliased during prep ----
  float* h            = (float*)take((size_t)NTOT * H * 4);
  unsigned short* hhi = (unsigned short*)take((size_t)NTOT * H * 2);
  unsigned short* hlo = (unsigned short*)take((size_t)NTOT * H * 2);
  float* A4           = (float*)take((size_t)NTOT * A4W * 4);
  float* ghb          = (float*)take((size_t)NTOT * GW * 4);
  unsigned short* vhi = (unsigned short*)take((size_t)NTOT * H * 2);
  unsigned short* vlo = (unsigned short*)take((size_t)NTOT * H * 2);
  float* vpart        = (float*)take((size_t)8 * NTOT * H * 4);
  unsigned short* swA = (unsigned short*)take((size_t)NTOT * NTOT * 32 * 2);
  unsigned short* twB = (unsigned short*)take((size_t)NTOT * H * 32 * 2);  // also gx partials
  // ---- permanent weights ----
  unsigned short* RsWt = (unsigned short*)take((size_t)2 * 16 * H * H * 2);
  unsigned short* Wm1bf = (unsigned short*)take((size_t)H * H * 2);
  unsigned short* W2sbf = (unsigned short*)take((size_t)16 * H * 2);
  unsigned short* W2dbf = (unsigned short*)take((size_t)16 * H * 2);
  unsigned short* W1cat = (unsigned short*)take((size_t)A4W * H * 2);
  float* b1cat        = (float*)take((size_t)A4W * 4);
  unsigned short* Whhh = (unsigned short*)take((size_t)GW * H * 2);
  unsigned short* Whhl = (unsigned short*)take((size_t)GW * H * 2);
  unsigned short* Wch  = (unsigned short*)take((size_t)GW * H * 2);
  unsigned short* Wcl  = (unsigned short*)take((size_t)GW * H * 2);
  float* bc           = (float*)take((size_t)GW * 4);
  // ---- prep-phase aliases (within step-scratch, after h/hhi/hlo @1,179,648) ----
  unsigned short* Wm2th = (unsigned short*)((char*)d_ws + 1179648);
  unsigned short* Wm2tl = Wm2th + (size_t)H * H;  // ends ~3.54 MB

  // ---- once-per-launch prep ----
  k_prep<<<5928, 256, 0, stream>>>(Wm1, W2s, W2d, Whh, Wih, Wm2, W1s, W1d, b1s, b1d,
                                   bm2, bih, asp, qry,
                                   Wm1bf, W2sbf, W2dbf, Whhh, Whhl,
                                   Wm2th, Wm2tl, W1cat, b1cat, bc, h, hhi, hlo);
  k_pre2<<<1584, 256, 0, stream>>>(Wm1bf, Rs, Rd, RsWt, Wih, Wm2th, Wm2tl, Wch, Wcl);

  // ---- propagation steps ----
  for (int step = 0; step < 3; ++step) {
    k_tile<<<702, 256, 0, stream>>>(hhi, hlo, W1cat, b1cat, Whhh, Whhl, bhh, RsWt,
                                    A4, ghb, twB);
    k_pairlog<<<dim3(192, 12), 256, 0, stream>>>(A4, W2sbf, W2dbf, b2s, b2d, swA);
    k_pairmsg<<<dim3(12, 3, 8), 256, 0, stream>>>(swA, twB, bm1, vpart);
    k_vred<<<576, 256, 0, stream>>>(vpart, vhi, vlo);
    k_btks<<<dim3(36, 3, 4), 256, 0, stream>>>(vhi, vlo, Wch, Wcl, (float*)twB);
    k_gru<<<576, 256, 0, stream>>>((float*)twB, bc, ghb, h, hhi, hlo, out, step == 2);
  }
  (void)in_sizes; (void)n_in; (void)out_size; (void)ws_size;
}

// Round 10
// 479.305 us; speedup vs baseline: 2.0107x; 1.0300x over previous
//
#include <hip/hip_runtime.h>
#include <hip/hip_bf16.h>

#define H 768
#define NTOT 192
#define A4W 3072
#define GW 2304

typedef __attribute__((ext_vector_type(4))) float f32x4;
typedef __attribute__((ext_vector_type(8))) unsigned short u16x8;
typedef __attribute__((ext_vector_type(4))) unsigned short u16x4;
typedef __attribute__((ext_vector_type(8))) __bf16 bf16x8v;

static __device__ __forceinline__ unsigned short f2bf(float f) {
  __hip_bfloat16 b = __float2bfloat16(f);
  return __builtin_bit_cast(unsigned short, b);
}
static __device__ __forceinline__ float bf2f(unsigned short u) {
  return __bfloat162float(__builtin_bit_cast(__hip_bfloat16, u));
}
static __device__ __forceinline__ f32x4 MFMA(u16x8 a, u16x8 b, f32x4 c) {
  return __builtin_amdgcn_mfma_f32_16x16x32_bf16(
      __builtin_bit_cast(bf16x8v, a), __builtin_bit_cast(bf16x8v, b), c, 0, 0, 0);
}
static __device__ __forceinline__ u16x8 ld8(const unsigned short* p) {
  return *(const u16x8*)p;
}
static __device__ __forceinline__ unsigned int cvtpk(float lo, float hi) {
  unsigned int r;
  asm("v_cvt_pk_bf16_f32 %0, %1, %2" : "=v"(r) : "v"(lo), "v"(hi));
  return r;
}
static __device__ __forceinline__ float relu(float x) { return fmaxf(x, 0.f); }

#define GLDS16(gp, lp)                                                   \
  __builtin_amdgcn_global_load_lds(                                      \
      (const __attribute__((address_space(1))) void*)(gp),               \
      (__attribute__((address_space(3))) void*)(lp), 16, 0, 0)

// ---------------- fused prep: weight conversions + bc + inith --------------
// segments: Wm1 576 | W2s 12 | W2d 12 | Whh 1728 | Wm2t 576 | W1cat 2304 |
//           bc 576 | inith 144  => grid 5928
__global__ void k_prep(const float* __restrict__ Wm1, const float* __restrict__ W2s,
                       const float* __restrict__ W2d, const float* __restrict__ Whh,
                       const float* __restrict__ Wih, const float* __restrict__ Wm2,
                       const float* __restrict__ W1s, const float* __restrict__ W1d,
                       const float* __restrict__ b1s, const float* __restrict__ b1d,
                       const float* __restrict__ bm2, const float* __restrict__ bih,
                       const float* __restrict__ asp, const float* __restrict__ qry,
                       unsigned short* __restrict__ Wm1bf, unsigned short* __restrict__ W2sbf,
                       unsigned short* __restrict__ W2dbf, unsigned short* __restrict__ Whhh,
                       unsigned short* __restrict__ Whhl, unsigned short* __restrict__ Wm2th,
                       unsigned short* __restrict__ Wm2tl, unsigned short* __restrict__ W1cat,
                       float* __restrict__ b1cat, float* __restrict__ bc,
                       float* __restrict__ h, unsigned short* __restrict__ hhi,
                       unsigned short* __restrict__ hlo) {
  const int b = blockIdx.x, tid = threadIdx.x;
  if (b < 576) {
    int u = b * 256 + tid;
    float4 v = ((const float4*)Wm1)[u];
    u16x4 o; o[0] = f2bf(v.x); o[1] = f2bf(v.y); o[2] = f2bf(v.z); o[3] = f2bf(v.w);
    ((u16x4*)Wm1bf)[u] = o;
  } else if (b < 588) {
    int u = (b - 576) * 256 + tid;
    float4 v = ((const float4*)W2s)[u];
    u16x4 o; o[0] = f2bf(v.x); o[1] = f2bf(v.y); o[2] = f2bf(v.z); o[3] = f2bf(v.w);
    ((u16x4*)W2sbf)[u] = o;
  } else if (b < 600) {
    int u = (b - 588) * 256 + tid;
    float4 v = ((const float4*)W2d)[u];
    u16x4 o; o[0] = f2bf(v.x); o[1] = f2bf(v.y); o[2] = f2bf(v.z); o[3] = f2bf(v.w);
    ((u16x4*)W2dbf)[u] = o;
  } else if (b < 2328) {
    int u = (b - 600) * 256 + tid;
    float4 v = ((const float4*)Whh)[u];
    u16x4 oh, ol;
#pragma unroll
    for (int j = 0; j < 4; ++j) {
      float f = ((const float*)&v)[j];
      oh[j] = f2bf(f); ol[j] = f2bf(f - bf2f(oh[j]));
    }
    ((u16x4*)Whhh)[u] = oh; ((u16x4*)Whhl)[u] = ol;
  } else if (b < 2904) {
    int u = (b - 2328) * 256 + tid;  // Wm2 f4 index; emit TRANSPOSED hi/lo
    float4 v = ((const float4*)Wm2)[u];
    int e_lin = u * 4;
    int er = e_lin / H, kc = e_lin - er * H;
#pragma unroll
    for (int j = 0; j < 4; ++j) {
      float f = ((const float*)&v)[j];
      unsigned short hi = f2bf(f);
      Wm2th[(size_t)(kc + j) * H + er] = hi;
      Wm2tl[(size_t)(kc + j) * H + er] = f2bf(f - bf2f(hi));
    }
  } else if (b < 5208) {
    int u = (b - 2904) * 256 + tid;  // f4 index into W1cat [3072][768]
    int e = u * 4;
    int row = e / H, k = e - row * H;
    int part = row / H, o = row - part * H;
    const float* W = (part < 2) ? W1s : W1d;
    float4 v = *(const float4*)(W + (size_t)o * (2 * H) + (part & 1) * H + k);
    u16x4 ov; ov[0] = f2bf(v.x); ov[1] = f2bf(v.y); ov[2] = f2bf(v.z); ov[3] = f2bf(v.w);
    *(u16x4*)(W1cat + e) = ov;
    if (u < 768) {
      int e2 = u * 4, pp = e2 / H, oo = e2 - pp * H;
      float4 bv;
      if (pp == 0) bv = *(const float4*)(b1s + oo);
      else if (pp == 2) bv = *(const float4*)(b1d + oo);
      else bv = (float4){0.f, 0.f, 0.f, 0.f};
      *(float4*)(b1cat + e2) = bv;
    }
  } else if (b < 5784) {
    // bc[g] = bih[g] + sum_e Wih[g][e]*bm2[e]
    const int w = tid >> 6, l = tid & 63;
    const int gg = (b - 5208) * 4 + w;
    const float* row = Wih + (size_t)gg * H;
    float s = 0.f;
#pragma unroll
    for (int q = 0; q < 12; ++q) s += row[l + q * 64] * bm2[l + q * 64];
#pragma unroll
    for (int m = 32; m; m >>= 1) s += __shfl_xor(s, m);
    if (l == 0) bc[gg] = bih[gg] + s;
  } else {
    int u = (b - 5784) * 256 + tid;  // f4 index, 36864
    float4 v = (u < 12288) ? ((const float4*)asp)[u] : ((const float4*)qry)[u - 12288];
    ((float4*)h)[u] = v;
    u16x4 oh, ol;
#pragma unroll
    for (int j = 0; j < 4; ++j) {
      float f = ((const float*)&v)[j];
      oh[j] = f2bf(f); ol[j] = f2bf(f - bf2f(oh[j]));
    }
    ((u16x4*)hhi)[u] = oh; ((u16x4*)hlo)[u] = ol;
  }
}

// ---------------- merged prep GEMM, 32 KB LDS, 1584 blocks ------------------
// blocks 0..1151: RsW (T14 async-STAGE: B(t+1) regs issued before compute(t))
// blocks 1152..1583: Wc = Wih @ Wm2t^T, 64x64 tiles (hilo x hilo)
__global__ __launch_bounds__(256) void k_pre2(const unsigned short* __restrict__ Wm1bf,
                                              const float* __restrict__ Rsf,
                                              const float* __restrict__ Rdf,
                                              unsigned short* __restrict__ RsWt,
                                              const float* __restrict__ Wih,
                                              const unsigned short* __restrict__ Bth,
                                              const unsigned short* __restrict__ Btl,
                                              unsigned short* __restrict__ Ch,
                                              unsigned short* __restrict__ Cl) {
  __shared__ unsigned short LDS[16384];  // 32 KB
  const int wg = blockIdx.x;
  const int tid = threadIdx.x, w = tid >> 6, l = tid & 63;
  const int g = l >> 4, ln = l & 15;
  const int srow = l >> 3;
  const int skb = ((l & 7) ^ srow) * 8;
  const int x7 = ln & 7;

  if (wg >= 1152) {
    // --------- Wc: 64x64 tile, BK=64; warp w owns cols n0+w*16 --------------
    unsigned short* Ahl = LDS;
    unsigned short* All = LDS + 4096;
    unsigned short* Bhl = LDS + 8192;
    unsigned short* Bll = LDS + 12288;
    const int bid = wg - 1152;
    const int m0 = (bid / 12) * 64, n0 = (bid % 12) * 64;
    const unsigned short* Bgh = Bth + (size_t)(n0 + srow) * H + skb;
    const unsigned short* Bgl = Btl + (size_t)(n0 + srow) * H + skb;
    f32x4 acc[4];
#pragma unroll
    for (int mi = 0; mi < 4; ++mi) acc[mi] = (f32x4){0.f, 0.f, 0.f, 0.f};
    for (int kb = 0; kb < H; kb += 64) {
#pragma unroll
      for (int c2 = 0; c2 < 2; ++c2) {
        const int c = w * 2 + c2;
        GLDS16(Bgh + (size_t)(c * 8) * H + kb, &Bhl[c * 512]);
        GLDS16(Bgl + (size_t)(c * 8) * H + kb, &Bll[c * 512]);
      }
#pragma unroll
      for (int q = 0; q < 2; ++q) {
        const int idx = q * 256 + tid;
        const int row = idx >> 3, kb8 = idx & 7;
        const float* src = Wih + (size_t)(m0 + row) * H + kb + kb8 * 8;
        float4 v0 = *(const float4*)src;
        float4 v1 = *(const float4*)(src + 4);
        float fv[8] = {v0.x, v0.y, v0.z, v0.w, v1.x, v1.y, v1.z, v1.w};
        u16x8 oh, ol;
#pragma unroll
        for (int jq = 0; jq < 8; ++jq) {
          unsigned short hi = f2bf(fv[jq]);
          oh[jq] = hi;
          ol[jq] = f2bf(fv[jq] - bf2f(hi));
        }
        const int dst = row * 64 + (kb8 ^ (row & 7)) * 8;
        *(u16x8*)&Ahl[dst] = oh;
        *(u16x8*)&All[dst] = ol;
      }
      __syncthreads();
#pragma unroll
      for (int kk = 0; kk < 2; ++kk) {
        const int pb = ((kk * 4 + g) ^ x7) * 8;
        u16x8 bh = ld8(&Bhl[(w * 16 + ln) * 64 + pb]);
        u16x8 bl = ld8(&Bll[(w * 16 + ln) * 64 + pb]);
#pragma unroll
        for (int mi = 0; mi < 4; ++mi) {
          u16x8 ah = ld8(&Ahl[(mi * 16 + ln) * 64 + pb]);
          u16x8 al = ld8(&All[(mi * 16 + ln) * 64 + pb]);
          acc[mi] = MFMA(ah, bh, acc[mi]);
          acc[mi] = MFMA(ah, bl, acc[mi]);
          acc[mi] = MFMA(al, bh, acc[mi]);
        }
      }
      __syncthreads();
    }
#pragma unroll
    for (int mi = 0; mi < 4; ++mi) {
      const int col = n0 + w * 16 + ln;
#pragma unroll
      for (int pp = 0; pp < 4; ++pp) {
        const int row = m0 + mi * 16 + g * 4 + pp;
        const float val = acc[mi][pp];
        unsigned short hi = f2bf(val);
        Ch[(size_t)row * H + col] = hi;
        Cl[(size_t)row * H + col] = f2bf(val - bf2f(hi));
      }
    }
    return;
  }

  // --------- RsW: z<16 -> Rs[z], else Rd[z-16]; out row = d*32+z ------------
  unsigned short* Asl = LDS;          // 128x64 bf16 = 16 KB
  unsigned short* Bsl = LDS + 8192;   // 128x64 bf16 = 16 KB
  const int nb = (wg & 7) * 144 + (wg >> 3);       // chunked XCD swizzle
  const int z = nb / 36, t5 = nb - z * 36;
  const int d0 = (t5 / 6) * 128, k0 = (t5 % 6) * 128;
  const int wr = w >> 1, wc = w & 1;
  const unsigned short* Ag = Wm1bf + (size_t)(d0 + srow) * H + skb;
  const float* Bg = ((z < 16) ? Rsf : Rdf) + (size_t)(z & 15) * (H * H);
  const int kb8 = tid & 7, rb = tid >> 3;
  const float* Bq = Bg + (size_t)(k0 + rb) * H + kb8 * 8;
  const int bdst = rb * 64 + (kb8 ^ (rb & 7)) * 8;

#define LOADB_(kbv, Ra, Rb)                                  \
  _Pragma("unroll") for (int q = 0; q < 4; ++q) {            \
    const float* s_ = Bq + (size_t)(q * 32) * H + (kbv);     \
    Ra[q] = *(const float4*)s_;                              \
    Rb[q] = *(const float4*)(s_ + 4);                        \
  }
#define WRITEB_(Ra, Rb)                                      \
  _Pragma("unroll") for (int q = 0; q < 4; ++q) {            \
    u16x8 o_; unsigned int* po_ = (unsigned int*)&o_;        \
    po_[0] = cvtpk(Ra[q].x, Ra[q].y);                        \
    po_[1] = cvtpk(Ra[q].z, Ra[q].w);                        \
    po_[2] = cvtpk(Rb[q].x, Rb[q].y);                        \
    po_[3] = cvtpk(Rb[q].z, Rb[q].w);                        \
    *(u16x8*)&Bsl[q * 2048 + bdst] = o_;                     \
  }
#define GLDSA_(kbv)                                          \
  _Pragma("unroll") for (int c4 = 0; c4 < 4; ++c4) {         \
    const int c_ = w * 4 + c4;                               \
    GLDS16(Ag + (size_t)(c_ * 8) * H + (kbv), &Asl[c_ * 512]); \
  }

  f32x4 acc[4][4];
#pragma unroll
  for (int mi = 0; mi < 4; ++mi)
#pragma unroll
    for (int ni = 0; ni < 4; ++ni) acc[mi][ni] = (f32x4){0.f, 0.f, 0.f, 0.f};
  float4 ra[4], rbv[4];
  // prologue: stage tile 0
  LOADB_(0, ra, rbv);
  GLDSA_(0);
  WRITEB_(ra, rbv);
  __syncthreads();
#pragma unroll
  for (int t = 0; t < 12; ++t) {
    // T14: issue B(t+1) global loads BEFORE compute(t) — latency hides under MFMA
    if (t < 11) { LOADB_((t + 1) * 64, ra, rbv); }
#pragma unroll
    for (int kk = 0; kk < 2; ++kk) {
      u16x8 af[4], bf[4];
      const int pb = ((kk * 4 + g) ^ x7) * 8;
#pragma unroll
      for (int mi = 0; mi < 4; ++mi) af[mi] = ld8(&Asl[(wr * 64 + mi * 16 + ln) * 64 + pb]);
#pragma unroll
      for (int ni = 0; ni < 4; ++ni) bf[ni] = ld8(&Bsl[(wc * 64 + ni * 16 + ln) * 64 + pb]);
#pragma unroll
      for (int mi = 0; mi < 4; ++mi)
#pragma unroll
        for (int ni = 0; ni < 4; ++ni) acc[mi][ni] = MFMA(af[mi], bf[ni], acc[mi][ni]);
    }
    __syncthreads();
    if (t < 11) {
      WRITEB_(ra, rbv);            // vmcnt wait here — mostly elapsed
      GLDSA_((t + 1) * 64);
      __syncthreads();
    }
  }
#pragma unroll
  for (int mi = 0; mi < 4; ++mi) {
    const int d = d0 + wr * 64 + mi * 16 + g * 4;
#pragma unroll
    for (int ni = 0; ni < 4; ++ni) {
      const int k = k0 + wc * 64 + ni * 16 + ln;
      unsigned short* o = RsWt + ((size_t)d * 32 + z) * H + k;
#pragma unroll
      for (int pp = 0; pp < 4; ++pp) o[(size_t)pp * 32 * H] = f2bf(acc[mi][ni][pp]);
    }
  }
#undef LOADB_
#undef WRITEB_
#undef GLDSA_
}

// ---------------- K-split(4) hilo GEMM for gx (no bias, raw partials) -------
__global__ __launch_bounds__(256) void k_btks(
    const unsigned short* __restrict__ Ahi, const unsigned short* __restrict__ Alo,
    const unsigned short* __restrict__ Bhi, const unsigned short* __restrict__ Blo,
    float* __restrict__ Cp) {
  const int tid = threadIdx.x;
  const int w = tid >> 6, l = tid & 63, g = l >> 4, ln = l & 15;
  const int m0 = blockIdx.y * 64 + w * 16;
  const int n0 = blockIdx.x * 64;
  const int kh = blockIdx.z, kb0 = kh * 192;
  const unsigned short* aph = Ahi + (size_t)(m0 + ln) * H + kb0 + g * 8;
  const unsigned short* apl = Alo + (size_t)(m0 + ln) * H + kb0 + g * 8;
  const unsigned short* bph[4];
  const unsigned short* bpl[4];
#pragma unroll
  for (int nt = 0; nt < 4; ++nt) {
    bph[nt] = Bhi + (size_t)(n0 + nt * 16 + ln) * H + kb0 + g * 8;
    bpl[nt] = Blo + (size_t)(n0 + nt * 16 + ln) * H + kb0 + g * 8;
  }
  f32x4 acc[4];
#pragma unroll
  for (int nt = 0; nt < 4; ++nt) acc[nt] = (f32x4){0.f, 0.f, 0.f, 0.f};
  u16x8 ah[2], al[2], bh[2][4], bl[2][4];
  ah[0] = ld8(aph);
  al[0] = ld8(apl);
#pragma unroll
  for (int nt = 0; nt < 4; ++nt) { bh[0][nt] = ld8(bph[nt]); bl[0][nt] = ld8(bpl[nt]); }
#pragma unroll
  for (int t = 0; t < 6; ++t) {
    const int cur = t & 1, nxt = cur ^ 1;
    if (t < 5) {
      const int ko = (t + 1) * 32;
      ah[nxt] = ld8(aph + ko);
      al[nxt] = ld8(apl + ko);
#pragma unroll
      for (int nt = 0; nt < 4; ++nt) {
        bh[nxt][nt] = ld8(bph[nt] + ko);
        bl[nxt][nt] = ld8(bpl[nt] + ko);
      }
    }
#pragma unroll
    for (int nt = 0; nt < 4; ++nt) {
      acc[nt] = MFMA(ah[cur], bh[cur][nt], acc[nt]);
      acc[nt] = MFMA(ah[cur], bl[cur][nt], acc[nt]);
      acc[nt] = MFMA(al[cur], bh[cur][nt], acc[nt]);
    }
  }
#pragma unroll
  for (int nt = 0; nt < 4; ++nt) {
    const int col = n0 + nt * 16 + ln;
#pragma unroll
    for (int pp = 0; pp < 4; ++pp) {
      const int row = m0 + g * 4 + pp;
      Cp[(size_t)kh * (NTOT * GW) + (size_t)row * GW + col] = acc[nt][pp];
    }
  }
}

// ---------------- per-step LDS-staged tiled GEMM: gh | A4 | twB -------------
// 64(M) x 128(N) tiles, BK=64. bid<54: gh (hilo); 54..125: A4; 126..701: twB.
// Bijective XCD swizzle (702 % 8 != 0) groups same-n blocks on one XCD.
__global__ __launch_bounds__(256) void k_tile(
    const unsigned short* __restrict__ hhi, const unsigned short* __restrict__ hlo,
    const unsigned short* __restrict__ W1cat, const float* __restrict__ b1cat,
    const unsigned short* __restrict__ Whhh, const unsigned short* __restrict__ Whhl,
    const float* __restrict__ bhh, const unsigned short* __restrict__ RsWt,
    float* __restrict__ A4, float* __restrict__ ghb, unsigned short* __restrict__ twB) {
  __shared__ unsigned short Ah[4096], Al[4096], Bh[8192], Bl[8192];  // 48 KB
  const int orig = blockIdx.x;           // 702 blocks
  const int qq = 87, rr = 6;             // 702 = 8*87 + 6
  const int xcd = orig & 7, idx = orig >> 3;
  const int bid = (xcd < rr ? xcd * (qq + 1) : rr * (qq + 1) + (xcd - rr) * qq) + idx;
  const int tid = threadIdx.x, w = tid >> 6, l = tid & 63, g = l >> 4, ln = l & 15;
  int path, m, n;
  if (bid < 54)       { path = 0; n = bid / 3;         m = bid % 3; }
  else if (bid < 126) { path = 1; n = (bid - 54) / 3;  m = (bid - 54) % 3; }
  else                { path = 2; n = (bid - 126) / 3; m = (bid - 126) % 3; }
  const int m0 = m * 64, n0 = n * 128;
  const bool isgh = (path == 0);
  const unsigned short* Bsrc = (path == 0) ? Whhh : (path == 1) ? W1cat : RsWt;
  const int srow = l >> 3;
  const int skb = ((l & 7) ^ srow) * 8;
  const unsigned short* Agh = hhi + (size_t)(m0 + srow) * H + skb;
  const unsigned short* Agl = hlo + (size_t)(m0 + srow) * H + skb;
  const unsigned short* Bgh = Bsrc + (size_t)(n0 + srow) * H + skb;
  const unsigned short* Bgl = Whhl + (size_t)((isgh ? n0 : 0) + srow) * H + skb;
  f32x4 acc[4][2];
#pragma unroll
  for (int mi = 0; mi < 4; ++mi)
#pragma unroll
    for (int ni = 0; ni < 2; ++ni) acc[mi][ni] = (f32x4){0.f, 0.f, 0.f, 0.f};
  const int x7 = ln & 7;
  for (int kb = 0; kb < H; kb += 64) {
#pragma unroll
    for (int c2 = 0; c2 < 2; ++c2) {
      const int c = w * 2 + c2;
      GLDS16(Agh + (size_t)(c * 8) * H + kb, &Ah[c * 512]);
      if (isgh) GLDS16(Agl + (size_t)(c * 8) * H + kb, &Al[c * 512]);
    }
#pragma unroll
    for (int c4 = 0; c4 < 4; ++c4) {
      const int c = w * 4 + c4;
      GLDS16(Bgh + (size_t)(c * 8) * H + kb, &Bh[c * 512]);
      if (isgh) GLDS16(Bgl + (size_t)(c * 8) * H + kb, &Bl[c * 512]);
    }
    __syncthreads();
#pragma unroll
    for (int kk = 0; kk < 2; ++kk) {
      const int pb = ((kk * 4 + g) ^ x7) * 8;
      u16x8 af[4], bf[2];
#pragma unroll
      for (int mi = 0; mi < 4; ++mi) af[mi] = ld8(&Ah[(mi * 16 + ln) * 64 + pb]);
#pragma unroll
      for (int ni = 0; ni < 2; ++ni) bf[ni] = ld8(&Bh[(w * 32 + ni * 16 + ln) * 64 + pb]);
      if (isgh) {
        u16x8 alf[4], blf[2];
#pragma unroll
        for (int mi = 0; mi < 4; ++mi) alf[mi] = ld8(&Al[(mi * 16 + ln) * 64 + pb]);
#pragma unroll
        for (int ni = 0; ni < 2; ++ni) blf[ni] = ld8(&Bl[(w * 32 + ni * 16 + ln) * 64 + pb]);
#pragma unroll
        for (int mi = 0; mi < 4; ++mi)
#pragma unroll
          for (int ni = 0; ni < 2; ++ni) {
            acc[mi][ni] = MFMA(af[mi], bf[ni], acc[mi][ni]);
            acc[mi][ni] = MFMA(af[mi], blf[ni], acc[mi][ni]);
            acc[mi][ni] = MFMA(alf[mi], bf[ni], acc[mi][ni]);
          }
      } else {
#pragma unroll
        for (int mi = 0; mi < 4; ++mi)
#pragma unroll
          for (int ni = 0; ni < 2; ++ni) acc[mi][ni] = MFMA(af[mi], bf[ni], acc[mi][ni]);
      }
    }
    __syncthreads();
  }
  if (path == 2) {
#pragma unroll
    for (int mi = 0; mi < 4; ++mi)
#pragma unroll
      for (int ni = 0; ni < 2; ++ni) {
        const int c = n0 + w * 32 + ni * 16 + ln;
#pragma unroll
        for (int pp = 0; pp < 4; ++pp) {
          const int j = m0 + mi * 16 + g * 4 + pp;
          twB[(size_t)j * 24576 + c] = f2bf(acc[mi][ni][pp]);
        }
      }
  } else {
    const int N = isgh ? GW : A4W;
    float* C = isgh ? ghb : A4;
    const float* bias = isgh ? bhh : b1cat;
#pragma unroll
    for (int mi = 0; mi < 4; ++mi)
#pragma unroll
      for (int ni = 0; ni < 2; ++ni) {
        const int col = n0 + w * 32 + ni * 16 + ln;
        const float bv = bias[col];
#pragma unroll
        for (int pp = 0; pp < 4; ++pp) {
          const int row = m0 + mi * 16 + g * 4 + pp;
          C[(size_t)row * N + col] = acc[mi][ni][pp] + bv;
        }
      }
  }
}

// ---------------- pair logits + softmax -> swA[j][i][32] (bf16) -------------
__global__ __launch_bounds__(256) void k_pairlog(
    const float* __restrict__ A4, const unsigned short* __restrict__ W2sbf,
    const unsigned short* __restrict__ W2dbf, const float* __restrict__ b2s,
    const float* __restrict__ b2d, unsigned short* __restrict__ swA) {
  __shared__ float red[8][16][17];
  const int i = blockIdx.x, jb = blockIdx.y;
  const int tid = threadIdx.x, w = tid >> 6, l = tid & 63;
  const int g = l >> 4, ln = l & 15;
  const int j = jb * 16 + ln;
  const float* BsP = A4 + (size_t)j * A4W + 768 + g * 8;
  const float* BdP = A4 + (size_t)j * A4W + 2304 + g * 8;
  const float* AsP = A4 + (size_t)i * A4W + g * 8;
  const float* AdP = A4 + (size_t)i * A4W + 1536 + g * 8;
  const unsigned short* WsP = W2sbf + (size_t)ln * H + g * 8;
  const unsigned short* WdP = W2dbf + (size_t)ln * H + g * 8;
  f32x4 accs = (f32x4){0.f, 0.f, 0.f, 0.f}, accd = (f32x4){0.f, 0.f, 0.f, 0.f};
#pragma unroll
  for (int tt = 0; tt < 6; ++tt) {
    const int ko = (w * 6 + tt) * 32;
    float4 b0 = *(const float4*)(BsP + ko), b1 = *(const float4*)(BsP + ko + 4);
    float4 a0 = *(const float4*)(AsP + ko), a1 = *(const float4*)(AsP + ko + 4);
    float4 e0 = *(const float4*)(BdP + ko), e1 = *(const float4*)(BdP + ko + 4);
    float4 c0 = *(const float4*)(AdP + ko), c1 = *(const float4*)(AdP + ko + 4);
    u16x8 afs, afd;
    unsigned int* ps = (unsigned int*)&afs;
    ps[0] = cvtpk(relu(a0.x + b0.x), relu(a0.y + b0.y));
    ps[1] = cvtpk(relu(a0.z + b0.z), relu(a0.w + b0.w));
    ps[2] = cvtpk(relu(a1.x + b1.x), relu(a1.y + b1.y));
    ps[3] = cvtpk(relu(a1.z + b1.z), relu(a1.w + b1.w));
    unsigned int* pd = (unsigned int*)&afd;
    pd[0] = cvtpk(relu(c0.x + e0.x), relu(c0.y + e0.y));
    pd[1] = cvtpk(relu(c0.z + e0.z), relu(c0.w + e0.w));
    pd[2] = cvtpk(relu(c1.x + e1.x), relu(c1.y + e1.y));
    pd[3] = cvtpk(relu(c1.z + e1.z), relu(c1.w + e1.w));
    accs = MFMA(afs, ld8(WsP + ko), accs);
    accd = MFMA(afd, ld8(WdP + ko), accd);
  }
#pragma unroll
  for (int pp = 0; pp < 4; ++pp) {
    red[w * 2][g * 4 + pp][ln] = accs[pp];
    red[w * 2 + 1][g * 4 + pp][ln] = accd[pp];
  }
  __syncthreads();
  const int j2 = tid >> 4, r = tid & 15;
  float vs = red[0][j2][r] + red[2][j2][r] + red[4][j2][r] + red[6][j2][r] + b2s[r];
  float vd = red[1][j2][r] + red[3][j2][r] + red[5][j2][r] + red[7][j2][r] + b2d[r];
  float ms = vs;
  ms = fmaxf(ms, __shfl_xor(ms, 1)); ms = fmaxf(ms, __shfl_xor(ms, 2));
  ms = fmaxf(ms, __shfl_xor(ms, 4)); ms = fmaxf(ms, __shfl_xor(ms, 8));
  float md = vd;
  md = fmaxf(md, __shfl_xor(md, 1)); md = fmaxf(md, __shfl_xor(md, 2));
  md = fmaxf(md, __shfl_xor(md, 4)); md = fmaxf(md, __shfl_xor(md, 8));
  float es = __expf(vs - ms), ed = __expf(vd - md);
  float ss = es;
  ss += __shfl_xor(ss, 1); ss += __shfl_xor(ss, 2); ss += __shfl_xor(ss, 4); ss += __shfl_xor(ss, 8);
  float sd = ed;
  sd += __shfl_xor(sd, 1); sd += __shfl_xor(sd, 2); sd += __shfl_xor(sd, 4); sd += __shfl_xor(sd, 8);
  const size_t o = (size_t)(jb * 16 + j2) * 6144 + (size_t)i * 32;
  swA[o + r] = f2bf(es / ss);
  swA[o + 16 + r] = f2bf(ed / sd);
}

// ---------------- per-pair weighted message + relu + sum_j -> v_part --------
__global__ __launch_bounds__(256) void k_pairmsg(const unsigned short* __restrict__ swA,
                                                 const unsigned short* __restrict__ twB,
                                                 const float* __restrict__ bm1,
                                                 float* __restrict__ vpart) {
  const int dt = blockIdx.x, it = blockIdx.y, js = blockIdx.z;
  const int tid = threadIdx.x;
  const int w = tid >> 6, l = tid & 63, g = l >> 4, ln = l & 15;
  const int i0 = it * 64 + w * 16;
  const int d0 = dt * 64;
  float bm1v[4];
#pragma unroll
  for (int nt = 0; nt < 4; ++nt) bm1v[nt] = bm1[d0 + nt * 16 + ln];
  f32x4 vacc[4];
#pragma unroll
  for (int nt = 0; nt < 4; ++nt) vacc[nt] = (f32x4){0.f, 0.f, 0.f, 0.f};
  const unsigned short* ap = swA + (size_t)(i0 + ln) * 32 + g * 8 + (size_t)js * 24 * 6144;
  const unsigned short* bp[4];
#pragma unroll
  for (int nt = 0; nt < 4; ++nt)
    bp[nt] = twB + (size_t)(d0 + nt * 16 + ln) * 32 + g * 8 + (size_t)js * 24 * 24576;
  const f32x4 z4 = (f32x4){0.f, 0.f, 0.f, 0.f};
#pragma unroll 4
  for (int jj = 0; jj < 24; ++jj) {
    u16x8 a = ld8(ap + (size_t)jj * 6144);
#pragma unroll
    for (int nt = 0; nt < 4; ++nt) {
      u16x8 b = ld8(bp[nt] + (size_t)jj * 24576);
      f32x4 mf = MFMA(a, b, z4);
#pragma unroll
      for (int pp = 0; pp < 4; ++pp) vacc[nt][pp] += fmaxf(mf[pp] + bm1v[nt], 0.f);
    }
  }
#pragma unroll
  for (int nt = 0; nt < 4; ++nt)
#pragma unroll
    for (int pp = 0; pp < 4; ++pp) {
      const int row = i0 + g * 4 + pp;
      vpart[(size_t)js * 147456 + (size_t)row * H + d0 + nt * 16 + ln] = vacc[nt][pp];
    }
}

__global__ void k_vred(const float* __restrict__ vpart, unsigned short* __restrict__ vhi,
                       unsigned short* __restrict__ vlo) {
  int e = blockIdx.x * 256 + threadIdx.x;  // 147456
  float s = 0.f;
#pragma unroll
  for (int q = 0; q < 8; ++q) s += vpart[(size_t)q * 147456 + e];
  s *= (1.0f / 192.0f);
  unsigned short hi = f2bf(s);
  vhi[e] = hi;
  vlo[e] = f2bf(s - bf2f(hi));
}

__global__ void k_gru(const float* __restrict__ gxp, const float* __restrict__ bcv,
                      const float* __restrict__ gh, float* __restrict__ h,
                      unsigned short* __restrict__ hhi, unsigned short* __restrict__ hlo,
                      float* __restrict__ out, int last) {
  int e = blockIdx.x * 256 + threadIdx.x;  // 147456
  int i = e / H, k = e - i * H;
  size_t base = (size_t)i * GW;
  const size_t S = (size_t)NTOT * GW;
  float rr = gxp[base + k] + gxp[S + base + k] + gxp[2 * S + base + k] +
             gxp[3 * S + base + k] + bcv[k] + gh[base + k];
  float zz = gxp[base + H + k] + gxp[S + base + H + k] + gxp[2 * S + base + H + k] +
             gxp[3 * S + base + H + k] + bcv[H + k] + gh[base + H + k];
  float r = 1.f / (1.f + __expf(-rr));
  float z = 1.f / (1.f + __expf(-zz));
  float nn = gxp[base + 2 * H + k] + gxp[S + base + 2 * H + k] +
             gxp[2 * S + base + 2 * H + k] + gxp[3 * S + base + 2 * H + k] +
             bcv[2 * H + k];
  float n = tanhf(nn + r * gh[base + 2 * H + k]);
  float hv = (1.f - z) * n + z * h[e];
  h[e] = hv;
  unsigned short hi = f2bf(hv);
  hhi[e] = hi;
  hlo[e] = f2bf(hv - bf2f(hi));
  if (last && i >= 64) out[(size_t)(i - 64) * H + k] = hv;
}

// ---------------- launch ----------------------------------------------------

extern "C" void kernel_launch(void* const* d_in, const int* in_sizes, int n_in,
                              void* d_out, int out_size, void* d_ws, size_t ws_size,
                              hipStream_t stream) {
  const float* asp = (const float*)d_in[0];
  const float* qry = (const float*)d_in[1];
  const float* W1s = (const float*)d_in[3];
  const float* b1s = (const float*)d_in[4];
  const float* W2s = (const float*)d_in[5];
  const float* b2s = (const float*)d_in[6];
  const float* W1d = (const float*)d_in[7];
  const float* b1d = (const float*)d_in[8];
  const float* W2d = (const float*)d_in[9];
  const float* b2d = (const float*)d_in[10];
  const float* Rs  = (const float*)d_in[11];
  const float* Rd  = (const float*)d_in[12];
  const float* Wm1 = (const float*)d_in[13];
  const float* bm1 = (const float*)d_in[14];
  const float* Wm2 = (const float*)d_in[15];
  const float* bm2 = (const float*)d_in[16];
  const float* Wih = (const float*)d_in[17];
  const float* Whh = (const float*)d_in[18];
  const float* bih = (const float*)d_in[19];
  const float* bhh = (const float*)d_in[20];
  float* out = (float*)d_out;

  char* p = (char*)d_ws;
  auto take = [&](size_t bytes) {
    char* q = p;
    p += (bytes + 255) & ~(size_t)255;
    return q;
  };
  // ---- step-scratch region, aliased during prep ----
  float* h            = (float*)take((size_t)NTOT * H * 4);
  unsigned short* hhi = (unsigned short*)take((size_t)NTOT * H * 2);
  unsigned short* hlo = (unsigned short*)take((size_t)NTOT * H * 2);
  float* A4           = (float*)take((size_t)NTOT * A4W * 4);
  float* ghb          = (float*)take((size_t)NTOT * GW * 4);
  unsigned short* vhi = (unsigned short*)take((size_t)NTOT * H * 2);
  unsigned short* vlo = (unsigned short*)take((size_t)NTOT * H * 2);
  float* vpart        = (float*)take((size_t)8 * NTOT * H * 4);
  unsigned short* swA = (unsigned short*)take((size_t)NTOT * NTOT * 32 * 2);
  unsigned short* twB = (unsigned short*)take((size_t)NTOT * H * 32 * 2);  // also gx partials
  // ---- permanent weights ----
  unsigned short* RsWt = (unsigned short*)take((size_t)2 * 16 * H * H * 2);
  unsigned short* Wm1bf = (unsigned short*)take((size_t)H * H * 2);
  unsigned short* W2sbf = (unsigned short*)take((size_t)16 * H * 2);
  unsigned short* W2dbf = (unsigned short*)take((size_t)16 * H * 2);
  unsigned short* W1cat = (unsigned short*)take((size_t)A4W * H * 2);
  float* b1cat        = (float*)take((size_t)A4W * 4);
  unsigned short* Whhh = (unsigned short*)take((size_t)GW * H * 2);
  unsigned short* Whhl = (unsigned short*)take((size_t)GW * H * 2);
  unsigned short* Wch  = (unsigned short*)take((size_t)GW * H * 2);
  unsigned short* Wcl  = (unsigned short*)take((size_t)GW * H * 2);
  float* bc           = (float*)take((size_t)GW * 4);
  // ---- prep-phase aliases (within step-scratch, after h/hhi/hlo @1,179,648) ----
  unsigned short* Wm2th = (unsigned short*)((char*)d_ws + 1179648);
  unsigned short* Wm2tl = Wm2th + (size_t)H * H;  // ends ~3.54 MB

  // ---- once-per-launch prep ----
  k_prep<<<5928, 256, 0, stream>>>(Wm1, W2s, W2d, Whh, Wih, Wm2, W1s, W1d, b1s, b1d,
                                   bm2, bih, asp, qry,
                                   Wm1bf, W2sbf, W2dbf, Whhh, Whhl,
                                   Wm2th, Wm2tl, W1cat, b1cat, bc, h, hhi, hlo);
  k_pre2<<<1584, 256, 0, stream>>>(Wm1bf, Rs, Rd, RsWt, Wih, Wm2th, Wm2tl, Wch, Wcl);

  // ---- propagation steps ----
  for (int step = 0; step < 3; ++step) {
    k_tile<<<702, 256, 0, stream>>>(hhi, hlo, W1cat, b1cat, Whhh, Whhl, bhh, RsWt,
                                    A4, ghb, twB);
    k_pairlog<<<dim3(192, 12), 256, 0, stream>>>(A4, W2sbf, W2dbf, b2s, b2d, swA);
    k_pairmsg<<<dim3(12, 3, 8), 256, 0, stream>>>(swA, twB, bm1, vpart);
    k_vred<<<576, 256, 0, stream>>>(vpart, vhi, vlo);
    k_btks<<<dim3(36, 3, 4), 256, 0, stream>>>(vhi, vlo, Wch, Wcl, (float*)twB);
    k_gru<<<576, 256, 0, stream>>>((float*)twB, bc, ghb, h, hhi, hlo, out, step == 2);
  }
  (void)in_sizes; (void)n_in; (void)out_size; (void)ws_size;
}

// Round 11
// 463.687 us; speedup vs baseline: 2.0785x; 1.0337x over previous
//
#include <hip/hip_runtime.h>
#include <hip/hip_bf16.h>

#define H 768
#define NTOT 192
#define A4W 3072
#define GW 2304

typedef __attribute__((ext_vector_type(4))) float f32x4;
typedef __attribute__((ext_vector_type(8))) unsigned short u16x8;
typedef __attribute__((ext_vector_type(4))) unsigned short u16x4;
typedef __attribute__((ext_vector_type(8))) __bf16 bf16x8v;

static __device__ __forceinline__ unsigned short f2bf(float f) {
  __hip_bfloat16 b = __float2bfloat16(f);
  return __builtin_bit_cast(unsigned short, b);
}
static __device__ __forceinline__ float bf2f(unsigned short u) {
  return __bfloat162float(__builtin_bit_cast(__hip_bfloat16, u));
}
static __device__ __forceinline__ f32x4 MFMA(u16x8 a, u16x8 b, f32x4 c) {
  return __builtin_amdgcn_mfma_f32_16x16x32_bf16(
      __builtin_bit_cast(bf16x8v, a), __builtin_bit_cast(bf16x8v, b), c, 0, 0, 0);
}
static __device__ __forceinline__ u16x8 ld8(const unsigned short* p) {
  return *(const u16x8*)p;
}
static __device__ __forceinline__ unsigned int cvtpk(float lo, float hi) {
  unsigned int r;
  asm("v_cvt_pk_bf16_f32 %0, %1, %2" : "=v"(r) : "v"(lo), "v"(hi));
  return r;
}
static __device__ __forceinline__ float relu(float x) { return fmaxf(x, 0.f); }

#define GLDS16(gp, lp)                                                   \
  __builtin_amdgcn_global_load_lds(                                      \
      (const __attribute__((address_space(1))) void*)(gp),               \
      (__attribute__((address_space(3))) void*)(lp), 16, 0, 0)

// ---------------- fused prep: weight conversions + bc + inith --------------
// segments: Wm1 576 | W2s 12 | W2d 12 | Whh 1728 | Wm2t 576 | W1cat 2304 |
//           bc 576 | inith 144  => grid 5928
__global__ void k_prep(const float* __restrict__ Wm1, const float* __restrict__ W2s,
                       const float* __restrict__ W2d, const float* __restrict__ Whh,
                       const float* __restrict__ Wih, const float* __restrict__ Wm2,
                       const float* __restrict__ W1s, const float* __restrict__ W1d,
                       const float* __restrict__ b1s, const float* __restrict__ b1d,
                       const float* __restrict__ bm2, const float* __restrict__ bih,
                       const float* __restrict__ asp, const float* __restrict__ qry,
                       unsigned short* __restrict__ Wm1bf, unsigned short* __restrict__ W2sbf,
                       unsigned short* __restrict__ W2dbf, unsigned short* __restrict__ Whhh,
                       unsigned short* __restrict__ Whhl, unsigned short* __restrict__ Wm2th,
                       unsigned short* __restrict__ Wm2tl, unsigned short* __restrict__ W1cat,
                       float* __restrict__ b1cat, float* __restrict__ bc,
                       float* __restrict__ h, unsigned short* __restrict__ hhi,
                       unsigned short* __restrict__ hlo) {
  const int b = blockIdx.x, tid = threadIdx.x;
  if (b < 576) {
    int u = b * 256 + tid;
    float4 v = ((const float4*)Wm1)[u];
    u16x4 o; o[0] = f2bf(v.x); o[1] = f2bf(v.y); o[2] = f2bf(v.z); o[3] = f2bf(v.w);
    ((u16x4*)Wm1bf)[u] = o;
  } else if (b < 588) {
    int u = (b - 576) * 256 + tid;
    float4 v = ((const float4*)W2s)[u];
    u16x4 o; o[0] = f2bf(v.x); o[1] = f2bf(v.y); o[2] = f2bf(v.z); o[3] = f2bf(v.w);
    ((u16x4*)W2sbf)[u] = o;
  } else if (b < 600) {
    int u = (b - 588) * 256 + tid;
    float4 v = ((const float4*)W2d)[u];
    u16x4 o; o[0] = f2bf(v.x); o[1] = f2bf(v.y); o[2] = f2bf(v.z); o[3] = f2bf(v.w);
    ((u16x4*)W2dbf)[u] = o;
  } else if (b < 2328) {
    int u = (b - 600) * 256 + tid;
    float4 v = ((const float4*)Whh)[u];
    u16x4 oh, ol;
#pragma unroll
    for (int j = 0; j < 4; ++j) {
      float f = ((const float*)&v)[j];
      oh[j] = f2bf(f); ol[j] = f2bf(f - bf2f(oh[j]));
    }
    ((u16x4*)Whhh)[u] = oh; ((u16x4*)Whhl)[u] = ol;
  } else if (b < 2904) {
    int u = (b - 2328) * 256 + tid;  // Wm2 f4 index; emit TRANSPOSED hi/lo
    float4 v = ((const float4*)Wm2)[u];
    int e_lin = u * 4;
    int er = e_lin / H, kc = e_lin - er * H;
#pragma unroll
    for (int j = 0; j < 4; ++j) {
      float f = ((const float*)&v)[j];
      unsigned short hi = f2bf(f);
      Wm2th[(size_t)(kc + j) * H + er] = hi;
      Wm2tl[(size_t)(kc + j) * H + er] = f2bf(f - bf2f(hi));
    }
  } else if (b < 5208) {
    int u = (b - 2904) * 256 + tid;  // f4 index into W1cat [3072][768]
    int e = u * 4;
    int row = e / H, k = e - row * H;
    int part = row / H, o = row - part * H;
    const float* W = (part < 2) ? W1s : W1d;
    float4 v = *(const float4*)(W + (size_t)o * (2 * H) + (part & 1) * H + k);
    u16x4 ov; ov[0] = f2bf(v.x); ov[1] = f2bf(v.y); ov[2] = f2bf(v.z); ov[3] = f2bf(v.w);
    *(u16x4*)(W1cat + e) = ov;
    if (u < 768) {
      int e2 = u * 4, pp = e2 / H, oo = e2 - pp * H;
      float4 bv;
      if (pp == 0) bv = *(const float4*)(b1s + oo);
      else if (pp == 2) bv = *(const float4*)(b1d + oo);
      else bv = (float4){0.f, 0.f, 0.f, 0.f};
      *(float4*)(b1cat + e2) = bv;
    }
  } else if (b < 5784) {
    // bc[g] = bih[g] + sum_e Wih[g][e]*bm2[e]
    const int w = tid >> 6, l = tid & 63;
    const int gg = (b - 5208) * 4 + w;
    const float* row = Wih + (size_t)gg * H;
    float s = 0.f;
#pragma unroll
    for (int q = 0; q < 12; ++q) s += row[l + q * 64] * bm2[l + q * 64];
#pragma unroll
    for (int m = 32; m; m >>= 1) s += __shfl_xor(s, m);
    if (l == 0) bc[gg] = bih[gg] + s;
  } else {
    int u = (b - 5784) * 256 + tid;  // f4 index, 36864
    float4 v = (u < 12288) ? ((const float4*)asp)[u] : ((const float4*)qry)[u - 12288];
    ((float4*)h)[u] = v;
    u16x4 oh, ol;
#pragma unroll
    for (int j = 0; j < 4; ++j) {
      float f = ((const float*)&v)[j];
      oh[j] = f2bf(f); ol[j] = f2bf(f - bf2f(oh[j]));
    }
    ((u16x4*)hhi)[u] = oh; ((u16x4*)hlo)[u] = ol;
  }
}

// ---------------- merged prep GEMM, 48 KB LDS, 1584 blocks ------------------
// blocks 0..1151: RsW — A double-buffered; A(t+1)+B(t+1) issued BEFORE
//   compute(t) (sched_barrier-pinned) so the post-compute barrier drain is
//   mostly hidden. blocks 1152..1583: Wc = Wih @ Wm2t^T, 64x64 tiles.
__global__ __launch_bounds__(256) void k_pre2(const unsigned short* __restrict__ Wm1bf,
                                              const float* __restrict__ Rsf,
                                              const float* __restrict__ Rdf,
                                              unsigned short* __restrict__ RsWt,
                                              const float* __restrict__ Wih,
                                              const unsigned short* __restrict__ Bth,
                                              const unsigned short* __restrict__ Btl,
                                              unsigned short* __restrict__ Ch,
                                              unsigned short* __restrict__ Cl) {
  __shared__ unsigned short LDS[24576];  // 48 KB
  const int wg = blockIdx.x;
  const int tid = threadIdx.x, w = tid >> 6, l = tid & 63;
  const int g = l >> 4, ln = l & 15;
  const int srow = l >> 3;
  const int skb = ((l & 7) ^ srow) * 8;
  const int x7 = ln & 7;

  if (wg >= 1152) {
    // --------- Wc: 64x64 tile, BK=64; warp w owns cols n0+w*16 --------------
    unsigned short* Ahl = LDS;
    unsigned short* All = LDS + 4096;
    unsigned short* Bhl = LDS + 8192;
    unsigned short* Bll = LDS + 12288;
    const int bid = wg - 1152;
    const int m0 = (bid / 12) * 64, n0 = (bid % 12) * 64;
    const unsigned short* Bgh = Bth + (size_t)(n0 + srow) * H + skb;
    const unsigned short* Bgl = Btl + (size_t)(n0 + srow) * H + skb;
    f32x4 acc[4];
#pragma unroll
    for (int mi = 0; mi < 4; ++mi) acc[mi] = (f32x4){0.f, 0.f, 0.f, 0.f};
    for (int kb = 0; kb < H; kb += 64) {
#pragma unroll
      for (int c2 = 0; c2 < 2; ++c2) {
        const int c = w * 2 + c2;
        GLDS16(Bgh + (size_t)(c * 8) * H + kb, &Bhl[c * 512]);
        GLDS16(Bgl + (size_t)(c * 8) * H + kb, &Bll[c * 512]);
      }
#pragma unroll
      for (int q = 0; q < 2; ++q) {
        const int idx = q * 256 + tid;
        const int row = idx >> 3, kb8 = idx & 7;
        const float* src = Wih + (size_t)(m0 + row) * H + kb + kb8 * 8;
        float4 v0 = *(const float4*)src;
        float4 v1 = *(const float4*)(src + 4);
        float fv[8] = {v0.x, v0.y, v0.z, v0.w, v1.x, v1.y, v1.z, v1.w};
        u16x8 oh, ol;
#pragma unroll
        for (int jq = 0; jq < 8; ++jq) {
          unsigned short hi = f2bf(fv[jq]);
          oh[jq] = hi;
          ol[jq] = f2bf(fv[jq] - bf2f(hi));
        }
        const int dst = row * 64 + (kb8 ^ (row & 7)) * 8;
        *(u16x8*)&Ahl[dst] = oh;
        *(u16x8*)&All[dst] = ol;
      }
      __syncthreads();
#pragma unroll
      for (int kk = 0; kk < 2; ++kk) {
        const int pb = ((kk * 4 + g) ^ x7) * 8;
        u16x8 bh = ld8(&Bhl[(w * 16 + ln) * 64 + pb]);
        u16x8 bl = ld8(&Bll[(w * 16 + ln) * 64 + pb]);
#pragma unroll
        for (int mi = 0; mi < 4; ++mi) {
          u16x8 ah = ld8(&Ahl[(mi * 16 + ln) * 64 + pb]);
          u16x8 al = ld8(&All[(mi * 16 + ln) * 64 + pb]);
          acc[mi] = MFMA(ah, bh, acc[mi]);
          acc[mi] = MFMA(ah, bl, acc[mi]);
          acc[mi] = MFMA(al, bh, acc[mi]);
        }
      }
      __syncthreads();
    }
#pragma unroll
    for (int mi = 0; mi < 4; ++mi) {
      const int col = n0 + w * 16 + ln;
#pragma unroll
      for (int pp = 0; pp < 4; ++pp) {
        const int row = m0 + mi * 16 + g * 4 + pp;
        const float val = acc[mi][pp];
        unsigned short hi = f2bf(val);
        Ch[(size_t)row * H + col] = hi;
        Cl[(size_t)row * H + col] = f2bf(val - bf2f(hi));
      }
    }
    return;
  }

  // --------- RsW: z<16 -> Rs[z], else Rd[z-16]; out row = d*32+z ------------
  unsigned short* Asl0 = LDS;           // 128x64 bf16 = 16 KB
  unsigned short* Asl1 = LDS + 8192;    // 16 KB (A double buffer)
  unsigned short* Bsl = LDS + 16384;    // 16 KB
  const int nb = (wg & 7) * 144 + (wg >> 3);       // chunked XCD swizzle
  const int z = nb / 36, t5 = nb - z * 36;
  const int d0 = (t5 / 6) * 128, k0 = (t5 % 6) * 128;
  const int wr = w >> 1, wc = w & 1;
  const unsigned short* Ag = Wm1bf + (size_t)(d0 + srow) * H + skb;
  const float* Bg = ((z < 16) ? Rsf : Rdf) + (size_t)(z & 15) * (H * H);
  const int kb8 = tid & 7, rb = tid >> 3;
  const float* Bq = Bg + (size_t)(k0 + rb) * H + kb8 * 8;
  const int bdst = rb * 64 + (kb8 ^ (rb & 7)) * 8;

#define LOADB_(kbv, Ra, Rb)                                  \
  _Pragma("unroll") for (int q = 0; q < 4; ++q) {            \
    const float* s_ = Bq + (size_t)(q * 32) * H + (kbv);     \
    Ra[q] = *(const float4*)s_;                              \
    Rb[q] = *(const float4*)(s_ + 4);                        \
  }
#define WRITEB_(Ra, Rb)                                      \
  _Pragma("unroll") for (int q = 0; q < 4; ++q) {            \
    u16x8 o_; unsigned int* po_ = (unsigned int*)&o_;        \
    po_[0] = cvtpk(Ra[q].x, Ra[q].y);                        \
    po_[1] = cvtpk(Ra[q].z, Ra[q].w);                        \
    po_[2] = cvtpk(Rb[q].x, Rb[q].y);                        \
    po_[3] = cvtpk(Rb[q].z, Rb[q].w);                        \
    *(u16x8*)&Bsl[q * 2048 + bdst] = o_;                     \
  }
#define GLDSA_(kbv, buf)                                     \
  _Pragma("unroll") for (int c4 = 0; c4 < 4; ++c4) {         \
    const int c_ = w * 4 + c4;                               \
    GLDS16(Ag + (size_t)(c_ * 8) * H + (kbv), &(buf)[c_ * 512]); \
  }

  f32x4 acc[4][4];
#pragma unroll
  for (int mi = 0; mi < 4; ++mi)
#pragma unroll
    for (int ni = 0; ni < 4; ++ni) acc[mi][ni] = (f32x4){0.f, 0.f, 0.f, 0.f};
  float4 ra[4], rbv[4];
  // prologue: stage tile 0 (full latency exposed once)
  GLDSA_(0, Asl0);
  LOADB_(0, ra, rbv);
  WRITEB_(ra, rbv);
  __syncthreads();
#pragma unroll
  for (int t = 0; t < 12; ++t) {
    unsigned short* Acur = (t & 1) ? Asl1 : Asl0;
    unsigned short* Anxt = (t & 1) ? Asl0 : Asl1;
    if (t < 11) {
      GLDSA_((t + 1) * 64, Anxt);      // A(t+1) -> other buffer, issued early
      LOADB_((t + 1) * 64, ra, rbv);   // B(t+1) -> regs, issued early
    }
    __builtin_amdgcn_sched_barrier(0); // pin issues above the MFMA block
#pragma unroll
    for (int kk = 0; kk < 2; ++kk) {
      u16x8 af[4], bf[4];
      const int pb = ((kk * 4 + g) ^ x7) * 8;
#pragma unroll
      for (int mi = 0; mi < 4; ++mi) af[mi] = ld8(&Acur[(wr * 64 + mi * 16 + ln) * 64 + pb]);
#pragma unroll
      for (int ni = 0; ni < 4; ++ni) bf[ni] = ld8(&Bsl[(wc * 64 + ni * 16 + ln) * 64 + pb]);
#pragma unroll
      for (int mi = 0; mi < 4; ++mi)
#pragma unroll
        for (int ni = 0; ni < 4; ++ni) acc[mi][ni] = MFMA(af[mi], bf[ni], acc[mi][ni]);
    }
    __syncthreads();                   // drains A(t+1)/B(t+1); compute hid most
    if (t < 11) {
      WRITEB_(ra, rbv);                // B regs ready; cvt+ds_write
      __syncthreads();                 // cheap: no outstanding VMEM
    }
  }
#pragma unroll
  for (int mi = 0; mi < 4; ++mi) {
    const int d = d0 + wr * 64 + mi * 16 + g * 4;
#pragma unroll
    for (int ni = 0; ni < 4; ++ni) {
      const int k = k0 + wc * 64 + ni * 16 + ln;
      unsigned short* o = RsWt + ((size_t)d * 32 + z) * H + k;
#pragma unroll
      for (int pp = 0; pp < 4; ++pp) o[(size_t)pp * 32 * H] = f2bf(acc[mi][ni][pp]);
    }
  }
#undef LOADB_
#undef WRITEB_
#undef GLDSA_
}

// ---------------- K-split(4) hilo GEMM for gx (no bias, raw partials) -------
__global__ __launch_bounds__(256) void k_btks(
    const unsigned short* __restrict__ Ahi, const unsigned short* __restrict__ Alo,
    const unsigned short* __restrict__ Bhi, const unsigned short* __restrict__ Blo,
    float* __restrict__ Cp) {
  const int tid = threadIdx.x;
  const int w = tid >> 6, l = tid & 63, g = l >> 4, ln = l & 15;
  const int m0 = blockIdx.y * 64 + w * 16;
  const int n0 = blockIdx.x * 64;
  const int kh = blockIdx.z, kb0 = kh * 192;
  const unsigned short* aph = Ahi + (size_t)(m0 + ln) * H + kb0 + g * 8;
  const unsigned short* apl = Alo + (size_t)(m0 + ln) * H + kb0 + g * 8;
  const unsigned short* bph[4];
  const unsigned short* bpl[4];
#pragma unroll
  for (int nt = 0; nt < 4; ++nt) {
    bph[nt] = Bhi + (size_t)(n0 + nt * 16 + ln) * H + kb0 + g * 8;
    bpl[nt] = Blo + (size_t)(n0 + nt * 16 + ln) * H + kb0 + g * 8;
  }
  f32x4 acc[4];
#pragma unroll
  for (int nt = 0; nt < 4; ++nt) acc[nt] = (f32x4){0.f, 0.f, 0.f, 0.f};
  u16x8 ah[2], al[2], bh[2][4], bl[2][4];
  ah[0] = ld8(aph);
  al[0] = ld8(apl);
#pragma unroll
  for (int nt = 0; nt < 4; ++nt) { bh[0][nt] = ld8(bph[nt]); bl[0][nt] = ld8(bpl[nt]); }
#pragma unroll
  for (int t = 0; t < 6; ++t) {
    const int cur = t & 1, nxt = cur ^ 1;
    if (t < 5) {
      const int ko = (t + 1) * 32;
      ah[nxt] = ld8(aph + ko);
      al[nxt] = ld8(apl + ko);
#pragma unroll
      for (int nt = 0; nt < 4; ++nt) {
        bh[nxt][nt] = ld8(bph[nt] + ko);
        bl[nxt][nt] = ld8(bpl[nt] + ko);
      }
    }
#pragma unroll
    for (int nt = 0; nt < 4; ++nt) {
      acc[nt] = MFMA(ah[cur], bh[cur][nt], acc[nt]);
      acc[nt] = MFMA(ah[cur], bl[cur][nt], acc[nt]);
      acc[nt] = MFMA(al[cur], bh[cur][nt], acc[nt]);
    }
  }
#pragma unroll
  for (int nt = 0; nt < 4; ++nt) {
    const int col = n0 + nt * 16 + ln;
#pragma unroll
    for (int pp = 0; pp < 4; ++pp) {
      const int row = m0 + g * 4 + pp;
      Cp[(size_t)kh * (NTOT * GW) + (size_t)row * GW + col] = acc[nt][pp];
    }
  }
}

// ---------------- per-step LDS-staged tiled GEMM: gh | A4 | twB -------------
// 64(M) x 128(N) tiles, BK=64. bid<54: gh (hilo); 54..125: A4; 126..701: twB.
// Bijective XCD swizzle (702 % 8 != 0) groups same-n blocks on one XCD.
__global__ __launch_bounds__(256) void k_tile(
    const unsigned short* __restrict__ hhi, const unsigned short* __restrict__ hlo,
    const unsigned short* __restrict__ W1cat, const float* __restrict__ b1cat,
    const unsigned short* __restrict__ Whhh, const unsigned short* __restrict__ Whhl,
    const float* __restrict__ bhh, const unsigned short* __restrict__ RsWt,
    float* __restrict__ A4, float* __restrict__ ghb, unsigned short* __restrict__ twB) {
  __shared__ unsigned short Ah[4096], Al[4096], Bh[8192], Bl[8192];  // 48 KB
  const int orig = blockIdx.x;           // 702 blocks
  const int qq = 87, rr = 6;             // 702 = 8*87 + 6
  const int xcd = orig & 7, idx = orig >> 3;
  const int bid = (xcd < rr ? xcd * (qq + 1) : rr * (qq + 1) + (xcd - rr) * qq) + idx;
  const int tid = threadIdx.x, w = tid >> 6, l = tid & 63, g = l >> 4, ln = l & 15;
  int path, m, n;
  if (bid < 54)       { path = 0; n = bid / 3;         m = bid % 3; }
  else if (bid < 126) { path = 1; n = (bid - 54) / 3;  m = (bid - 54) % 3; }
  else                { path = 2; n = (bid - 126) / 3; m = (bid - 126) % 3; }
  const int m0 = m * 64, n0 = n * 128;
  const bool isgh = (path == 0);
  const unsigned short* Bsrc = (path == 0) ? Whhh : (path == 1) ? W1cat : RsWt;
  const int srow = l >> 3;
  const int skb = ((l & 7) ^ srow) * 8;
  const unsigned short* Agh = hhi + (size_t)(m0 + srow) * H + skb;
  const unsigned short* Agl = hlo + (size_t)(m0 + srow) * H + skb;
  const unsigned short* Bgh = Bsrc + (size_t)(n0 + srow) * H + skb;
  const unsigned short* Bgl = Whhl + (size_t)((isgh ? n0 : 0) + srow) * H + skb;
  f32x4 acc[4][2];
#pragma unroll
  for (int mi = 0; mi < 4; ++mi)
#pragma unroll
    for (int ni = 0; ni < 2; ++ni) acc[mi][ni] = (f32x4){0.f, 0.f, 0.f, 0.f};
  const int x7 = ln & 7;
  for (int kb = 0; kb < H; kb += 64) {
#pragma unroll
    for (int c2 = 0; c2 < 2; ++c2) {
      const int c = w * 2 + c2;
      GLDS16(Agh + (size_t)(c * 8) * H + kb, &Ah[c * 512]);
      if (isgh) GLDS16(Agl + (size_t)(c * 8) * H + kb, &Al[c * 512]);
    }
#pragma unroll
    for (int c4 = 0; c4 < 4; ++c4) {
      const int c = w * 4 + c4;
      GLDS16(Bgh + (size_t)(c * 8) * H + kb, &Bh[c * 512]);
      if (isgh) GLDS16(Bgl + (size_t)(c * 8) * H + kb, &Bl[c * 512]);
    }
    __syncthreads();
#pragma unroll
    for (int kk = 0; kk < 2; ++kk) {
      const int pb = ((kk * 4 + g) ^ x7) * 8;
      u16x8 af[4], bf[2];
#pragma unroll
      for (int mi = 0; mi < 4; ++mi) af[mi] = ld8(&Ah[(mi * 16 + ln) * 64 + pb]);
#pragma unroll
      for (int ni = 0; ni < 2; ++ni) bf[ni] = ld8(&Bh[(w * 32 + ni * 16 + ln) * 64 + pb]);
      if (isgh) {
        u16x8 alf[4], blf[2];
#pragma unroll
        for (int mi = 0; mi < 4; ++mi) alf[mi] = ld8(&Al[(mi * 16 + ln) * 64 + pb]);
#pragma unroll
        for (int ni = 0; ni < 2; ++ni) blf[ni] = ld8(&Bl[(w * 32 + ni * 16 + ln) * 64 + pb]);
#pragma unroll
        for (int mi = 0; mi < 4; ++mi)
#pragma unroll
          for (int ni = 0; ni < 2; ++ni) {
            acc[mi][ni] = MFMA(af[mi], bf[ni], acc[mi][ni]);
            acc[mi][ni] = MFMA(af[mi], blf[ni], acc[mi][ni]);
            acc[mi][ni] = MFMA(alf[mi], bf[ni], acc[mi][ni]);
          }
      } else {
#pragma unroll
        for (int mi = 0; mi < 4; ++mi)
#pragma unroll
          for (int ni = 0; ni < 2; ++ni) acc[mi][ni] = MFMA(af[mi], bf[ni], acc[mi][ni]);
      }
    }
    __syncthreads();
  }
  if (path == 2) {
#pragma unroll
    for (int mi = 0; mi < 4; ++mi)
#pragma unroll
      for (int ni = 0; ni < 2; ++ni) {
        const int c = n0 + w * 32 + ni * 16 + ln;
#pragma unroll
        for (int pp = 0; pp < 4; ++pp) {
          const int j = m0 + mi * 16 + g * 4 + pp;
          twB[(size_t)j * 24576 + c] = f2bf(acc[mi][ni][pp]);
        }
      }
  } else {
    const int N = isgh ? GW : A4W;
    float* C = isgh ? ghb : A4;
    const float* bias = isgh ? bhh : b1cat;
#pragma unroll
    for (int mi = 0; mi < 4; ++mi)
#pragma unroll
      for (int ni = 0; ni < 2; ++ni) {
        const int col = n0 + w * 32 + ni * 16 + ln;
        const float bv = bias[col];
#pragma unroll
        for (int pp = 0; pp < 4; ++pp) {
          const int row = m0 + mi * 16 + g * 4 + pp;
          C[(size_t)row * N + col] = acc[mi][ni][pp] + bv;
        }
      }
  }
}

// ---------------- pair logits + softmax -> swA[j][i][32] (bf16) -------------
__global__ __launch_bounds__(256) void k_pairlog(
    const float* __restrict__ A4, const unsigned short* __restrict__ W2sbf,
    const unsigned short* __restrict__ W2dbf, const float* __restrict__ b2s,
    const float* __restrict__ b2d, unsigned short* __restrict__ swA) {
  __shared__ float red[8][16][17];
  const int i = blockIdx.x, jb = blockIdx.y;
  const int tid = threadIdx.x, w = tid >> 6, l = tid & 63;
  const int g = l >> 4, ln = l & 15;
  const int j = jb * 16 + ln;
  const float* BsP = A4 + (size_t)j * A4W + 768 + g * 8;
  const float* BdP = A4 + (size_t)j * A4W + 2304 + g * 8;
  const float* AsP = A4 + (size_t)i * A4W + g * 8;
  const float* AdP = A4 + (size_t)i * A4W + 1536 + g * 8;
  const unsigned short* WsP = W2sbf + (size_t)ln * H + g * 8;
  const unsigned short* WdP = W2dbf + (size_t)ln * H + g * 8;
  f32x4 accs = (f32x4){0.f, 0.f, 0.f, 0.f}, accd = (f32x4){0.f, 0.f, 0.f, 0.f};
#pragma unroll
  for (int tt = 0; tt < 6; ++tt) {
    const int ko = (w * 6 + tt) * 32;
    float4 b0 = *(const float4*)(BsP + ko), b1 = *(const float4*)(BsP + ko + 4);
    float4 a0 = *(const float4*)(AsP + ko), a1 = *(const float4*)(AsP + ko + 4);
    float4 e0 = *(const float4*)(BdP + ko), e1 = *(const float4*)(BdP + ko + 4);
    float4 c0 = *(const float4*)(AdP + ko), c1 = *(const float4*)(AdP + ko + 4);
    u16x8 afs, afd;
    unsigned int* ps = (unsigned int*)&afs;
    ps[0] = cvtpk(relu(a0.x + b0.x), relu(a0.y + b0.y));
    ps[1] = cvtpk(relu(a0.z + b0.z), relu(a0.w + b0.w));
    ps[2] = cvtpk(relu(a1.x + b1.x), relu(a1.y + b1.y));
    ps[3] = cvtpk(relu(a1.z + b1.z), relu(a1.w + b1.w));
    unsigned int* pd = (unsigned int*)&afd;
    pd[0] = cvtpk(relu(c0.x + e0.x), relu(c0.y + e0.y));
    pd[1] = cvtpk(relu(c0.z + e0.z), relu(c0.w + e0.w));
    pd[2] = cvtpk(relu(c1.x + e1.x), relu(c1.y + e1.y));
    pd[3] = cvtpk(relu(c1.z + e1.z), relu(c1.w + e1.w));
    accs = MFMA(afs, ld8(WsP + ko), accs);
    accd = MFMA(afd, ld8(WdP + ko), accd);
  }
#pragma unroll
  for (int pp = 0; pp < 4; ++pp) {
    red[w * 2][g * 4 + pp][ln] = accs[pp];
    red[w * 2 + 1][g * 4 + pp][ln] = accd[pp];
  }
  __syncthreads();
  const int j2 = tid >> 4, r = tid & 15;
  float vs = red[0][j2][r] + red[2][j2][r] + red[4][j2][r] + red[6][j2][r] + b2s[r];
  float vd = red[1][j2][r] + red[3][j2][r] + red[5][j2][r] + red[7][j2][r] + b2d[r];
  float ms = vs;
  ms = fmaxf(ms, __shfl_xor(ms, 1)); ms = fmaxf(ms, __shfl_xor(ms, 2));
  ms = fmaxf(ms, __shfl_xor(ms, 4)); ms = fmaxf(ms, __shfl_xor(ms, 8));
  float md = vd;
  md = fmaxf(md, __shfl_xor(md, 1)); md = fmaxf(md, __shfl_xor(md, 2));
  md = fmaxf(md, __shfl_xor(md, 4)); md = fmaxf(md, __shfl_xor(md, 8));
  float es = __expf(vs - ms), ed = __expf(vd - md);
  float ss = es;
  ss += __shfl_xor(ss, 1); ss += __shfl_xor(ss, 2); ss += __shfl_xor(ss, 4); ss += __shfl_xor(ss, 8);
  float sd = ed;
  sd += __shfl_xor(sd, 1); sd += __shfl_xor(sd, 2); sd += __shfl_xor(sd, 4); sd += __shfl_xor(sd, 8);
  const size_t o = (size_t)(jb * 16 + j2) * 6144 + (size_t)i * 32;
  swA[o + r] = f2bf(es / ss);
  swA[o + 16 + r] = f2bf(ed / sd);
}

// ---------------- per-pair weighted message + relu + sum_j -> v_part --------
__global__ __launch_bounds__(256) void k_pairmsg(const unsigned short* __restrict__ swA,
                                                 const unsigned short* __restrict__ twB,
                                                 const float* __restrict__ bm1,
                                                 float* __restrict__ vpart) {
  const int dt = blockIdx.x, it = blockIdx.y, js = blockIdx.z;
  const int tid = threadIdx.x;
  const int w = tid >> 6, l = tid & 63, g = l >> 4, ln = l & 15;
  const int i0 = it * 64 + w * 16;
  const int d0 = dt * 64;
  float bm1v[4];
#pragma unroll
  for (int nt = 0; nt < 4; ++nt) bm1v[nt] = bm1[d0 + nt * 16 + ln];
  f32x4 vacc[4];
#pragma unroll
  for (int nt = 0; nt < 4; ++nt) vacc[nt] = (f32x4){0.f, 0.f, 0.f, 0.f};
  const unsigned short* ap = swA + (size_t)(i0 + ln) * 32 + g * 8 + (size_t)js * 24 * 6144;
  const unsigned short* bp[4];
#pragma unroll
  for (int nt = 0; nt < 4; ++nt)
    bp[nt] = twB + (size_t)(d0 + nt * 16 + ln) * 32 + g * 8 + (size_t)js * 24 * 24576;
  const f32x4 z4 = (f32x4){0.f, 0.f, 0.f, 0.f};
#pragma unroll 4
  for (int jj = 0; jj < 24; ++jj) {
    u16x8 a = ld8(ap + (size_t)jj * 6144);
#pragma unroll
    for (int nt = 0; nt < 4; ++nt) {
      u16x8 b = ld8(bp[nt] + (size_t)jj * 24576);
      f32x4 mf = MFMA(a, b, z4);
#pragma unroll
      for (int pp = 0; pp < 4; ++pp) vacc[nt][pp] += fmaxf(mf[pp] + bm1v[nt], 0.f);
    }
  }
#pragma unroll
  for (int nt = 0; nt < 4; ++nt)
#pragma unroll
    for (int pp = 0; pp < 4; ++pp) {
      const int row = i0 + g * 4 + pp;
      vpart[(size_t)js * 147456 + (size_t)row * H + d0 + nt * 16 + ln] = vacc[nt][pp];
    }
}

__global__ void k_vred(const float* __restrict__ vpart, unsigned short* __restrict__ vhi,
                       unsigned short* __restrict__ vlo) {
  int e = blockIdx.x * 256 + threadIdx.x;  // 147456
  float s = 0.f;
#pragma unroll
  for (int q = 0; q < 8; ++q) s += vpart[(size_t)q * 147456 + e];
  s *= (1.0f / 192.0f);
  unsigned short hi = f2bf(s);
  vhi[e] = hi;
  vlo[e] = f2bf(s - bf2f(hi));
}

__global__ void k_gru(const float* __restrict__ gxp, const float* __restrict__ bcv,
                      const float* __restrict__ gh, float* __restrict__ h,
                      unsigned short* __restrict__ hhi, unsigned short* __restrict__ hlo,
                      float* __restrict__ out, int last) {
  int e = blockIdx.x * 256 + threadIdx.x;  // 147456
  int i = e / H, k = e - i * H;
  size_t base = (size_t)i * GW;
  const size_t S = (size_t)NTOT * GW;
  float rr = gxp[base + k] + gxp[S + base + k] + gxp[2 * S + base + k] +
             gxp[3 * S + base + k] + bcv[k] + gh[base + k];
  float zz = gxp[base + H + k] + gxp[S + base + H + k] + gxp[2 * S + base + H + k] +
             gxp[3 * S + base + H + k] + bcv[H + k] + gh[base + H + k];
  float r = 1.f / (1.f + __expf(-rr));
  float z = 1.f / (1.f + __expf(-zz));
  float nn = gxp[base + 2 * H + k] + gxp[S + base + 2 * H + k] +
             gxp[2 * S + base + 2 * H + k] + gxp[3 * S + base + 2 * H + k] +
             bcv[2 * H + k];
  float n = tanhf(nn + r * gh[base + 2 * H + k]);
  float hv = (1.f - z) * n + z * h[e];
  h[e] = hv;
  unsigned short hi = f2bf(hv);
  hhi[e] = hi;
  hlo[e] = f2bf(hv - bf2f(hi));
  if (last && i >= 64) out[(size_t)(i - 64) * H + k] = hv;
}

// ---------------- launch ----------------------------------------------------

extern "C" void kernel_launch(void* const* d_in, const int* in_sizes, int n_in,
                              void* d_out, int out_size, void* d_ws, size_t ws_size,
                              hipStream_t stream) {
  const float* asp = (const float*)d_in[0];
  const float* qry = (const float*)d_in[1];
  const float* W1s = (const float*)d_in[3];
  const float* b1s = (const float*)d_in[4];
  const float* W2s = (const float*)d_in[5];
  const float* b2s = (const float*)d_in[6];
  const float* W1d = (const float*)d_in[7];
  const float* b1d = (const float*)d_in[8];
  const float* W2d = (const float*)d_in[9];
  const float* b2d = (const float*)d_in[10];
  const float* Rs  = (const float*)d_in[11];
  const float* Rd  = (const float*)d_in[12];
  const float* Wm1 = (const float*)d_in[13];
  const float* bm1 = (const float*)d_in[14];
  const float* Wm2 = (const float*)d_in[15];
  const float* bm2 = (const float*)d_in[16];
  const float* Wih = (const float*)d_in[17];
  const float* Whh = (const float*)d_in[18];
  const float* bih = (const float*)d_in[19];
  const float* bhh = (const float*)d_in[20];
  float* out = (float*)d_out;

  char* p = (char*)d_ws;
  auto take = [&](size_t bytes) {
    char* q = p;
    p += (bytes + 255) & ~(size_t)255;
    return q;
  };
  // ---- step-scratch region, aliased during prep ----
  float* h            = (float*)take((size_t)NTOT * H * 4);
  unsigned short* hhi = (unsigned short*)take((size_t)NTOT * H * 2);
  unsigned short* hlo = (unsigned short*)take((size_t)NTOT * H * 2);
  float* A4           = (float*)take((size_t)NTOT * A4W * 4);
  float* ghb          = (float*)take((size_t)NTOT * GW * 4);
  unsigned short* vhi = (unsigned short*)take((size_t)NTOT * H * 2);
  unsigned short* vlo = (unsigned short*)take((size_t)NTOT * H * 2);
  float* vpart        = (float*)take((size_t)8 * NTOT * H * 4);
  unsigned short* swA = (unsigned short*)take((size_t)NTOT * NTOT * 32 * 2);
  unsigned short* twB = (unsigned short*)take((size_t)NTOT * H * 32 * 2);  // also gx partials
  // ---- permanent weights ----
  unsigned short* RsWt = (unsigned short*)take((size_t)2 * 16 * H * H * 2);
  unsigned short* Wm1bf = (unsigned short*)take((size_t)H * H * 2);
  unsigned short* W2sbf = (unsigned short*)take((size_t)16 * H * 2);
  unsigned short* W2dbf = (unsigned short*)take((size_t)16 * H * 2);
  unsigned short* W1cat = (unsigned short*)take((size_t)A4W * H * 2);
  float* b1cat        = (float*)take((size_t)A4W * 4);
  unsigned short* Whhh = (unsigned short*)take((size_t)GW * H * 2);
  unsigned short* Whhl = (unsigned short*)take((size_t)GW * H * 2);
  unsigned short* Wch  = (unsigned short*)take((size_t)GW * H * 2);
  unsigned short* Wcl  = (unsigned short*)take((size_t)GW * H * 2);
  float* bc           = (float*)take((size_t)GW * 4);
  // ---- prep-phase aliases (within step-scratch, after h/hhi/hlo @1,179,648) ----
  unsigned short* Wm2th = (unsigned short*)((char*)d_ws + 1179648);
  unsigned short* Wm2tl = Wm2th + (size_t)H * H;  // ends ~3.54 MB

  // ---- once-per-launch prep ----
  k_prep<<<5928, 256, 0, stream>>>(Wm1, W2s, W2d, Whh, Wih, Wm2, W1s, W1d, b1s, b1d,
                                   bm2, bih, asp, qry,
                                   Wm1bf, W2sbf, W2dbf, Whhh, Whhl,
                                   Wm2th, Wm2tl, W1cat, b1cat, bc, h, hhi, hlo);
  k_pre2<<<1584, 256, 0, stream>>>(Wm1bf, Rs, Rd, RsWt, Wih, Wm2th, Wm2tl, Wch, Wcl);

  // ---- propagation steps ----
  for (int step = 0; step < 3; ++step) {
    k_tile<<<702, 256, 0, stream>>>(hhi, hlo, W1cat, b1cat, Whhh, Whhl, bhh, RsWt,
                                    A4, ghb, twB);
    k_pairlog<<<dim3(192, 12), 256, 0, stream>>>(A4, W2sbf, W2dbf, b2s, b2d, swA);
    k_pairmsg<<<dim3(12, 3, 8), 256, 0, stream>>>(swA, twB, bm1, vpart);
    k_vred<<<576, 256, 0, stream>>>(vpart, vhi, vlo);
    k_btks<<<dim3(36, 3, 4), 256, 0, stream>>>(vhi, vlo, Wch, Wcl, (float*)twB);
    k_gru<<<576, 256, 0, stream>>>((float*)twB, bc, ghb, h, hhi, hlo, out, step == 2);
  }
  (void)in_sizes; (void)n_in; (void)out_size; (void)ws_size;
}

// Round 13
// 414.597 us; speedup vs baseline: 2.3246x; 1.1184x over previous
//
#include <hip/hip_runtime.h>
#include <hip/hip_bf16.h>

#define H 768
#define NTOT 192
#define A4W 3072
#define GW 2304

typedef __attribute__((ext_vector_type(4))) float f32x4;
typedef __attribute__((ext_vector_type(8))) unsigned short u16x8;
typedef __attribute__((ext_vector_type(4))) unsigned short u16x4;
typedef __attribute__((ext_vector_type(8))) __bf16 bf16x8v;

static __device__ __forceinline__ unsigned short f2bf(float f) {
  __hip_bfloat16 b = __float2bfloat16(f);
  return __builtin_bit_cast(unsigned short, b);
}
static __device__ __forceinline__ float bf2f(unsigned short u) {
  return __bfloat162float(__builtin_bit_cast(__hip_bfloat16, u));
}
static __device__ __forceinline__ f32x4 MFMA(u16x8 a, u16x8 b, f32x4 c) {
  return __builtin_amdgcn_mfma_f32_16x16x32_bf16(
      __builtin_bit_cast(bf16x8v, a), __builtin_bit_cast(bf16x8v, b), c, 0, 0, 0);
}
static __device__ __forceinline__ u16x8 ld8(const unsigned short* p) {
  return *(const u16x8*)p;
}
static __device__ __forceinline__ unsigned int cvtpk(float lo, float hi) {
  unsigned int r;
  asm("v_cvt_pk_bf16_f32 %0, %1, %2" : "=v"(r) : "v"(lo), "v"(hi));
  return r;
}
static __device__ __forceinline__ float relu(float x) { return fmaxf(x, 0.f); }

#define GLDS16(gp, lp)                                                   \
  __builtin_amdgcn_global_load_lds(                                      \
      (const __attribute__((address_space(1))) void*)(gp),               \
      (__attribute__((address_space(3))) void*)(lp), 16, 0, 0)

// ---------------- fused prep: weight conversions + bc + inith --------------
__global__ void k_prep(const float* __restrict__ Wm1, const float* __restrict__ W2s,
                       const float* __restrict__ W2d, const float* __restrict__ Whh,
                       const float* __restrict__ Wih, const float* __restrict__ Wm2,
                       const float* __restrict__ W1s, const float* __restrict__ W1d,
                       const float* __restrict__ b1s, const float* __restrict__ b1d,
                       const float* __restrict__ bm2, const float* __restrict__ bih,
                       const float* __restrict__ asp, const float* __restrict__ qry,
                       unsigned short* __restrict__ Wm1bf, unsigned short* __restrict__ W2sbf,
                       unsigned short* __restrict__ W2dbf, unsigned short* __restrict__ Whhh,
                       unsigned short* __restrict__ Whhl, unsigned short* __restrict__ Wm2th,
                       unsigned short* __restrict__ Wm2tl, unsigned short* __restrict__ W1cat,
                       float* __restrict__ b1cat, float* __restrict__ bc,
                       float* __restrict__ h, unsigned short* __restrict__ hhi,
                       unsigned short* __restrict__ hlo) {
  const int b = blockIdx.x, tid = threadIdx.x;
  if (b < 576) {
    int u = b * 256 + tid;
    float4 v = ((const float4*)Wm1)[u];
    u16x4 o; o[0] = f2bf(v.x); o[1] = f2bf(v.y); o[2] = f2bf(v.z); o[3] = f2bf(v.w);
    ((u16x4*)Wm1bf)[u] = o;
  } else if (b < 588) {
    int u = (b - 576) * 256 + tid;
    float4 v = ((const float4*)W2s)[u];
    u16x4 o; o[0] = f2bf(v.x); o[1] = f2bf(v.y); o[2] = f2bf(v.z); o[3] = f2bf(v.w);
    ((u16x4*)W2sbf)[u] = o;
  } else if (b < 600) {
    int u = (b - 588) * 256 + tid;
    float4 v = ((const float4*)W2d)[u];
    u16x4 o; o[0] = f2bf(v.x); o[1] = f2bf(v.y); o[2] = f2bf(v.z); o[3] = f2bf(v.w);
    ((u16x4*)W2dbf)[u] = o;
  } else if (b < 2328) {
    int u = (b - 600) * 256 + tid;
    float4 v = ((const float4*)Whh)[u];
    u16x4 oh, ol;
#pragma unroll
    for (int j = 0; j < 4; ++j) {
      float f = ((const float*)&v)[j];
      oh[j] = f2bf(f); ol[j] = f2bf(f - bf2f(oh[j]));
    }
    ((u16x4*)Whhh)[u] = oh; ((u16x4*)Whhl)[u] = ol;
  } else if (b < 2904) {
    int u = (b - 2328) * 256 + tid;  // Wm2 f4 index; emit TRANSPOSED hi/lo
    float4 v = ((const float4*)Wm2)[u];
    int e_lin = u * 4;
    int er = e_lin / H, kc = e_lin - er * H;
#pragma unroll
    for (int j = 0; j < 4; ++j) {
      float f = ((const float*)&v)[j];
      unsigned short hi = f2bf(f);
      Wm2th[(size_t)(kc + j) * H + er] = hi;
      Wm2tl[(size_t)(kc + j) * H + er] = f2bf(f - bf2f(hi));
    }
  } else if (b < 5208) {
    int u = (b - 2904) * 256 + tid;  // f4 index into W1cat [3072][768]
    int e = u * 4;
    int row = e / H, k = e - row * H;
    int part = row / H, o = row - part * H;
    const float* W = (part < 2) ? W1s : W1d;
    float4 v = *(const float4*)(W + (size_t)o * (2 * H) + (part & 1) * H + k);
    u16x4 ov; ov[0] = f2bf(v.x); ov[1] = f2bf(v.y); ov[2] = f2bf(v.z); ov[3] = f2bf(v.w);
    *(u16x4*)(W1cat + e) = ov;
    if (u < 768) {
      int e2 = u * 4, pp = e2 / H, oo = e2 - pp * H;
      float4 bv;
      if (pp == 0) bv = *(const float4*)(b1s + oo);
      else if (pp == 2) bv = *(const float4*)(b1d + oo);
      else bv = (float4){0.f, 0.f, 0.f, 0.f};
      *(float4*)(b1cat + e2) = bv;
    }
  } else if (b < 5784) {
    const int w = tid >> 6, l = tid & 63;
    const int gg = (b - 5208) * 4 + w;
    const float* row = Wih + (size_t)gg * H;
    float s = 0.f;
#pragma unroll
    for (int q = 0; q < 12; ++q) s += row[l + q * 64] * bm2[l + q * 64];
#pragma unroll
    for (int m = 32; m; m >>= 1) s += __shfl_xor(s, m);
    if (l == 0) bc[gg] = bih[gg] + s;
  } else {
    int u = (b - 5784) * 256 + tid;  // f4 index, 36864
    float4 v = (u < 12288) ? ((const float4*)asp)[u] : ((const float4*)qry)[u - 12288];
    ((float4*)h)[u] = v;
    u16x4 oh, ol;
#pragma unroll
    for (int j = 0; j < 4; ++j) {
      float f = ((const float*)&v)[j];
      oh[j] = f2bf(f); ol[j] = f2bf(f - bf2f(oh[j]));
    }
    ((u16x4*)hhi)[u] = oh; ((u16x4*)hlo)[u] = ol;
  }
}

// ---------------- merged prep GEMM, 48 KB LDS, 1584 blocks ------------------
// blocks 0..1151: RsW — A double-buffered; A(t+1)+B(t+1) issued BEFORE
//   compute(t) (sched_barrier-pinned). (round-11 proven form)
// blocks 1152..1583: Wc = Wih @ Wm2t^T, 64x64 tiles.
__global__ __launch_bounds__(256) void k_pre2(const unsigned short* __restrict__ Wm1bf,
                                              const float* __restrict__ Rsf,
                                              const float* __restrict__ Rdf,
                                              unsigned short* __restrict__ RsWt,
                                              const float* __restrict__ Wih,
                                              const unsigned short* __restrict__ Bth,
                                              const unsigned short* __restrict__ Btl,
                                              unsigned short* __restrict__ Ch,
                                              unsigned short* __restrict__ Cl) {
  __shared__ unsigned short LDS[24576];  // 48 KB
  const int wg = blockIdx.x;
  const int tid = threadIdx.x, w = tid >> 6, l = tid & 63;
  const int g = l >> 4, ln = l & 15;
  const int srow = l >> 3;
  const int skb = ((l & 7) ^ srow) * 8;
  const int x7 = ln & 7;

  if (wg >= 1152) {
    // --------- Wc: 64x64 tile, BK=64 ---------------------------------------
    unsigned short* Ahl = LDS;
    unsigned short* All = LDS + 4096;
    unsigned short* Bhl = LDS + 8192;
    unsigned short* Bll = LDS + 12288;
    const int bid = wg - 1152;
    const int m0 = (bid / 12) * 64, n0 = (bid % 12) * 64;
    const unsigned short* Bgh = Bth + (size_t)(n0 + srow) * H + skb;
    const unsigned short* Bgl = Btl + (size_t)(n0 + srow) * H + skb;
    f32x4 acc[4];
#pragma unroll
    for (int mi = 0; mi < 4; ++mi) acc[mi] = (f32x4){0.f, 0.f, 0.f, 0.f};
    for (int kb = 0; kb < H; kb += 64) {
#pragma unroll
      for (int c2 = 0; c2 < 2; ++c2) {
        const int c = w * 2 + c2;
        GLDS16(Bgh + (size_t)(c * 8) * H + kb, &Bhl[c * 512]);
        GLDS16(Bgl + (size_t)(c * 8) * H + kb, &Bll[c * 512]);
      }
#pragma unroll
      for (int q = 0; q < 2; ++q) {
        const int idx = q * 256 + tid;
        const int row = idx >> 3, kb8 = idx & 7;
        const float* src = Wih + (size_t)(m0 + row) * H + kb + kb8 * 8;
        float4 v0 = *(const float4*)src;
        float4 v1 = *(const float4*)(src + 4);
        float fv[8] = {v0.x, v0.y, v0.z, v0.w, v1.x, v1.y, v1.z, v1.w};
        u16x8 oh, ol;
#pragma unroll
        for (int jq = 0; jq < 8; ++jq) {
          unsigned short hi = f2bf(fv[jq]);
          oh[jq] = hi;
          ol[jq] = f2bf(fv[jq] - bf2f(hi));
        }
        const int dst = row * 64 + (kb8 ^ (row & 7)) * 8;
        *(u16x8*)&Ahl[dst] = oh;
        *(u16x8*)&All[dst] = ol;
      }
      __syncthreads();
#pragma unroll
      for (int kk = 0; kk < 2; ++kk) {
        const int pb = ((kk * 4 + g) ^ x7) * 8;
        u16x8 bh = ld8(&Bhl[(w * 16 + ln) * 64 + pb]);
        u16x8 bl = ld8(&Bll[(w * 16 + ln) * 64 + pb]);
#pragma unroll
        for (int mi = 0; mi < 4; ++mi) {
          u16x8 ah = ld8(&Ahl[(mi * 16 + ln) * 64 + pb]);
          u16x8 al = ld8(&All[(mi * 16 + ln) * 64 + pb]);
          acc[mi] = MFMA(ah, bh, acc[mi]);
          acc[mi] = MFMA(ah, bl, acc[mi]);
          acc[mi] = MFMA(al, bh, acc[mi]);
        }
      }
      __syncthreads();
    }
#pragma unroll
    for (int mi = 0; mi < 4; ++mi) {
      const int col = n0 + w * 16 + ln;
#pragma unroll
      for (int pp = 0; pp < 4; ++pp) {
        const int row = m0 + mi * 16 + g * 4 + pp;
        const float val = acc[mi][pp];
        unsigned short hi = f2bf(val);
        Ch[(size_t)row * H + col] = hi;
        Cl[(size_t)row * H + col] = f2bf(val - bf2f(hi));
      }
    }
    return;
  }

  // --------- RsW: z<16 -> Rs[z], else Rd[z-16]; out row = d*32+z ------------
  unsigned short* Asl0 = LDS;           // 16 KB
  unsigned short* Asl1 = LDS + 8192;    // 16 KB (A double buffer)
  unsigned short* Bsl = LDS + 16384;    // 16 KB
  const int nb = (wg & 7) * 144 + (wg >> 3);       // chunked XCD swizzle
  const int z = nb / 36, t5 = nb - z * 36;
  const int d0 = (t5 / 6) * 128, k0 = (t5 % 6) * 128;
  const int wr = w >> 1, wc = w & 1;
  const unsigned short* Ag = Wm1bf + (size_t)(d0 + srow) * H + skb;
  const float* Bg = ((z < 16) ? Rsf : Rdf) + (size_t)(z & 15) * (H * H);
  const int kb8 = tid & 7, rb = tid >> 3;
  const float* Bq = Bg + (size_t)(k0 + rb) * H + kb8 * 8;
  const int bdst = rb * 64 + (kb8 ^ (rb & 7)) * 8;

#define LOADB_(kbv, Ra, Rb)                                  \
  _Pragma("unroll") for (int q = 0; q < 4; ++q) {            \
    const float* s_ = Bq + (size_t)(q * 32) * H + (kbv);     \
    Ra[q] = *(const float4*)s_;                              \
    Rb[q] = *(const float4*)(s_ + 4);                        \
  }
#define WRITEB_(Ra, Rb)                                      \
  _Pragma("unroll") for (int q = 0; q < 4; ++q) {            \
    u16x8 o_; unsigned int* po_ = (unsigned int*)&o_;        \
    po_[0] = cvtpk(Ra[q].x, Ra[q].y);                        \
    po_[1] = cvtpk(Ra[q].z, Ra[q].w);                        \
    po_[2] = cvtpk(Rb[q].x, Rb[q].y);                        \
    po_[3] = cvtpk(Rb[q].z, Rb[q].w);                        \
    *(u16x8*)&Bsl[q * 2048 + bdst] = o_;                     \
  }
#define GLDSA_(kbv, buf)                                     \
  _Pragma("unroll") for (int c4 = 0; c4 < 4; ++c4) {         \
    const int c_ = w * 4 + c4;                               \
    GLDS16(Ag + (size_t)(c_ * 8) * H + (kbv), &(buf)[c_ * 512]); \
  }

  f32x4 acc[4][4];
#pragma unroll
  for (int mi = 0; mi < 4; ++mi)
#pragma unroll
    for (int ni = 0; ni < 4; ++ni) acc[mi][ni] = (f32x4){0.f, 0.f, 0.f, 0.f};
  float4 ra[4], rbv[4];
  // prologue: stage tile 0 (full latency exposed once)
  GLDSA_(0, Asl0);
  LOADB_(0, ra, rbv);
  WRITEB_(ra, rbv);
  __syncthreads();
#pragma unroll
  for (int t = 0; t < 12; ++t) {
    unsigned short* Acur = (t & 1) ? Asl1 : Asl0;
    unsigned short* Anxt = (t & 1) ? Asl0 : Asl1;
    if (t < 11) {
      GLDSA_((t + 1) * 64, Anxt);      // A(t+1) -> other buffer, issued early
      LOADB_((t + 1) * 64, ra, rbv);   // B(t+1) -> regs, issued early
    }
    __builtin_amdgcn_sched_barrier(0); // pin issues above the MFMA block
#pragma unroll
    for (int kk = 0; kk < 2; ++kk) {
      u16x8 af[4], bf[4];
      const int pb = ((kk * 4 + g) ^ x7) * 8;
#pragma unroll
      for (int mi = 0; mi < 4; ++mi) af[mi] = ld8(&Acur[(wr * 64 + mi * 16 + ln) * 64 + pb]);
#pragma unroll
      for (int ni = 0; ni < 4; ++ni) bf[ni] = ld8(&Bsl[(wc * 64 + ni * 16 + ln) * 64 + pb]);
#pragma unroll
      for (int mi = 0; mi < 4; ++mi)
#pragma unroll
        for (int ni = 0; ni < 4; ++ni) acc[mi][ni] = MFMA(af[mi], bf[ni], acc[mi][ni]);
    }
    __syncthreads();                   // drains A(t+1)/B(t+1); compute hid most
    if (t < 11) {
      WRITEB_(ra, rbv);                // B regs ready; cvt+ds_write
      __syncthreads();                 // cheap: no outstanding VMEM
    }
  }
#pragma unroll
  for (int mi = 0; mi < 4; ++mi) {
    const int d = d0 + wr * 64 + mi * 16 + g * 4;
#pragma unroll
    for (int ni = 0; ni < 4; ++ni) {
      const int k = k0 + wc * 64 + ni * 16 + ln;
      unsigned short* o = RsWt + ((size_t)d * 32 + z) * H + k;
#pragma unroll
      for (int pp = 0; pp < 4; ++pp) o[(size_t)pp * 32 * H] = f2bf(acc[mi][ni][pp]);
    }
  }
#undef LOADB_
#undef WRITEB_
#undef GLDSA_
}

// ---------------- K-split(4) hilo GEMM for gx (no bias, raw partials) -------
__global__ __launch_bounds__(256) void k_btks(
    const unsigned short* __restrict__ Ahi, const unsigned short* __restrict__ Alo,
    const unsigned short* __restrict__ Bhi, const unsigned short* __restrict__ Blo,
    float* __restrict__ Cp) {
  const int tid = threadIdx.x;
  const int w = tid >> 6, l = tid & 63, g = l >> 4, ln = l & 15;
  const int m0 = blockIdx.y * 64 + w * 16;
  const int n0 = blockIdx.x * 64;
  const int kh = blockIdx.z, kb0 = kh * 192;
  const unsigned short* aph = Ahi + (size_t)(m0 + ln) * H + kb0 + g * 8;
  const unsigned short* apl = Alo + (size_t)(m0 + ln) * H + kb0 + g * 8;
  const unsigned short* bph[4];
  const unsigned short* bpl[4];
#pragma unroll
  for (int nt = 0; nt < 4; ++nt) {
    bph[nt] = Bhi + (size_t)(n0 + nt * 16 + ln) * H + kb0 + g * 8;
    bpl[nt] = Blo + (size_t)(n0 + nt * 16 + ln) * H + kb0 + g * 8;
  }
  f32x4 acc[4];
#pragma unroll
  for (int nt = 0; nt < 4; ++nt) acc[nt] = (f32x4){0.f, 0.f, 0.f, 0.f};
  u16x8 ah[2], al[2], bh[2][4], bl[2][4];
  ah[0] = ld8(aph);
  al[0] = ld8(apl);
#pragma unroll
  for (int nt = 0; nt < 4; ++nt) { bh[0][nt] = ld8(bph[nt]); bl[0][nt] = ld8(bpl[nt]); }
#pragma unroll
  for (int t = 0; t < 6; ++t) {
    const int cur = t & 1, nxt = cur ^ 1;
    if (t < 5) {
      const int ko = (t + 1) * 32;
      ah[nxt] = ld8(aph + ko);
      al[nxt] = ld8(apl + ko);
#pragma unroll
      for (int nt = 0; nt < 4; ++nt) {
        bh[nxt][nt] = ld8(bph[nt] + ko);
        bl[nxt][nt] = ld8(bpl[nt] + ko);
      }
    }
#pragma unroll
    for (int nt = 0; nt < 4; ++nt) {
      acc[nt] = MFMA(ah[cur], bh[cur][nt], acc[nt]);
      acc[nt] = MFMA(ah[cur], bl[cur][nt], acc[nt]);
      acc[nt] = MFMA(al[cur], bh[cur][nt], acc[nt]);
    }
  }
#pragma unroll
  for (int nt = 0; nt < 4; ++nt) {
    const int col = n0 + nt * 16 + ln;
#pragma unroll
    for (int pp = 0; pp < 4; ++pp) {
      const int row = m0 + g * 4 + pp;
      Cp[(size_t)kh * (NTOT * GW) + (size_t)row * GW + col] = acc[nt][pp];
    }
  }
}

// ---------------- per-step LDS-staged tiled GEMM: gh | A4 | twB -------------
// 64(M) x 128(N) tiles, BK=64. Bijective XCD swizzle.
__global__ __launch_bounds__(256) void k_tile(
    const unsigned short* __restrict__ hhi, const unsigned short* __restrict__ hlo,
    const unsigned short* __restrict__ W1cat, const float* __restrict__ b1cat,
    const unsigned short* __restrict__ Whhh, const unsigned short* __restrict__ Whhl,
    const float* __restrict__ bhh, const unsigned short* __restrict__ RsWt,
    float* __restrict__ A4, float* __restrict__ ghb, unsigned short* __restrict__ twB) {
  __shared__ unsigned short Ah[4096], Al[4096], Bh[8192], Bl[8192];  // 48 KB
  const int orig = blockIdx.x;           // 702 blocks
  const int qq = 87, rr = 6;             // 702 = 8*87 + 6
  const int xcd = orig & 7, idx = orig >> 3;
  const int bid = (xcd < rr ? xcd * (qq + 1) : rr * (qq + 1) + (xcd - rr) * qq) + idx;
  const int tid = threadIdx.x, w = tid >> 6, l = tid & 63, g = l >> 4, ln = l & 15;
  int path, m, n;
  if (bid < 54)       { path = 0; n = bid / 3;         m = bid % 3; }
  else if (bid < 126) { path = 1; n = (bid - 54) / 3;  m = (bid - 54) % 3; }
  else                { path = 2; n = (bid - 126) / 3; m = (bid - 126) % 3; }
  const int m0 = m * 64, n0 = n * 128;
  const bool isgh = (path == 0);
  const unsigned short* Bsrc = (path == 0) ? Whhh : (path == 1) ? W1cat : RsWt;
  const int srow = l >> 3;
  const int skb = ((l & 7) ^ srow) * 8;
  const unsigned short* Agh = hhi + (size_t)(m0 + srow) * H + skb;
  const unsigned short* Agl = hlo + (size_t)(m0 + srow) * H + skb;
  const unsigned short* Bgh = Bsrc + (size_t)(n0 + srow) * H + skb;
  const unsigned short* Bgl = Whhl + (size_t)((isgh ? n0 : 0) + srow) * H + skb;
  f32x4 acc[4][2];
#pragma unroll
  for (int mi = 0; mi < 4; ++mi)
#pragma unroll
    for (int ni = 0; ni < 2; ++ni) acc[mi][ni] = (f32x4){0.f, 0.f, 0.f, 0.f};
  const int x7 = ln & 7;
  for (int kb = 0; kb < H; kb += 64) {
#pragma unroll
    for (int c2 = 0; c2 < 2; ++c2) {
      const int c = w * 2 + c2;
      GLDS16(Agh + (size_t)(c * 8) * H + kb, &Ah[c * 512]);
      if (isgh) GLDS16(Agl + (size_t)(c * 8) * H + kb, &Al[c * 512]);
    }
#pragma unroll
    for (int c4 = 0; c4 < 4; ++c4) {
      const int c = w * 4 + c4;
      GLDS16(Bgh + (size_t)(c * 8) * H + kb, &Bh[c * 512]);
      if (isgh) GLDS16(Bgl + (size_t)(c * 8) * H + kb, &Bl[c * 512]);
    }
    __syncthreads();
#pragma unroll
    for (int kk = 0; kk < 2; ++kk) {
      const int pb = ((kk * 4 + g) ^ x7) * 8;
      u16x8 af[4], bf[2];
#pragma unroll
      for (int mi = 0; mi < 4; ++mi) af[mi] = ld8(&Ah[(mi * 16 + ln) * 64 + pb]);
#pragma unroll
      for (int ni = 0; ni < 2; ++ni) bf[ni] = ld8(&Bh[(w * 32 + ni * 16 + ln) * 64 + pb]);
      if (isgh) {
        u16x8 alf[4], blf[2];
#pragma unroll
        for (int mi = 0; mi < 4; ++mi) alf[mi] = ld8(&Al[(mi * 16 + ln) * 64 + pb]);
#pragma unroll
        for (int ni = 0; ni < 2; ++ni) blf[ni] = ld8(&Bl[(w * 32 + ni * 16 + ln) * 64 + pb]);
#pragma unroll
        for (int mi = 0; mi < 4; ++mi)
#pragma unroll
          for (int ni = 0; ni < 2; ++ni) {
            acc[mi][ni] = MFMA(af[mi], bf[ni], acc[mi][ni]);
            acc[mi][ni] = MFMA(af[mi], blf[ni], acc[mi][ni]);
            acc[mi][ni] = MFMA(alf[mi], bf[ni], acc[mi][ni]);
          }
      } else {
#pragma unroll
        for (int mi = 0; mi < 4; ++mi)
#pragma unroll
          for (int ni = 0; ni < 2; ++ni) acc[mi][ni] = MFMA(af[mi], bf[ni], acc[mi][ni]);
      }
    }
    __syncthreads();
  }
  if (path == 2) {
#pragma unroll
    for (int mi = 0; mi < 4; ++mi)
#pragma unroll
      for (int ni = 0; ni < 2; ++ni) {
        const int c = n0 + w * 32 + ni * 16 + ln;
#pragma unroll
        for (int pp = 0; pp < 4; ++pp) {
          const int j = m0 + mi * 16 + g * 4 + pp;
          twB[(size_t)j * 24576 + c] = f2bf(acc[mi][ni][pp]);
        }
      }
  } else {
    const int N = isgh ? GW : A4W;
    float* C = isgh ? ghb : A4;
    const float* bias = isgh ? bhh : b1cat;
#pragma unroll
    for (int mi = 0; mi < 4; ++mi)
#pragma unroll
      for (int ni = 0; ni < 2; ++ni) {
        const int col = n0 + w * 32 + ni * 16 + ln;
        const float bv = bias[col];
#pragma unroll
        for (int pp = 0; pp < 4; ++pp) {
          const int row = m0 + mi * 16 + g * 4 + pp;
          C[(size_t)row * N + col] = acc[mi][ni][pp] + bv;
        }
      }
  }
}

// ---------------- pair logits + softmax -> swA[j][i][32] (bf16) -------------
__global__ __launch_bounds__(256) void k_pairlog(
    const float* __restrict__ A4, const unsigned short* __restrict__ W2sbf,
    const unsigned short* __restrict__ W2dbf, const float* __restrict__ b2s,
    const float* __restrict__ b2d, unsigned short* __restrict__ swA) {
  __shared__ float red[8][16][17];
  const int i = blockIdx.x, jb = blockIdx.y;
  const int tid = threadIdx.x, w = tid >> 6, l = tid & 63;
  const int g = l >> 4, ln = l & 15;
  const int j = jb * 16 + ln;
  const float* BsP = A4 + (size_t)j * A4W + 768 + g * 8;
  const float* BdP = A4 + (size_t)j * A4W + 2304 + g * 8;
  const float* AsP = A4 + (size_t)i * A4W + g * 8;
  const float* AdP = A4 + (size_t)i * A4W + 1536 + g * 8;
  const unsigned short* WsP = W2sbf + (size_t)ln * H + g * 8;
  const unsigned short* WdP = W2dbf + (size_t)ln * H + g * 8;
  f32x4 accs = (f32x4){0.f, 0.f, 0.f, 0.f}, accd = (f32x4){0.f, 0.f, 0.f, 0.f};
#pragma unroll
  for (int tt = 0; tt < 6; ++tt) {
    const int ko = (w * 6 + tt) * 32;
    float4 b0 = *(const float4*)(BsP + ko), b1 = *(const float4*)(BsP + ko + 4);
    float4 a0 = *(const float4*)(AsP + ko), a1 = *(const float4*)(AsP + ko + 4);
    float4 e0 = *(const float4*)(BdP + ko), e1 = *(const float4*)(BdP + ko + 4);
    float4 c0 = *(const float4*)(AdP + ko), c1 = *(const float4*)(AdP + ko + 4);
    u16x8 afs, afd;
    unsigned int* ps = (unsigned int*)&afs;
    ps[0] = cvtpk(relu(a0.x + b0.x), relu(a0.y + b0.y));
    ps[1] = cvtpk(relu(a0.z + b0.z), relu(a0.w + b0.w));
    ps[2] = cvtpk(relu(a1.x + b1.x), relu(a1.y + b1.y));
    ps[3] = cvtpk(relu(a1.z + b1.z), relu(a1.w + b1.w));
    unsigned int* pd = (unsigned int*)&afd;
    pd[0] = cvtpk(relu(c0.x + e0.x), relu(c0.y + e0.y));
    pd[1] = cvtpk(relu(c0.z + e0.z), relu(c0.w + e0.w));
    pd[2] = cvtpk(relu(c1.x + e1.x), relu(c1.y + e1.y));
    pd[3] = cvtpk(relu(c1.z + e1.z), relu(c1.w + e1.w));
    accs = MFMA(afs, ld8(WsP + ko), accs);
    accd = MFMA(afd, ld8(WdP + ko), accd);
  }
#pragma unroll
  for (int pp = 0; pp < 4; ++pp) {
    red[w * 2][g * 4 + pp][ln] = accs[pp];
    red[w * 2 + 1][g * 4 + pp][ln] = accd[pp];
  }
  __syncthreads();
  const int j2 = tid >> 4, r = tid & 15;
  float vs = red[0][j2][r] + red[2][j2][r] + red[4][j2][r] + red[6][j2][r] + b2s[r];
  float vd = red[1][j2][r] + red[3][j2][r] + red[5][j2][r] + red[7][j2][r] + b2d[r];
  float ms = vs;
  ms = fmaxf(ms, __shfl_xor(ms, 1)); ms = fmaxf(ms, __shfl_xor(ms, 2));
  ms = fmaxf(ms, __shfl_xor(ms, 4)); ms = fmaxf(ms, __shfl_xor(ms, 8));
  float md = vd;
  md = fmaxf(md, __shfl_xor(md, 1)); md = fmaxf(md, __shfl_xor(md, 2));
  md = fmaxf(md, __shfl_xor(md, 4)); md = fmaxf(md, __shfl_xor(md, 8));
  float es = __expf(vs - ms), ed = __expf(vd - md);
  float ss = es;
  ss += __shfl_xor(ss, 1); ss += __shfl_xor(ss, 2); ss += __shfl_xor(ss, 4); ss += __shfl_xor(ss, 8);
  float sd = ed;
  sd += __shfl_xor(sd, 1); sd += __shfl_xor(sd, 2); sd += __shfl_xor(sd, 4); sd += __shfl_xor(sd, 8);
  const size_t o = (size_t)(jb * 16 + j2) * 6144 + (size_t)i * 32;
  swA[o + r] = f2bf(es / ss);
  swA[o + 16 + r] = f2bf(ed / sd);
}

// ---------------- per-pair weighted message + relu + sum_j -> v_part --------
// js in [0,16): 12 j each. Grid (12,3,16) = 576 blocks.
__global__ __launch_bounds__(256) void k_pairmsg(const unsigned short* __restrict__ swA,
                                                 const unsigned short* __restrict__ twB,
                                                 const float* __restrict__ bm1,
                                                 float* __restrict__ vpart) {
  const int dt = blockIdx.x, it = blockIdx.y, js = blockIdx.z;
  const int tid = threadIdx.x;
  const int w = tid >> 6, l = tid & 63, g = l >> 4, ln = l & 15;
  const int i0 = it * 64 + w * 16;
  const int d0 = dt * 64;
  float bm1v[4];
#pragma unroll
  for (int nt = 0; nt < 4; ++nt) bm1v[nt] = bm1[d0 + nt * 16 + ln];
  f32x4 vacc[4];
#pragma unroll
  for (int nt = 0; nt < 4; ++nt) vacc[nt] = (f32x4){0.f, 0.f, 0.f, 0.f};
  const unsigned short* ap = swA + (size_t)(i0 + ln) * 32 + g * 8 + (size_t)js * 12 * 6144;
  const unsigned short* bp[4];
#pragma unroll
  for (int nt = 0; nt < 4; ++nt)
    bp[nt] = twB + (size_t)(d0 + nt * 16 + ln) * 32 + g * 8 + (size_t)js * 12 * 24576;
  const f32x4 z4 = (f32x4){0.f, 0.f, 0.f, 0.f};
#pragma unroll 4
  for (int jj = 0; jj < 12; ++jj) {
    u16x8 a = ld8(ap + (size_t)jj * 6144);
#pragma unroll
    for (int nt = 0; nt < 4; ++nt) {
      u16x8 b = ld8(bp[nt] + (size_t)jj * 24576);
      f32x4 mf = MFMA(a, b, z4);
#pragma unroll
      for (int pp = 0; pp < 4; ++pp) vacc[nt][pp] += fmaxf(mf[pp] + bm1v[nt], 0.f);
    }
  }
#pragma unroll
  for (int nt = 0; nt < 4; ++nt)
#pragma unroll
    for (int pp = 0; pp < 4; ++pp) {
      const int row = i0 + g * 4 + pp;
      vpart[(size_t)js * 147456 + (size_t)row * H + d0 + nt * 16 + ln] = vacc[nt][pp];
    }
}

__global__ void k_vred(const float* __restrict__ vpart, unsigned short* __restrict__ vhi,
                       unsigned short* __restrict__ vlo) {
  int e = blockIdx.x * 256 + threadIdx.x;  // 147456
  float s = 0.f;
#pragma unroll
  for (int q = 0; q < 16; ++q) s += vpart[(size_t)q * 147456 + e];
  s *= (1.0f / 192.0f);
  unsigned short hi = f2bf(s);
  vhi[e] = hi;
  vlo[e] = f2bf(s - bf2f(hi));
}

__global__ void k_gru(const float* __restrict__ gxp, const float* __restrict__ bcv,
                      const float* __restrict__ gh, float* __restrict__ h,
                      unsigned short* __restrict__ hhi, unsigned short* __restrict__ hlo,
                      float* __restrict__ out, int last) {
  int e = blockIdx.x * 256 + threadIdx.x;  // 147456
  int i = e / H, k = e - i * H;
  size_t base = (size_t)i * GW;
  const size_t S = (size_t)NTOT * GW;
  float rr = gxp[base + k] + gxp[S + base + k] + gxp[2 * S + base + k] +
             gxp[3 * S + base + k] + bcv[k] + gh[base + k];
  float zz = gxp[base + H + k] + gxp[S + base + H + k] + gxp[2 * S + base + H + k] +
             gxp[3 * S + base + H + k] + bcv[H + k] + gh[base + H + k];
  float r = 1.f / (1.f + __expf(-rr));
  float z = 1.f / (1.f + __expf(-zz));
  float nn = gxp[base + 2 * H + k] + gxp[S + base + 2 * H + k] +
             gxp[2 * S + base + 2 * H + k] + gxp[3 * S + base + 2 * H + k] +
             bcv[2 * H + k];
  float n = tanhf(nn + r * gh[base + 2 * H + k]);
  float hv = (1.f - z) * n + z * h[e];
  h[e] = hv;
  unsigned short hi = f2bf(hv);
  hhi[e] = hi;
  hlo[e] = f2bf(hv - bf2f(hi));
  if (last && i >= 64) out[(size_t)(i - 64) * H + k] = hv;
}

// ---------------- launch ----------------------------------------------------

extern "C" void kernel_launch(void* const* d_in, const int* in_sizes, int n_in,
                              void* d_out, int out_size, void* d_ws, size_t ws_size,
                              hipStream_t stream) {
  const float* asp = (const float*)d_in[0];
  const float* qry = (const float*)d_in[1];
  const float* W1s = (const float*)d_in[3];
  const float* b1s = (const float*)d_in[4];
  const float* W2s = (const float*)d_in[5];
  const float* b2s = (const float*)d_in[6];
  const float* W1d = (const float*)d_in[7];
  const float* b1d = (const float*)d_in[8];
  const float* W2d = (const float*)d_in[9];
  const float* b2d = (const float*)d_in[10];
  const float* Rs  = (const float*)d_in[11];
  const float* Rd  = (const float*)d_in[12];
  const float* Wm1 = (const float*)d_in[13];
  const float* bm1 = (const float*)d_in[14];
  const float* Wm2 = (const float*)d_in[15];
  const float* bm2 = (const float*)d_in[16];
  const float* Wih = (const float*)d_in[17];
  const float* Whh = (const float*)d_in[18];
  const float* bih = (const float*)d_in[19];
  const float* bhh = (const float*)d_in[20];
  float* out = (float*)d_out;

  char* p = (char*)d_ws;
  auto take = [&](size_t bytes) {
    char* q = p;
    p += (bytes + 255) & ~(size_t)255;
    return q;
  };
  // ---- step-scratch region, aliased during prep ----
  float* h            = (float*)take((size_t)NTOT * H * 4);
  unsigned short* hhi = (unsigned short*)take((size_t)NTOT * H * 2);
  unsigned short* hlo = (unsigned short*)take((size_t)NTOT * H * 2);
  float* A4           = (float*)take((size_t)NTOT * A4W * 4);
  float* ghb          = (float*)take((size_t)NTOT * GW * 4);
  unsigned short* vhi = (unsigned short*)take((size_t)NTOT * H * 2);
  unsigned short* vlo = (unsigned short*)take((size_t)NTOT * H * 2);
  float* vpart        = (float*)take((size_t)16 * NTOT * H * 4);
  unsigned short* swA = (unsigned short*)take((size_t)NTOT * NTOT * 32 * 2);
  unsigned short* twB = (unsigned short*)take((size_t)NTOT * H * 32 * 2);  // also gx partials
  // ---- permanent weights ----
  unsigned short* RsWt = (unsigned short*)take((size_t)2 * 16 * H * H * 2);
  unsigned short* Wm1bf = (unsigned short*)take((size_t)H * H * 2);
  unsigned short* W2sbf = (unsigned short*)take((size_t)16 * H * 2);
  unsigned short* W2dbf = (unsigned short*)take((size_t)16 * H * 2);
  unsigned short* W1cat = (unsigned short*)take((size_t)A4W * H * 2);
  float* b1cat        = (float*)take((size_t)A4W * 4);
  unsigned short* Whhh = (unsigned short*)take((size_t)GW * H * 2);
  unsigned short* Whhl = (unsigned short*)take((size_t)GW * H * 2);
  unsigned short* Wch  = (unsigned short*)take((size_t)GW * H * 2);
  unsigned short* Wcl  = (unsigned short*)take((size_t)GW * H * 2);
  float* bc           = (float*)take((size_t)GW * 4);
  // ---- prep-phase aliases (within step-scratch, after h/hhi/hlo @1,179,648) ----
  unsigned short* Wm2th = (unsigned short*)((char*)d_ws + 1179648);
  unsigned short* Wm2tl = Wm2th + (size_t)H * H;  // ends ~3.54 MB

  // ---- once-per-launch prep ----
  k_prep<<<5928, 256, 0, stream>>>(Wm1, W2s, W2d, Whh, Wih, Wm2, W1s, W1d, b1s, b1d,
                                   bm2, bih, asp, qry,
                                   Wm1bf, W2sbf, W2dbf, Whhh, Whhl,
                                   Wm2th, Wm2tl, W1cat, b1cat, bc, h, hhi, hlo);
  k_pre2<<<1584, 256, 0, stream>>>(Wm1bf, Rs, Rd, RsWt, Wih, Wm2th, Wm2tl, Wch, Wcl);

  // ---- propagation steps ----
  for (int step = 0; step < 3; ++step) {
    k_tile<<<702, 256, 0, stream>>>(hhi, hlo, W1cat, b1cat, Whhh, Whhl, bhh, RsWt,
                                    A4, ghb, twB);
    k_pairlog<<<dim3(192, 12), 256, 0, stream>>>(A4, W2sbf, W2dbf, b2s, b2d, swA);
    k_pairmsg<<<dim3(12, 3, 16), 256, 0, stream>>>(swA, twB, bm1, vpart);
    k_vred<<<576, 256, 0, stream>>>(vpart, vhi, vlo);
    k_btks<<<dim3(36, 3, 4), 256, 0, stream>>>(vhi, vlo, Wch, Wcl, (float*)twB);
    k_gru<<<576, 256, 0, stream>>>((float*)twB, bc, ghb, h, hhi, hlo, out, step == 2);
  }
  (void)in_sizes; (void)n_in; (void)out_size; (void)ws_size;
}